// Round 8
// baseline (1706.800 us; speedup 1.0000x reference)
//
#include <hip/hip_runtime.h>
#include <hip/hip_bf16.h>

#define EPS 1e-5f

typedef short bf16x8 __attribute__((ext_vector_type(8)));
typedef short short4v __attribute__((ext_vector_type(4)));
typedef float f32x4 __attribute__((ext_vector_type(4)));

static __device__ __forceinline__ short f2bf(float x) {
    __hip_bfloat16 h = __float2bfloat16(x);
    return *reinterpret_cast<short*>(&h);
}
static __device__ __forceinline__ float bf2f(short x) {
    __hip_bfloat16 h;
    *reinterpret_cast<short*>(&h) = x;
    return __bfloat162float(h);
}

// ========== split-bf16 MFMA GEMM: C = act(A[M,K](f32) @ BT[N,K]^T + bias) ==========
template<int SPLIT, int ACT, int OUTM>
__global__ __launch_bounds__(256) void gemm_split(const float* __restrict__ A,
                                                  const short* __restrict__ BTh,
                                                  const short* __restrict__ BTl,
                                                  const float* __restrict__ bias,
                                                  void* __restrict__ Cout,
                                                  void* __restrict__ Cout2,
                                                  int M, int N, int K) {
    __shared__ short Ah[128][40];
    __shared__ short Al[128][40];
    __shared__ short Bh[128][40];
    __shared__ short Bl[128][40];
    const int tid = threadIdx.x;
    const int row0 = blockIdx.y * 128, col0 = blockIdx.x * 128;
    const int lane = tid & 63, w = tid >> 6;
    const int wr = w >> 1, wc = w & 1;
    const int lr = lane & 15, lg = lane >> 4;
    f32x4 acc[4][4] = {};

    for (int k0 = 0; k0 < K; k0 += 32) {
        #pragma unroll
        for (int i = 0; i < 4; ++i) {
            int idx = i * 256 + tid;
            int r = idx >> 3, q = idx & 7;
            int gr = row0 + r, gk = k0 + q * 4;
            f32x4 v;
            if (gr < M && gk + 3 < K) {
                v = *reinterpret_cast<const f32x4*>(&A[(size_t)gr * K + gk]);
            } else {
                #pragma unroll
                for (int j = 0; j < 4; ++j)
                    v[j] = (gr < M && gk + j < K) ? A[(size_t)gr * K + gk + j] : 0.f;
            }
            short4v h, l;
            #pragma unroll
            for (int j = 0; j < 4; ++j) {
                h[j] = f2bf(v[j]);
                l[j] = f2bf(v[j] - bf2f(h[j]));
            }
            *reinterpret_cast<short4v*>(&Ah[r][q * 4]) = h;
            *reinterpret_cast<short4v*>(&Al[r][q * 4]) = l;
        }
        #pragma unroll
        for (int i = 0; i < 4; ++i) {
            int idx = i * 256 + tid;
            int r = idx >> 3, q = idx & 7;
            int gc = col0 + r, gk = k0 + q * 4;
            short4v u, ul;
            if (gk + 3 < K) {
                u = *reinterpret_cast<const short4v*>(&BTh[(size_t)gc * K + gk]);
                if (SPLIT == 3) ul = *reinterpret_cast<const short4v*>(&BTl[(size_t)gc * K + gk]);
            } else {
                #pragma unroll
                for (int j = 0; j < 4; ++j) {
                    u[j] = (gk + j < K) ? BTh[(size_t)gc * K + gk + j] : (short)0;
                    if (SPLIT == 3) ul[j] = (gk + j < K) ? BTl[(size_t)gc * K + gk + j] : (short)0;
                }
            }
            *reinterpret_cast<short4v*>(&Bh[r][q * 4]) = u;
            if (SPLIT == 3) *reinterpret_cast<short4v*>(&Bl[r][q * 4]) = ul;
        }
        __syncthreads();
        bf16x8 afh[4], afl[4], bfh[4];
        #pragma unroll
        for (int mi = 0; mi < 4; ++mi) {
            afh[mi] = *reinterpret_cast<const bf16x8*>(&Ah[wr * 64 + mi * 16 + lr][lg * 8]);
            afl[mi] = *reinterpret_cast<const bf16x8*>(&Al[wr * 64 + mi * 16 + lr][lg * 8]);
        }
        #pragma unroll
        for (int ni = 0; ni < 4; ++ni)
            bfh[ni] = *reinterpret_cast<const bf16x8*>(&Bh[wc * 64 + ni * 16 + lr][lg * 8]);
        #pragma unroll
        for (int mi = 0; mi < 4; ++mi)
            #pragma unroll
            for (int ni = 0; ni < 4; ++ni) {
                acc[mi][ni] = __builtin_amdgcn_mfma_f32_16x16x32_bf16(afh[mi], bfh[ni], acc[mi][ni], 0, 0, 0);
                acc[mi][ni] = __builtin_amdgcn_mfma_f32_16x16x32_bf16(afl[mi], bfh[ni], acc[mi][ni], 0, 0, 0);
            }
        if (SPLIT == 3) {
            bf16x8 bfl[4];
            #pragma unroll
            for (int ni = 0; ni < 4; ++ni)
                bfl[ni] = *reinterpret_cast<const bf16x8*>(&Bl[wc * 64 + ni * 16 + lr][lg * 8]);
            #pragma unroll
            for (int mi = 0; mi < 4; ++mi)
                #pragma unroll
                for (int ni = 0; ni < 4; ++ni)
                    acc[mi][ni] = __builtin_amdgcn_mfma_f32_16x16x32_bf16(afh[mi], bfl[ni], acc[mi][ni], 0, 0, 0);
        }
        __syncthreads();
    }

    #pragma unroll
    for (int mi = 0; mi < 4; ++mi) {
        #pragma unroll
        for (int ni = 0; ni < 4; ++ni) {
            int col = col0 + wc * 64 + ni * 16 + lr;
            float bv = bias ? bias[col] : 0.f;
            #pragma unroll
            for (int r = 0; r < 4; ++r) {
                int row = row0 + wr * 64 + mi * 16 + lg * 4 + r;
                if (row >= M) continue;
                float v = acc[mi][ni][r] + bv;
                if (ACT) v = fmaxf(v, 0.f);
                if (OUTM == 0) ((float*)Cout)[(size_t)row * N + col] = v;
                else ((short*)Cout)[(size_t)row * N + col] = f2bf(v);
            }
        }
    }
}

// ========== plain bf16 GEMM (tolerant path: ep projection) ==========
template<int ACT, int OUTBF>
__global__ __launch_bounds__(256) void gemm_bf16(const short* __restrict__ A,
                                                 const short* __restrict__ BT,
                                                 const float* __restrict__ bias,
                                                 void* __restrict__ Cout,
                                                 int M, int N, int K) {
    __shared__ short As[128][40];
    __shared__ short Bs[128][40];
    const int tid = threadIdx.x;
    const int row0 = blockIdx.y * 128, col0 = blockIdx.x * 128;
    const int lane = tid & 63, w = tid >> 6;
    const int wr = w >> 1, wc = w & 1;
    const int lr = lane & 15, lg = lane >> 4;
    f32x4 acc[4][4] = {};

    for (int k0 = 0; k0 < K; k0 += 32) {
        #pragma unroll
        for (int i = 0; i < 4; ++i) {
            int idx = i * 256 + tid;
            int r = idx >> 3, q = idx & 7;
            int gk = k0 + q * 4;
            int gr = row0 + r;
            short4v v;
            if (gr < M && gk + 3 < K) {
                v = *reinterpret_cast<const short4v*>(&A[(size_t)gr * K + gk]);
            } else {
                #pragma unroll
                for (int j = 0; j < 4; ++j)
                    v[j] = (gr < M && gk + j < K) ? A[(size_t)gr * K + gk + j] : (short)0;
            }
            *reinterpret_cast<short4v*>(&As[r][q * 4]) = v;
            int gc = col0 + r;
            short4v u;
            if (gc < N && gk + 3 < K) {
                u = *reinterpret_cast<const short4v*>(&BT[(size_t)gc * K + gk]);
            } else {
                #pragma unroll
                for (int j = 0; j < 4; ++j)
                    u[j] = (gc < N && gk + j < K) ? BT[(size_t)gc * K + gk + j] : (short)0;
            }
            *reinterpret_cast<short4v*>(&Bs[r][q * 4]) = u;
        }
        __syncthreads();
        bf16x8 af[4], bfr[4];
        #pragma unroll
        for (int mi = 0; mi < 4; ++mi)
            af[mi] = *reinterpret_cast<const bf16x8*>(&As[wr * 64 + mi * 16 + lr][lg * 8]);
        #pragma unroll
        for (int ni = 0; ni < 4; ++ni)
            bfr[ni] = *reinterpret_cast<const bf16x8*>(&Bs[wc * 64 + ni * 16 + lr][lg * 8]);
        #pragma unroll
        for (int mi = 0; mi < 4; ++mi)
            #pragma unroll
            for (int ni = 0; ni < 4; ++ni)
                acc[mi][ni] = __builtin_amdgcn_mfma_f32_16x16x32_bf16(af[mi], bfr[ni], acc[mi][ni], 0, 0, 0);
        __syncthreads();
    }

    #pragma unroll
    for (int mi = 0; mi < 4; ++mi) {
        #pragma unroll
        for (int ni = 0; ni < 4; ++ni) {
            int col = col0 + wc * 64 + ni * 16 + lr;
            float bv = bias ? bias[col] : 0.f;
            #pragma unroll
            for (int r = 0; r < 4; ++r) {
                int row = row0 + wr * 64 + mi * 16 + lg * 4 + r;
                if (row >= M) continue;
                float v = acc[mi][ni][r] + bv;
                if (ACT) v = fmaxf(v, 0.f);
                if (OUTBF) ((short*)Cout)[(size_t)row * N + col] = f2bf(v);
                else       ((float*)Cout)[(size_t)row * N + col] = v;
            }
        }
    }
}

// ========== fused xp + Y kernel v2 ==========
// grid (2 colhalves, M/128). Phase 1: xp = h @ wnT (split-3) -> LDS (hi only) + global hi/lo
// (colhalf 0 writes global). Phase 2: Y[:, colhalf*512 .. +512] = xp_hi @ wbBT^T + wl1 colbias.
// LDS: 40960 B single buffer; phase-1 staging aliases the phase-2 xpH region.
__global__ __launch_bounds__(512) void fused_xpy(const float* __restrict__ h,
                                                 const short* __restrict__ wnTh,
                                                 const short* __restrict__ wnTl,
                                                 const short* __restrict__ wbBT,
                                                 const float* __restrict__ wl1,
                                                 short* __restrict__ xph,
                                                 short* __restrict__ xpl,
                                                 short* __restrict__ Y, int M) {
    __shared__ short sbuf[20480];          // 40 KB
    short* Ah = sbuf;                       // 128x40
    short* Al = sbuf + 5120;
    short* Bh = sbuf + 10240;
    short* Bl = sbuf + 15360;
    short* xpH = sbuf;                      // 128x136 (phase 2, overwrites staging)

    const int tid = threadIdx.x;
    const int colhalf = blockIdx.x;
    const int row0 = blockIdx.y * 128;
    const int lane = tid & 63, w = tid >> 6;
    const int wr = w >> 2, wc = w & 3;      // 2 x 4 wave grid
    const int lr = lane & 15, lg = lane >> 4;

    // ---- phase 1: xp = h @ wnT, split-3 ----
    f32x4 acc1[4][2] = {};
    for (int k0 = 0; k0 < 128; k0 += 32) {
        #pragma unroll
        for (int i = 0; i < 2; ++i) {
            int idx = i * 512 + tid;
            int r = idx >> 3, q = idx & 7;
            int gr = row0 + r, gk = k0 + q * 4;
            f32x4 v;
            if (gr < M) {
                v = *reinterpret_cast<const f32x4*>(&h[(size_t)gr * 128 + gk]);
            } else {
                #pragma unroll
                for (int j = 0; j < 4; ++j) v[j] = 0.f;
            }
            short4v hh, ll;
            #pragma unroll
            for (int j = 0; j < 4; ++j) {
                hh[j] = f2bf(v[j]);
                ll[j] = f2bf(v[j] - bf2f(hh[j]));
            }
            *reinterpret_cast<short4v*>(&Ah[r * 40 + q * 4]) = hh;
            *reinterpret_cast<short4v*>(&Al[r * 40 + q * 4]) = ll;
            short4v bh = *reinterpret_cast<const short4v*>(&wnTh[(size_t)r * 128 + gk]);
            short4v bl = *reinterpret_cast<const short4v*>(&wnTl[(size_t)r * 128 + gk]);
            *reinterpret_cast<short4v*>(&Bh[r * 40 + q * 4]) = bh;
            *reinterpret_cast<short4v*>(&Bl[r * 40 + q * 4]) = bl;
        }
        __syncthreads();
        bf16x8 afh[4], afl[4], bfh[2], bfl[2];
        #pragma unroll
        for (int mi = 0; mi < 4; ++mi) {
            afh[mi] = *reinterpret_cast<const bf16x8*>(&Ah[(wr * 64 + mi * 16 + lr) * 40 + lg * 8]);
            afl[mi] = *reinterpret_cast<const bf16x8*>(&Al[(wr * 64 + mi * 16 + lr) * 40 + lg * 8]);
        }
        #pragma unroll
        for (int ni = 0; ni < 2; ++ni) {
            bfh[ni] = *reinterpret_cast<const bf16x8*>(&Bh[(wc * 32 + ni * 16 + lr) * 40 + lg * 8]);
            bfl[ni] = *reinterpret_cast<const bf16x8*>(&Bl[(wc * 32 + ni * 16 + lr) * 40 + lg * 8]);
        }
        #pragma unroll
        for (int mi = 0; mi < 4; ++mi)
            #pragma unroll
            for (int ni = 0; ni < 2; ++ni) {
                acc1[mi][ni] = __builtin_amdgcn_mfma_f32_16x16x32_bf16(afh[mi], bfh[ni], acc1[mi][ni], 0, 0, 0);
                acc1[mi][ni] = __builtin_amdgcn_mfma_f32_16x16x32_bf16(afl[mi], bfh[ni], acc1[mi][ni], 0, 0, 0);
                acc1[mi][ni] = __builtin_amdgcn_mfma_f32_16x16x32_bf16(afh[mi], bfl[ni], acc1[mi][ni], 0, 0, 0);
            }
        __syncthreads();
    }

    // ---- write xp: LDS hi (overwrites staging; safe after final barrier), global hi/lo ----
    #pragma unroll
    for (int mi = 0; mi < 4; ++mi) {
        #pragma unroll
        for (int ni = 0; ni < 2; ++ni) {
            int col = wc * 32 + ni * 16 + lr;
            #pragma unroll
            for (int r = 0; r < 4; ++r) {
                int rl = wr * 64 + mi * 16 + lg * 4 + r;
                float v = acc1[mi][ni][r];
                short hi = f2bf(v);
                xpH[rl * 136 + col] = hi;
                int row = row0 + rl;
                if (colhalf == 0 && row < M) {
                    xph[(size_t)row * 128 + col] = hi;
                    xpl[(size_t)row * 128 + col] = f2bf(v - bf2f(hi));
                }
            }
        }
    }
    __syncthreads();

    // ---- phase 2: Y columns [colhalf*512, +512) = xp_hi @ wbBT^T + colbias ----
    for (int c2 = 0; c2 < 4; ++c2) {
        int ct = colhalf * 4 + c2;
        f32x4 acc[4][2] = {};
        #pragma unroll
        for (int k = 0; k < 4; ++k) {
            bf16x8 bfr[2];
            #pragma unroll
            for (int ni = 0; ni < 2; ++ni) {
                int col = ct * 128 + wc * 32 + ni * 16 + lr;
                bfr[ni] = *reinterpret_cast<const bf16x8*>(&wbBT[(size_t)col * 128 + k * 32 + lg * 8]);
            }
            bf16x8 ah[4];
            #pragma unroll
            for (int mi = 0; mi < 4; ++mi)
                ah[mi] = *reinterpret_cast<const bf16x8*>(&xpH[(wr * 64 + mi * 16 + lr) * 136 + k * 32 + lg * 8]);
            #pragma unroll
            for (int mi = 0; mi < 4; ++mi)
                #pragma unroll
                for (int ni = 0; ni < 2; ++ni)
                    acc[mi][ni] = __builtin_amdgcn_mfma_f32_16x16x32_bf16(ah[mi], bfr[ni], acc[mi][ni], 0, 0, 0);
        }
        #pragma unroll
        for (int mi = 0; mi < 4; ++mi) {
            #pragma unroll
            for (int ni = 0; ni < 2; ++ni) {
                int col = ct * 128 + wc * 32 + ni * 16 + lr;
                float bv = wl1[((col & 127) << 3) + (col >> 7)];
                #pragma unroll
                for (int r = 0; r < 4; ++r) {
                    int row = row0 + wr * 64 + mi * 16 + lg * 4 + r;
                    if (row >= M) continue;
                    Y[(size_t)row * 1024 + col] = f2bf(acc[mi][ni][r] + bv);
                }
            }
        }
    }
}

// ========== rowdot8 ==========
template<int SPLITIN>
__global__ __launch_bounds__(256) void rowdot8(const short* __restrict__ Ah,
                                               const short* __restrict__ Al,
                                               const float* __restrict__ Wg,
                                               const float* __restrict__ bias8,
                                               float* __restrict__ out, int M) {
    __shared__ float sw[128][9];
    __shared__ float sb[8];
    for (int i = threadIdx.x; i < 1024; i += 256) sw[i >> 3][i & 7] = Wg[i];
    if (threadIdx.x < 8) sb[threadIdx.x] = bias8 ? bias8[threadIdx.x] : 0.f;
    __syncthreads();
    int r = blockIdx.x * 4 + (threadIdx.x >> 6);
    if (r >= M) return;
    int l = threadIdx.x & 63;
    int s = l & 7, c0 = (l >> 3) * 16;
    const short* ah = Ah + (size_t)r * 128 + c0;
    bf16x8 h0 = *reinterpret_cast<const bf16x8*>(ah);
    bf16x8 h1 = *reinterpret_cast<const bf16x8*>(ah + 8);
    float p = 0.f;
    if (SPLITIN) {
        const short* alr = Al + (size_t)r * 128 + c0;
        bf16x8 l0 = *reinterpret_cast<const bf16x8*>(alr);
        bf16x8 l1 = *reinterpret_cast<const bf16x8*>(alr + 8);
        #pragma unroll
        for (int j = 0; j < 8; ++j) {
            p += (bf2f(h0[j]) + bf2f(l0[j])) * sw[c0 + j][s];
            p += (bf2f(h1[j]) + bf2f(l1[j])) * sw[c0 + 8 + j][s];
        }
    } else {
        #pragma unroll
        for (int j = 0; j < 8; ++j) {
            p += bf2f(h0[j]) * sw[c0 + j][s];
            p += bf2f(h1[j]) * sw[c0 + 8 + j][s];
        }
    }
    p += __shfl_xor(p, 8); p += __shfl_xor(p, 16); p += __shfl_xor(p, 32);
    if (l < 8) out[(size_t)r * 8 + l] = p + sb[l];
}

// ========== fused edge kernel v2 ==========
__global__ __launch_bounds__(256) void edge_fused2(const short* __restrict__ xph,
                                                   const short* __restrict__ xpl,
                                                   const short* __restrict__ ep,
                                                   const short* __restrict__ Y,
                                                   const int* __restrict__ ei,
                                                   const float* __restrict__ u,
                                                   const float* __restrict__ v,
                                                   float* __restrict__ agg, int E) {
    int e = blockIdx.x * 4 + (threadIdx.x >> 6);
    if (e >= E) return;
    int l = threadIdx.x & 63;
    int s = l & 7, c0 = (l >> 3) * 16;
    int src = ei[e], dst = ei[E + e];
    const short* y  = Y + (size_t)src * 1024 + s * 128 + c0;
    const short* xih = xph + (size_t)dst * 128 + c0;
    const short* xil = xpl + (size_t)dst * 128 + c0;
    bf16x8 y0 = *reinterpret_cast<const bf16x8*>(y);
    bf16x8 y1 = *reinterpret_cast<const bf16x8*>(y + 8);
    bf16x8 a0 = *reinterpret_cast<const bf16x8*>(xih);
    bf16x8 a1 = *reinterpret_cast<const bf16x8*>(xih + 8);
    bf16x8 b0 = *reinterpret_cast<const bf16x8*>(xil);
    bf16x8 b1 = *reinterpret_cast<const bf16x8*>(xil + 8);
    float p = 0.f;
    #pragma unroll
    for (int j = 0; j < 8; ++j) {
        p += (bf2f(a0[j]) + bf2f(b0[j])) * bf2f(y0[j]);
        p += (bf2f(a1[j]) + bf2f(b1[j])) * bf2f(y1[j]);
    }
    p += __shfl_xor(p, 8); p += __shfl_xor(p, 16); p += __shfl_xor(p, 32);
    float alpha = tanhf(p + u[(size_t)src * 8 + s] + v[(size_t)e * 8 + s]);
    float aa0 = __shfl(alpha, l >> 4);
    float aa1 = __shfl(alpha, 4 + (l >> 4));
    float xj0 = bf2f(xph[(size_t)src * 128 + l]) + bf2f(xpl[(size_t)src * 128 + l]);
    float xj1 = bf2f(xph[(size_t)src * 128 + l + 64]) + bf2f(xpl[(size_t)src * 128 + l + 64]);
    float e0 = bf2f(ep[(size_t)e * 128 + l]);
    float e1 = bf2f(ep[(size_t)e * 128 + l + 64]);
    atomicAdd(&agg[(size_t)dst * 128 + l],      fmaxf(xj0, e0) * aa0);
    atomicAdd(&agg[(size_t)dst * 128 + l + 64], fmaxf(xj1, e1) * aa1);
}

// ========== gate GEMM (split-3, K=256 combined weights, in place) ==========
__global__ __launch_bounds__(256) void gate_gemm_split(float* __restrict__ h,
                                                       const float* __restrict__ aggv,
                                                       const short* __restrict__ BTh,
                                                       const short* __restrict__ BTl,
                                                       const float* __restrict__ gb,
                                                       int M) {
    __shared__ short Ah[128][40];
    __shared__ short Al[128][40];
    __shared__ short Bh[128][40];
    __shared__ short Bl[128][40];
    const int tid = threadIdx.x;
    const int row0 = blockIdx.y * 128;
    const int lane = tid & 63, w = tid >> 6;
    const int wr = w >> 1, wc = w & 1;
    const int lr = lane & 15, lg = lane >> 4;
    f32x4 acc[4][4] = {};

    for (int k0 = 0; k0 < 256; k0 += 32) {
        int sec = k0 >> 7;
        #pragma unroll
        for (int i = 0; i < 4; ++i) {
            int idx = i * 256 + tid;
            int r = idx >> 3, q = idx & 7;
            int gr = row0 + r;
            int ks = (k0 & 127) + q * 4;
            f32x4 v;
            if (gr < M) {
                if (sec == 0) {
                    v = *reinterpret_cast<const f32x4*>(&h[(size_t)gr * 128 + ks]);
                } else {
                    f32x4 a = *reinterpret_cast<const f32x4*>(&aggv[(size_t)gr * 128 + ks]);
                    #pragma unroll
                    for (int j = 0; j < 4; ++j) v[j] = fmaxf(a[j], 0.f);
                }
            } else {
                #pragma unroll
                for (int j = 0; j < 4; ++j) v[j] = 0.f;
            }
            short4v hh, ll;
            #pragma unroll
            for (int j = 0; j < 4; ++j) {
                hh[j] = f2bf(v[j]);
                ll[j] = f2bf(v[j] - bf2f(hh[j]));
            }
            *reinterpret_cast<short4v*>(&Ah[r][q * 4]) = hh;
            *reinterpret_cast<short4v*>(&Al[r][q * 4]) = ll;
        }
        #pragma unroll
        for (int i = 0; i < 4; ++i) {
            int idx = i * 256 + tid;
            int r = idx >> 3, q = idx & 7;
            short4v uu = *reinterpret_cast<const short4v*>(&BTh[(size_t)r * 256 + k0 + q * 4]);
            short4v ul = *reinterpret_cast<const short4v*>(&BTl[(size_t)r * 256 + k0 + q * 4]);
            *reinterpret_cast<short4v*>(&Bh[r][q * 4]) = uu;
            *reinterpret_cast<short4v*>(&Bl[r][q * 4]) = ul;
        }
        __syncthreads();
        bf16x8 afh[4], afl[4], bfh[4], bfl[4];
        #pragma unroll
        for (int mi = 0; mi < 4; ++mi) {
            afh[mi] = *reinterpret_cast<const bf16x8*>(&Ah[wr * 64 + mi * 16 + lr][lg * 8]);
            afl[mi] = *reinterpret_cast<const bf16x8*>(&Al[wr * 64 + mi * 16 + lr][lg * 8]);
        }
        #pragma unroll
        for (int ni = 0; ni < 4; ++ni) {
            bfh[ni] = *reinterpret_cast<const bf16x8*>(&Bh[wc * 64 + ni * 16 + lr][lg * 8]);
            bfl[ni] = *reinterpret_cast<const bf16x8*>(&Bl[wc * 64 + ni * 16 + lr][lg * 8]);
        }
        #pragma unroll
        for (int mi = 0; mi < 4; ++mi)
            #pragma unroll
            for (int ni = 0; ni < 4; ++ni) {
                acc[mi][ni] = __builtin_amdgcn_mfma_f32_16x16x32_bf16(afh[mi], bfh[ni], acc[mi][ni], 0, 0, 0);
                acc[mi][ni] = __builtin_amdgcn_mfma_f32_16x16x32_bf16(afl[mi], bfh[ni], acc[mi][ni], 0, 0, 0);
                acc[mi][ni] = __builtin_amdgcn_mfma_f32_16x16x32_bf16(afh[mi], bfl[ni], acc[mi][ni], 0, 0, 0);
            }
        __syncthreads();
    }

    #pragma unroll
    for (int mi = 0; mi < 4; ++mi) {
        #pragma unroll
        for (int ni = 0; ni < 4; ++ni) {
            int col = wc * 64 + ni * 16 + lr;
            float gbv = gb[col];
            #pragma unroll
            for (int r = 0; r < 4; ++r) {
                int row = row0 + wr * 64 + mi * 16 + lg * 4 + r;
                if (row >= M) continue;
                float beta = fmaxf(acc[mi][ni][r] + gbv, 0.f);
                float hv = h[(size_t)row * 128 + col];
                float hh = fmaxf(aggv[(size_t)row * 128 + col], 0.f);
                h[(size_t)row * 128 + col] = beta * hv + (1.f - beta) * hh;
            }
        }
    }
}

// ========== batch norm ==========
__global__ void bn_stats(const float* __restrict__ z, float* __restrict__ gsum,
                         float* __restrict__ gsq, int M) {
    int c = threadIdx.x & 127;
    int rr = threadIdx.x >> 7;
    float s = 0.f, q = 0.f;
    for (int r = blockIdx.x * 2 + rr; r < M; r += gridDim.x * 2) {
        float v = z[(size_t)r * 128 + c];
        s += v; q += v * v;
    }
    __shared__ float ls[256], lq[256];
    ls[threadIdx.x] = s; lq[threadIdx.x] = q;
    __syncthreads();
    if (threadIdx.x < 128) {
        atomicAdd(&gsum[c], ls[threadIdx.x] + ls[threadIdx.x + 128]);
        atomicAdd(&gsq[c],  lq[threadIdx.x] + lq[threadIdx.x + 128]);
    }
}

__global__ void bn_apply(float* __restrict__ z, const float* __restrict__ gsum,
                         const float* __restrict__ gsq, const float* __restrict__ g,
                         const float* __restrict__ b, int M) {
    size_t total = (size_t)M * 128;
    for (size_t idx = (size_t)blockIdx.x * 256 + threadIdx.x; idx < total;
         idx += (size_t)gridDim.x * 256) {
        int c = idx & 127;
        float mu = gsum[c] / (float)M;
        float var = gsq[c] / (float)M - mu * mu;
        float rs = rsqrtf(var + EPS);
        float v = (z[idx] - mu) * rs * g[c] + b[c];
        z[idx] = fmaxf(v, 0.f);
    }
}

__global__ void bn_stats_bf(const short* __restrict__ z, float* __restrict__ gsum,
                            float* __restrict__ gsq, int M) {
    int c = threadIdx.x & 127;
    int rr = threadIdx.x >> 7;
    float s = 0.f, q = 0.f;
    for (int r = blockIdx.x * 2 + rr; r < M; r += gridDim.x * 2) {
        float v = bf2f(z[(size_t)r * 128 + c]);
        s += v; q += v * v;
    }
    __shared__ float ls[256], lq[256];
    ls[threadIdx.x] = s; lq[threadIdx.x] = q;
    __syncthreads();
    if (threadIdx.x < 128) {
        atomicAdd(&gsum[c], ls[threadIdx.x] + ls[threadIdx.x + 128]);
        atomicAdd(&gsq[c],  lq[threadIdx.x] + lq[threadIdx.x + 128]);
    }
}

__global__ void bn_apply_bf(short* __restrict__ z, const float* __restrict__ gsum,
                            const float* __restrict__ gsq, const float* __restrict__ g,
                            const float* __restrict__ b, int M) {
    size_t total = (size_t)M * 128;
    for (size_t idx = (size_t)blockIdx.x * 256 + threadIdx.x; idx < total;
         idx += (size_t)gridDim.x * 256) {
        int c = idx & 127;
        float mu = gsum[c] / (float)M;
        float var = gsq[c] / (float)M - mu * mu;
        float rs = rsqrtf(var + EPS);
        float v = (bf2f(z[idx]) - mu) * rs * g[c] + b[c];
        z[idx] = f2bf(fmaxf(v, 0.f));
    }
}

// ========== prep ==========
__global__ void transpose_split(const float* __restrict__ in, short* __restrict__ outh,
                                short* __restrict__ outl, int K, int N) {
    int idx = blockIdx.x * 256 + threadIdx.x;
    if (idx >= K * N) return;
    int nI = idx / K, k = idx - nI * K;
    float v = in[(size_t)k * N + nI];
    short h = f2bf(v);
    outh[idx] = h;
    outl[idx] = f2bf(v - bf2f(h));
}

__global__ void cvt_f2b(const float* __restrict__ in, short* __restrict__ out, int n) {
    int i = blockIdx.x * 256 + threadIdx.x;
    if (i < n) out[i] = f2bf(in[i]);
}

__global__ void gate_combine_split(const float* __restrict__ gw, short* __restrict__ BTh,
                                   short* __restrict__ BTl) {
    int idx = blockIdx.x * 256 + threadIdx.x;
    if (idx >= 128 * 256) return;
    int n = idx >> 8, k = idx & 255;
    float v;
    if (k < 128) v = gw[(size_t)k * 128 + n] + gw[(size_t)(256 + k) * 128 + n];
    else {
        int kk = k - 128;
        v = gw[(size_t)(128 + kk) * 128 + n] - gw[(size_t)(256 + kk) * 128 + n];
    }
    short h = f2bf(v);
    BTh[idx] = h;
    BTl[idx] = f2bf(v - bf2f(h));
}

__global__ void build_wm(const float* __restrict__ wsrc, float* __restrict__ wm) {
    int idx = blockIdx.x * 256 + threadIdx.x;
    if (idx >= 128 * 128) return;
    int d = idx >> 7, c = idx & 127;
    float s = 0.f;
    #pragma unroll
    for (int h = 0; h < 8; ++h) s += wsrc[(size_t)d * 1024 + h * 128 + c];
    wm[idx] = s * 0.125f;
}

__global__ void perm_build(const int* __restrict__ ci, int* __restrict__ perm, int NF) {
    int i = blockIdx.x * 256 + threadIdx.x;
    if (i >= NF) return;
    int c = ci[i];
    if (i == 0 || ci[i - 1] != c) perm[c] = i;
}

__global__ void seg_pool(const float* __restrict__ fx, const int* __restrict__ perm,
                         float* __restrict__ pool, int F, int NF) {
    int idx = blockIdx.x * 256 + threadIdx.x;
    if (idx >= F * 128) return;
    int f = idx >> 7, c = idx & 127;
    int s = perm[f];
    int e = (f + 1 < F) ? perm[f + 1] : NF;
    float acc = 0.f;
    for (int i = s; i < e; ++i) acc += fx[(size_t)i * 128 + c];
    pool[idx] = fmaxf(acc, 0.f);
}

// ========== output ==========
__global__ __launch_bounds__(256) void out_phase1(const float* __restrict__ h,
                                                  const float* __restrict__ out_w,
                                                  const float* __restrict__ out_b,
                                                  const float* __restrict__ gat_bias,
                                                  float* __restrict__ out, int M) {
    int n = blockIdx.x * 4 + (threadIdx.x >> 6);
    if (n >= M) return;
    int l = threadIdx.x & 63;
    float p = fmaxf(h[(size_t)n * 128 + l], 0.f) * out_w[l]
            + fmaxf(h[(size_t)n * 128 + l + 64], 0.f) * out_w[l + 64];
    p += fmaxf(gat_bias[l], 0.f) * out_w[128 + l]
       + fmaxf(gat_bias[l + 64], 0.f) * out_w[128 + l + 64];
    #pragma unroll
    for (int off = 32; off; off >>= 1) p += __shfl_xor(p, off);
    if (l == 0) out[n] = p + out_b[0];
}

__global__ __launch_bounds__(256) void out_phase2(const float* __restrict__ fmv,
                                                  const int* __restrict__ perm,
                                                  const float* __restrict__ out_w,
                                                  const float* __restrict__ gat_bias,
                                                  float* __restrict__ out, int F) {
    int f = blockIdx.x * 4 + (threadIdx.x >> 6);
    if (f >= F) return;
    int l = threadIdx.x & 63;
    float p = fmv[(size_t)f * 128 + l] * out_w[128 + l]
            + fmv[(size_t)f * 128 + l + 64] * out_w[128 + l + 64];
    float b = fmaxf(gat_bias[l], 0.f) * out_w[128 + l]
            + fmaxf(gat_bias[l + 64], 0.f) * out_w[128 + l + 64];
    float d = p - b;
    #pragma unroll
    for (int off = 32; off; off >>= 1) d += __shfl_xor(d, off);
    if (l == 0) out[perm[f]] += d;
}

// ========== host ==========
extern "C" void kernel_launch(void* const* d_in, const int* in_sizes, int n_in,
                              void* d_out, int out_size, void* d_ws, size_t ws_size,
                              hipStream_t stream) {
    const int N = 50000, E = 100000, NF = 20000, EF = 40000, F = 10000;

    const float* x          = (const float*)d_in[0];
    const float* edge_attr  = (const float*)d_in[1];
    const float* frag_x     = (const float*)d_in[2];
    const float* frag_ea    = (const float*)d_in[3];
    const float* la_w = (const float*)d_in[4];
    const float* la_b = (const float*)d_in[5];
    const float* lb_w = (const float*)d_in[6];
    const float* lb_b = (const float*)d_in[7];
    const float* bn1_g = (const float*)d_in[8];
    const float* bn1_b = (const float*)d_in[9];
    const float* bn2_g = (const float*)d_in[10];
    const float* bn2_b = (const float*)d_in[11];
    const float* wn = (const float*)d_in[12];
    const float* wb = (const float*)d_in[13];
    const float* wl = (const float*)d_in[14];
    const float* wlb = (const float*)d_in[15];
    const float* gate_w = (const float*)d_in[16];
    const float* gate_b = (const float*)d_in[17];
    const float* gat_wsrc = (const float*)d_in[18];
    const float* gat_bias = (const float*)d_in[22];
    const float* out_w = (const float*)d_in[23];
    const float* out_b = (const float*)d_in[24];
    const int* edge_index = (const int*)d_in[25];
    const int* frag_edge_index = (const int*)d_in[26];
    const int* cluster_index = (const int*)d_in[27];

    char* p = (char*)d_ws;
    auto alloc = [&](size_t bytes) { char* r = p; p += (bytes + 255) & ~(size_t)255; return (void*)r; };
    float* hA    = (float*)alloc((size_t)N * 128 * 4);
    short* ea1   = (short*)alloc((size_t)E * 128 * 2);
    short* xph   = (short*)alloc((size_t)N * 128 * 2);
    short* xpl   = (short*)alloc((size_t)N * 128 * 2);
    short* ep    = (short*)alloc((size_t)E * 128 * 2);
    short* Y     = (short*)alloc((size_t)N * 1024 * 2);
    float* agg   = (float*)alloc((size_t)N * 128 * 4);
    float* ubuf  = (float*)alloc((size_t)N * 8 * 4);
    float* vbuf  = (float*)alloc((size_t)E * 8 * 4);
    short* la_wTh = (short*)alloc(128 * 128 * 2);
    short* la_wTl = (short*)alloc(128 * 128 * 2);
    short* lb_wTh = (short*)alloc(128 * 16 * 2);
    short* lb_wTl = (short*)alloc(128 * 16 * 2);
    short* wnTh   = (short*)alloc(3 * 128 * 128 * 2);
    short* wnTl   = (short*)alloc(3 * 128 * 128 * 2);
    short* wbH    = (short*)alloc(3 * 1024 * 128 * 2);
    short* gate2Th = (short*)alloc(128 * 256 * 2);
    short* gate2Tl = (short*)alloc(128 * 256 * 2);
    float* wmF    = (float*)alloc(128 * 128 * 4);
    short* wmTh   = (short*)alloc(128 * 128 * 2);
    short* wmTl   = (short*)alloc(128 * 128 * 2);
    float* stats  = (float*)alloc(256 * 4);
    char* yq = (char*)Y;
    float* fpool = (float*)yq;              yq += (size_t)F * 128 * 4;
    float* fmv   = (float*)yq;              yq += (size_t)F * 128 * 4;
    int*   perm  = (int*)yq;

    auto cdiv = [](int a, int b) { return (a + b - 1) / b; };

    // ---- weight prep ----
    transpose_split<<<cdiv(128 * 128, 256), 256, 0, stream>>>(la_w, la_wTh, la_wTl, 128, 128);
    transpose_split<<<cdiv(16 * 128, 256), 256, 0, stream>>>(lb_w, lb_wTh, lb_wTl, 16, 128);
    for (int l = 0; l < 3; ++l)
        transpose_split<<<cdiv(128 * 128, 256), 256, 0, stream>>>(
            wn + (size_t)l * 16384, wnTh + (size_t)l * 16384, wnTl + (size_t)l * 16384, 128, 128);
    cvt_f2b<<<cdiv(3 * 1024 * 128, 256), 256, 0, stream>>>(wb, wbH, 3 * 1024 * 128);
    gate_combine_split<<<cdiv(128 * 256, 256), 256, 0, stream>>>(gate_w, gate2Th, gate2Tl);
    build_wm<<<cdiv(128 * 128, 256), 256, 0, stream>>>(gat_wsrc, wmF);
    transpose_split<<<cdiv(128 * 128, 256), 256, 0, stream>>>(wmF, wmTh, wmTl, 128, 128);

    auto run_layer = [&](float* h, const short* ea_buf, const int* ei, int Mn, int Me, int layer) {
        const short* wnTh_l = wnTh + (size_t)layer * 16384;
        const short* wnTl_l = wnTl + (size_t)layer * 16384;
        const short* wb_l   = wbH + (size_t)layer * 131072;
        const float* wl_l   = wl + (size_t)layer * 384 * 8;
        const float* wlb_l  = wlb + (size_t)layer * 8;
        fused_xpy<<<dim3(2, cdiv(Mn, 128)), 512, 0, stream>>>(h, wnTh_l, wnTl_l, wb_l, wl_l, xph, xpl, Y, Mn);
        gemm_bf16<0, 1><<<dim3(1, cdiv(Me, 128)), 256, 0, stream>>>(ea_buf, wnTh_l, nullptr, ep, Me, 128, 128);
        rowdot8<1><<<cdiv(Mn, 4), 256, 0, stream>>>(xph, xpl, wl_l + 256 * 8, wlb_l, ubuf, Mn);
        rowdot8<0><<<cdiv(Me, 4), 256, 0, stream>>>(ep, nullptr, wl_l + 128 * 8, nullptr, vbuf, Me);
        hipMemsetAsync(agg, 0, (size_t)Mn * 128 * 4, stream);
        edge_fused2<<<cdiv(Me, 4), 256, 0, stream>>>(xph, xpl, ep, Y, ei, ubuf, vbuf, agg, Me);
        gate_gemm_split<<<dim3(1, cdiv(Mn, 128)), 256, 0, stream>>>(h, agg, gate2Th, gate2Tl, gate_b, Mn);
    };

    // ---- atom path ----
    gemm_split<3, 0, 0><<<dim3(1, cdiv(N, 128)), 256, 0, stream>>>(x, la_wTh, la_wTl, la_b, hA, nullptr, N, 128, 128);
    hipMemsetAsync(stats, 0, 1024, stream);
    bn_stats<<<256, 256, 0, stream>>>(hA, stats, stats + 128, N);
    bn_apply<<<2048, 256, 0, stream>>>(hA, stats, stats + 128, bn1_g, bn1_b, N);

    gemm_split<3, 0, 1><<<dim3(1, cdiv(E, 128)), 256, 0, stream>>>(edge_attr, lb_wTh, lb_wTl, lb_b, ea1, nullptr, E, 128, 16);
    hipMemsetAsync(stats, 0, 1024, stream);
    bn_stats_bf<<<256, 256, 0, stream>>>(ea1, stats, stats + 128, E);
    bn_apply_bf<<<2048, 256, 0, stream>>>(ea1, stats, stats + 128, bn2_g, bn2_b, E);

    for (int l = 0; l < 3; ++l) run_layer(hA, ea1, edge_index, N, E, l);
    out_phase1<<<cdiv(N, 4), 256, 0, stream>>>(hA, out_w, out_b, gat_bias, (float*)d_out, N);

    // ---- fragment path ----
    gemm_split<3, 1, 0><<<dim3(1, cdiv(NF, 128)), 256, 0, stream>>>(frag_x, la_wTh, la_wTl, la_b, hA, nullptr, NF, 128, 128);

    gemm_split<3, 0, 1><<<dim3(1, cdiv(EF, 128)), 256, 0, stream>>>(frag_ea, lb_wTh, lb_wTl, lb_b, ea1, nullptr, EF, 128, 16);
    hipMemsetAsync(stats, 0, 1024, stream);
    bn_stats_bf<<<256, 256, 0, stream>>>(ea1, stats, stats + 128, EF);
    bn_apply_bf<<<2048, 256, 0, stream>>>(ea1, stats, stats + 128, bn2_g, bn2_b, EF);

    for (int l = 0; l < 3; ++l) run_layer(hA, ea1, frag_edge_index, NF, EF, l);

    perm_build<<<cdiv(NF, 256), 256, 0, stream>>>(cluster_index, perm, NF);
    seg_pool<<<cdiv(F * 128, 256), 256, 0, stream>>>(hA, perm, fpool, F, NF);
    gemm_split<3, 1, 0><<<dim3(1, cdiv(F, 128)), 256, 0, stream>>>(fpool, wmTh, wmTl, gat_bias, fmv, nullptr, F, 128, 128);
    out_phase2<<<cdiv(F, 4), 256, 0, stream>>>(fmv, perm, out_w, gat_bias, (float*)d_out, F);
}

// Round 9
// 1635.057 us; speedup vs baseline: 1.0439x; 1.0439x over previous
//
#include <hip/hip_runtime.h>
#include <hip/hip_bf16.h>

#define EPS 1e-5f

typedef short bf16x8 __attribute__((ext_vector_type(8)));
typedef short short4v __attribute__((ext_vector_type(4)));
typedef float f32x4 __attribute__((ext_vector_type(4)));

static __device__ __forceinline__ short f2bf(float x) {
    __hip_bfloat16 h = __float2bfloat16(x);
    return *reinterpret_cast<short*>(&h);
}
static __device__ __forceinline__ float bf2f(short x) {
    __hip_bfloat16 h;
    *reinterpret_cast<short*>(&h) = x;
    return __bfloat162float(h);
}

// ========== split-bf16 MFMA GEMM: C = act(A[M,K](f32) @ BT[N,K]^T + bias) ==========
template<int SPLIT, int ACT, int OUTM>
__global__ __launch_bounds__(256) void gemm_split(const float* __restrict__ A,
                                                  const short* __restrict__ BTh,
                                                  const short* __restrict__ BTl,
                                                  const float* __restrict__ bias,
                                                  void* __restrict__ Cout,
                                                  void* __restrict__ Cout2,
                                                  int M, int N, int K) {
    __shared__ short Ah[128][40];
    __shared__ short Al[128][40];
    __shared__ short Bh[128][40];
    __shared__ short Bl[128][40];
    const int tid = threadIdx.x;
    const int row0 = blockIdx.y * 128, col0 = blockIdx.x * 128;
    const int lane = tid & 63, w = tid >> 6;
    const int wr = w >> 1, wc = w & 1;
    const int lr = lane & 15, lg = lane >> 4;
    f32x4 acc[4][4] = {};

    for (int k0 = 0; k0 < K; k0 += 32) {
        #pragma unroll
        for (int i = 0; i < 4; ++i) {
            int idx = i * 256 + tid;
            int r = idx >> 3, q = idx & 7;
            int gr = row0 + r, gk = k0 + q * 4;
            f32x4 v;
            if (gr < M && gk + 3 < K) {
                v = *reinterpret_cast<const f32x4*>(&A[(size_t)gr * K + gk]);
            } else {
                #pragma unroll
                for (int j = 0; j < 4; ++j)
                    v[j] = (gr < M && gk + j < K) ? A[(size_t)gr * K + gk + j] : 0.f;
            }
            short4v h, l;
            #pragma unroll
            for (int j = 0; j < 4; ++j) {
                h[j] = f2bf(v[j]);
                l[j] = f2bf(v[j] - bf2f(h[j]));
            }
            *reinterpret_cast<short4v*>(&Ah[r][q * 4]) = h;
            *reinterpret_cast<short4v*>(&Al[r][q * 4]) = l;
        }
        #pragma unroll
        for (int i = 0; i < 4; ++i) {
            int idx = i * 256 + tid;
            int r = idx >> 3, q = idx & 7;
            int gc = col0 + r, gk = k0 + q * 4;
            short4v u, ul;
            if (gk + 3 < K) {
                u = *reinterpret_cast<const short4v*>(&BTh[(size_t)gc * K + gk]);
                if (SPLIT == 3) ul = *reinterpret_cast<const short4v*>(&BTl[(size_t)gc * K + gk]);
            } else {
                #pragma unroll
                for (int j = 0; j < 4; ++j) {
                    u[j] = (gk + j < K) ? BTh[(size_t)gc * K + gk + j] : (short)0;
                    if (SPLIT == 3) ul[j] = (gk + j < K) ? BTl[(size_t)gc * K + gk + j] : (short)0;
                }
            }
            *reinterpret_cast<short4v*>(&Bh[r][q * 4]) = u;
            if (SPLIT == 3) *reinterpret_cast<short4v*>(&Bl[r][q * 4]) = ul;
        }
        __syncthreads();
        bf16x8 afh[4], afl[4], bfh[4];
        #pragma unroll
        for (int mi = 0; mi < 4; ++mi) {
            afh[mi] = *reinterpret_cast<const bf16x8*>(&Ah[wr * 64 + mi * 16 + lr][lg * 8]);
            afl[mi] = *reinterpret_cast<const bf16x8*>(&Al[wr * 64 + mi * 16 + lr][lg * 8]);
        }
        #pragma unroll
        for (int ni = 0; ni < 4; ++ni)
            bfh[ni] = *reinterpret_cast<const bf16x8*>(&Bh[wc * 64 + ni * 16 + lr][lg * 8]);
        #pragma unroll
        for (int mi = 0; mi < 4; ++mi)
            #pragma unroll
            for (int ni = 0; ni < 4; ++ni) {
                acc[mi][ni] = __builtin_amdgcn_mfma_f32_16x16x32_bf16(afh[mi], bfh[ni], acc[mi][ni], 0, 0, 0);
                acc[mi][ni] = __builtin_amdgcn_mfma_f32_16x16x32_bf16(afl[mi], bfh[ni], acc[mi][ni], 0, 0, 0);
            }
        if (SPLIT == 3) {
            bf16x8 bfl[4];
            #pragma unroll
            for (int ni = 0; ni < 4; ++ni)
                bfl[ni] = *reinterpret_cast<const bf16x8*>(&Bl[wc * 64 + ni * 16 + lr][lg * 8]);
            #pragma unroll
            for (int mi = 0; mi < 4; ++mi)
                #pragma unroll
                for (int ni = 0; ni < 4; ++ni)
                    acc[mi][ni] = __builtin_amdgcn_mfma_f32_16x16x32_bf16(afh[mi], bfl[ni], acc[mi][ni], 0, 0, 0);
        }
        __syncthreads();
    }

    #pragma unroll
    for (int mi = 0; mi < 4; ++mi) {
        #pragma unroll
        for (int ni = 0; ni < 4; ++ni) {
            int col = col0 + wc * 64 + ni * 16 + lr;
            float bv = bias ? bias[col] : 0.f;
            #pragma unroll
            for (int r = 0; r < 4; ++r) {
                int row = row0 + wr * 64 + mi * 16 + lg * 4 + r;
                if (row >= M) continue;
                float v = acc[mi][ni][r] + bv;
                if (ACT) v = fmaxf(v, 0.f);
                if (OUTM == 0) ((float*)Cout)[(size_t)row * N + col] = v;
                else ((short*)Cout)[(size_t)row * N + col] = f2bf(v);
            }
        }
    }
}

// ========== plain bf16 GEMM (tolerant path: ep projection) ==========
template<int ACT, int OUTBF>
__global__ __launch_bounds__(256) void gemm_bf16(const short* __restrict__ A,
                                                 const short* __restrict__ BT,
                                                 const float* __restrict__ bias,
                                                 void* __restrict__ Cout,
                                                 int M, int N, int K) {
    __shared__ short As[128][40];
    __shared__ short Bs[128][40];
    const int tid = threadIdx.x;
    const int row0 = blockIdx.y * 128, col0 = blockIdx.x * 128;
    const int lane = tid & 63, w = tid >> 6;
    const int wr = w >> 1, wc = w & 1;
    const int lr = lane & 15, lg = lane >> 4;
    f32x4 acc[4][4] = {};

    for (int k0 = 0; k0 < K; k0 += 32) {
        #pragma unroll
        for (int i = 0; i < 4; ++i) {
            int idx = i * 256 + tid;
            int r = idx >> 3, q = idx & 7;
            int gk = k0 + q * 4;
            int gr = row0 + r;
            short4v v;
            if (gr < M && gk + 3 < K) {
                v = *reinterpret_cast<const short4v*>(&A[(size_t)gr * K + gk]);
            } else {
                #pragma unroll
                for (int j = 0; j < 4; ++j)
                    v[j] = (gr < M && gk + j < K) ? A[(size_t)gr * K + gk + j] : (short)0;
            }
            *reinterpret_cast<short4v*>(&As[r][q * 4]) = v;
            int gc = col0 + r;
            short4v u;
            if (gc < N && gk + 3 < K) {
                u = *reinterpret_cast<const short4v*>(&BT[(size_t)gc * K + gk]);
            } else {
                #pragma unroll
                for (int j = 0; j < 4; ++j)
                    u[j] = (gc < N && gk + j < K) ? BT[(size_t)gc * K + gk + j] : (short)0;
            }
            *reinterpret_cast<short4v*>(&Bs[r][q * 4]) = u;
        }
        __syncthreads();
        bf16x8 af[4], bfr[4];
        #pragma unroll
        for (int mi = 0; mi < 4; ++mi)
            af[mi] = *reinterpret_cast<const bf16x8*>(&As[wr * 64 + mi * 16 + lr][lg * 8]);
        #pragma unroll
        for (int ni = 0; ni < 4; ++ni)
            bfr[ni] = *reinterpret_cast<const bf16x8*>(&Bs[wc * 64 + ni * 16 + lr][lg * 8]);
        #pragma unroll
        for (int mi = 0; mi < 4; ++mi)
            #pragma unroll
            for (int ni = 0; ni < 4; ++ni)
                acc[mi][ni] = __builtin_amdgcn_mfma_f32_16x16x32_bf16(af[mi], bfr[ni], acc[mi][ni], 0, 0, 0);
        __syncthreads();
    }

    #pragma unroll
    for (int mi = 0; mi < 4; ++mi) {
        #pragma unroll
        for (int ni = 0; ni < 4; ++ni) {
            int col = col0 + wc * 64 + ni * 16 + lr;
            float bv = bias ? bias[col] : 0.f;
            #pragma unroll
            for (int r = 0; r < 4; ++r) {
                int row = row0 + wr * 64 + mi * 16 + lg * 4 + r;
                if (row >= M) continue;
                float v = acc[mi][ni][r] + bv;
                if (ACT) v = fmaxf(v, 0.f);
                if (OUTBF) ((short*)Cout)[(size_t)row * N + col] = f2bf(v);
                else       ((float*)Cout)[(size_t)row * N + col] = v;
            }
        }
    }
}

// ========== fused xp + Y kernel v3: 64-row tiles, 4 waves ==========
// Phase 1: xp[64,128] = h @ wnT (split-3) -> global hi/lo + LDS hi.
// Phase 2: Y[64,1024] = xp_hi @ wbBT^T + wl1 colbias (B from L2).
// LDS 30720 B: staging (Ah 64x40 | Al 64x40 | Bh 128x40 | Bl 128x40) aliased by xpH 64x136.
__global__ __launch_bounds__(256) void fused_xpy(const float* __restrict__ h,
                                                 const short* __restrict__ wnTh,
                                                 const short* __restrict__ wnTl,
                                                 const short* __restrict__ wbBT,
                                                 const float* __restrict__ wl1,
                                                 short* __restrict__ xph,
                                                 short* __restrict__ xpl,
                                                 short* __restrict__ Y, int M) {
    __shared__ short sbuf[15360];
    short* Ah = sbuf;                 // 64 x 40
    short* Al = sbuf + 2560;
    short* Bh = sbuf + 5120;          // 128 x 40
    short* Bl = sbuf + 10240;
    short* xpH = sbuf;                // 64 x 136 (phase 2; overwrites staging after final barrier)

    const int tid = threadIdx.x;
    const int row0 = blockIdx.x * 64;
    const int lane = tid & 63, w = tid >> 6;   // 4 waves, each owns 32 output cols
    const int lr = lane & 15, lg = lane >> 4;

    // ---- phase 1 ----
    f32x4 acc1[4][2] = {};
    for (int k0 = 0; k0 < 128; k0 += 32) {
        #pragma unroll
        for (int i = 0; i < 2; ++i) {          // A: 64 rows x 8 chunks = 512
            int idx = i * 256 + tid;
            int r = idx >> 3, q = idx & 7;
            int gr = row0 + r, gk = k0 + q * 4;
            f32x4 v;
            if (gr < M) {
                v = *reinterpret_cast<const f32x4*>(&h[(size_t)gr * 128 + gk]);
            } else {
                #pragma unroll
                for (int j = 0; j < 4; ++j) v[j] = 0.f;
            }
            short4v hh, ll;
            #pragma unroll
            for (int j = 0; j < 4; ++j) {
                hh[j] = f2bf(v[j]);
                ll[j] = f2bf(v[j] - bf2f(hh[j]));
            }
            *reinterpret_cast<short4v*>(&Ah[r * 40 + q * 4]) = hh;
            *reinterpret_cast<short4v*>(&Al[r * 40 + q * 4]) = ll;
        }
        #pragma unroll
        for (int i = 0; i < 4; ++i) {          // B: 128 rows x 8 chunks = 1024
            int idx = i * 256 + tid;
            int r = idx >> 3, q = idx & 7;
            int gk = k0 + q * 4;
            short4v bh = *reinterpret_cast<const short4v*>(&wnTh[(size_t)r * 128 + gk]);
            short4v bl = *reinterpret_cast<const short4v*>(&wnTl[(size_t)r * 128 + gk]);
            *reinterpret_cast<short4v*>(&Bh[r * 40 + q * 4]) = bh;
            *reinterpret_cast<short4v*>(&Bl[r * 40 + q * 4]) = bl;
        }
        __syncthreads();
        bf16x8 afh[4], afl[4], bfh[2], bfl[2];
        #pragma unroll
        for (int mi = 0; mi < 4; ++mi) {
            afh[mi] = *reinterpret_cast<const bf16x8*>(&Ah[(mi * 16 + lr) * 40 + lg * 8]);
            afl[mi] = *reinterpret_cast<const bf16x8*>(&Al[(mi * 16 + lr) * 40 + lg * 8]);
        }
        #pragma unroll
        for (int ni = 0; ni < 2; ++ni) {
            bfh[ni] = *reinterpret_cast<const bf16x8*>(&Bh[(w * 32 + ni * 16 + lr) * 40 + lg * 8]);
            bfl[ni] = *reinterpret_cast<const bf16x8*>(&Bl[(w * 32 + ni * 16 + lr) * 40 + lg * 8]);
        }
        #pragma unroll
        for (int mi = 0; mi < 4; ++mi)
            #pragma unroll
            for (int ni = 0; ni < 2; ++ni) {
                acc1[mi][ni] = __builtin_amdgcn_mfma_f32_16x16x32_bf16(afh[mi], bfh[ni], acc1[mi][ni], 0, 0, 0);
                acc1[mi][ni] = __builtin_amdgcn_mfma_f32_16x16x32_bf16(afl[mi], bfh[ni], acc1[mi][ni], 0, 0, 0);
                acc1[mi][ni] = __builtin_amdgcn_mfma_f32_16x16x32_bf16(afh[mi], bfl[ni], acc1[mi][ni], 0, 0, 0);
            }
        __syncthreads();
    }

    // ---- write xp: LDS hi (overwrites staging; safe after final barrier) + global hi/lo ----
    #pragma unroll
    for (int mi = 0; mi < 4; ++mi) {
        #pragma unroll
        for (int ni = 0; ni < 2; ++ni) {
            int col = w * 32 + ni * 16 + lr;
            #pragma unroll
            for (int r = 0; r < 4; ++r) {
                int rl = mi * 16 + lg * 4 + r;
                float v = acc1[mi][ni][r];
                short hi = f2bf(v);
                xpH[rl * 136 + col] = hi;
                int row = row0 + rl;
                if (row < M) {
                    xph[(size_t)row * 128 + col] = hi;
                    xpl[(size_t)row * 128 + col] = f2bf(v - bf2f(hi));
                }
            }
        }
    }
    __syncthreads();

    // ---- phase 2: Y = xp_hi @ wbBT^T + colbias ----
    for (int ct = 0; ct < 8; ++ct) {
        f32x4 acc[4][2] = {};
        #pragma unroll
        for (int k = 0; k < 4; ++k) {
            bf16x8 bfr[2];
            #pragma unroll
            for (int ni = 0; ni < 2; ++ni) {
                int col = ct * 128 + w * 32 + ni * 16 + lr;
                bfr[ni] = *reinterpret_cast<const bf16x8*>(&wbBT[(size_t)col * 128 + k * 32 + lg * 8]);
            }
            bf16x8 ah[4];
            #pragma unroll
            for (int mi = 0; mi < 4; ++mi)
                ah[mi] = *reinterpret_cast<const bf16x8*>(&xpH[(mi * 16 + lr) * 136 + k * 32 + lg * 8]);
            #pragma unroll
            for (int mi = 0; mi < 4; ++mi)
                #pragma unroll
                for (int ni = 0; ni < 2; ++ni)
                    acc[mi][ni] = __builtin_amdgcn_mfma_f32_16x16x32_bf16(ah[mi], bfr[ni], acc[mi][ni], 0, 0, 0);
        }
        #pragma unroll
        for (int mi = 0; mi < 4; ++mi) {
            #pragma unroll
            for (int ni = 0; ni < 2; ++ni) {
                int col = ct * 128 + w * 32 + ni * 16 + lr;
                float bv = wl1[((col & 127) << 3) + (col >> 7)];
                #pragma unroll
                for (int r = 0; r < 4; ++r) {
                    int row = row0 + mi * 16 + lg * 4 + r;
                    if (row >= M) continue;
                    Y[(size_t)row * 1024 + col] = f2bf(acc[mi][ni][r] + bv);
                }
            }
        }
    }
}

// ========== rowdot8 ==========
template<int SPLITIN>
__global__ __launch_bounds__(256) void rowdot8(const short* __restrict__ Ah,
                                               const short* __restrict__ Al,
                                               const float* __restrict__ Wg,
                                               const float* __restrict__ bias8,
                                               float* __restrict__ out, int M) {
    __shared__ float sw[128][9];
    __shared__ float sb[8];
    for (int i = threadIdx.x; i < 1024; i += 256) sw[i >> 3][i & 7] = Wg[i];
    if (threadIdx.x < 8) sb[threadIdx.x] = bias8 ? bias8[threadIdx.x] : 0.f;
    __syncthreads();
    int r = blockIdx.x * 4 + (threadIdx.x >> 6);
    if (r >= M) return;
    int l = threadIdx.x & 63;
    int s = l & 7, c0 = (l >> 3) * 16;
    const short* ah = Ah + (size_t)r * 128 + c0;
    bf16x8 h0 = *reinterpret_cast<const bf16x8*>(ah);
    bf16x8 h1 = *reinterpret_cast<const bf16x8*>(ah + 8);
    float p = 0.f;
    if (SPLITIN) {
        const short* alr = Al + (size_t)r * 128 + c0;
        bf16x8 l0 = *reinterpret_cast<const bf16x8*>(alr);
        bf16x8 l1 = *reinterpret_cast<const bf16x8*>(alr + 8);
        #pragma unroll
        for (int j = 0; j < 8; ++j) {
            p += (bf2f(h0[j]) + bf2f(l0[j])) * sw[c0 + j][s];
            p += (bf2f(h1[j]) + bf2f(l1[j])) * sw[c0 + 8 + j][s];
        }
    } else {
        #pragma unroll
        for (int j = 0; j < 8; ++j) {
            p += bf2f(h0[j]) * sw[c0 + j][s];
            p += bf2f(h1[j]) * sw[c0 + 8 + j][s];
        }
    }
    p += __shfl_xor(p, 8); p += __shfl_xor(p, 16); p += __shfl_xor(p, 32);
    if (l < 8) out[(size_t)r * 8 + l] = p + sb[l];
}

// ========== fused edge kernel v2 ==========
__global__ __launch_bounds__(256) void edge_fused2(const short* __restrict__ xph,
                                                   const short* __restrict__ xpl,
                                                   const short* __restrict__ ep,
                                                   const short* __restrict__ Y,
                                                   const int* __restrict__ ei,
                                                   const float* __restrict__ u,
                                                   const float* __restrict__ v,
                                                   float* __restrict__ agg, int E) {
    int e = blockIdx.x * 4 + (threadIdx.x >> 6);
    if (e >= E) return;
    int l = threadIdx.x & 63;
    int s = l & 7, c0 = (l >> 3) * 16;
    int src = ei[e], dst = ei[E + e];
    const short* y  = Y + (size_t)src * 1024 + s * 128 + c0;
    const short* xih = xph + (size_t)dst * 128 + c0;
    const short* xil = xpl + (size_t)dst * 128 + c0;
    bf16x8 y0 = *reinterpret_cast<const bf16x8*>(y);
    bf16x8 y1 = *reinterpret_cast<const bf16x8*>(y + 8);
    bf16x8 a0 = *reinterpret_cast<const bf16x8*>(xih);
    bf16x8 a1 = *reinterpret_cast<const bf16x8*>(xih + 8);
    bf16x8 b0 = *reinterpret_cast<const bf16x8*>(xil);
    bf16x8 b1 = *reinterpret_cast<const bf16x8*>(xil + 8);
    float p = 0.f;
    #pragma unroll
    for (int j = 0; j < 8; ++j) {
        p += (bf2f(a0[j]) + bf2f(b0[j])) * bf2f(y0[j]);
        p += (bf2f(a1[j]) + bf2f(b1[j])) * bf2f(y1[j]);
    }
    p += __shfl_xor(p, 8); p += __shfl_xor(p, 16); p += __shfl_xor(p, 32);
    float alpha = tanhf(p + u[(size_t)src * 8 + s] + v[(size_t)e * 8 + s]);
    float aa0 = __shfl(alpha, l >> 4);
    float aa1 = __shfl(alpha, 4 + (l >> 4));
    float xj0 = bf2f(xph[(size_t)src * 128 + l]) + bf2f(xpl[(size_t)src * 128 + l]);
    float xj1 = bf2f(xph[(size_t)src * 128 + l + 64]) + bf2f(xpl[(size_t)src * 128 + l + 64]);
    float e0 = bf2f(ep[(size_t)e * 128 + l]);
    float e1 = bf2f(ep[(size_t)e * 128 + l + 64]);
    atomicAdd(&agg[(size_t)dst * 128 + l],      fmaxf(xj0, e0) * aa0);
    atomicAdd(&agg[(size_t)dst * 128 + l + 64], fmaxf(xj1, e1) * aa1);
}

// ========== gate GEMM (split-3, K=256 combined weights, in place) ==========
__global__ __launch_bounds__(256) void gate_gemm_split(float* __restrict__ h,
                                                       const float* __restrict__ aggv,
                                                       const short* __restrict__ BTh,
                                                       const short* __restrict__ BTl,
                                                       const float* __restrict__ gb,
                                                       int M) {
    __shared__ short Ah[128][40];
    __shared__ short Al[128][40];
    __shared__ short Bh[128][40];
    __shared__ short Bl[128][40];
    const int tid = threadIdx.x;
    const int row0 = blockIdx.y * 128;
    const int lane = tid & 63, w = tid >> 6;
    const int wr = w >> 1, wc = w & 1;
    const int lr = lane & 15, lg = lane >> 4;
    f32x4 acc[4][4] = {};

    for (int k0 = 0; k0 < 256; k0 += 32) {
        int sec = k0 >> 7;
        #pragma unroll
        for (int i = 0; i < 4; ++i) {
            int idx = i * 256 + tid;
            int r = idx >> 3, q = idx & 7;
            int gr = row0 + r;
            int ks = (k0 & 127) + q * 4;
            f32x4 v;
            if (gr < M) {
                if (sec == 0) {
                    v = *reinterpret_cast<const f32x4*>(&h[(size_t)gr * 128 + ks]);
                } else {
                    f32x4 a = *reinterpret_cast<const f32x4*>(&aggv[(size_t)gr * 128 + ks]);
                    #pragma unroll
                    for (int j = 0; j < 4; ++j) v[j] = fmaxf(a[j], 0.f);
                }
            } else {
                #pragma unroll
                for (int j = 0; j < 4; ++j) v[j] = 0.f;
            }
            short4v hh, ll;
            #pragma unroll
            for (int j = 0; j < 4; ++j) {
                hh[j] = f2bf(v[j]);
                ll[j] = f2bf(v[j] - bf2f(hh[j]));
            }
            *reinterpret_cast<short4v*>(&Ah[r][q * 4]) = hh;
            *reinterpret_cast<short4v*>(&Al[r][q * 4]) = ll;
        }
        #pragma unroll
        for (int i = 0; i < 4; ++i) {
            int idx = i * 256 + tid;
            int r = idx >> 3, q = idx & 7;
            short4v uu = *reinterpret_cast<const short4v*>(&BTh[(size_t)r * 256 + k0 + q * 4]);
            short4v ul = *reinterpret_cast<const short4v*>(&BTl[(size_t)r * 256 + k0 + q * 4]);
            *reinterpret_cast<short4v*>(&Bh[r][q * 4]) = uu;
            *reinterpret_cast<short4v*>(&Bl[r][q * 4]) = ul;
        }
        __syncthreads();
        bf16x8 afh[4], afl[4], bfh[4], bfl[4];
        #pragma unroll
        for (int mi = 0; mi < 4; ++mi) {
            afh[mi] = *reinterpret_cast<const bf16x8*>(&Ah[wr * 64 + mi * 16 + lr][lg * 8]);
            afl[mi] = *reinterpret_cast<const bf16x8*>(&Al[wr * 64 + mi * 16 + lr][lg * 8]);
        }
        #pragma unroll
        for (int ni = 0; ni < 4; ++ni) {
            bfh[ni] = *reinterpret_cast<const bf16x8*>(&Bh[wc * 64 + ni * 16 + lr][lg * 8]);
            bfl[ni] = *reinterpret_cast<const bf16x8*>(&Bl[wc * 64 + ni * 16 + lr][lg * 8]);
        }
        #pragma unroll
        for (int mi = 0; mi < 4; ++mi)
            #pragma unroll
            for (int ni = 0; ni < 4; ++ni) {
                acc[mi][ni] = __builtin_amdgcn_mfma_f32_16x16x32_bf16(afh[mi], bfh[ni], acc[mi][ni], 0, 0, 0);
                acc[mi][ni] = __builtin_amdgcn_mfma_f32_16x16x32_bf16(afl[mi], bfh[ni], acc[mi][ni], 0, 0, 0);
                acc[mi][ni] = __builtin_amdgcn_mfma_f32_16x16x32_bf16(afh[mi], bfl[ni], acc[mi][ni], 0, 0, 0);
            }
        __syncthreads();
    }

    #pragma unroll
    for (int mi = 0; mi < 4; ++mi) {
        #pragma unroll
        for (int ni = 0; ni < 4; ++ni) {
            int col = wc * 64 + ni * 16 + lr;
            float gbv = gb[col];
            #pragma unroll
            for (int r = 0; r < 4; ++r) {
                int row = row0 + wr * 64 + mi * 16 + lg * 4 + r;
                if (row >= M) continue;
                float beta = fmaxf(acc[mi][ni][r] + gbv, 0.f);
                float hv = h[(size_t)row * 128 + col];
                float hh = fmaxf(aggv[(size_t)row * 128 + col], 0.f);
                h[(size_t)row * 128 + col] = beta * hv + (1.f - beta) * hh;
            }
        }
    }
}

// ========== batch norm ==========
__global__ void bn_stats(const float* __restrict__ z, float* __restrict__ gsum,
                         float* __restrict__ gsq, int M) {
    int c = threadIdx.x & 127;
    int rr = threadIdx.x >> 7;
    float s = 0.f, q = 0.f;
    for (int r = blockIdx.x * 2 + rr; r < M; r += gridDim.x * 2) {
        float v = z[(size_t)r * 128 + c];
        s += v; q += v * v;
    }
    __shared__ float ls[256], lq[256];
    ls[threadIdx.x] = s; lq[threadIdx.x] = q;
    __syncthreads();
    if (threadIdx.x < 128) {
        atomicAdd(&gsum[c], ls[threadIdx.x] + ls[threadIdx.x + 128]);
        atomicAdd(&gsq[c],  lq[threadIdx.x] + lq[threadIdx.x + 128]);
    }
}

__global__ void bn_apply(float* __restrict__ z, const float* __restrict__ gsum,
                         const float* __restrict__ gsq, const float* __restrict__ g,
                         const float* __restrict__ b, int M) {
    size_t total = (size_t)M * 128;
    for (size_t idx = (size_t)blockIdx.x * 256 + threadIdx.x; idx < total;
         idx += (size_t)gridDim.x * 256) {
        int c = idx & 127;
        float mu = gsum[c] / (float)M;
        float var = gsq[c] / (float)M - mu * mu;
        float rs = rsqrtf(var + EPS);
        float v = (z[idx] - mu) * rs * g[c] + b[c];
        z[idx] = fmaxf(v, 0.f);
    }
}

__global__ void bn_stats_bf(const short* __restrict__ z, float* __restrict__ gsum,
                            float* __restrict__ gsq, int M) {
    int c = threadIdx.x & 127;
    int rr = threadIdx.x >> 7;
    float s = 0.f, q = 0.f;
    for (int r = blockIdx.x * 2 + rr; r < M; r += gridDim.x * 2) {
        float v = bf2f(z[(size_t)r * 128 + c]);
        s += v; q += v * v;
    }
    __shared__ float ls[256], lq[256];
    ls[threadIdx.x] = s; lq[threadIdx.x] = q;
    __syncthreads();
    if (threadIdx.x < 128) {
        atomicAdd(&gsum[c], ls[threadIdx.x] + ls[threadIdx.x + 128]);
        atomicAdd(&gsq[c],  lq[threadIdx.x] + lq[threadIdx.x + 128]);
    }
}

__global__ void bn_apply_bf(short* __restrict__ z, const float* __restrict__ gsum,
                            const float* __restrict__ gsq, const float* __restrict__ g,
                            const float* __restrict__ b, int M) {
    size_t total = (size_t)M * 128;
    for (size_t idx = (size_t)blockIdx.x * 256 + threadIdx.x; idx < total;
         idx += (size_t)gridDim.x * 256) {
        int c = idx & 127;
        float mu = gsum[c] / (float)M;
        float var = gsq[c] / (float)M - mu * mu;
        float rs = rsqrtf(var + EPS);
        float v = (bf2f(z[idx]) - mu) * rs * g[c] + b[c];
        z[idx] = f2bf(fmaxf(v, 0.f));
    }
}

// ========== prep ==========
__global__ void transpose_split(const float* __restrict__ in, short* __restrict__ outh,
                                short* __restrict__ outl, int K, int N) {
    int idx = blockIdx.x * 256 + threadIdx.x;
    if (idx >= K * N) return;
    int nI = idx / K, k = idx - nI * K;
    float v = in[(size_t)k * N + nI];
    short h = f2bf(v);
    outh[idx] = h;
    outl[idx] = f2bf(v - bf2f(h));
}

__global__ void cvt_f2b(const float* __restrict__ in, short* __restrict__ out, int n) {
    int i = blockIdx.x * 256 + threadIdx.x;
    if (i < n) out[i] = f2bf(in[i]);
}

__global__ void gate_combine_split(const float* __restrict__ gw, short* __restrict__ BTh,
                                   short* __restrict__ BTl) {
    int idx = blockIdx.x * 256 + threadIdx.x;
    if (idx >= 128 * 256) return;
    int n = idx >> 8, k = idx & 255;
    float v;
    if (k < 128) v = gw[(size_t)k * 128 + n] + gw[(size_t)(256 + k) * 128 + n];
    else {
        int kk = k - 128;
        v = gw[(size_t)(128 + kk) * 128 + n] - gw[(size_t)(256 + kk) * 128 + n];
    }
    short h = f2bf(v);
    BTh[idx] = h;
    BTl[idx] = f2bf(v - bf2f(h));
}

__global__ void build_wm(const float* __restrict__ wsrc, float* __restrict__ wm) {
    int idx = blockIdx.x * 256 + threadIdx.x;
    if (idx >= 128 * 128) return;
    int d = idx >> 7, c = idx & 127;
    float s = 0.f;
    #pragma unroll
    for (int h = 0; h < 8; ++h) s += wsrc[(size_t)d * 1024 + h * 128 + c];
    wm[idx] = s * 0.125f;
}

__global__ void perm_build(const int* __restrict__ ci, int* __restrict__ perm, int NF) {
    int i = blockIdx.x * 256 + threadIdx.x;
    if (i >= NF) return;
    int c = ci[i];
    if (i == 0 || ci[i - 1] != c) perm[c] = i;
}

__global__ void seg_pool(const float* __restrict__ fx, const int* __restrict__ perm,
                         float* __restrict__ pool, int F, int NF) {
    int idx = blockIdx.x * 256 + threadIdx.x;
    if (idx >= F * 128) return;
    int f = idx >> 7, c = idx & 127;
    int s = perm[f];
    int e = (f + 1 < F) ? perm[f + 1] : NF;
    float acc = 0.f;
    for (int i = s; i < e; ++i) acc += fx[(size_t)i * 128 + c];
    pool[idx] = fmaxf(acc, 0.f);
}

// ========== output ==========
__global__ __launch_bounds__(256) void out_phase1(const float* __restrict__ h,
                                                  const float* __restrict__ out_w,
                                                  const float* __restrict__ out_b,
                                                  const float* __restrict__ gat_bias,
                                                  float* __restrict__ out, int M) {
    int n = blockIdx.x * 4 + (threadIdx.x >> 6);
    if (n >= M) return;
    int l = threadIdx.x & 63;
    float p = fmaxf(h[(size_t)n * 128 + l], 0.f) * out_w[l]
            + fmaxf(h[(size_t)n * 128 + l + 64], 0.f) * out_w[l + 64];
    p += fmaxf(gat_bias[l], 0.f) * out_w[128 + l]
       + fmaxf(gat_bias[l + 64], 0.f) * out_w[128 + l + 64];
    #pragma unroll
    for (int off = 32; off; off >>= 1) p += __shfl_xor(p, off);
    if (l == 0) out[n] = p + out_b[0];
}

__global__ __launch_bounds__(256) void out_phase2(const float* __restrict__ fmv,
                                                  const int* __restrict__ perm,
                                                  const float* __restrict__ out_w,
                                                  const float* __restrict__ gat_bias,
                                                  float* __restrict__ out, int F) {
    int f = blockIdx.x * 4 + (threadIdx.x >> 6);
    if (f >= F) return;
    int l = threadIdx.x & 63;
    float p = fmv[(size_t)f * 128 + l] * out_w[128 + l]
            + fmv[(size_t)f * 128 + l + 64] * out_w[128 + l + 64];
    float b = fmaxf(gat_bias[l], 0.f) * out_w[128 + l]
            + fmaxf(gat_bias[l + 64], 0.f) * out_w[128 + l + 64];
    float d = p - b;
    #pragma unroll
    for (int off = 32; off; off >>= 1) d += __shfl_xor(d, off);
    if (l == 0) out[perm[f]] += d;
}

// ========== host ==========
extern "C" void kernel_launch(void* const* d_in, const int* in_sizes, int n_in,
                              void* d_out, int out_size, void* d_ws, size_t ws_size,
                              hipStream_t stream) {
    const int N = 50000, E = 100000, NF = 20000, EF = 40000, F = 10000;

    const float* x          = (const float*)d_in[0];
    const float* edge_attr  = (const float*)d_in[1];
    const float* frag_x     = (const float*)d_in[2];
    const float* frag_ea    = (const float*)d_in[3];
    const float* la_w = (const float*)d_in[4];
    const float* la_b = (const float*)d_in[5];
    const float* lb_w = (const float*)d_in[6];
    const float* lb_b = (const float*)d_in[7];
    const float* bn1_g = (const float*)d_in[8];
    const float* bn1_b = (const float*)d_in[9];
    const float* bn2_g = (const float*)d_in[10];
    const float* bn2_b = (const float*)d_in[11];
    const float* wn = (const float*)d_in[12];
    const float* wb = (const float*)d_in[13];
    const float* wl = (const float*)d_in[14];
    const float* wlb = (const float*)d_in[15];
    const float* gate_w = (const float*)d_in[16];
    const float* gate_b = (const float*)d_in[17];
    const float* gat_wsrc = (const float*)d_in[18];
    const float* gat_bias = (const float*)d_in[22];
    const float* out_w = (const float*)d_in[23];
    const float* out_b = (const float*)d_in[24];
    const int* edge_index = (const int*)d_in[25];
    const int* frag_edge_index = (const int*)d_in[26];
    const int* cluster_index = (const int*)d_in[27];

    char* p = (char*)d_ws;
    auto alloc = [&](size_t bytes) { char* r = p; p += (bytes + 255) & ~(size_t)255; return (void*)r; };
    float* hA    = (float*)alloc((size_t)N * 128 * 4);
    short* ea1   = (short*)alloc((size_t)E * 128 * 2);
    short* xph   = (short*)alloc((size_t)N * 128 * 2);
    short* xpl   = (short*)alloc((size_t)N * 128 * 2);
    short* ep    = (short*)alloc((size_t)E * 128 * 2);
    short* Y     = (short*)alloc((size_t)N * 1024 * 2);
    float* agg   = (float*)alloc((size_t)N * 128 * 4);
    float* ubuf  = (float*)alloc((size_t)N * 8 * 4);
    float* vbuf  = (float*)alloc((size_t)E * 8 * 4);
    short* la_wTh = (short*)alloc(128 * 128 * 2);
    short* la_wTl = (short*)alloc(128 * 128 * 2);
    short* lb_wTh = (short*)alloc(128 * 16 * 2);
    short* lb_wTl = (short*)alloc(128 * 16 * 2);
    short* wnTh   = (short*)alloc(3 * 128 * 128 * 2);
    short* wnTl   = (short*)alloc(3 * 128 * 128 * 2);
    short* wbH    = (short*)alloc(3 * 1024 * 128 * 2);
    short* gate2Th = (short*)alloc(128 * 256 * 2);
    short* gate2Tl = (short*)alloc(128 * 256 * 2);
    float* wmF    = (float*)alloc(128 * 128 * 4);
    short* wmTh   = (short*)alloc(128 * 128 * 2);
    short* wmTl   = (short*)alloc(128 * 128 * 2);
    float* stats  = (float*)alloc(256 * 4);
    char* yq = (char*)Y;
    float* fpool = (float*)yq;              yq += (size_t)F * 128 * 4;
    float* fmv   = (float*)yq;              yq += (size_t)F * 128 * 4;
    int*   perm  = (int*)yq;

    auto cdiv = [](int a, int b) { return (a + b - 1) / b; };

    // ---- weight prep ----
    transpose_split<<<cdiv(128 * 128, 256), 256, 0, stream>>>(la_w, la_wTh, la_wTl, 128, 128);
    transpose_split<<<cdiv(16 * 128, 256), 256, 0, stream>>>(lb_w, lb_wTh, lb_wTl, 16, 128);
    for (int l = 0; l < 3; ++l)
        transpose_split<<<cdiv(128 * 128, 256), 256, 0, stream>>>(
            wn + (size_t)l * 16384, wnTh + (size_t)l * 16384, wnTl + (size_t)l * 16384, 128, 128);
    cvt_f2b<<<cdiv(3 * 1024 * 128, 256), 256, 0, stream>>>(wb, wbH, 3 * 1024 * 128);
    gate_combine_split<<<cdiv(128 * 256, 256), 256, 0, stream>>>(gate_w, gate2Th, gate2Tl);
    build_wm<<<cdiv(128 * 128, 256), 256, 0, stream>>>(gat_wsrc, wmF);
    transpose_split<<<cdiv(128 * 128, 256), 256, 0, stream>>>(wmF, wmTh, wmTl, 128, 128);

    auto run_layer = [&](float* h, const short* ea_buf, const int* ei, int Mn, int Me, int layer) {
        const short* wnTh_l = wnTh + (size_t)layer * 16384;
        const short* wnTl_l = wnTl + (size_t)layer * 16384;
        const short* wb_l   = wbH + (size_t)layer * 131072;
        const float* wl_l   = wl + (size_t)layer * 384 * 8;
        const float* wlb_l  = wlb + (size_t)layer * 8;
        fused_xpy<<<cdiv(Mn, 64), 256, 0, stream>>>(h, wnTh_l, wnTl_l, wb_l, wl_l, xph, xpl, Y, Mn);
        gemm_bf16<0, 1><<<dim3(1, cdiv(Me, 128)), 256, 0, stream>>>(ea_buf, wnTh_l, nullptr, ep, Me, 128, 128);
        rowdot8<1><<<cdiv(Mn, 4), 256, 0, stream>>>(xph, xpl, wl_l + 256 * 8, wlb_l, ubuf, Mn);
        rowdot8<0><<<cdiv(Me, 4), 256, 0, stream>>>(ep, nullptr, wl_l + 128 * 8, nullptr, vbuf, Me);
        hipMemsetAsync(agg, 0, (size_t)Mn * 128 * 4, stream);
        edge_fused2<<<cdiv(Me, 4), 256, 0, stream>>>(xph, xpl, ep, Y, ei, ubuf, vbuf, agg, Me);
        gate_gemm_split<<<dim3(1, cdiv(Mn, 128)), 256, 0, stream>>>(h, agg, gate2Th, gate2Tl, gate_b, Mn);
    };

    // ---- atom path ----
    gemm_split<3, 0, 0><<<dim3(1, cdiv(N, 128)), 256, 0, stream>>>(x, la_wTh, la_wTl, la_b, hA, nullptr, N, 128, 128);
    hipMemsetAsync(stats, 0, 1024, stream);
    bn_stats<<<256, 256, 0, stream>>>(hA, stats, stats + 128, N);
    bn_apply<<<2048, 256, 0, stream>>>(hA, stats, stats + 128, bn1_g, bn1_b, N);

    gemm_split<3, 0, 1><<<dim3(1, cdiv(E, 128)), 256, 0, stream>>>(edge_attr, lb_wTh, lb_wTl, lb_b, ea1, nullptr, E, 128, 16);
    hipMemsetAsync(stats, 0, 1024, stream);
    bn_stats_bf<<<256, 256, 0, stream>>>(ea1, stats, stats + 128, E);
    bn_apply_bf<<<2048, 256, 0, stream>>>(ea1, stats, stats + 128, bn2_g, bn2_b, E);

    for (int l = 0; l < 3; ++l) run_layer(hA, ea1, edge_index, N, E, l);
    out_phase1<<<cdiv(N, 4), 256, 0, stream>>>(hA, out_w, out_b, gat_bias, (float*)d_out, N);

    // ---- fragment path ----
    gemm_split<3, 1, 0><<<dim3(1, cdiv(NF, 128)), 256, 0, stream>>>(frag_x, la_wTh, la_wTl, la_b, hA, nullptr, NF, 128, 128);

    gemm_split<3, 0, 1><<<dim3(1, cdiv(EF, 128)), 256, 0, stream>>>(frag_ea, lb_wTh, lb_wTl, lb_b, ea1, nullptr, EF, 128, 16);
    hipMemsetAsync(stats, 0, 1024, stream);
    bn_stats_bf<<<256, 256, 0, stream>>>(ea1, stats, stats + 128, EF);
    bn_apply_bf<<<2048, 256, 0, stream>>>(ea1, stats, stats + 128, bn2_g, bn2_b, EF);

    for (int l = 0; l < 3; ++l) run_layer(hA, ea1, frag_edge_index, NF, EF, l);

    perm_build<<<cdiv(NF, 256), 256, 0, stream>>>(cluster_index, perm, NF);
    seg_pool<<<cdiv(F * 128, 256), 256, 0, stream>>>(hA, perm, fpool, F, NF);
    gemm_split<3, 1, 0><<<dim3(1, cdiv(F, 128)), 256, 0, stream>>>(fpool, wmTh, wmTl, gat_bias, fmv, nullptr, F, 128, 128);
    out_phase2<<<cdiv(F, 4), 256, 0, stream>>>(fmv, perm, out_w, gat_bias, (float*)d_out, F);
}

// Round 10
// 1484.444 us; speedup vs baseline: 1.1498x; 1.1015x over previous
//
#include <hip/hip_runtime.h>
#include <hip/hip_bf16.h>

#define EPS 1e-5f

typedef short bf16x8 __attribute__((ext_vector_type(8)));
typedef short short4v __attribute__((ext_vector_type(4)));
typedef short short16v __attribute__((ext_vector_type(16)));
typedef float f32x4 __attribute__((ext_vector_type(4)));

static __device__ __forceinline__ short f2bf(float x) {
    __hip_bfloat16 h = __float2bfloat16(x);
    return *reinterpret_cast<short*>(&h);
}
static __device__ __forceinline__ float bf2f(short x) {
    __hip_bfloat16 h;
    *reinterpret_cast<short*>(&h) = x;
    return __bfloat162float(h);
}

// ========== split-bf16 MFMA GEMM: C = act(A[M,K](f32) @ BT[N,K]^T + bias) ==========
template<int SPLIT, int ACT, int OUTM>
__global__ __launch_bounds__(256) void gemm_split(const float* __restrict__ A,
                                                  const short* __restrict__ BTh,
                                                  const short* __restrict__ BTl,
                                                  const float* __restrict__ bias,
                                                  void* __restrict__ Cout,
                                                  void* __restrict__ Cout2,
                                                  int M, int N, int K) {
    __shared__ short Ah[128][40];
    __shared__ short Al[128][40];
    __shared__ short Bh[128][40];
    __shared__ short Bl[128][40];
    const int tid = threadIdx.x;
    const int row0 = blockIdx.y * 128, col0 = blockIdx.x * 128;
    const int lane = tid & 63, w = tid >> 6;
    const int wr = w >> 1, wc = w & 1;
    const int lr = lane & 15, lg = lane >> 4;
    f32x4 acc[4][4] = {};

    for (int k0 = 0; k0 < K; k0 += 32) {
        #pragma unroll
        for (int i = 0; i < 4; ++i) {
            int idx = i * 256 + tid;
            int r = idx >> 3, q = idx & 7;
            int gr = row0 + r, gk = k0 + q * 4;
            f32x4 v;
            if (gr < M && gk + 3 < K) {
                v = *reinterpret_cast<const f32x4*>(&A[(size_t)gr * K + gk]);
            } else {
                #pragma unroll
                for (int j = 0; j < 4; ++j)
                    v[j] = (gr < M && gk + j < K) ? A[(size_t)gr * K + gk + j] : 0.f;
            }
            short4v h, l;
            #pragma unroll
            for (int j = 0; j < 4; ++j) {
                h[j] = f2bf(v[j]);
                l[j] = f2bf(v[j] - bf2f(h[j]));
            }
            *reinterpret_cast<short4v*>(&Ah[r][q * 4]) = h;
            *reinterpret_cast<short4v*>(&Al[r][q * 4]) = l;
        }
        #pragma unroll
        for (int i = 0; i < 4; ++i) {
            int idx = i * 256 + tid;
            int r = idx >> 3, q = idx & 7;
            int gc = col0 + r, gk = k0 + q * 4;
            short4v u, ul;
            if (gk + 3 < K) {
                u = *reinterpret_cast<const short4v*>(&BTh[(size_t)gc * K + gk]);
                if (SPLIT == 3) ul = *reinterpret_cast<const short4v*>(&BTl[(size_t)gc * K + gk]);
            } else {
                #pragma unroll
                for (int j = 0; j < 4; ++j) {
                    u[j] = (gk + j < K) ? BTh[(size_t)gc * K + gk + j] : (short)0;
                    if (SPLIT == 3) ul[j] = (gk + j < K) ? BTl[(size_t)gc * K + gk + j] : (short)0;
                }
            }
            *reinterpret_cast<short4v*>(&Bh[r][q * 4]) = u;
            if (SPLIT == 3) *reinterpret_cast<short4v*>(&Bl[r][q * 4]) = ul;
        }
        __syncthreads();
        bf16x8 afh[4], afl[4], bfh[4];
        #pragma unroll
        for (int mi = 0; mi < 4; ++mi) {
            afh[mi] = *reinterpret_cast<const bf16x8*>(&Ah[wr * 64 + mi * 16 + lr][lg * 8]);
            afl[mi] = *reinterpret_cast<const bf16x8*>(&Al[wr * 64 + mi * 16 + lr][lg * 8]);
        }
        #pragma unroll
        for (int ni = 0; ni < 4; ++ni)
            bfh[ni] = *reinterpret_cast<const bf16x8*>(&Bh[wc * 64 + ni * 16 + lr][lg * 8]);
        #pragma unroll
        for (int mi = 0; mi < 4; ++mi)
            #pragma unroll
            for (int ni = 0; ni < 4; ++ni) {
                acc[mi][ni] = __builtin_amdgcn_mfma_f32_16x16x32_bf16(afh[mi], bfh[ni], acc[mi][ni], 0, 0, 0);
                acc[mi][ni] = __builtin_amdgcn_mfma_f32_16x16x32_bf16(afl[mi], bfh[ni], acc[mi][ni], 0, 0, 0);
            }
        if (SPLIT == 3) {
            bf16x8 bfl[4];
            #pragma unroll
            for (int ni = 0; ni < 4; ++ni)
                bfl[ni] = *reinterpret_cast<const bf16x8*>(&Bl[wc * 64 + ni * 16 + lr][lg * 8]);
            #pragma unroll
            for (int mi = 0; mi < 4; ++mi)
                #pragma unroll
                for (int ni = 0; ni < 4; ++ni)
                    acc[mi][ni] = __builtin_amdgcn_mfma_f32_16x16x32_bf16(afh[mi], bfl[ni], acc[mi][ni], 0, 0, 0);
        }
        __syncthreads();
    }

    #pragma unroll
    for (int mi = 0; mi < 4; ++mi) {
        #pragma unroll
        for (int ni = 0; ni < 4; ++ni) {
            int col = col0 + wc * 64 + ni * 16 + lr;
            float bv = bias ? bias[col] : 0.f;
            #pragma unroll
            for (int r = 0; r < 4; ++r) {
                int row = row0 + wr * 64 + mi * 16 + lg * 4 + r;
                if (row >= M) continue;
                float v = acc[mi][ni][r] + bv;
                if (ACT) v = fmaxf(v, 0.f);
                if (OUTM == 0) ((float*)Cout)[(size_t)row * N + col] = v;
                else ((short*)Cout)[(size_t)row * N + col] = f2bf(v);
            }
        }
    }
}

// ========== plain bf16 GEMM (tolerant path: ep projection) ==========
template<int ACT, int OUTBF>
__global__ __launch_bounds__(256) void gemm_bf16(const short* __restrict__ A,
                                                 const short* __restrict__ BT,
                                                 const float* __restrict__ bias,
                                                 void* __restrict__ Cout,
                                                 int M, int N, int K) {
    __shared__ short As[128][40];
    __shared__ short Bs[128][40];
    const int tid = threadIdx.x;
    const int row0 = blockIdx.y * 128, col0 = blockIdx.x * 128;
    const int lane = tid & 63, w = tid >> 6;
    const int wr = w >> 1, wc = w & 1;
    const int lr = lane & 15, lg = lane >> 4;
    f32x4 acc[4][4] = {};

    for (int k0 = 0; k0 < K; k0 += 32) {
        #pragma unroll
        for (int i = 0; i < 4; ++i) {
            int idx = i * 256 + tid;
            int r = idx >> 3, q = idx & 7;
            int gk = k0 + q * 4;
            int gr = row0 + r;
            short4v v;
            if (gr < M && gk + 3 < K) {
                v = *reinterpret_cast<const short4v*>(&A[(size_t)gr * K + gk]);
            } else {
                #pragma unroll
                for (int j = 0; j < 4; ++j)
                    v[j] = (gr < M && gk + j < K) ? A[(size_t)gr * K + gk + j] : (short)0;
            }
            *reinterpret_cast<short4v*>(&As[r][q * 4]) = v;
            int gc = col0 + r;
            short4v u;
            if (gc < N && gk + 3 < K) {
                u = *reinterpret_cast<const short4v*>(&BT[(size_t)gc * K + gk]);
            } else {
                #pragma unroll
                for (int j = 0; j < 4; ++j)
                    u[j] = (gc < N && gk + j < K) ? BT[(size_t)gc * K + gk + j] : (short)0;
            }
            *reinterpret_cast<short4v*>(&Bs[r][q * 4]) = u;
        }
        __syncthreads();
        bf16x8 af[4], bfr[4];
        #pragma unroll
        for (int mi = 0; mi < 4; ++mi)
            af[mi] = *reinterpret_cast<const bf16x8*>(&As[wr * 64 + mi * 16 + lr][lg * 8]);
        #pragma unroll
        for (int ni = 0; ni < 4; ++ni)
            bfr[ni] = *reinterpret_cast<const bf16x8*>(&Bs[wc * 64 + ni * 16 + lr][lg * 8]);
        #pragma unroll
        for (int mi = 0; mi < 4; ++mi)
            #pragma unroll
            for (int ni = 0; ni < 4; ++ni)
                acc[mi][ni] = __builtin_amdgcn_mfma_f32_16x16x32_bf16(af[mi], bfr[ni], acc[mi][ni], 0, 0, 0);
        __syncthreads();
    }

    #pragma unroll
    for (int mi = 0; mi < 4; ++mi) {
        #pragma unroll
        for (int ni = 0; ni < 4; ++ni) {
            int col = col0 + wc * 64 + ni * 16 + lr;
            float bv = bias ? bias[col] : 0.f;
            #pragma unroll
            for (int r = 0; r < 4; ++r) {
                int row = row0 + wr * 64 + mi * 16 + lg * 4 + r;
                if (row >= M) continue;
                float v = acc[mi][ni][r] + bv;
                if (ACT) v = fmaxf(v, 0.f);
                if (OUTBF) ((short*)Cout)[(size_t)row * N + col] = f2bf(v);
                else       ((float*)Cout)[(size_t)row * N + col] = v;
            }
        }
    }
}

// ========== fused xp + Y kernel v4: 64-row tiles, 4 waves, coalesced stores ==========
// Phase 1: xp[64,128] = h @ wnT (split-3) -> global packed hi|lo (int) + LDS hi.
// u[64,8] = xp_hi . wl2 + wlb  (from LDS).
// Phase 2: Y[64,1024] = xp_hi @ wbBT^T + wl1 colbias, bounced through LDS for
// fully-coalesced 16B stores.
__global__ __launch_bounds__(256) void fused_xpy(const float* __restrict__ h,
                                                 const short* __restrict__ wnTh,
                                                 const short* __restrict__ wnTl,
                                                 const short* __restrict__ wbBT,
                                                 const float* __restrict__ wl1,
                                                 const float* __restrict__ wl2,
                                                 const float* __restrict__ wlb,
                                                 int* __restrict__ xphl,
                                                 float* __restrict__ ubuf,
                                                 short* __restrict__ Y, int M) {
    __shared__ short sbuf[15360];
    __shared__ short ybounce[64 * 136];
    short* Ah = sbuf;                 // 64 x 40
    short* Al = sbuf + 2560;
    short* Bh = sbuf + 5120;          // 128 x 40
    short* Bl = sbuf + 10240;
    short* xpH = sbuf;                // 64 x 136 (aliases staging after final phase-1 barrier)

    const int tid = threadIdx.x;
    const int row0 = blockIdx.x * 64;
    const int lane = tid & 63, w = tid >> 6;
    const int lr = lane & 15, lg = lane >> 4;

    // ---- phase 1 ----
    f32x4 acc1[4][2] = {};
    for (int k0 = 0; k0 < 128; k0 += 32) {
        #pragma unroll
        for (int i = 0; i < 2; ++i) {
            int idx = i * 256 + tid;
            int r = idx >> 3, q = idx & 7;
            int gr = row0 + r, gk = k0 + q * 4;
            f32x4 v;
            if (gr < M) {
                v = *reinterpret_cast<const f32x4*>(&h[(size_t)gr * 128 + gk]);
            } else {
                #pragma unroll
                for (int j = 0; j < 4; ++j) v[j] = 0.f;
            }
            short4v hh, ll;
            #pragma unroll
            for (int j = 0; j < 4; ++j) {
                hh[j] = f2bf(v[j]);
                ll[j] = f2bf(v[j] - bf2f(hh[j]));
            }
            *reinterpret_cast<short4v*>(&Ah[r * 40 + q * 4]) = hh;
            *reinterpret_cast<short4v*>(&Al[r * 40 + q * 4]) = ll;
        }
        #pragma unroll
        for (int i = 0; i < 4; ++i) {
            int idx = i * 256 + tid;
            int r = idx >> 3, q = idx & 7;
            int gk = k0 + q * 4;
            short4v bh = *reinterpret_cast<const short4v*>(&wnTh[(size_t)r * 128 + gk]);
            short4v bl = *reinterpret_cast<const short4v*>(&wnTl[(size_t)r * 128 + gk]);
            *reinterpret_cast<short4v*>(&Bh[r * 40 + q * 4]) = bh;
            *reinterpret_cast<short4v*>(&Bl[r * 40 + q * 4]) = bl;
        }
        __syncthreads();
        bf16x8 afh[4], afl[4], bfh[2], bfl[2];
        #pragma unroll
        for (int mi = 0; mi < 4; ++mi) {
            afh[mi] = *reinterpret_cast<const bf16x8*>(&Ah[(mi * 16 + lr) * 40 + lg * 8]);
            afl[mi] = *reinterpret_cast<const bf16x8*>(&Al[(mi * 16 + lr) * 40 + lg * 8]);
        }
        #pragma unroll
        for (int ni = 0; ni < 2; ++ni) {
            bfh[ni] = *reinterpret_cast<const bf16x8*>(&Bh[(w * 32 + ni * 16 + lr) * 40 + lg * 8]);
            bfl[ni] = *reinterpret_cast<const bf16x8*>(&Bl[(w * 32 + ni * 16 + lr) * 40 + lg * 8]);
        }
        #pragma unroll
        for (int mi = 0; mi < 4; ++mi)
            #pragma unroll
            for (int ni = 0; ni < 2; ++ni) {
                acc1[mi][ni] = __builtin_amdgcn_mfma_f32_16x16x32_bf16(afh[mi], bfh[ni], acc1[mi][ni], 0, 0, 0);
                acc1[mi][ni] = __builtin_amdgcn_mfma_f32_16x16x32_bf16(afl[mi], bfh[ni], acc1[mi][ni], 0, 0, 0);
                acc1[mi][ni] = __builtin_amdgcn_mfma_f32_16x16x32_bf16(afh[mi], bfl[ni], acc1[mi][ni], 0, 0, 0);
            }
        __syncthreads();
    }

    // ---- write xp: LDS hi + global packed {hi,lo} int (64B segments) ----
    #pragma unroll
    for (int mi = 0; mi < 4; ++mi) {
        #pragma unroll
        for (int ni = 0; ni < 2; ++ni) {
            int col = w * 32 + ni * 16 + lr;
            #pragma unroll
            for (int r = 0; r < 4; ++r) {
                int rl = mi * 16 + lg * 4 + r;
                float v = acc1[mi][ni][r];
                short hi = f2bf(v);
                short lo = f2bf(v - bf2f(hi));
                xpH[rl * 136 + col] = hi;
                int row = row0 + rl;
                if (row < M)
                    xphl[(size_t)row * 128 + col] =
                        ((int)(unsigned short)lo << 16) | (unsigned short)hi;
            }
        }
    }
    __syncthreads();

    // ---- u = xp_hi . wl2 + wlb ----
    #pragma unroll
    for (int o = tid; o < 512; o += 256) {
        int rl = o >> 3, s = o & 7;
        int row = row0 + rl;
        if (row < M) {
            float p = wlb[s];
            for (int c = 0; c < 128; ++c)
                p += bf2f(xpH[rl * 136 + c]) * wl2[c * 8 + s];
            ubuf[(size_t)row * 8 + s] = p;
        }
    }

    // ---- phase 2: Y = xp_hi @ wbBT^T + wl1 colbias, via LDS bounce ----
    for (int ct = 0; ct < 8; ++ct) {
        f32x4 acc[4][2] = {};
        #pragma unroll
        for (int k = 0; k < 4; ++k) {
            bf16x8 bfr[2];
            #pragma unroll
            for (int ni = 0; ni < 2; ++ni) {
                int col = ct * 128 + w * 32 + ni * 16 + lr;
                bfr[ni] = *reinterpret_cast<const bf16x8*>(&wbBT[(size_t)col * 128 + k * 32 + lg * 8]);
            }
            bf16x8 ah[4];
            #pragma unroll
            for (int mi = 0; mi < 4; ++mi)
                ah[mi] = *reinterpret_cast<const bf16x8*>(&xpH[(mi * 16 + lr) * 136 + k * 32 + lg * 8]);
            #pragma unroll
            for (int mi = 0; mi < 4; ++mi)
                #pragma unroll
                for (int ni = 0; ni < 2; ++ni)
                    acc[mi][ni] = __builtin_amdgcn_mfma_f32_16x16x32_bf16(ah[mi], bfr[ni], acc[mi][ni], 0, 0, 0);
        }
        // bounce acc (+bias) into LDS
        #pragma unroll
        for (int ni = 0; ni < 2; ++ni) {
            int loc = w * 32 + ni * 16 + lr;
            float bv = wl1[loc * 8 + ct];
            #pragma unroll
            for (int mi = 0; mi < 4; ++mi)
                #pragma unroll
                for (int r = 0; r < 4; ++r) {
                    int rl = mi * 16 + lg * 4 + r;
                    ybounce[rl * 136 + loc] = f2bf(acc[mi][ni][r] + bv);
                }
        }
        __syncthreads();
        // coalesced store: 16KB tile, 256 threads x 4 passes x 16B
        #pragma unroll
        for (int pass = 0; pass < 4; ++pass) {
            int flat = pass * 4096 + tid * 16;          // byte offset in tile
            int rl = flat >> 8;                          // 256B per row
            int cs = (flat & 255) >> 1;                  // short offset in row
            int row = row0 + rl;
            if (row < M) {
                bf16x8 v = *reinterpret_cast<const bf16x8*>(&ybounce[rl * 136 + cs]);
                *reinterpret_cast<bf16x8*>(&Y[(size_t)row * 1024 + ct * 128 + cs]) = v;
            }
        }
        __syncthreads();
    }
}

// ========== rowdot8 (v only) ==========
template<int SPLITIN>
__global__ __launch_bounds__(256) void rowdot8(const short* __restrict__ Ah,
                                               const short* __restrict__ Al,
                                               const float* __restrict__ Wg,
                                               const float* __restrict__ bias8,
                                               float* __restrict__ out, int M) {
    __shared__ float sw[128][9];
    __shared__ float sb[8];
    for (int i = threadIdx.x; i < 1024; i += 256) sw[i >> 3][i & 7] = Wg[i];
    if (threadIdx.x < 8) sb[threadIdx.x] = bias8 ? bias8[threadIdx.x] : 0.f;
    __syncthreads();
    int r = blockIdx.x * 4 + (threadIdx.x >> 6);
    if (r >= M) return;
    int l = threadIdx.x & 63;
    int s = l & 7, c0 = (l >> 3) * 16;
    const short* ah = Ah + (size_t)r * 128 + c0;
    bf16x8 h0 = *reinterpret_cast<const bf16x8*>(ah);
    bf16x8 h1 = *reinterpret_cast<const bf16x8*>(ah + 8);
    float p = 0.f;
    #pragma unroll
    for (int j = 0; j < 8; ++j) {
        p += bf2f(h0[j]) * sw[c0 + j][s];
        p += bf2f(h1[j]) * sw[c0 + 8 + j][s];
    }
    p += __shfl_xor(p, 8); p += __shfl_xor(p, 16); p += __shfl_xor(p, 32);
    if (l < 8) out[(size_t)r * 8 + l] = p + sb[l];
}

// ========== fused edge kernel v3 (packed xp) ==========
__global__ __launch_bounds__(256) void edge_fused2(const int* __restrict__ xphl,
                                                   const short* __restrict__ ep,
                                                   const short* __restrict__ Y,
                                                   const int* __restrict__ ei,
                                                   const float* __restrict__ u,
                                                   const float* __restrict__ v,
                                                   float* __restrict__ agg, int E) {
    int e = blockIdx.x * 4 + (threadIdx.x >> 6);
    if (e >= E) return;
    int l = threadIdx.x & 63;
    int s = l & 7, c0 = (l >> 3) * 16;
    int src = ei[e], dst = ei[E + e];
    const short* y = Y + (size_t)src * 1024 + s * 128 + c0;
    bf16x8 y0 = *reinterpret_cast<const bf16x8*>(y);
    bf16x8 y1 = *reinterpret_cast<const bf16x8*>(y + 8);
    const short* xi = (const short*)(xphl + (size_t)dst * 128 + c0);
    short16v xv0 = *reinterpret_cast<const short16v*>(xi);        // pairs c0..c0+7
    short16v xv1 = *reinterpret_cast<const short16v*>(xi + 16);   // pairs c0+8..c0+15
    float p = 0.f;
    #pragma unroll
    for (int j = 0; j < 8; ++j) {
        p += (bf2f(xv0[2 * j]) + bf2f(xv0[2 * j + 1])) * bf2f(y0[j]);
        p += (bf2f(xv1[2 * j]) + bf2f(xv1[2 * j + 1])) * bf2f(y1[j]);
    }
    p += __shfl_xor(p, 8); p += __shfl_xor(p, 16); p += __shfl_xor(p, 32);
    float alpha = tanhf(p + u[(size_t)src * 8 + s] + v[(size_t)e * 8 + s]);
    float aa0 = __shfl(alpha, l >> 4);
    float aa1 = __shfl(alpha, 4 + (l >> 4));
    int pj0 = xphl[(size_t)src * 128 + l];
    int pj1 = xphl[(size_t)src * 128 + l + 64];
    float xj0 = bf2f((short)(pj0 & 0xffff)) + bf2f((short)(pj0 >> 16));
    float xj1 = bf2f((short)(pj1 & 0xffff)) + bf2f((short)(pj1 >> 16));
    float e0 = bf2f(ep[(size_t)e * 128 + l]);
    float e1 = bf2f(ep[(size_t)e * 128 + l + 64]);
    atomicAdd(&agg[(size_t)dst * 128 + l],      fmaxf(xj0, e0) * aa0);
    atomicAdd(&agg[(size_t)dst * 128 + l + 64], fmaxf(xj1, e1) * aa1);
}

// ========== gate GEMM (split-3, K=256 combined weights, in place) ==========
__global__ __launch_bounds__(256) void gate_gemm_split(float* __restrict__ h,
                                                       const float* __restrict__ aggv,
                                                       const short* __restrict__ BTh,
                                                       const short* __restrict__ BTl,
                                                       const float* __restrict__ gb,
                                                       int M) {
    __shared__ short Ah[128][40];
    __shared__ short Al[128][40];
    __shared__ short Bh[128][40];
    __shared__ short Bl[128][40];
    const int tid = threadIdx.x;
    const int row0 = blockIdx.y * 128;
    const int lane = tid & 63, w = tid >> 6;
    const int wr = w >> 1, wc = w & 1;
    const int lr = lane & 15, lg = lane >> 4;
    f32x4 acc[4][4] = {};

    for (int k0 = 0; k0 < 256; k0 += 32) {
        int sec = k0 >> 7;
        #pragma unroll
        for (int i = 0; i < 4; ++i) {
            int idx = i * 256 + tid;
            int r = idx >> 3, q = idx & 7;
            int gr = row0 + r;
            int ks = (k0 & 127) + q * 4;
            f32x4 v;
            if (gr < M) {
                if (sec == 0) {
                    v = *reinterpret_cast<const f32x4*>(&h[(size_t)gr * 128 + ks]);
                } else {
                    f32x4 a = *reinterpret_cast<const f32x4*>(&aggv[(size_t)gr * 128 + ks]);
                    #pragma unroll
                    for (int j = 0; j < 4; ++j) v[j] = fmaxf(a[j], 0.f);
                }
            } else {
                #pragma unroll
                for (int j = 0; j < 4; ++j) v[j] = 0.f;
            }
            short4v hh, ll;
            #pragma unroll
            for (int j = 0; j < 4; ++j) {
                hh[j] = f2bf(v[j]);
                ll[j] = f2bf(v[j] - bf2f(hh[j]));
            }
            *reinterpret_cast<short4v*>(&Ah[r][q * 4]) = hh;
            *reinterpret_cast<short4v*>(&Al[r][q * 4]) = ll;
        }
        #pragma unroll
        for (int i = 0; i < 4; ++i) {
            int idx = i * 256 + tid;
            int r = idx >> 3, q = idx & 7;
            short4v uu = *reinterpret_cast<const short4v*>(&BTh[(size_t)r * 256 + k0 + q * 4]);
            short4v ul = *reinterpret_cast<const short4v*>(&BTl[(size_t)r * 256 + k0 + q * 4]);
            *reinterpret_cast<short4v*>(&Bh[r][q * 4]) = uu;
            *reinterpret_cast<short4v*>(&Bl[r][q * 4]) = ul;
        }
        __syncthreads();
        bf16x8 afh[4], afl[4], bfh[4], bfl[4];
        #pragma unroll
        for (int mi = 0; mi < 4; ++mi) {
            afh[mi] = *reinterpret_cast<const bf16x8*>(&Ah[wr * 64 + mi * 16 + lr][lg * 8]);
            afl[mi] = *reinterpret_cast<const bf16x8*>(&Al[wr * 64 + mi * 16 + lr][lg * 8]);
        }
        #pragma unroll
        for (int ni = 0; ni < 4; ++ni) {
            bfh[ni] = *reinterpret_cast<const bf16x8*>(&Bh[wc * 64 + ni * 16 + lr][lg * 8]);
            bfl[ni] = *reinterpret_cast<const bf16x8*>(&Bl[wc * 64 + ni * 16 + lr][lg * 8]);
        }
        #pragma unroll
        for (int mi = 0; mi < 4; ++mi)
            #pragma unroll
            for (int ni = 0; ni < 4; ++ni) {
                acc[mi][ni] = __builtin_amdgcn_mfma_f32_16x16x32_bf16(afh[mi], bfh[ni], acc[mi][ni], 0, 0, 0);
                acc[mi][ni] = __builtin_amdgcn_mfma_f32_16x16x32_bf16(afl[mi], bfh[ni], acc[mi][ni], 0, 0, 0);
                acc[mi][ni] = __builtin_amdgcn_mfma_f32_16x16x32_bf16(afh[mi], bfl[ni], acc[mi][ni], 0, 0, 0);
            }
        __syncthreads();
    }

    #pragma unroll
    for (int mi = 0; mi < 4; ++mi) {
        #pragma unroll
        for (int ni = 0; ni < 4; ++ni) {
            int col = wc * 64 + ni * 16 + lr;
            float gbv = gb[col];
            #pragma unroll
            for (int r = 0; r < 4; ++r) {
                int row = row0 + wr * 64 + mi * 16 + lg * 4 + r;
                if (row >= M) continue;
                float beta = fmaxf(acc[mi][ni][r] + gbv, 0.f);
                float hv = h[(size_t)row * 128 + col];
                float hh = fmaxf(aggv[(size_t)row * 128 + col], 0.f);
                h[(size_t)row * 128 + col] = beta * hv + (1.f - beta) * hh;
            }
        }
    }
}

// ========== batch norm ==========
__global__ void bn_stats(const float* __restrict__ z, float* __restrict__ gsum,
                         float* __restrict__ gsq, int M) {
    int c = threadIdx.x & 127;
    int rr = threadIdx.x >> 7;
    float s = 0.f, q = 0.f;
    for (int r = blockIdx.x * 2 + rr; r < M; r += gridDim.x * 2) {
        float v = z[(size_t)r * 128 + c];
        s += v; q += v * v;
    }
    __shared__ float ls[256], lq[256];
    ls[threadIdx.x] = s; lq[threadIdx.x] = q;
    __syncthreads();
    if (threadIdx.x < 128) {
        atomicAdd(&gsum[c], ls[threadIdx.x] + ls[threadIdx.x + 128]);
        atomicAdd(&gsq[c],  lq[threadIdx.x] + lq[threadIdx.x + 128]);
    }
}

__global__ void bn_apply(float* __restrict__ z, const float* __restrict__ gsum,
                         const float* __restrict__ gsq, const float* __restrict__ g,
                         const float* __restrict__ b, int M) {
    size_t total = (size_t)M * 128;
    for (size_t idx = (size_t)blockIdx.x * 256 + threadIdx.x; idx < total;
         idx += (size_t)gridDim.x * 256) {
        int c = idx & 127;
        float mu = gsum[c] / (float)M;
        float var = gsq[c] / (float)M - mu * mu;
        float rs = rsqrtf(var + EPS);
        float v = (z[idx] - mu) * rs * g[c] + b[c];
        z[idx] = fmaxf(v, 0.f);
    }
}

__global__ void bn_stats_bf(const short* __restrict__ z, float* __restrict__ gsum,
                            float* __restrict__ gsq, int M) {
    int c = threadIdx.x & 127;
    int rr = threadIdx.x >> 7;
    float s = 0.f, q = 0.f;
    for (int r = blockIdx.x * 2 + rr; r < M; r += gridDim.x * 2) {
        float v = bf2f(z[(size_t)r * 128 + c]);
        s += v; q += v * v;
    }
    __shared__ float ls[256], lq[256];
    ls[threadIdx.x] = s; lq[threadIdx.x] = q;
    __syncthreads();
    if (threadIdx.x < 128) {
        atomicAdd(&gsum[c], ls[threadIdx.x] + ls[threadIdx.x + 128]);
        atomicAdd(&gsq[c],  lq[threadIdx.x] + lq[threadIdx.x + 128]);
    }
}

__global__ void bn_apply_bf(short* __restrict__ z, const float* __restrict__ gsum,
                            const float* __restrict__ gsq, const float* __restrict__ g,
                            const float* __restrict__ b, int M) {
    size_t total = (size_t)M * 128;
    for (size_t idx = (size_t)blockIdx.x * 256 + threadIdx.x; idx < total;
         idx += (size_t)gridDim.x * 256) {
        int c = idx & 127;
        float mu = gsum[c] / (float)M;
        float var = gsq[c] / (float)M - mu * mu;
        float rs = rsqrtf(var + EPS);
        float v = (bf2f(z[idx]) - mu) * rs * g[c] + b[c];
        z[idx] = f2bf(fmaxf(v, 0.f));
    }
}

// ========== prep ==========
__global__ void transpose_split(const float* __restrict__ in, short* __restrict__ outh,
                                short* __restrict__ outl, int K, int N) {
    int idx = blockIdx.x * 256 + threadIdx.x;
    if (idx >= K * N) return;
    int nI = idx / K, k = idx - nI * K;
    float v = in[(size_t)k * N + nI];
    short h = f2bf(v);
    outh[idx] = h;
    outl[idx] = f2bf(v - bf2f(h));
}

__global__ void cvt_f2b(const float* __restrict__ in, short* __restrict__ out, int n) {
    int i = blockIdx.x * 256 + threadIdx.x;
    if (i < n) out[i] = f2bf(in[i]);
}

__global__ void gate_combine_split(const float* __restrict__ gw, short* __restrict__ BTh,
                                   short* __restrict__ BTl) {
    int idx = blockIdx.x * 256 + threadIdx.x;
    if (idx >= 128 * 256) return;
    int n = idx >> 8, k = idx & 255;
    float v;
    if (k < 128) v = gw[(size_t)k * 128 + n] + gw[(size_t)(256 + k) * 128 + n];
    else {
        int kk = k - 128;
        v = gw[(size_t)(128 + kk) * 128 + n] - gw[(size_t)(256 + kk) * 128 + n];
    }
    short h = f2bf(v);
    BTh[idx] = h;
    BTl[idx] = f2bf(v - bf2f(h));
}

__global__ void build_wm(const float* __restrict__ wsrc, float* __restrict__ wm) {
    int idx = blockIdx.x * 256 + threadIdx.x;
    if (idx >= 128 * 128) return;
    int d = idx >> 7, c = idx & 127;
    float s = 0.f;
    #pragma unroll
    for (int h = 0; h < 8; ++h) s += wsrc[(size_t)d * 1024 + h * 128 + c];
    wm[idx] = s * 0.125f;
}

__global__ void perm_build(const int* __restrict__ ci, int* __restrict__ perm, int NF) {
    int i = blockIdx.x * 256 + threadIdx.x;
    if (i >= NF) return;
    int c = ci[i];
    if (i == 0 || ci[i - 1] != c) perm[c] = i;
}

__global__ void seg_pool(const float* __restrict__ fx, const int* __restrict__ perm,
                         float* __restrict__ pool, int F, int NF) {
    int idx = blockIdx.x * 256 + threadIdx.x;
    if (idx >= F * 128) return;
    int f = idx >> 7, c = idx & 127;
    int s = perm[f];
    int e = (f + 1 < F) ? perm[f + 1] : NF;
    float acc = 0.f;
    for (int i = s; i < e; ++i) acc += fx[(size_t)i * 128 + c];
    pool[idx] = fmaxf(acc, 0.f);
}

// ========== output ==========
__global__ __launch_bounds__(256) void out_phase1(const float* __restrict__ h,
                                                  const float* __restrict__ out_w,
                                                  const float* __restrict__ out_b,
                                                  const float* __restrict__ gat_bias,
                                                  float* __restrict__ out, int M) {
    int n = blockIdx.x * 4 + (threadIdx.x >> 6);
    if (n >= M) return;
    int l = threadIdx.x & 63;
    float p = fmaxf(h[(size_t)n * 128 + l], 0.f) * out_w[l]
            + fmaxf(h[(size_t)n * 128 + l + 64], 0.f) * out_w[l + 64];
    p += fmaxf(gat_bias[l], 0.f) * out_w[128 + l]
       + fmaxf(gat_bias[l + 64], 0.f) * out_w[128 + l + 64];
    #pragma unroll
    for (int off = 32; off; off >>= 1) p += __shfl_xor(p, off);
    if (l == 0) out[n] = p + out_b[0];
}

__global__ __launch_bounds__(256) void out_phase2(const float* __restrict__ fmv,
                                                  const int* __restrict__ perm,
                                                  const float* __restrict__ out_w,
                                                  const float* __restrict__ gat_bias,
                                                  float* __restrict__ out, int F) {
    int f = blockIdx.x * 4 + (threadIdx.x >> 6);
    if (f >= F) return;
    int l = threadIdx.x & 63;
    float p = fmv[(size_t)f * 128 + l] * out_w[128 + l]
            + fmv[(size_t)f * 128 + l + 64] * out_w[128 + l + 64];
    float b = fmaxf(gat_bias[l], 0.f) * out_w[128 + l]
            + fmaxf(gat_bias[l + 64], 0.f) * out_w[128 + l + 64];
    float d = p - b;
    #pragma unroll
    for (int off = 32; off; off >>= 1) d += __shfl_xor(d, off);
    if (l == 0) out[perm[f]] += d;
}

// ========== host ==========
extern "C" void kernel_launch(void* const* d_in, const int* in_sizes, int n_in,
                              void* d_out, int out_size, void* d_ws, size_t ws_size,
                              hipStream_t stream) {
    const int N = 50000, E = 100000, NF = 20000, EF = 40000, F = 10000;

    const float* x          = (const float*)d_in[0];
    const float* edge_attr  = (const float*)d_in[1];
    const float* frag_x     = (const float*)d_in[2];
    const float* frag_ea    = (const float*)d_in[3];
    const float* la_w = (const float*)d_in[4];
    const float* la_b = (const float*)d_in[5];
    const float* lb_w = (const float*)d_in[6];
    const float* lb_b = (const float*)d_in[7];
    const float* bn1_g = (const float*)d_in[8];
    const float* bn1_b = (const float*)d_in[9];
    const float* bn2_g = (const float*)d_in[10];
    const float* bn2_b = (const float*)d_in[11];
    const float* wn = (const float*)d_in[12];
    const float* wb = (const float*)d_in[13];
    const float* wl = (const float*)d_in[14];
    const float* wlb = (const float*)d_in[15];
    const float* gate_w = (const float*)d_in[16];
    const float* gate_b = (const float*)d_in[17];
    const float* gat_wsrc = (const float*)d_in[18];
    const float* gat_bias = (const float*)d_in[22];
    const float* out_w = (const float*)d_in[23];
    const float* out_b = (const float*)d_in[24];
    const int* edge_index = (const int*)d_in[25];
    const int* frag_edge_index = (const int*)d_in[26];
    const int* cluster_index = (const int*)d_in[27];

    char* p = (char*)d_ws;
    auto alloc = [&](size_t bytes) { char* r = p; p += (bytes + 255) & ~(size_t)255; return (void*)r; };
    float* hA    = (float*)alloc((size_t)N * 128 * 4);
    short* ea1   = (short*)alloc((size_t)E * 128 * 2);
    int*   xphl  = (int*)alloc((size_t)N * 128 * 4);
    short* ep    = (short*)alloc((size_t)E * 128 * 2);
    short* Y     = (short*)alloc((size_t)N * 1024 * 2);
    float* agg   = (float*)alloc((size_t)N * 128 * 4);
    float* ubuf  = (float*)alloc((size_t)N * 8 * 4);
    float* vbuf  = (float*)alloc((size_t)E * 8 * 4);
    short* la_wTh = (short*)alloc(128 * 128 * 2);
    short* la_wTl = (short*)alloc(128 * 128 * 2);
    short* lb_wTh = (short*)alloc(128 * 16 * 2);
    short* lb_wTl = (short*)alloc(128 * 16 * 2);
    short* wnTh   = (short*)alloc(3 * 128 * 128 * 2);
    short* wnTl   = (short*)alloc(3 * 128 * 128 * 2);
    short* wbH    = (short*)alloc(3 * 1024 * 128 * 2);
    short* gate2Th = (short*)alloc(128 * 256 * 2);
    short* gate2Tl = (short*)alloc(128 * 256 * 2);
    float* wmF    = (float*)alloc(128 * 128 * 4);
    short* wmTh   = (short*)alloc(128 * 128 * 2);
    short* wmTl   = (short*)alloc(128 * 128 * 2);
    float* stats  = (float*)alloc(256 * 4);
    char* yq = (char*)Y;
    float* fpool = (float*)yq;              yq += (size_t)F * 128 * 4;
    float* fmv   = (float*)yq;              yq += (size_t)F * 128 * 4;
    int*   perm  = (int*)yq;

    auto cdiv = [](int a, int b) { return (a + b - 1) / b; };

    // ---- weight prep ----
    transpose_split<<<cdiv(128 * 128, 256), 256, 0, stream>>>(la_w, la_wTh, la_wTl, 128, 128);
    transpose_split<<<cdiv(16 * 128, 256), 256, 0, stream>>>(lb_w, lb_wTh, lb_wTl, 16, 128);
    for (int l = 0; l < 3; ++l)
        transpose_split<<<cdiv(128 * 128, 256), 256, 0, stream>>>(
            wn + (size_t)l * 16384, wnTh + (size_t)l * 16384, wnTl + (size_t)l * 16384, 128, 128);
    cvt_f2b<<<cdiv(3 * 1024 * 128, 256), 256, 0, stream>>>(wb, wbH, 3 * 1024 * 128);
    gate_combine_split<<<cdiv(128 * 256, 256), 256, 0, stream>>>(gate_w, gate2Th, gate2Tl);
    build_wm<<<cdiv(128 * 128, 256), 256, 0, stream>>>(gat_wsrc, wmF);
    transpose_split<<<cdiv(128 * 128, 256), 256, 0, stream>>>(wmF, wmTh, wmTl, 128, 128);

    auto run_layer = [&](float* h, const short* ea_buf, const int* ei, int Mn, int Me, int layer) {
        const short* wnTh_l = wnTh + (size_t)layer * 16384;
        const short* wnTl_l = wnTl + (size_t)layer * 16384;
        const short* wb_l   = wbH + (size_t)layer * 131072;
        const float* wl_l   = wl + (size_t)layer * 384 * 8;
        const float* wlb_l  = wlb + (size_t)layer * 8;
        fused_xpy<<<cdiv(Mn, 64), 256, 0, stream>>>(h, wnTh_l, wnTl_l, wb_l, wl_l,
                                                    wl_l + 256 * 8, wlb_l, xphl, ubuf, Y, Mn);
        gemm_bf16<0, 1><<<dim3(1, cdiv(Me, 128)), 256, 0, stream>>>(ea_buf, wnTh_l, nullptr, ep, Me, 128, 128);
        rowdot8<0><<<cdiv(Me, 4), 256, 0, stream>>>(ep, nullptr, wl_l + 128 * 8, nullptr, vbuf, Me);
        hipMemsetAsync(agg, 0, (size_t)Mn * 128 * 4, stream);
        edge_fused2<<<cdiv(Me, 4), 256, 0, stream>>>(xphl, ep, Y, ei, ubuf, vbuf, agg, Me);
        gate_gemm_split<<<dim3(1, cdiv(Mn, 128)), 256, 0, stream>>>(h, agg, gate2Th, gate2Tl, gate_b, Mn);
    };

    // ---- atom path ----
    gemm_split<3, 0, 0><<<dim3(1, cdiv(N, 128)), 256, 0, stream>>>(x, la_wTh, la_wTl, la_b, hA, nullptr, N, 128, 128);
    hipMemsetAsync(stats, 0, 1024, stream);
    bn_stats<<<256, 256, 0, stream>>>(hA, stats, stats + 128, N);
    bn_apply<<<2048, 256, 0, stream>>>(hA, stats, stats + 128, bn1_g, bn1_b, N);

    gemm_split<3, 0, 1><<<dim3(1, cdiv(E, 128)), 256, 0, stream>>>(edge_attr, lb_wTh, lb_wTl, lb_b, ea1, nullptr, E, 128, 16);
    hipMemsetAsync(stats, 0, 1024, stream);
    bn_stats_bf<<<256, 256, 0, stream>>>(ea1, stats, stats + 128, E);
    bn_apply_bf<<<2048, 256, 0, stream>>>(ea1, stats, stats + 128, bn2_g, bn2_b, E);

    for (int l = 0; l < 3; ++l) run_layer(hA, ea1, edge_index, N, E, l);
    out_phase1<<<cdiv(N, 4), 256, 0, stream>>>(hA, out_w, out_b, gat_bias, (float*)d_out, N);

    // ---- fragment path ----
    gemm_split<3, 1, 0><<<dim3(1, cdiv(NF, 128)), 256, 0, stream>>>(frag_x, la_wTh, la_wTl, la_b, hA, nullptr, NF, 128, 128);

    gemm_split<3, 0, 1><<<dim3(1, cdiv(EF, 128)), 256, 0, stream>>>(frag_ea, lb_wTh, lb_wTl, lb_b, ea1, nullptr, EF, 128, 16);
    hipMemsetAsync(stats, 0, 1024, stream);
    bn_stats_bf<<<256, 256, 0, stream>>>(ea1, stats, stats + 128, EF);
    bn_apply_bf<<<2048, 256, 0, stream>>>(ea1, stats, stats + 128, bn2_g, bn2_b, EF);

    for (int l = 0; l < 3; ++l) run_layer(hA, ea1, frag_edge_index, NF, EF, l);

    perm_build<<<cdiv(NF, 256), 256, 0, stream>>>(cluster_index, perm, NF);
    seg_pool<<<cdiv(F * 128, 256), 256, 0, stream>>>(hA, perm, fpool, F, NF);
    gemm_split<3, 1, 0><<<dim3(1, cdiv(F, 128)), 256, 0, stream>>>(fpool, wmTh, wmTl, gat_bias, fmv, nullptr, F, 128, 128);
    out_phase2<<<cdiv(F, 4), 256, 0, stream>>>(fmv, perm, out_w, gat_bias, (float*)d_out, F);
}

// Round 11
// 1345.614 us; speedup vs baseline: 1.2684x; 1.1032x over previous
//
#include <hip/hip_runtime.h>
#include <hip/hip_bf16.h>

#define EPS 1e-5f

typedef short bf16x8 __attribute__((ext_vector_type(8)));
typedef short short4v __attribute__((ext_vector_type(4)));
typedef short short16v __attribute__((ext_vector_type(16)));
typedef float f32x4 __attribute__((ext_vector_type(4)));

static __device__ __forceinline__ short f2bf(float x) {
    __hip_bfloat16 h = __float2bfloat16(x);
    return *reinterpret_cast<short*>(&h);
}
static __device__ __forceinline__ float bf2f(short x) {
    __hip_bfloat16 h;
    *reinterpret_cast<short*>(&h) = x;
    return __bfloat162float(h);
}

// ========== split-bf16 MFMA GEMM: C = act(A[M,K](f32) @ BT[N,K]^T + bias) ==========
template<int SPLIT, int ACT, int OUTM>
__global__ __launch_bounds__(256) void gemm_split(const float* __restrict__ A,
                                                  const short* __restrict__ BTh,
                                                  const short* __restrict__ BTl,
                                                  const float* __restrict__ bias,
                                                  void* __restrict__ Cout,
                                                  void* __restrict__ Cout2,
                                                  int M, int N, int K) {
    __shared__ short Ah[128][40];
    __shared__ short Al[128][40];
    __shared__ short Bh[128][40];
    __shared__ short Bl[128][40];
    const int tid = threadIdx.x;
    const int row0 = blockIdx.y * 128, col0 = blockIdx.x * 128;
    const int lane = tid & 63, w = tid >> 6;
    const int wr = w >> 1, wc = w & 1;
    const int lr = lane & 15, lg = lane >> 4;
    f32x4 acc[4][4] = {};

    for (int k0 = 0; k0 < K; k0 += 32) {
        #pragma unroll
        for (int i = 0; i < 4; ++i) {
            int idx = i * 256 + tid;
            int r = idx >> 3, q = idx & 7;
            int gr = row0 + r, gk = k0 + q * 4;
            f32x4 v;
            if (gr < M && gk + 3 < K) {
                v = *reinterpret_cast<const f32x4*>(&A[(size_t)gr * K + gk]);
            } else {
                #pragma unroll
                for (int j = 0; j < 4; ++j)
                    v[j] = (gr < M && gk + j < K) ? A[(size_t)gr * K + gk + j] : 0.f;
            }
            short4v h, l;
            #pragma unroll
            for (int j = 0; j < 4; ++j) {
                h[j] = f2bf(v[j]);
                l[j] = f2bf(v[j] - bf2f(h[j]));
            }
            *reinterpret_cast<short4v*>(&Ah[r][q * 4]) = h;
            *reinterpret_cast<short4v*>(&Al[r][q * 4]) = l;
        }
        #pragma unroll
        for (int i = 0; i < 4; ++i) {
            int idx = i * 256 + tid;
            int r = idx >> 3, q = idx & 7;
            int gc = col0 + r, gk = k0 + q * 4;
            short4v u, ul;
            if (gk + 3 < K) {
                u = *reinterpret_cast<const short4v*>(&BTh[(size_t)gc * K + gk]);
                if (SPLIT == 3) ul = *reinterpret_cast<const short4v*>(&BTl[(size_t)gc * K + gk]);
            } else {
                #pragma unroll
                for (int j = 0; j < 4; ++j) {
                    u[j] = (gk + j < K) ? BTh[(size_t)gc * K + gk + j] : (short)0;
                    if (SPLIT == 3) ul[j] = (gk + j < K) ? BTl[(size_t)gc * K + gk + j] : (short)0;
                }
            }
            *reinterpret_cast<short4v*>(&Bh[r][q * 4]) = u;
            if (SPLIT == 3) *reinterpret_cast<short4v*>(&Bl[r][q * 4]) = ul;
        }
        __syncthreads();
        bf16x8 afh[4], afl[4], bfh[4];
        #pragma unroll
        for (int mi = 0; mi < 4; ++mi) {
            afh[mi] = *reinterpret_cast<const bf16x8*>(&Ah[wr * 64 + mi * 16 + lr][lg * 8]);
            afl[mi] = *reinterpret_cast<const bf16x8*>(&Al[wr * 64 + mi * 16 + lr][lg * 8]);
        }
        #pragma unroll
        for (int ni = 0; ni < 4; ++ni)
            bfh[ni] = *reinterpret_cast<const bf16x8*>(&Bh[wc * 64 + ni * 16 + lr][lg * 8]);
        #pragma unroll
        for (int mi = 0; mi < 4; ++mi)
            #pragma unroll
            for (int ni = 0; ni < 4; ++ni) {
                acc[mi][ni] = __builtin_amdgcn_mfma_f32_16x16x32_bf16(afh[mi], bfh[ni], acc[mi][ni], 0, 0, 0);
                acc[mi][ni] = __builtin_amdgcn_mfma_f32_16x16x32_bf16(afl[mi], bfh[ni], acc[mi][ni], 0, 0, 0);
            }
        if (SPLIT == 3) {
            bf16x8 bfl[4];
            #pragma unroll
            for (int ni = 0; ni < 4; ++ni)
                bfl[ni] = *reinterpret_cast<const bf16x8*>(&Bl[wc * 64 + ni * 16 + lr][lg * 8]);
            #pragma unroll
            for (int mi = 0; mi < 4; ++mi)
                #pragma unroll
                for (int ni = 0; ni < 4; ++ni)
                    acc[mi][ni] = __builtin_amdgcn_mfma_f32_16x16x32_bf16(afh[mi], bfl[ni], acc[mi][ni], 0, 0, 0);
        }
        __syncthreads();
    }

    #pragma unroll
    for (int mi = 0; mi < 4; ++mi) {
        #pragma unroll
        for (int ni = 0; ni < 4; ++ni) {
            int col = col0 + wc * 64 + ni * 16 + lr;
            float bv = bias ? bias[col] : 0.f;
            #pragma unroll
            for (int r = 0; r < 4; ++r) {
                int row = row0 + wr * 64 + mi * 16 + lg * 4 + r;
                if (row >= M) continue;
                float v = acc[mi][ni][r] + bv;
                if (ACT) v = fmaxf(v, 0.f);
                if (OUTM == 0) ((float*)Cout)[(size_t)row * N + col] = v;
                else ((short*)Cout)[(size_t)row * N + col] = f2bf(v);
            }
        }
    }
}

// ========== plain bf16 GEMM (tolerant path: ep projection) ==========
template<int ACT, int OUTBF>
__global__ __launch_bounds__(256) void gemm_bf16(const short* __restrict__ A,
                                                 const short* __restrict__ BT,
                                                 const float* __restrict__ bias,
                                                 void* __restrict__ Cout,
                                                 int M, int N, int K) {
    __shared__ short As[128][40];
    __shared__ short Bs[128][40];
    const int tid = threadIdx.x;
    const int row0 = blockIdx.y * 128, col0 = blockIdx.x * 128;
    const int lane = tid & 63, w = tid >> 6;
    const int wr = w >> 1, wc = w & 1;
    const int lr = lane & 15, lg = lane >> 4;
    f32x4 acc[4][4] = {};

    for (int k0 = 0; k0 < K; k0 += 32) {
        #pragma unroll
        for (int i = 0; i < 4; ++i) {
            int idx = i * 256 + tid;
            int r = idx >> 3, q = idx & 7;
            int gk = k0 + q * 4;
            int gr = row0 + r;
            short4v v;
            if (gr < M && gk + 3 < K) {
                v = *reinterpret_cast<const short4v*>(&A[(size_t)gr * K + gk]);
            } else {
                #pragma unroll
                for (int j = 0; j < 4; ++j)
                    v[j] = (gr < M && gk + j < K) ? A[(size_t)gr * K + gk + j] : (short)0;
            }
            *reinterpret_cast<short4v*>(&As[r][q * 4]) = v;
            int gc = col0 + r;
            short4v u;
            if (gc < N && gk + 3 < K) {
                u = *reinterpret_cast<const short4v*>(&BT[(size_t)gc * K + gk]);
            } else {
                #pragma unroll
                for (int j = 0; j < 4; ++j)
                    u[j] = (gc < N && gk + j < K) ? BT[(size_t)gc * K + gk + j] : (short)0;
            }
            *reinterpret_cast<short4v*>(&Bs[r][q * 4]) = u;
        }
        __syncthreads();
        bf16x8 af[4], bfr[4];
        #pragma unroll
        for (int mi = 0; mi < 4; ++mi)
            af[mi] = *reinterpret_cast<const bf16x8*>(&As[wr * 64 + mi * 16 + lr][lg * 8]);
        #pragma unroll
        for (int ni = 0; ni < 4; ++ni)
            bfr[ni] = *reinterpret_cast<const bf16x8*>(&Bs[wc * 64 + ni * 16 + lr][lg * 8]);
        #pragma unroll
        for (int mi = 0; mi < 4; ++mi)
            #pragma unroll
            for (int ni = 0; ni < 4; ++ni)
                acc[mi][ni] = __builtin_amdgcn_mfma_f32_16x16x32_bf16(af[mi], bfr[ni], acc[mi][ni], 0, 0, 0);
        __syncthreads();
    }

    #pragma unroll
    for (int mi = 0; mi < 4; ++mi) {
        #pragma unroll
        for (int ni = 0; ni < 4; ++ni) {
            int col = col0 + wc * 64 + ni * 16 + lr;
            float bv = bias ? bias[col] : 0.f;
            #pragma unroll
            for (int r = 0; r < 4; ++r) {
                int row = row0 + wr * 64 + mi * 16 + lg * 4 + r;
                if (row >= M) continue;
                float v = acc[mi][ni][r] + bv;
                if (ACT) v = fmaxf(v, 0.f);
                if (OUTBF) ((short*)Cout)[(size_t)row * N + col] = f2bf(v);
                else       ((float*)Cout)[(size_t)row * N + col] = v;
            }
        }
    }
}

// ========== fused xp + Y kernel v5: 64-row tiles, 4 waves, 40KB LDS (4 blocks/CU) ==========
// Phase 1: xp[64,128] = h @ wnT (split-3) -> global packed hi|lo + LDS hi.
// u[64,8] = xp_hi . wl2 + wlb (vectorized from LDS).
// Phase 2: Y[64,1024] = xp_hi @ wbBT^T + wl1 colbias, bounced per 64-col half.
__global__ __launch_bounds__(256) void fused_xpy(const float* __restrict__ h,
                                                 const short* __restrict__ wnTh,
                                                 const short* __restrict__ wnTl,
                                                 const short* __restrict__ wbBT,
                                                 const float* __restrict__ wl1,
                                                 const float* __restrict__ wl2,
                                                 const float* __restrict__ wlb,
                                                 int* __restrict__ xphl,
                                                 float* __restrict__ ubuf,
                                                 short* __restrict__ Y, int M) {
    __shared__ short sbuf[15360];
    __shared__ short yb[64 * 72];           // 9216 B half-tile bounce
    short* Ah = sbuf;                       // 64 x 40
    short* Al = sbuf + 2560;
    short* Bh = sbuf + 5120;                // 128 x 40
    short* Bl = sbuf + 10240;
    short* xpH = sbuf;                      // 64 x 136 (aliases staging after phase-1 final barrier)

    const int tid = threadIdx.x;
    const int row0 = blockIdx.x * 64;
    const int lane = tid & 63, w = tid >> 6;
    const int lr = lane & 15, lg = lane >> 4;

    // ---- phase 1 ----
    f32x4 acc1[4][2] = {};
    for (int k0 = 0; k0 < 128; k0 += 32) {
        #pragma unroll
        for (int i = 0; i < 2; ++i) {
            int idx = i * 256 + tid;
            int r = idx >> 3, q = idx & 7;
            int gr = row0 + r, gk = k0 + q * 4;
            f32x4 v;
            if (gr < M) {
                v = *reinterpret_cast<const f32x4*>(&h[(size_t)gr * 128 + gk]);
            } else {
                #pragma unroll
                for (int j = 0; j < 4; ++j) v[j] = 0.f;
            }
            short4v hh, ll;
            #pragma unroll
            for (int j = 0; j < 4; ++j) {
                hh[j] = f2bf(v[j]);
                ll[j] = f2bf(v[j] - bf2f(hh[j]));
            }
            *reinterpret_cast<short4v*>(&Ah[r * 40 + q * 4]) = hh;
            *reinterpret_cast<short4v*>(&Al[r * 40 + q * 4]) = ll;
        }
        #pragma unroll
        for (int i = 0; i < 4; ++i) {
            int idx = i * 256 + tid;
            int r = idx >> 3, q = idx & 7;
            int gk = k0 + q * 4;
            short4v bh = *reinterpret_cast<const short4v*>(&wnTh[(size_t)r * 128 + gk]);
            short4v bl = *reinterpret_cast<const short4v*>(&wnTl[(size_t)r * 128 + gk]);
            *reinterpret_cast<short4v*>(&Bh[r * 40 + q * 4]) = bh;
            *reinterpret_cast<short4v*>(&Bl[r * 40 + q * 4]) = bl;
        }
        __syncthreads();
        bf16x8 afh[4], afl[4], bfh[2], bfl[2];
        #pragma unroll
        for (int mi = 0; mi < 4; ++mi) {
            afh[mi] = *reinterpret_cast<const bf16x8*>(&Ah[(mi * 16 + lr) * 40 + lg * 8]);
            afl[mi] = *reinterpret_cast<const bf16x8*>(&Al[(mi * 16 + lr) * 40 + lg * 8]);
        }
        #pragma unroll
        for (int ni = 0; ni < 2; ++ni) {
            bfh[ni] = *reinterpret_cast<const bf16x8*>(&Bh[(w * 32 + ni * 16 + lr) * 40 + lg * 8]);
            bfl[ni] = *reinterpret_cast<const bf16x8*>(&Bl[(w * 32 + ni * 16 + lr) * 40 + lg * 8]);
        }
        #pragma unroll
        for (int mi = 0; mi < 4; ++mi)
            #pragma unroll
            for (int ni = 0; ni < 2; ++ni) {
                acc1[mi][ni] = __builtin_amdgcn_mfma_f32_16x16x32_bf16(afh[mi], bfh[ni], acc1[mi][ni], 0, 0, 0);
                acc1[mi][ni] = __builtin_amdgcn_mfma_f32_16x16x32_bf16(afl[mi], bfh[ni], acc1[mi][ni], 0, 0, 0);
                acc1[mi][ni] = __builtin_amdgcn_mfma_f32_16x16x32_bf16(afh[mi], bfl[ni], acc1[mi][ni], 0, 0, 0);
            }
        __syncthreads();
    }

    // ---- write xp: LDS hi + global packed {hi,lo} ----
    #pragma unroll
    for (int mi = 0; mi < 4; ++mi) {
        #pragma unroll
        for (int ni = 0; ni < 2; ++ni) {
            int col = w * 32 + ni * 16 + lr;
            #pragma unroll
            for (int r = 0; r < 4; ++r) {
                int rl = mi * 16 + lg * 4 + r;
                float v = acc1[mi][ni][r];
                short hi = f2bf(v);
                short lo = f2bf(v - bf2f(hi));
                xpH[rl * 136 + col] = hi;
                int row = row0 + rl;
                if (row < M)
                    xphl[(size_t)row * 128 + col] =
                        ((int)(unsigned short)lo << 16) | (unsigned short)hi;
            }
        }
    }
    __syncthreads();

    // ---- u = xp_hi . wl2 + wlb (vectorized LDS reads) ----
    #pragma unroll
    for (int o = tid; o < 512; o += 256) {
        int rl = o >> 3, s = o & 7;
        int row = row0 + rl;
        if (row < M) {
            float p = wlb[s];
            #pragma unroll
            for (int j = 0; j < 16; ++j) {
                bf16x8 xv = *reinterpret_cast<const bf16x8*>(&xpH[rl * 136 + j * 8]);
                #pragma unroll
                for (int k = 0; k < 8; ++k)
                    p += bf2f(xv[k]) * wl2[(j * 8 + k) * 8 + s];
            }
            ubuf[(size_t)row * 8 + s] = p;
        }
    }

    // ---- phase 2: per ct, MFMA then two 64-col bounced stores ----
    for (int ct = 0; ct < 8; ++ct) {
        f32x4 acc[4][2] = {};
        #pragma unroll
        for (int k = 0; k < 4; ++k) {
            bf16x8 bfr[2];
            #pragma unroll
            for (int ni = 0; ni < 2; ++ni) {
                int col = ct * 128 + ni * 64 + w * 16 + lr;
                bfr[ni] = *reinterpret_cast<const bf16x8*>(&wbBT[(size_t)col * 128 + k * 32 + lg * 8]);
            }
            bf16x8 ah[4];
            #pragma unroll
            for (int mi = 0; mi < 4; ++mi)
                ah[mi] = *reinterpret_cast<const bf16x8*>(&xpH[(mi * 16 + lr) * 136 + k * 32 + lg * 8]);
            #pragma unroll
            for (int mi = 0; mi < 4; ++mi)
                #pragma unroll
                for (int ni = 0; ni < 2; ++ni)
                    acc[mi][ni] = __builtin_amdgcn_mfma_f32_16x16x32_bf16(ah[mi], bfr[ni], acc[mi][ni], 0, 0, 0);
        }
        #pragma unroll
        for (int ni = 0; ni < 2; ++ni) {
            int loc = w * 16 + lr;                       // col within half
            int gcolbase = ct * 128 + ni * 64;
            float bv = wl1[(ni * 64 + loc) * 8 + ct];
            #pragma unroll
            for (int mi = 0; mi < 4; ++mi)
                #pragma unroll
                for (int r = 0; r < 4; ++r) {
                    int rl = mi * 16 + lg * 4 + r;
                    yb[rl * 72 + loc] = f2bf(acc[mi][ni][r] + bv);
                }
            __syncthreads();
            #pragma unroll
            for (int pass = 0; pass < 2; ++pass) {
                int flat = pass * 4096 + tid * 16;       // byte offset in 8KB half
                int rl = flat >> 7;                       // 128 B data per row
                int cs = (flat & 127) >> 1;
                int row = row0 + rl;
                if (row < M) {
                    bf16x8 v = *reinterpret_cast<const bf16x8*>(&yb[rl * 72 + cs]);
                    *reinterpret_cast<bf16x8*>(&Y[(size_t)row * 1024 + gcolbase + cs]) = v;
                }
            }
            __syncthreads();
        }
    }
}

// ========== rowdot8 (v only) ==========
template<int SPLITIN>
__global__ __launch_bounds__(256) void rowdot8(const short* __restrict__ Ah,
                                               const short* __restrict__ Al,
                                               const float* __restrict__ Wg,
                                               const float* __restrict__ bias8,
                                               float* __restrict__ out, int M) {
    __shared__ float sw[128][9];
    __shared__ float sb[8];
    for (int i = threadIdx.x; i < 1024; i += 256) sw[i >> 3][i & 7] = Wg[i];
    if (threadIdx.x < 8) sb[threadIdx.x] = bias8 ? bias8[threadIdx.x] : 0.f;
    __syncthreads();
    int r = blockIdx.x * 4 + (threadIdx.x >> 6);
    if (r >= M) return;
    int l = threadIdx.x & 63;
    int s = l & 7, c0 = (l >> 3) * 16;
    const short* ah = Ah + (size_t)r * 128 + c0;
    bf16x8 h0 = *reinterpret_cast<const bf16x8*>(ah);
    bf16x8 h1 = *reinterpret_cast<const bf16x8*>(ah + 8);
    float p = 0.f;
    #pragma unroll
    for (int j = 0; j < 8; ++j) {
        p += bf2f(h0[j]) * sw[c0 + j][s];
        p += bf2f(h1[j]) * sw[c0 + 8 + j][s];
    }
    p += __shfl_xor(p, 8); p += __shfl_xor(p, 16); p += __shfl_xor(p, 32);
    if (l < 8) out[(size_t)r * 8 + l] = p + sb[l];
}

// ========== fused edge kernel v3 (packed xp) ==========
__global__ __launch_bounds__(256) void edge_fused2(const int* __restrict__ xphl,
                                                   const short* __restrict__ ep,
                                                   const short* __restrict__ Y,
                                                   const int* __restrict__ ei,
                                                   const float* __restrict__ u,
                                                   const float* __restrict__ v,
                                                   float* __restrict__ agg, int E) {
    int e = blockIdx.x * 4 + (threadIdx.x >> 6);
    if (e >= E) return;
    int l = threadIdx.x & 63;
    int s = l & 7, c0 = (l >> 3) * 16;
    int src = ei[e], dst = ei[E + e];
    const short* y = Y + (size_t)src * 1024 + s * 128 + c0;
    bf16x8 y0 = *reinterpret_cast<const bf16x8*>(y);
    bf16x8 y1 = *reinterpret_cast<const bf16x8*>(y + 8);
    const short* xi = (const short*)(xphl + (size_t)dst * 128 + c0);
    short16v xv0 = *reinterpret_cast<const short16v*>(xi);
    short16v xv1 = *reinterpret_cast<const short16v*>(xi + 16);
    float p = 0.f;
    #pragma unroll
    for (int j = 0; j < 8; ++j) {
        p += (bf2f(xv0[2 * j]) + bf2f(xv0[2 * j + 1])) * bf2f(y0[j]);
        p += (bf2f(xv1[2 * j]) + bf2f(xv1[2 * j + 1])) * bf2f(y1[j]);
    }
    p += __shfl_xor(p, 8); p += __shfl_xor(p, 16); p += __shfl_xor(p, 32);
    float alpha = tanhf(p + u[(size_t)src * 8 + s] + v[(size_t)e * 8 + s]);
    float aa0 = __shfl(alpha, l >> 4);
    float aa1 = __shfl(alpha, 4 + (l >> 4));
    int pj0 = xphl[(size_t)src * 128 + l];
    int pj1 = xphl[(size_t)src * 128 + l + 64];
    float xj0 = bf2f((short)(pj0 & 0xffff)) + bf2f((short)(pj0 >> 16));
    float xj1 = bf2f((short)(pj1 & 0xffff)) + bf2f((short)(pj1 >> 16));
    float e0 = bf2f(ep[(size_t)e * 128 + l]);
    float e1 = bf2f(ep[(size_t)e * 128 + l + 64]);
    atomicAdd(&agg[(size_t)dst * 128 + l],      fmaxf(xj0, e0) * aa0);
    atomicAdd(&agg[(size_t)dst * 128 + l + 64], fmaxf(xj1, e1) * aa1);
}

// ========== gate GEMM v2: 64-row tiles, split-3, K=256 combined, in place ==========
__global__ __launch_bounds__(256) void gate_gemm_split(float* __restrict__ h,
                                                       const float* __restrict__ aggv,
                                                       const short* __restrict__ BTh,  // [128][256]
                                                       const short* __restrict__ BTl,
                                                       const float* __restrict__ gb,
                                                       int M) {
    __shared__ short Ah[64][40];
    __shared__ short Al[64][40];
    __shared__ short Bh[128][40];
    __shared__ short Bl[128][40];
    const int tid = threadIdx.x;
    const int row0 = blockIdx.x * 64;
    const int lane = tid & 63, w = tid >> 6;
    const int lr = lane & 15, lg = lane >> 4;
    f32x4 acc[4][2] = {};

    for (int k0 = 0; k0 < 256; k0 += 32) {
        int sec = k0 >> 7;
        #pragma unroll
        for (int i = 0; i < 2; ++i) {
            int idx = i * 256 + tid;
            int r = idx >> 3, q = idx & 7;
            int gr = row0 + r;
            int ks = (k0 & 127) + q * 4;
            f32x4 v;
            if (gr < M) {
                if (sec == 0) {
                    v = *reinterpret_cast<const f32x4*>(&h[(size_t)gr * 128 + ks]);
                } else {
                    f32x4 a = *reinterpret_cast<const f32x4*>(&aggv[(size_t)gr * 128 + ks]);
                    #pragma unroll
                    for (int j = 0; j < 4; ++j) v[j] = fmaxf(a[j], 0.f);
                }
            } else {
                #pragma unroll
                for (int j = 0; j < 4; ++j) v[j] = 0.f;
            }
            short4v hh, ll;
            #pragma unroll
            for (int j = 0; j < 4; ++j) {
                hh[j] = f2bf(v[j]);
                ll[j] = f2bf(v[j] - bf2f(hh[j]));
            }
            *reinterpret_cast<short4v*>(&Ah[r][q * 4]) = hh;
            *reinterpret_cast<short4v*>(&Al[r][q * 4]) = ll;
        }
        #pragma unroll
        for (int i = 0; i < 4; ++i) {
            int idx = i * 256 + tid;
            int r = idx >> 3, q = idx & 7;
            short4v uu = *reinterpret_cast<const short4v*>(&BTh[(size_t)r * 256 + k0 + q * 4]);
            short4v ul = *reinterpret_cast<const short4v*>(&BTl[(size_t)r * 256 + k0 + q * 4]);
            *reinterpret_cast<short4v*>(&Bh[r][q * 4]) = uu;
            *reinterpret_cast<short4v*>(&Bl[r][q * 4]) = ul;
        }
        __syncthreads();
        bf16x8 afh[4], afl[4], bfh[2], bfl[2];
        #pragma unroll
        for (int mi = 0; mi < 4; ++mi) {
            afh[mi] = *reinterpret_cast<const bf16x8*>(&Ah[mi * 16 + lr][lg * 8]);
            afl[mi] = *reinterpret_cast<const bf16x8*>(&Al[mi * 16 + lr][lg * 8]);
        }
        #pragma unroll
        for (int ni = 0; ni < 2; ++ni) {
            bfh[ni] = *reinterpret_cast<const bf16x8*>(&Bh[w * 32 + ni * 16 + lr][lg * 8]);
            bfl[ni] = *reinterpret_cast<const bf16x8*>(&Bl[w * 32 + ni * 16 + lr][lg * 8]);
        }
        #pragma unroll
        for (int mi = 0; mi < 4; ++mi)
            #pragma unroll
            for (int ni = 0; ni < 2; ++ni) {
                acc[mi][ni] = __builtin_amdgcn_mfma_f32_16x16x32_bf16(afh[mi], bfh[ni], acc[mi][ni], 0, 0, 0);
                acc[mi][ni] = __builtin_amdgcn_mfma_f32_16x16x32_bf16(afl[mi], bfh[ni], acc[mi][ni], 0, 0, 0);
                acc[mi][ni] = __builtin_amdgcn_mfma_f32_16x16x32_bf16(afh[mi], bfl[ni], acc[mi][ni], 0, 0, 0);
            }
        __syncthreads();
    }

    #pragma unroll
    for (int mi = 0; mi < 4; ++mi) {
        #pragma unroll
        for (int ni = 0; ni < 2; ++ni) {
            int col = w * 32 + ni * 16 + lr;
            float gbv = gb[col];
            #pragma unroll
            for (int r = 0; r < 4; ++r) {
                int row = row0 + mi * 16 + lg * 4 + r;
                if (row >= M) continue;
                float beta = fmaxf(acc[mi][ni][r] + gbv, 0.f);
                float hv = h[(size_t)row * 128 + col];
                float hh = fmaxf(aggv[(size_t)row * 128 + col], 0.f);
                h[(size_t)row * 128 + col] = beta * hv + (1.f - beta) * hh;
            }
        }
    }
}

// ========== batch norm ==========
__global__ void bn_stats(const float* __restrict__ z, float* __restrict__ gsum,
                         float* __restrict__ gsq, int M) {
    int c = threadIdx.x & 127;
    int rr = threadIdx.x >> 7;
    float s = 0.f, q = 0.f;
    for (int r = blockIdx.x * 2 + rr; r < M; r += gridDim.x * 2) {
        float v = z[(size_t)r * 128 + c];
        s += v; q += v * v;
    }
    __shared__ float ls[256], lq[256];
    ls[threadIdx.x] = s; lq[threadIdx.x] = q;
    __syncthreads();
    if (threadIdx.x < 128) {
        atomicAdd(&gsum[c], ls[threadIdx.x] + ls[threadIdx.x + 128]);
        atomicAdd(&gsq[c],  lq[threadIdx.x] + lq[threadIdx.x + 128]);
    }
}

__global__ void bn_apply(float* __restrict__ z, const float* __restrict__ gsum,
                         const float* __restrict__ gsq, const float* __restrict__ g,
                         const float* __restrict__ b, int M) {
    size_t total = (size_t)M * 128;
    for (size_t idx = (size_t)blockIdx.x * 256 + threadIdx.x; idx < total;
         idx += (size_t)gridDim.x * 256) {
        int c = idx & 127;
        float mu = gsum[c] / (float)M;
        float var = gsq[c] / (float)M - mu * mu;
        float rs = rsqrtf(var + EPS);
        float v = (z[idx] - mu) * rs * g[c] + b[c];
        z[idx] = fmaxf(v, 0.f);
    }
}

__global__ void bn_stats_bf(const short* __restrict__ z, float* __restrict__ gsum,
                            float* __restrict__ gsq, int M) {
    int c = threadIdx.x & 127;
    int rr = threadIdx.x >> 7;
    float s = 0.f, q = 0.f;
    for (int r = blockIdx.x * 2 + rr; r < M; r += gridDim.x * 2) {
        float v = bf2f(z[(size_t)r * 128 + c]);
        s += v; q += v * v;
    }
    __shared__ float ls[256], lq[256];
    ls[threadIdx.x] = s; lq[threadIdx.x] = q;
    __syncthreads();
    if (threadIdx.x < 128) {
        atomicAdd(&gsum[c], ls[threadIdx.x] + ls[threadIdx.x + 128]);
        atomicAdd(&gsq[c],  lq[threadIdx.x] + lq[threadIdx.x + 128]);
    }
}

__global__ void bn_apply_bf(short* __restrict__ z, const float* __restrict__ gsum,
                            const float* __restrict__ gsq, const float* __restrict__ g,
                            const float* __restrict__ b, int M) {
    size_t total = (size_t)M * 128;
    for (size_t idx = (size_t)blockIdx.x * 256 + threadIdx.x; idx < total;
         idx += (size_t)gridDim.x * 256) {
        int c = idx & 127;
        float mu = gsum[c] / (float)M;
        float var = gsq[c] / (float)M - mu * mu;
        float rs = rsqrtf(var + EPS);
        float v = (bf2f(z[idx]) - mu) * rs * g[c] + b[c];
        z[idx] = f2bf(fmaxf(v, 0.f));
    }
}

// ========== prep ==========
__global__ void transpose_split(const float* __restrict__ in, short* __restrict__ outh,
                                short* __restrict__ outl, int K, int N) {
    int idx = blockIdx.x * 256 + threadIdx.x;
    if (idx >= K * N) return;
    int nI = idx / K, k = idx - nI * K;
    float v = in[(size_t)k * N + nI];
    short h = f2bf(v);
    outh[idx] = h;
    outl[idx] = f2bf(v - bf2f(h));
}

__global__ void cvt_f2b(const float* __restrict__ in, short* __restrict__ out, int n) {
    int i = blockIdx.x * 256 + threadIdx.x;
    if (i < n) out[i] = f2bf(in[i]);
}

__global__ void gate_combine_split(const float* __restrict__ gw, short* __restrict__ BTh,
                                   short* __restrict__ BTl) {
    int idx = blockIdx.x * 256 + threadIdx.x;
    if (idx >= 128 * 256) return;
    int n = idx >> 8, k = idx & 255;
    float v;
    if (k < 128) v = gw[(size_t)k * 128 + n] + gw[(size_t)(256 + k) * 128 + n];
    else {
        int kk = k - 128;
        v = gw[(size_t)(128 + kk) * 128 + n] - gw[(size_t)(256 + kk) * 128 + n];
    }
    short h = f2bf(v);
    BTh[idx] = h;
    BTl[idx] = f2bf(v - bf2f(h));
}

__global__ void build_wm(const float* __restrict__ wsrc, float* __restrict__ wm) {
    int idx = blockIdx.x * 256 + threadIdx.x;
    if (idx >= 128 * 128) return;
    int d = idx >> 7, c = idx & 127;
    float s = 0.f;
    #pragma unroll
    for (int h = 0; h < 8; ++h) s += wsrc[(size_t)d * 1024 + h * 128 + c];
    wm[idx] = s * 0.125f;
}

__global__ void perm_build(const int* __restrict__ ci, int* __restrict__ perm, int NF) {
    int i = blockIdx.x * 256 + threadIdx.x;
    if (i >= NF) return;
    int c = ci[i];
    if (i == 0 || ci[i - 1] != c) perm[c] = i;
}

__global__ void seg_pool(const float* __restrict__ fx, const int* __restrict__ perm,
                         float* __restrict__ pool, int F, int NF) {
    int idx = blockIdx.x * 256 + threadIdx.x;
    if (idx >= F * 128) return;
    int f = idx >> 7, c = idx & 127;
    int s = perm[f];
    int e = (f + 1 < F) ? perm[f + 1] : NF;
    float acc = 0.f;
    for (int i = s; i < e; ++i) acc += fx[(size_t)i * 128 + c];
    pool[idx] = fmaxf(acc, 0.f);
}

// ========== output ==========
__global__ __launch_bounds__(256) void out_phase1(const float* __restrict__ h,
                                                  const float* __restrict__ out_w,
                                                  const float* __restrict__ out_b,
                                                  const float* __restrict__ gat_bias,
                                                  float* __restrict__ out, int M) {
    int n = blockIdx.x * 4 + (threadIdx.x >> 6);
    if (n >= M) return;
    int l = threadIdx.x & 63;
    float p = fmaxf(h[(size_t)n * 128 + l], 0.f) * out_w[l]
            + fmaxf(h[(size_t)n * 128 + l + 64], 0.f) * out_w[l + 64];
    p += fmaxf(gat_bias[l], 0.f) * out_w[128 + l]
       + fmaxf(gat_bias[l + 64], 0.f) * out_w[128 + l + 64];
    #pragma unroll
    for (int off = 32; off; off >>= 1) p += __shfl_xor(p, off);
    if (l == 0) out[n] = p + out_b[0];
}

__global__ __launch_bounds__(256) void out_phase2(const float* __restrict__ fmv,
                                                  const int* __restrict__ perm,
                                                  const float* __restrict__ out_w,
                                                  const float* __restrict__ gat_bias,
                                                  float* __restrict__ out, int F) {
    int f = blockIdx.x * 4 + (threadIdx.x >> 6);
    if (f >= F) return;
    int l = threadIdx.x & 63;
    float p = fmv[(size_t)f * 128 + l] * out_w[128 + l]
            + fmv[(size_t)f * 128 + l + 64] * out_w[128 + l + 64];
    float b = fmaxf(gat_bias[l], 0.f) * out_w[128 + l]
            + fmaxf(gat_bias[l + 64], 0.f) * out_w[128 + l + 64];
    float d = p - b;
    #pragma unroll
    for (int off = 32; off; off >>= 1) d += __shfl_xor(d, off);
    if (l == 0) out[perm[f]] += d;
}

// ========== host ==========
extern "C" void kernel_launch(void* const* d_in, const int* in_sizes, int n_in,
                              void* d_out, int out_size, void* d_ws, size_t ws_size,
                              hipStream_t stream) {
    const int N = 50000, E = 100000, NF = 20000, EF = 40000, F = 10000;

    const float* x          = (const float*)d_in[0];
    const float* edge_attr  = (const float*)d_in[1];
    const float* frag_x     = (const float*)d_in[2];
    const float* frag_ea    = (const float*)d_in[3];
    const float* la_w = (const float*)d_in[4];
    const float* la_b = (const float*)d_in[5];
    const float* lb_w = (const float*)d_in[6];
    const float* lb_b = (const float*)d_in[7];
    const float* bn1_g = (const float*)d_in[8];
    const float* bn1_b = (const float*)d_in[9];
    const float* bn2_g = (const float*)d_in[10];
    const float* bn2_b = (const float*)d_in[11];
    const float* wn = (const float*)d_in[12];
    const float* wb = (const float*)d_in[13];
    const float* wl = (const float*)d_in[14];
    const float* wlb = (const float*)d_in[15];
    const float* gate_w = (const float*)d_in[16];
    const float* gate_b = (const float*)d_in[17];
    const float* gat_wsrc = (const float*)d_in[18];
    const float* gat_bias = (const float*)d_in[22];
    const float* out_w = (const float*)d_in[23];
    const float* out_b = (const float*)d_in[24];
    const int* edge_index = (const int*)d_in[25];
    const int* frag_edge_index = (const int*)d_in[26];
    const int* cluster_index = (const int*)d_in[27];

    char* p = (char*)d_ws;
    auto alloc = [&](size_t bytes) { char* r = p; p += (bytes + 255) & ~(size_t)255; return (void*)r; };
    float* hA    = (float*)alloc((size_t)N * 128 * 4);
    short* ea1   = (short*)alloc((size_t)E * 128 * 2);
    int*   xphl  = (int*)alloc((size_t)N * 128 * 4);
    short* ep    = (short*)alloc((size_t)E * 128 * 2);
    short* Y     = (short*)alloc((size_t)N * 1024 * 2);
    float* agg   = (float*)alloc((size_t)N * 128 * 4);
    float* ubuf  = (float*)alloc((size_t)N * 8 * 4);
    float* vbuf  = (float*)alloc((size_t)E * 8 * 4);
    short* la_wTh = (short*)alloc(128 * 128 * 2);
    short* la_wTl = (short*)alloc(128 * 128 * 2);
    short* lb_wTh = (short*)alloc(128 * 16 * 2);
    short* lb_wTl = (short*)alloc(128 * 16 * 2);
    short* wnTh   = (short*)alloc(3 * 128 * 128 * 2);
    short* wnTl   = (short*)alloc(3 * 128 * 128 * 2);
    short* wbH    = (short*)alloc(3 * 1024 * 128 * 2);
    short* gate2Th = (short*)alloc(128 * 256 * 2);
    short* gate2Tl = (short*)alloc(128 * 256 * 2);
    float* wmF    = (float*)alloc(128 * 128 * 4);
    short* wmTh   = (short*)alloc(128 * 128 * 2);
    short* wmTl   = (short*)alloc(128 * 128 * 2);
    float* stats  = (float*)alloc(256 * 4);
    char* yq = (char*)Y;
    float* fpool = (float*)yq;              yq += (size_t)F * 128 * 4;
    float* fmv   = (float*)yq;              yq += (size_t)F * 128 * 4;
    int*   perm  = (int*)yq;

    auto cdiv = [](int a, int b) { return (a + b - 1) / b; };

    // ---- weight prep ----
    transpose_split<<<cdiv(128 * 128, 256), 256, 0, stream>>>(la_w, la_wTh, la_wTl, 128, 128);
    transpose_split<<<cdiv(16 * 128, 256), 256, 0, stream>>>(lb_w, lb_wTh, lb_wTl, 16, 128);
    for (int l = 0; l < 3; ++l)
        transpose_split<<<cdiv(128 * 128, 256), 256, 0, stream>>>(
            wn + (size_t)l * 16384, wnTh + (size_t)l * 16384, wnTl + (size_t)l * 16384, 128, 128);
    cvt_f2b<<<cdiv(3 * 1024 * 128, 256), 256, 0, stream>>>(wb, wbH, 3 * 1024 * 128);
    gate_combine_split<<<cdiv(128 * 256, 256), 256, 0, stream>>>(gate_w, gate2Th, gate2Tl);
    build_wm<<<cdiv(128 * 128, 256), 256, 0, stream>>>(gat_wsrc, wmF);
    transpose_split<<<cdiv(128 * 128, 256), 256, 0, stream>>>(wmF, wmTh, wmTl, 128, 128);

    auto run_layer = [&](float* h, const short* ea_buf, const int* ei, int Mn, int Me, int layer) {
        const short* wnTh_l = wnTh + (size_t)layer * 16384;
        const short* wnTl_l = wnTl + (size_t)layer * 16384;
        const short* wb_l   = wbH + (size_t)layer * 131072;
        const float* wl_l   = wl + (size_t)layer * 384 * 8;
        const float* wlb_l  = wlb + (size_t)layer * 8;
        fused_xpy<<<cdiv(Mn, 64), 256, 0, stream>>>(h, wnTh_l, wnTl_l, wb_l, wl_l,
                                                    wl_l + 256 * 8, wlb_l, xphl, ubuf, Y, Mn);
        gemm_bf16<0, 1><<<dim3(1, cdiv(Me, 128)), 256, 0, stream>>>(ea_buf, wnTh_l, nullptr, ep, Me, 128, 128);
        rowdot8<0><<<cdiv(Me, 4), 256, 0, stream>>>(ep, nullptr, wl_l + 128 * 8, nullptr, vbuf, Me);
        hipMemsetAsync(agg, 0, (size_t)Mn * 128 * 4, stream);
        edge_fused2<<<cdiv(Me, 4), 256, 0, stream>>>(xphl, ep, Y, ei, ubuf, vbuf, agg, Me);
        gate_gemm_split<<<cdiv(Mn, 64), 256, 0, stream>>>(h, agg, gate2Th, gate2Tl, gate_b, Mn);
    };

    // ---- atom path ----
    gemm_split<3, 0, 0><<<dim3(1, cdiv(N, 128)), 256, 0, stream>>>(x, la_wTh, la_wTl, la_b, hA, nullptr, N, 128, 128);
    hipMemsetAsync(stats, 0, 1024, stream);
    bn_stats<<<256, 256, 0, stream>>>(hA, stats, stats + 128, N);
    bn_apply<<<2048, 256, 0, stream>>>(hA, stats, stats + 128, bn1_g, bn1_b, N);

    gemm_split<3, 0, 1><<<dim3(1, cdiv(E, 128)), 256, 0, stream>>>(edge_attr, lb_wTh, lb_wTl, lb_b, ea1, nullptr, E, 128, 16);
    hipMemsetAsync(stats, 0, 1024, stream);
    bn_stats_bf<<<256, 256, 0, stream>>>(ea1, stats, stats + 128, E);
    bn_apply_bf<<<2048, 256, 0, stream>>>(ea1, stats, stats + 128, bn2_g, bn2_b, E);

    for (int l = 0; l < 3; ++l) run_layer(hA, ea1, edge_index, N, E, l);
    out_phase1<<<cdiv(N, 4), 256, 0, stream>>>(hA, out_w, out_b, gat_bias, (float*)d_out, N);

    // ---- fragment path ----
    gemm_split<3, 1, 0><<<dim3(1, cdiv(NF, 128)), 256, 0, stream>>>(frag_x, la_wTh, la_wTl, la_b, hA, nullptr, NF, 128, 128);

    gemm_split<3, 0, 1><<<dim3(1, cdiv(EF, 128)), 256, 0, stream>>>(frag_ea, lb_wTh, lb_wTl, lb_b, ea1, nullptr, EF, 128, 16);
    hipMemsetAsync(stats, 0, 1024, stream);
    bn_stats_bf<<<256, 256, 0, stream>>>(ea1, stats, stats + 128, EF);
    bn_apply_bf<<<2048, 256, 0, stream>>>(ea1, stats, stats + 128, bn2_g, bn2_b, EF);

    for (int l = 0; l < 3; ++l) run_layer(hA, ea1, frag_edge_index, NF, EF, l);

    perm_build<<<cdiv(NF, 256), 256, 0, stream>>>(cluster_index, perm, NF);
    seg_pool<<<cdiv(F * 128, 256), 256, 0, stream>>>(hA, perm, fpool, F, NF);
    gemm_split<3, 1, 0><<<dim3(1, cdiv(F, 128)), 256, 0, stream>>>(fpool, wmTh, wmTl, gat_bias, fmv, nullptr, F, 128, 128);
    out_phase2<<<cdiv(F, 4), 256, 0, stream>>>(fmv, perm, out_w, gat_bias, (float*)d_out, F);
}

// Round 12
// 1262.871 us; speedup vs baseline: 1.3515x; 1.0655x over previous
//
#include <hip/hip_runtime.h>
#include <hip/hip_bf16.h>
#include <hip/hip_fp8.h>

#define EPS 1e-5f

typedef short bf16x8 __attribute__((ext_vector_type(8)));
typedef short short4v __attribute__((ext_vector_type(4)));
typedef short short16v __attribute__((ext_vector_type(16)));
typedef float f32x4 __attribute__((ext_vector_type(4)));
typedef unsigned char uchar16v __attribute__((ext_vector_type(16)));

static __device__ __forceinline__ short f2bf(float x) {
    __hip_bfloat16 h = __float2bfloat16(x);
    return *reinterpret_cast<short*>(&h);
}
static __device__ __forceinline__ float bf2f(short x) {
    __hip_bfloat16 h;
    *reinterpret_cast<short*>(&h) = x;
    return __bfloat162float(h);
}
static __device__ __forceinline__ unsigned char f2fp8(float x) {
    __hip_fp8_e4m3 q(x);
    return (unsigned char)q.__x;
}
static __device__ __forceinline__ float fp82f(unsigned char b) {
    __hip_fp8_e4m3 q;
    q.__x = (__hip_fp8_storage_t)b;
    return (float)q;
}

// ========== split-bf16 MFMA GEMM: C = act(A[M,K](f32) @ BT[N,K]^T + bias) ==========
template<int SPLIT, int ACT, int OUTM>
__global__ __launch_bounds__(256) void gemm_split(const float* __restrict__ A,
                                                  const short* __restrict__ BTh,
                                                  const short* __restrict__ BTl,
                                                  const float* __restrict__ bias,
                                                  void* __restrict__ Cout,
                                                  void* __restrict__ Cout2,
                                                  int M, int N, int K) {
    __shared__ short Ah[128][40];
    __shared__ short Al[128][40];
    __shared__ short Bh[128][40];
    __shared__ short Bl[128][40];
    const int tid = threadIdx.x;
    const int row0 = blockIdx.y * 128, col0 = blockIdx.x * 128;
    const int lane = tid & 63, w = tid >> 6;
    const int wr = w >> 1, wc = w & 1;
    const int lr = lane & 15, lg = lane >> 4;
    f32x4 acc[4][4] = {};

    for (int k0 = 0; k0 < K; k0 += 32) {
        #pragma unroll
        for (int i = 0; i < 4; ++i) {
            int idx = i * 256 + tid;
            int r = idx >> 3, q = idx & 7;
            int gr = row0 + r, gk = k0 + q * 4;
            f32x4 v;
            if (gr < M && gk + 3 < K) {
                v = *reinterpret_cast<const f32x4*>(&A[(size_t)gr * K + gk]);
            } else {
                #pragma unroll
                for (int j = 0; j < 4; ++j)
                    v[j] = (gr < M && gk + j < K) ? A[(size_t)gr * K + gk + j] : 0.f;
            }
            short4v h, l;
            #pragma unroll
            for (int j = 0; j < 4; ++j) {
                h[j] = f2bf(v[j]);
                l[j] = f2bf(v[j] - bf2f(h[j]));
            }
            *reinterpret_cast<short4v*>(&Ah[r][q * 4]) = h;
            *reinterpret_cast<short4v*>(&Al[r][q * 4]) = l;
        }
        #pragma unroll
        for (int i = 0; i < 4; ++i) {
            int idx = i * 256 + tid;
            int r = idx >> 3, q = idx & 7;
            int gc = col0 + r, gk = k0 + q * 4;
            short4v u, ul;
            if (gk + 3 < K) {
                u = *reinterpret_cast<const short4v*>(&BTh[(size_t)gc * K + gk]);
                if (SPLIT == 3) ul = *reinterpret_cast<const short4v*>(&BTl[(size_t)gc * K + gk]);
            } else {
                #pragma unroll
                for (int j = 0; j < 4; ++j) {
                    u[j] = (gk + j < K) ? BTh[(size_t)gc * K + gk + j] : (short)0;
                    if (SPLIT == 3) ul[j] = (gk + j < K) ? BTl[(size_t)gc * K + gk + j] : (short)0;
                }
            }
            *reinterpret_cast<short4v*>(&Bh[r][q * 4]) = u;
            if (SPLIT == 3) *reinterpret_cast<short4v*>(&Bl[r][q * 4]) = ul;
        }
        __syncthreads();
        bf16x8 afh[4], afl[4], bfh[4];
        #pragma unroll
        for (int mi = 0; mi < 4; ++mi) {
            afh[mi] = *reinterpret_cast<const bf16x8*>(&Ah[wr * 64 + mi * 16 + lr][lg * 8]);
            afl[mi] = *reinterpret_cast<const bf16x8*>(&Al[wr * 64 + mi * 16 + lr][lg * 8]);
        }
        #pragma unroll
        for (int ni = 0; ni < 4; ++ni)
            bfh[ni] = *reinterpret_cast<const bf16x8*>(&Bh[wc * 64 + ni * 16 + lr][lg * 8]);
        #pragma unroll
        for (int mi = 0; mi < 4; ++mi)
            #pragma unroll
            for (int ni = 0; ni < 4; ++ni) {
                acc[mi][ni] = __builtin_amdgcn_mfma_f32_16x16x32_bf16(afh[mi], bfh[ni], acc[mi][ni], 0, 0, 0);
                acc[mi][ni] = __builtin_amdgcn_mfma_f32_16x16x32_bf16(afl[mi], bfh[ni], acc[mi][ni], 0, 0, 0);
            }
        if (SPLIT == 3) {
            bf16x8 bfl[4];
            #pragma unroll
            for (int ni = 0; ni < 4; ++ni)
                bfl[ni] = *reinterpret_cast<const bf16x8*>(&Bl[wc * 64 + ni * 16 + lr][lg * 8]);
            #pragma unroll
            for (int mi = 0; mi < 4; ++mi)
                #pragma unroll
                for (int ni = 0; ni < 4; ++ni)
                    acc[mi][ni] = __builtin_amdgcn_mfma_f32_16x16x32_bf16(afh[mi], bfl[ni], acc[mi][ni], 0, 0, 0);
        }
        __syncthreads();
    }

    #pragma unroll
    for (int mi = 0; mi < 4; ++mi) {
        #pragma unroll
        for (int ni = 0; ni < 4; ++ni) {
            int col = col0 + wc * 64 + ni * 16 + lr;
            float bv = bias ? bias[col] : 0.f;
            #pragma unroll
            for (int r = 0; r < 4; ++r) {
                int row = row0 + wr * 64 + mi * 16 + lg * 4 + r;
                if (row >= M) continue;
                float v = acc[mi][ni][r] + bv;
                if (ACT) v = fmaxf(v, 0.f);
                if (OUTM == 0) ((float*)Cout)[(size_t)row * N + col] = v;
                else ((short*)Cout)[(size_t)row * N + col] = f2bf(v);
            }
        }
    }
}

// ========== plain bf16 GEMM (tolerant path: ep projection) ==========
template<int ACT, int OUTBF>
__global__ __launch_bounds__(256) void gemm_bf16(const short* __restrict__ A,
                                                 const short* __restrict__ BT,
                                                 const float* __restrict__ bias,
                                                 void* __restrict__ Cout,
                                                 int M, int N, int K) {
    __shared__ short As[128][40];
    __shared__ short Bs[128][40];
    const int tid = threadIdx.x;
    const int row0 = blockIdx.y * 128, col0 = blockIdx.x * 128;
    const int lane = tid & 63, w = tid >> 6;
    const int wr = w >> 1, wc = w & 1;
    const int lr = lane & 15, lg = lane >> 4;
    f32x4 acc[4][4] = {};

    for (int k0 = 0; k0 < K; k0 += 32) {
        #pragma unroll
        for (int i = 0; i < 4; ++i) {
            int idx = i * 256 + tid;
            int r = idx >> 3, q = idx & 7;
            int gk = k0 + q * 4;
            int gr = row0 + r;
            short4v v;
            if (gr < M && gk + 3 < K) {
                v = *reinterpret_cast<const short4v*>(&A[(size_t)gr * K + gk]);
            } else {
                #pragma unroll
                for (int j = 0; j < 4; ++j)
                    v[j] = (gr < M && gk + j < K) ? A[(size_t)gr * K + gk + j] : (short)0;
            }
            *reinterpret_cast<short4v*>(&As[r][q * 4]) = v;
            int gc = col0 + r;
            short4v u;
            if (gc < N && gk + 3 < K) {
                u = *reinterpret_cast<const short4v*>(&BT[(size_t)gc * K + gk]);
            } else {
                #pragma unroll
                for (int j = 0; j < 4; ++j)
                    u[j] = (gc < N && gk + j < K) ? BT[(size_t)gc * K + gk + j] : (short)0;
            }
            *reinterpret_cast<short4v*>(&Bs[r][q * 4]) = u;
        }
        __syncthreads();
        bf16x8 af[4], bfr[4];
        #pragma unroll
        for (int mi = 0; mi < 4; ++mi)
            af[mi] = *reinterpret_cast<const bf16x8*>(&As[wr * 64 + mi * 16 + lr][lg * 8]);
        #pragma unroll
        for (int ni = 0; ni < 4; ++ni)
            bfr[ni] = *reinterpret_cast<const bf16x8*>(&Bs[wc * 64 + ni * 16 + lr][lg * 8]);
        #pragma unroll
        for (int mi = 0; mi < 4; ++mi)
            #pragma unroll
            for (int ni = 0; ni < 4; ++ni)
                acc[mi][ni] = __builtin_amdgcn_mfma_f32_16x16x32_bf16(af[mi], bfr[ni], acc[mi][ni], 0, 0, 0);
        __syncthreads();
    }

    #pragma unroll
    for (int mi = 0; mi < 4; ++mi) {
        #pragma unroll
        for (int ni = 0; ni < 4; ++ni) {
            int col = col0 + wc * 64 + ni * 16 + lr;
            float bv = bias ? bias[col] : 0.f;
            #pragma unroll
            for (int r = 0; r < 4; ++r) {
                int row = row0 + wr * 64 + mi * 16 + lg * 4 + r;
                if (row >= M) continue;
                float v = acc[mi][ni][r] + bv;
                if (ACT) v = fmaxf(v, 0.f);
                if (OUTBF) ((short*)Cout)[(size_t)row * N + col] = f2bf(v);
                else       ((float*)Cout)[(size_t)row * N + col] = v;
            }
        }
    }
}

// ========== fused xp + Y kernel v6: 64-row tiles, fp8 Y output ==========
// Phase 1: xp[64,128] = h @ wnT (split-3) -> global packed hi|lo + LDS hi.
// u[64,8] = xp_hi . wl2 + wlb (vectorized from LDS).
// Phase 2: Y[64,1024](fp8) = fp8(xp_hi @ wbBT^T + wl1 colbias), bounced per 64-col half.
__global__ __launch_bounds__(256) void fused_xpy(const float* __restrict__ h,
                                                 const short* __restrict__ wnTh,
                                                 const short* __restrict__ wnTl,
                                                 const short* __restrict__ wbBT,
                                                 const float* __restrict__ wl1,
                                                 const float* __restrict__ wl2,
                                                 const float* __restrict__ wlb,
                                                 int* __restrict__ xphl,
                                                 float* __restrict__ ubuf,
                                                 unsigned char* __restrict__ Y, int M) {
    __shared__ short sbuf[15360];
    __shared__ unsigned char yb[64 * 80];    // 5120 B fp8 half-tile bounce (80B rows, 16B aligned)
    short* Ah = sbuf;                        // 64 x 40
    short* Al = sbuf + 2560;
    short* Bh = sbuf + 5120;                 // 128 x 40
    short* Bl = sbuf + 10240;
    short* xpH = sbuf;                       // 64 x 136 (aliases staging after phase-1 final barrier)

    const int tid = threadIdx.x;
    const int row0 = blockIdx.x * 64;
    const int lane = tid & 63, w = tid >> 6;
    const int lr = lane & 15, lg = lane >> 4;

    // ---- phase 1 ----
    f32x4 acc1[4][2] = {};
    for (int k0 = 0; k0 < 128; k0 += 32) {
        #pragma unroll
        for (int i = 0; i < 2; ++i) {
            int idx = i * 256 + tid;
            int r = idx >> 3, q = idx & 7;
            int gr = row0 + r, gk = k0 + q * 4;
            f32x4 v;
            if (gr < M) {
                v = *reinterpret_cast<const f32x4*>(&h[(size_t)gr * 128 + gk]);
            } else {
                #pragma unroll
                for (int j = 0; j < 4; ++j) v[j] = 0.f;
            }
            short4v hh, ll;
            #pragma unroll
            for (int j = 0; j < 4; ++j) {
                hh[j] = f2bf(v[j]);
                ll[j] = f2bf(v[j] - bf2f(hh[j]));
            }
            *reinterpret_cast<short4v*>(&Ah[r * 40 + q * 4]) = hh;
            *reinterpret_cast<short4v*>(&Al[r * 40 + q * 4]) = ll;
        }
        #pragma unroll
        for (int i = 0; i < 4; ++i) {
            int idx = i * 256 + tid;
            int r = idx >> 3, q = idx & 7;
            int gk = k0 + q * 4;
            short4v bh = *reinterpret_cast<const short4v*>(&wnTh[(size_t)r * 128 + gk]);
            short4v bl = *reinterpret_cast<const short4v*>(&wnTl[(size_t)r * 128 + gk]);
            *reinterpret_cast<short4v*>(&Bh[r * 40 + q * 4]) = bh;
            *reinterpret_cast<short4v*>(&Bl[r * 40 + q * 4]) = bl;
        }
        __syncthreads();
        bf16x8 afh[4], afl[4], bfh[2], bfl[2];
        #pragma unroll
        for (int mi = 0; mi < 4; ++mi) {
            afh[mi] = *reinterpret_cast<const bf16x8*>(&Ah[(mi * 16 + lr) * 40 + lg * 8]);
            afl[mi] = *reinterpret_cast<const bf16x8*>(&Al[(mi * 16 + lr) * 40 + lg * 8]);
        }
        #pragma unroll
        for (int ni = 0; ni < 2; ++ni) {
            bfh[ni] = *reinterpret_cast<const bf16x8*>(&Bh[(w * 32 + ni * 16 + lr) * 40 + lg * 8]);
            bfl[ni] = *reinterpret_cast<const bf16x8*>(&Bl[(w * 32 + ni * 16 + lr) * 40 + lg * 8]);
        }
        #pragma unroll
        for (int mi = 0; mi < 4; ++mi)
            #pragma unroll
            for (int ni = 0; ni < 2; ++ni) {
                acc1[mi][ni] = __builtin_amdgcn_mfma_f32_16x16x32_bf16(afh[mi], bfh[ni], acc1[mi][ni], 0, 0, 0);
                acc1[mi][ni] = __builtin_amdgcn_mfma_f32_16x16x32_bf16(afl[mi], bfh[ni], acc1[mi][ni], 0, 0, 0);
                acc1[mi][ni] = __builtin_amdgcn_mfma_f32_16x16x32_bf16(afh[mi], bfl[ni], acc1[mi][ni], 0, 0, 0);
            }
        __syncthreads();
    }

    // ---- write xp: LDS hi + global packed {hi,lo} ----
    #pragma unroll
    for (int mi = 0; mi < 4; ++mi) {
        #pragma unroll
        for (int ni = 0; ni < 2; ++ni) {
            int col = w * 32 + ni * 16 + lr;
            #pragma unroll
            for (int r = 0; r < 4; ++r) {
                int rl = mi * 16 + lg * 4 + r;
                float v = acc1[mi][ni][r];
                short hi = f2bf(v);
                short lo = f2bf(v - bf2f(hi));
                xpH[rl * 136 + col] = hi;
                int row = row0 + rl;
                if (row < M)
                    xphl[(size_t)row * 128 + col] =
                        ((int)(unsigned short)lo << 16) | (unsigned short)hi;
            }
        }
    }
    __syncthreads();

    // ---- u = xp_hi . wl2 + wlb (vectorized LDS reads) ----
    #pragma unroll
    for (int o = tid; o < 512; o += 256) {
        int rl = o >> 3, s = o & 7;
        int row = row0 + rl;
        if (row < M) {
            float p = wlb[s];
            #pragma unroll
            for (int j = 0; j < 16; ++j) {
                bf16x8 xv = *reinterpret_cast<const bf16x8*>(&xpH[rl * 136 + j * 8]);
                #pragma unroll
                for (int k = 0; k < 8; ++k)
                    p += bf2f(xv[k]) * wl2[(j * 8 + k) * 8 + s];
            }
            ubuf[(size_t)row * 8 + s] = p;
        }
    }

    // ---- phase 2: per ct, MFMA then two 64-col fp8 bounced stores ----
    for (int ct = 0; ct < 8; ++ct) {
        f32x4 acc[4][2] = {};
        #pragma unroll
        for (int k = 0; k < 4; ++k) {
            bf16x8 bfr[2];
            #pragma unroll
            for (int ni = 0; ni < 2; ++ni) {
                int col = ct * 128 + ni * 64 + w * 16 + lr;
                bfr[ni] = *reinterpret_cast<const bf16x8*>(&wbBT[(size_t)col * 128 + k * 32 + lg * 8]);
            }
            bf16x8 ah[4];
            #pragma unroll
            for (int mi = 0; mi < 4; ++mi)
                ah[mi] = *reinterpret_cast<const bf16x8*>(&xpH[(mi * 16 + lr) * 136 + k * 32 + lg * 8]);
            #pragma unroll
            for (int mi = 0; mi < 4; ++mi)
                #pragma unroll
                for (int ni = 0; ni < 2; ++ni)
                    acc[mi][ni] = __builtin_amdgcn_mfma_f32_16x16x32_bf16(ah[mi], bfr[ni], acc[mi][ni], 0, 0, 0);
        }
        #pragma unroll
        for (int ni = 0; ni < 2; ++ni) {
            int loc = w * 16 + lr;                        // col within half
            int gcolbase = ct * 128 + ni * 64;
            float bv = wl1[(ni * 64 + loc) * 8 + ct];
            #pragma unroll
            for (int mi = 0; mi < 4; ++mi)
                #pragma unroll
                for (int r = 0; r < 4; ++r) {
                    int rl = mi * 16 + lg * 4 + r;
                    yb[rl * 80 + loc] = f2fp8(acc[mi][ni][r] + bv);
                }
            __syncthreads();
            // coalesced store: 4KB half, 256 threads x 16B
            {
                int rl = tid >> 2;                        // 64 B data per row
                int cs = (tid & 3) * 16;
                int row = row0 + rl;
                if (row < M) {
                    uchar16v v = *reinterpret_cast<const uchar16v*>(&yb[rl * 80 + cs]);
                    *reinterpret_cast<uchar16v*>(&Y[(size_t)row * 1024 + gcolbase + cs]) = v;
                }
            }
            __syncthreads();
        }
    }
}

// ========== rowdot8 (v only) ==========
template<int SPLITIN>
__global__ __launch_bounds__(256) void rowdot8(const short* __restrict__ Ah,
                                               const short* __restrict__ Al,
                                               const float* __restrict__ Wg,
                                               const float* __restrict__ bias8,
                                               float* __restrict__ out, int M) {
    __shared__ float sw[128][9];
    __shared__ float sb[8];
    for (int i = threadIdx.x; i < 1024; i += 256) sw[i >> 3][i & 7] = Wg[i];
    if (threadIdx.x < 8) sb[threadIdx.x] = bias8 ? bias8[threadIdx.x] : 0.f;
    __syncthreads();
    int r = blockIdx.x * 4 + (threadIdx.x >> 6);
    if (r >= M) return;
    int l = threadIdx.x & 63;
    int s = l & 7, c0 = (l >> 3) * 16;
    const short* ah = Ah + (size_t)r * 128 + c0;
    bf16x8 h0 = *reinterpret_cast<const bf16x8*>(ah);
    bf16x8 h1 = *reinterpret_cast<const bf16x8*>(ah + 8);
    float p = 0.f;
    #pragma unroll
    for (int j = 0; j < 8; ++j) {
        p += bf2f(h0[j]) * sw[c0 + j][s];
        p += bf2f(h1[j]) * sw[c0 + 8 + j][s];
    }
    p += __shfl_xor(p, 8); p += __shfl_xor(p, 16); p += __shfl_xor(p, 32);
    if (l < 8) out[(size_t)r * 8 + l] = p + sb[l];
}

// ========== fused edge kernel v4 (packed xp, fp8 Y) ==========
__global__ __launch_bounds__(256) void edge_fused2(const int* __restrict__ xphl,
                                                   const short* __restrict__ ep,
                                                   const unsigned char* __restrict__ Y,
                                                   const int* __restrict__ ei,
                                                   const float* __restrict__ u,
                                                   const float* __restrict__ v,
                                                   float* __restrict__ agg, int E) {
    int e = blockIdx.x * 4 + (threadIdx.x >> 6);
    if (e >= E) return;
    int l = threadIdx.x & 63;
    int s = l & 7, c0 = (l >> 3) * 16;
    int src = ei[e], dst = ei[E + e];
    const unsigned char* y = Y + (size_t)src * 1024 + s * 128 + c0;
    uchar16v yv = *reinterpret_cast<const uchar16v*>(y);
    const short* xi = (const short*)(xphl + (size_t)dst * 128 + c0);
    short16v xv0 = *reinterpret_cast<const short16v*>(xi);
    short16v xv1 = *reinterpret_cast<const short16v*>(xi + 16);
    float p = 0.f;
    #pragma unroll
    for (int j = 0; j < 8; ++j) {
        p += (bf2f(xv0[2 * j]) + bf2f(xv0[2 * j + 1])) * fp82f(yv[j]);
        p += (bf2f(xv1[2 * j]) + bf2f(xv1[2 * j + 1])) * fp82f(yv[8 + j]);
    }
    p += __shfl_xor(p, 8); p += __shfl_xor(p, 16); p += __shfl_xor(p, 32);
    float alpha = tanhf(p + u[(size_t)src * 8 + s] + v[(size_t)e * 8 + s]);
    float aa0 = __shfl(alpha, l >> 4);
    float aa1 = __shfl(alpha, 4 + (l >> 4));
    int pj0 = xphl[(size_t)src * 128 + l];
    int pj1 = xphl[(size_t)src * 128 + l + 64];
    float xj0 = bf2f((short)(pj0 & 0xffff)) + bf2f((short)(pj0 >> 16));
    float xj1 = bf2f((short)(pj1 & 0xffff)) + bf2f((short)(pj1 >> 16));
    float e0 = bf2f(ep[(size_t)e * 128 + l]);
    float e1 = bf2f(ep[(size_t)e * 128 + l + 64]);
    atomicAdd(&agg[(size_t)dst * 128 + l],      fmaxf(xj0, e0) * aa0);
    atomicAdd(&agg[(size_t)dst * 128 + l + 64], fmaxf(xj1, e1) * aa1);
}

// ========== gate GEMM v2: 64-row tiles, split-3, K=256 combined, in place ==========
__global__ __launch_bounds__(256) void gate_gemm_split(float* __restrict__ h,
                                                       const float* __restrict__ aggv,
                                                       const short* __restrict__ BTh,
                                                       const short* __restrict__ BTl,
                                                       const float* __restrict__ gb,
                                                       int M) {
    __shared__ short Ah[64][40];
    __shared__ short Al[64][40];
    __shared__ short Bh[128][40];
    __shared__ short Bl[128][40];
    const int tid = threadIdx.x;
    const int row0 = blockIdx.x * 64;
    const int lane = tid & 63, w = tid >> 6;
    const int lr = lane & 15, lg = lane >> 4;
    f32x4 acc[4][2] = {};

    for (int k0 = 0; k0 < 256; k0 += 32) {
        int sec = k0 >> 7;
        #pragma unroll
        for (int i = 0; i < 2; ++i) {
            int idx = i * 256 + tid;
            int r = idx >> 3, q = idx & 7;
            int gr = row0 + r;
            int ks = (k0 & 127) + q * 4;
            f32x4 v;
            if (gr < M) {
                if (sec == 0) {
                    v = *reinterpret_cast<const f32x4*>(&h[(size_t)gr * 128 + ks]);
                } else {
                    f32x4 a = *reinterpret_cast<const f32x4*>(&aggv[(size_t)gr * 128 + ks]);
                    #pragma unroll
                    for (int j = 0; j < 4; ++j) v[j] = fmaxf(a[j], 0.f);
                }
            } else {
                #pragma unroll
                for (int j = 0; j < 4; ++j) v[j] = 0.f;
            }
            short4v hh, ll;
            #pragma unroll
            for (int j = 0; j < 4; ++j) {
                hh[j] = f2bf(v[j]);
                ll[j] = f2bf(v[j] - bf2f(hh[j]));
            }
            *reinterpret_cast<short4v*>(&Ah[r][q * 4]) = hh;
            *reinterpret_cast<short4v*>(&Al[r][q * 4]) = ll;
        }
        #pragma unroll
        for (int i = 0; i < 4; ++i) {
            int idx = i * 256 + tid;
            int r = idx >> 3, q = idx & 7;
            short4v uu = *reinterpret_cast<const short4v*>(&BTh[(size_t)r * 256 + k0 + q * 4]);
            short4v ul = *reinterpret_cast<const short4v*>(&BTl[(size_t)r * 256 + k0 + q * 4]);
            *reinterpret_cast<short4v*>(&Bh[r][q * 4]) = uu;
            *reinterpret_cast<short4v*>(&Bl[r][q * 4]) = ul;
        }
        __syncthreads();
        bf16x8 afh[4], afl[4], bfh[2], bfl[2];
        #pragma unroll
        for (int mi = 0; mi < 4; ++mi) {
            afh[mi] = *reinterpret_cast<const bf16x8*>(&Ah[mi * 16 + lr][lg * 8]);
            afl[mi] = *reinterpret_cast<const bf16x8*>(&Al[mi * 16 + lr][lg * 8]);
        }
        #pragma unroll
        for (int ni = 0; ni < 2; ++ni) {
            bfh[ni] = *reinterpret_cast<const bf16x8*>(&Bh[w * 32 + ni * 16 + lr][lg * 8]);
            bfl[ni] = *reinterpret_cast<const bf16x8*>(&Bl[w * 32 + ni * 16 + lr][lg * 8]);
        }
        #pragma unroll
        for (int mi = 0; mi < 4; ++mi)
            #pragma unroll
            for (int ni = 0; ni < 2; ++ni) {
                acc[mi][ni] = __builtin_amdgcn_mfma_f32_16x16x32_bf16(afh[mi], bfh[ni], acc[mi][ni], 0, 0, 0);
                acc[mi][ni] = __builtin_amdgcn_mfma_f32_16x16x32_bf16(afl[mi], bfh[ni], acc[mi][ni], 0, 0, 0);
                acc[mi][ni] = __builtin_amdgcn_mfma_f32_16x16x32_bf16(afh[mi], bfl[ni], acc[mi][ni], 0, 0, 0);
            }
        __syncthreads();
    }

    #pragma unroll
    for (int mi = 0; mi < 4; ++mi) {
        #pragma unroll
        for (int ni = 0; ni < 2; ++ni) {
            int col = w * 32 + ni * 16 + lr;
            float gbv = gb[col];
            #pragma unroll
            for (int r = 0; r < 4; ++r) {
                int row = row0 + mi * 16 + lg * 4 + r;
                if (row >= M) continue;
                float beta = fmaxf(acc[mi][ni][r] + gbv, 0.f);
                float hv = h[(size_t)row * 128 + col];
                float hh = fmaxf(aggv[(size_t)row * 128 + col], 0.f);
                h[(size_t)row * 128 + col] = beta * hv + (1.f - beta) * hh;
            }
        }
    }
}

// ========== batch norm ==========
__global__ void bn_stats(const float* __restrict__ z, float* __restrict__ gsum,
                         float* __restrict__ gsq, int M) {
    int c = threadIdx.x & 127;
    int rr = threadIdx.x >> 7;
    float s = 0.f, q = 0.f;
    for (int r = blockIdx.x * 2 + rr; r < M; r += gridDim.x * 2) {
        float v = z[(size_t)r * 128 + c];
        s += v; q += v * v;
    }
    __shared__ float ls[256], lq[256];
    ls[threadIdx.x] = s; lq[threadIdx.x] = q;
    __syncthreads();
    if (threadIdx.x < 128) {
        atomicAdd(&gsum[c], ls[threadIdx.x] + ls[threadIdx.x + 128]);
        atomicAdd(&gsq[c],  lq[threadIdx.x] + lq[threadIdx.x + 128]);
    }
}

__global__ void bn_apply(float* __restrict__ z, const float* __restrict__ gsum,
                         const float* __restrict__ gsq, const float* __restrict__ g,
                         const float* __restrict__ b, int M) {
    size_t total = (size_t)M * 128;
    for (size_t idx = (size_t)blockIdx.x * 256 + threadIdx.x; idx < total;
         idx += (size_t)gridDim.x * 256) {
        int c = idx & 127;
        float mu = gsum[c] / (float)M;
        float var = gsq[c] / (float)M - mu * mu;
        float rs = rsqrtf(var + EPS);
        float v = (z[idx] - mu) * rs * g[c] + b[c];
        z[idx] = fmaxf(v, 0.f);
    }
}

__global__ void bn_stats_bf(const short* __restrict__ z, float* __restrict__ gsum,
                            float* __restrict__ gsq, int M) {
    int c = threadIdx.x & 127;
    int rr = threadIdx.x >> 7;
    float s = 0.f, q = 0.f;
    for (int r = blockIdx.x * 2 + rr; r < M; r += gridDim.x * 2) {
        float v = bf2f(z[(size_t)r * 128 + c]);
        s += v; q += v * v;
    }
    __shared__ float ls[256], lq[256];
    ls[threadIdx.x] = s; lq[threadIdx.x] = q;
    __syncthreads();
    if (threadIdx.x < 128) {
        atomicAdd(&gsum[c], ls[threadIdx.x] + ls[threadIdx.x + 128]);
        atomicAdd(&gsq[c],  lq[threadIdx.x] + lq[threadIdx.x + 128]);
    }
}

__global__ void bn_apply_bf(short* __restrict__ z, const float* __restrict__ gsum,
                            const float* __restrict__ gsq, const float* __restrict__ g,
                            const float* __restrict__ b, int M) {
    size_t total = (size_t)M * 128;
    for (size_t idx = (size_t)blockIdx.x * 256 + threadIdx.x; idx < total;
         idx += (size_t)gridDim.x * 256) {
        int c = idx & 127;
        float mu = gsum[c] / (float)M;
        float var = gsq[c] / (float)M - mu * mu;
        float rs = rsqrtf(var + EPS);
        float v = (bf2f(z[idx]) - mu) * rs * g[c] + b[c];
        z[idx] = f2bf(fmaxf(v, 0.f));
    }
}

// ========== prep ==========
__global__ void transpose_split(const float* __restrict__ in, short* __restrict__ outh,
                                short* __restrict__ outl, int K, int N) {
    int idx = blockIdx.x * 256 + threadIdx.x;
    if (idx >= K * N) return;
    int nI = idx / K, k = idx - nI * K;
    float v = in[(size_t)k * N + nI];
    short h = f2bf(v);
    outh[idx] = h;
    outl[idx] = f2bf(v - bf2f(h));
}

__global__ void cvt_f2b(const float* __restrict__ in, short* __restrict__ out, int n) {
    int i = blockIdx.x * 256 + threadIdx.x;
    if (i < n) out[i] = f2bf(in[i]);
}

__global__ void gate_combine_split(const float* __restrict__ gw, short* __restrict__ BTh,
                                   short* __restrict__ BTl) {
    int idx = blockIdx.x * 256 + threadIdx.x;
    if (idx >= 128 * 256) return;
    int n = idx >> 8, k = idx & 255;
    float v;
    if (k < 128) v = gw[(size_t)k * 128 + n] + gw[(size_t)(256 + k) * 128 + n];
    else {
        int kk = k - 128;
        v = gw[(size_t)(128 + kk) * 128 + n] - gw[(size_t)(256 + kk) * 128 + n];
    }
    short h = f2bf(v);
    BTh[idx] = h;
    BTl[idx] = f2bf(v - bf2f(h));
}

__global__ void build_wm(const float* __restrict__ wsrc, float* __restrict__ wm) {
    int idx = blockIdx.x * 256 + threadIdx.x;
    if (idx >= 128 * 128) return;
    int d = idx >> 7, c = idx & 127;
    float s = 0.f;
    #pragma unroll
    for (int h = 0; h < 8; ++h) s += wsrc[(size_t)d * 1024 + h * 128 + c];
    wm[idx] = s * 0.125f;
}

__global__ void perm_build(const int* __restrict__ ci, int* __restrict__ perm, int NF) {
    int i = blockIdx.x * 256 + threadIdx.x;
    if (i >= NF) return;
    int c = ci[i];
    if (i == 0 || ci[i - 1] != c) perm[c] = i;
}

__global__ void seg_pool(const float* __restrict__ fx, const int* __restrict__ perm,
                         float* __restrict__ pool, int F, int NF) {
    int idx = blockIdx.x * 256 + threadIdx.x;
    if (idx >= F * 128) return;
    int f = idx >> 7, c = idx & 127;
    int s = perm[f];
    int e = (f + 1 < F) ? perm[f + 1] : NF;
    float acc = 0.f;
    for (int i = s; i < e; ++i) acc += fx[(size_t)i * 128 + c];
    pool[idx] = fmaxf(acc, 0.f);
}

// ========== output ==========
__global__ __launch_bounds__(256) void out_phase1(const float* __restrict__ h,
                                                  const float* __restrict__ out_w,
                                                  const float* __restrict__ out_b,
                                                  const float* __restrict__ gat_bias,
                                                  float* __restrict__ out, int M) {
    int n = blockIdx.x * 4 + (threadIdx.x >> 6);
    if (n >= M) return;
    int l = threadIdx.x & 63;
    float p = fmaxf(h[(size_t)n * 128 + l], 0.f) * out_w[l]
            + fmaxf(h[(size_t)n * 128 + l + 64], 0.f) * out_w[l + 64];
    p += fmaxf(gat_bias[l], 0.f) * out_w[128 + l]
       + fmaxf(gat_bias[l + 64], 0.f) * out_w[128 + l + 64];
    #pragma unroll
    for (int off = 32; off; off >>= 1) p += __shfl_xor(p, off);
    if (l == 0) out[n] = p + out_b[0];
}

__global__ __launch_bounds__(256) void out_phase2(const float* __restrict__ fmv,
                                                  const int* __restrict__ perm,
                                                  const float* __restrict__ out_w,
                                                  const float* __restrict__ gat_bias,
                                                  float* __restrict__ out, int F) {
    int f = blockIdx.x * 4 + (threadIdx.x >> 6);
    if (f >= F) return;
    int l = threadIdx.x & 63;
    float p = fmv[(size_t)f * 128 + l] * out_w[128 + l]
            + fmv[(size_t)f * 128 + l + 64] * out_w[128 + l + 64];
    float b = fmaxf(gat_bias[l], 0.f) * out_w[128 + l]
            + fmaxf(gat_bias[l + 64], 0.f) * out_w[128 + l + 64];
    float d = p - b;
    #pragma unroll
    for (int off = 32; off; off >>= 1) d += __shfl_xor(d, off);
    if (l == 0) out[perm[f]] += d;
}

// ========== host ==========
extern "C" void kernel_launch(void* const* d_in, const int* in_sizes, int n_in,
                              void* d_out, int out_size, void* d_ws, size_t ws_size,
                              hipStream_t stream) {
    const int N = 50000, E = 100000, NF = 20000, EF = 40000, F = 10000;

    const float* x          = (const float*)d_in[0];
    const float* edge_attr  = (const float*)d_in[1];
    const float* frag_x     = (const float*)d_in[2];
    const float* frag_ea    = (const float*)d_in[3];
    const float* la_w = (const float*)d_in[4];
    const float* la_b = (const float*)d_in[5];
    const float* lb_w = (const float*)d_in[6];
    const float* lb_b = (const float*)d_in[7];
    const float* bn1_g = (const float*)d_in[8];
    const float* bn1_b = (const float*)d_in[9];
    const float* bn2_g = (const float*)d_in[10];
    const float* bn2_b = (const float*)d_in[11];
    const float* wn = (const float*)d_in[12];
    const float* wb = (const float*)d_in[13];
    const float* wl = (const float*)d_in[14];
    const float* wlb = (const float*)d_in[15];
    const float* gate_w = (const float*)d_in[16];
    const float* gate_b = (const float*)d_in[17];
    const float* gat_wsrc = (const float*)d_in[18];
    const float* gat_bias = (const float*)d_in[22];
    const float* out_w = (const float*)d_in[23];
    const float* out_b = (const float*)d_in[24];
    const int* edge_index = (const int*)d_in[25];
    const int* frag_edge_index = (const int*)d_in[26];
    const int* cluster_index = (const int*)d_in[27];

    char* p = (char*)d_ws;
    auto alloc = [&](size_t bytes) { char* r = p; p += (bytes + 255) & ~(size_t)255; return (void*)r; };
    float* hA    = (float*)alloc((size_t)N * 128 * 4);
    short* ea1   = (short*)alloc((size_t)E * 128 * 2);
    int*   xphl  = (int*)alloc((size_t)N * 128 * 4);
    short* ep    = (short*)alloc((size_t)E * 128 * 2);
    unsigned char* Y = (unsigned char*)alloc((size_t)N * 1024);
    float* agg   = (float*)alloc((size_t)N * 128 * 4);
    float* ubuf  = (float*)alloc((size_t)N * 8 * 4);
    float* vbuf  = (float*)alloc((size_t)E * 8 * 4);
    short* la_wTh = (short*)alloc(128 * 128 * 2);
    short* la_wTl = (short*)alloc(128 * 128 * 2);
    short* lb_wTh = (short*)alloc(128 * 16 * 2);
    short* lb_wTl = (short*)alloc(128 * 16 * 2);
    short* wnTh   = (short*)alloc(3 * 128 * 128 * 2);
    short* wnTl   = (short*)alloc(3 * 128 * 128 * 2);
    short* wbH    = (short*)alloc(3 * 1024 * 128 * 2);
    short* gate2Th = (short*)alloc(128 * 256 * 2);
    short* gate2Tl = (short*)alloc(128 * 256 * 2);
    float* wmF    = (float*)alloc(128 * 128 * 4);
    short* wmTh   = (short*)alloc(128 * 128 * 2);
    short* wmTl   = (short*)alloc(128 * 128 * 2);
    float* stats  = (float*)alloc(256 * 4);
    char* yq = (char*)Y;
    float* fpool = (float*)yq;              yq += (size_t)F * 128 * 4;
    float* fmv   = (float*)yq;              yq += (size_t)F * 128 * 4;
    int*   perm  = (int*)yq;

    auto cdiv = [](int a, int b) { return (a + b - 1) / b; };

    // ---- weight prep ----
    transpose_split<<<cdiv(128 * 128, 256), 256, 0, stream>>>(la_w, la_wTh, la_wTl, 128, 128);
    transpose_split<<<cdiv(16 * 128, 256), 256, 0, stream>>>(lb_w, lb_wTh, lb_wTl, 16, 128);
    for (int l = 0; l < 3; ++l)
        transpose_split<<<cdiv(128 * 128, 256), 256, 0, stream>>>(
            wn + (size_t)l * 16384, wnTh + (size_t)l * 16384, wnTl + (size_t)l * 16384, 128, 128);
    cvt_f2b<<<cdiv(3 * 1024 * 128, 256), 256, 0, stream>>>(wb, wbH, 3 * 1024 * 128);
    gate_combine_split<<<cdiv(128 * 256, 256), 256, 0, stream>>>(gate_w, gate2Th, gate2Tl);
    build_wm<<<cdiv(128 * 128, 256), 256, 0, stream>>>(gat_wsrc, wmF);
    transpose_split<<<cdiv(128 * 128, 256), 256, 0, stream>>>(wmF, wmTh, wmTl, 128, 128);

    auto run_layer = [&](float* h, const short* ea_buf, const int* ei, int Mn, int Me, int layer) {
        const short* wnTh_l = wnTh + (size_t)layer * 16384;
        const short* wnTl_l = wnTl + (size_t)layer * 16384;
        const short* wb_l   = wbH + (size_t)layer * 131072;
        const float* wl_l   = wl + (size_t)layer * 384 * 8;
        const float* wlb_l  = wlb + (size_t)layer * 8;
        fused_xpy<<<cdiv(Mn, 64), 256, 0, stream>>>(h, wnTh_l, wnTl_l, wb_l, wl_l,
                                                    wl_l + 256 * 8, wlb_l, xphl, ubuf, Y, Mn);
        gemm_bf16<0, 1><<<dim3(1, cdiv(Me, 128)), 256, 0, stream>>>(ea_buf, wnTh_l, nullptr, ep, Me, 128, 128);
        rowdot8<0><<<cdiv(Me, 4), 256, 0, stream>>>(ep, nullptr, wl_l + 128 * 8, nullptr, vbuf, Me);
        hipMemsetAsync(agg, 0, (size_t)Mn * 128 * 4, stream);
        edge_fused2<<<cdiv(Me, 4), 256, 0, stream>>>(xphl, ep, Y, ei, ubuf, vbuf, agg, Me);
        gate_gemm_split<<<cdiv(Mn, 64), 256, 0, stream>>>(h, agg, gate2Th, gate2Tl, gate_b, Mn);
    };

    // ---- atom path ----
    gemm_split<3, 0, 0><<<dim3(1, cdiv(N, 128)), 256, 0, stream>>>(x, la_wTh, la_wTl, la_b, hA, nullptr, N, 128, 128);
    hipMemsetAsync(stats, 0, 1024, stream);
    bn_stats<<<256, 256, 0, stream>>>(hA, stats, stats + 128, N);
    bn_apply<<<2048, 256, 0, stream>>>(hA, stats, stats + 128, bn1_g, bn1_b, N);

    gemm_split<3, 0, 1><<<dim3(1, cdiv(E, 128)), 256, 0, stream>>>(edge_attr, lb_wTh, lb_wTl, lb_b, ea1, nullptr, E, 128, 16);
    hipMemsetAsync(stats, 0, 1024, stream);
    bn_stats_bf<<<256, 256, 0, stream>>>(ea1, stats, stats + 128, E);
    bn_apply_bf<<<2048, 256, 0, stream>>>(ea1, stats, stats + 128, bn2_g, bn2_b, E);

    for (int l = 0; l < 3; ++l) run_layer(hA, ea1, edge_index, N, E, l);
    out_phase1<<<cdiv(N, 4), 256, 0, stream>>>(hA, out_w, out_b, gat_bias, (float*)d_out, N);

    // ---- fragment path ----
    gemm_split<3, 1, 0><<<dim3(1, cdiv(NF, 128)), 256, 0, stream>>>(frag_x, la_wTh, la_wTl, la_b, hA, nullptr, NF, 128, 128);

    gemm_split<3, 0, 1><<<dim3(1, cdiv(EF, 128)), 256, 0, stream>>>(frag_ea, lb_wTh, lb_wTl, lb_b, ea1, nullptr, EF, 128, 16);
    hipMemsetAsync(stats, 0, 1024, stream);
    bn_stats_bf<<<256, 256, 0, stream>>>(ea1, stats, stats + 128, EF);
    bn_apply_bf<<<2048, 256, 0, stream>>>(ea1, stats, stats + 128, bn2_g, bn2_b, EF);

    for (int l = 0; l < 3; ++l) run_layer(hA, ea1, frag_edge_index, NF, EF, l);

    perm_build<<<cdiv(NF, 256), 256, 0, stream>>>(cluster_index, perm, NF);
    seg_pool<<<cdiv(F * 128, 256), 256, 0, stream>>>(hA, perm, fpool, F, NF);
    gemm_split<3, 1, 0><<<dim3(1, cdiv(F, 128)), 256, 0, stream>>>(fpool, wmTh, wmTl, gat_bias, fmv, nullptr, F, 128, 128);
    out_phase2<<<cdiv(F, 4), 256, 0, stream>>>(fmv, perm, out_w, gat_bias, (float*)d_out, F);
}

// Round 13
// 1243.250 us; speedup vs baseline: 1.3729x; 1.0158x over previous
//
#include <hip/hip_runtime.h>
#include <hip/hip_bf16.h>
#include <hip/hip_fp8.h>

#define EPS 1e-5f

typedef short bf16x8 __attribute__((ext_vector_type(8)));
typedef short short4v __attribute__((ext_vector_type(4)));
typedef short short16v __attribute__((ext_vector_type(16)));
typedef float f32x4 __attribute__((ext_vector_type(4)));
typedef unsigned char uchar16v __attribute__((ext_vector_type(16)));

static __device__ __forceinline__ short f2bf(float x) {
    __hip_bfloat16 h = __float2bfloat16(x);
    return *reinterpret_cast<short*>(&h);
}
static __device__ __forceinline__ float bf2f(short x) {
    __hip_bfloat16 h;
    *reinterpret_cast<short*>(&h) = x;
    return __bfloat162float(h);
}
static __device__ __forceinline__ unsigned char f2fp8(float x) {
    __hip_fp8_e4m3 q(x);
    return (unsigned char)q.__x;
}
static __device__ __forceinline__ float fp82f(unsigned char b) {
    __hip_fp8_e4m3 q;
    q.__x = (__hip_fp8_storage_t)b;
    return (float)q;
}

// ========== split-bf16 MFMA GEMM: C = act(A[M,K](f32) @ BT[N,K]^T + bias) ==========
template<int SPLIT, int ACT, int OUTM>
__global__ __launch_bounds__(256) void gemm_split(const float* __restrict__ A,
                                                  const short* __restrict__ BTh,
                                                  const short* __restrict__ BTl,
                                                  const float* __restrict__ bias,
                                                  void* __restrict__ Cout,
                                                  void* __restrict__ Cout2,
                                                  int M, int N, int K) {
    __shared__ short Ah[128][40];
    __shared__ short Al[128][40];
    __shared__ short Bh[128][40];
    __shared__ short Bl[128][40];
    const int tid = threadIdx.x;
    const int row0 = blockIdx.y * 128, col0 = blockIdx.x * 128;
    const int lane = tid & 63, w = tid >> 6;
    const int wr = w >> 1, wc = w & 1;
    const int lr = lane & 15, lg = lane >> 4;
    f32x4 acc[4][4] = {};

    for (int k0 = 0; k0 < K; k0 += 32) {
        #pragma unroll
        for (int i = 0; i < 4; ++i) {
            int idx = i * 256 + tid;
            int r = idx >> 3, q = idx & 7;
            int gr = row0 + r, gk = k0 + q * 4;
            f32x4 v;
            if (gr < M && gk + 3 < K) {
                v = *reinterpret_cast<const f32x4*>(&A[(size_t)gr * K + gk]);
            } else {
                #pragma unroll
                for (int j = 0; j < 4; ++j)
                    v[j] = (gr < M && gk + j < K) ? A[(size_t)gr * K + gk + j] : 0.f;
            }
            short4v h, l;
            #pragma unroll
            for (int j = 0; j < 4; ++j) {
                h[j] = f2bf(v[j]);
                l[j] = f2bf(v[j] - bf2f(h[j]));
            }
            *reinterpret_cast<short4v*>(&Ah[r][q * 4]) = h;
            *reinterpret_cast<short4v*>(&Al[r][q * 4]) = l;
        }
        #pragma unroll
        for (int i = 0; i < 4; ++i) {
            int idx = i * 256 + tid;
            int r = idx >> 3, q = idx & 7;
            int gc = col0 + r, gk = k0 + q * 4;
            short4v u, ul;
            if (gk + 3 < K) {
                u = *reinterpret_cast<const short4v*>(&BTh[(size_t)gc * K + gk]);
                if (SPLIT == 3) ul = *reinterpret_cast<const short4v*>(&BTl[(size_t)gc * K + gk]);
            } else {
                #pragma unroll
                for (int j = 0; j < 4; ++j) {
                    u[j] = (gk + j < K) ? BTh[(size_t)gc * K + gk + j] : (short)0;
                    if (SPLIT == 3) ul[j] = (gk + j < K) ? BTl[(size_t)gc * K + gk + j] : (short)0;
                }
            }
            *reinterpret_cast<short4v*>(&Bh[r][q * 4]) = u;
            if (SPLIT == 3) *reinterpret_cast<short4v*>(&Bl[r][q * 4]) = ul;
        }
        __syncthreads();
        bf16x8 afh[4], afl[4], bfh[4];
        #pragma unroll
        for (int mi = 0; mi < 4; ++mi) {
            afh[mi] = *reinterpret_cast<const bf16x8*>(&Ah[wr * 64 + mi * 16 + lr][lg * 8]);
            afl[mi] = *reinterpret_cast<const bf16x8*>(&Al[wr * 64 + mi * 16 + lr][lg * 8]);
        }
        #pragma unroll
        for (int ni = 0; ni < 4; ++ni)
            bfh[ni] = *reinterpret_cast<const bf16x8*>(&Bh[wc * 64 + ni * 16 + lr][lg * 8]);
        #pragma unroll
        for (int mi = 0; mi < 4; ++mi)
            #pragma unroll
            for (int ni = 0; ni < 4; ++ni) {
                acc[mi][ni] = __builtin_amdgcn_mfma_f32_16x16x32_bf16(afh[mi], bfh[ni], acc[mi][ni], 0, 0, 0);
                acc[mi][ni] = __builtin_amdgcn_mfma_f32_16x16x32_bf16(afl[mi], bfh[ni], acc[mi][ni], 0, 0, 0);
            }
        if (SPLIT == 3) {
            bf16x8 bfl[4];
            #pragma unroll
            for (int ni = 0; ni < 4; ++ni)
                bfl[ni] = *reinterpret_cast<const bf16x8*>(&Bl[wc * 64 + ni * 16 + lr][lg * 8]);
            #pragma unroll
            for (int mi = 0; mi < 4; ++mi)
                #pragma unroll
                for (int ni = 0; ni < 4; ++ni)
                    acc[mi][ni] = __builtin_amdgcn_mfma_f32_16x16x32_bf16(afh[mi], bfl[ni], acc[mi][ni], 0, 0, 0);
        }
        __syncthreads();
    }

    #pragma unroll
    for (int mi = 0; mi < 4; ++mi) {
        #pragma unroll
        for (int ni = 0; ni < 4; ++ni) {
            int col = col0 + wc * 64 + ni * 16 + lr;
            float bv = bias ? bias[col] : 0.f;
            #pragma unroll
            for (int r = 0; r < 4; ++r) {
                int row = row0 + wr * 64 + mi * 16 + lg * 4 + r;
                if (row >= M) continue;
                float v = acc[mi][ni][r] + bv;
                if (ACT) v = fmaxf(v, 0.f);
                if (OUTM == 0) ((float*)Cout)[(size_t)row * N + col] = v;
                else ((short*)Cout)[(size_t)row * N + col] = f2bf(v);
            }
        }
    }
}

// ========== plain bf16 GEMM (tolerant path: ep projection) ==========
template<int ACT, int OUTBF>
__global__ __launch_bounds__(256) void gemm_bf16(const short* __restrict__ A,
                                                 const short* __restrict__ BT,
                                                 const float* __restrict__ bias,
                                                 void* __restrict__ Cout,
                                                 int M, int N, int K) {
    __shared__ short As[128][40];
    __shared__ short Bs[128][40];
    const int tid = threadIdx.x;
    const int row0 = blockIdx.y * 128, col0 = blockIdx.x * 128;
    const int lane = tid & 63, w = tid >> 6;
    const int wr = w >> 1, wc = w & 1;
    const int lr = lane & 15, lg = lane >> 4;
    f32x4 acc[4][4] = {};

    for (int k0 = 0; k0 < K; k0 += 32) {
        #pragma unroll
        for (int i = 0; i < 4; ++i) {
            int idx = i * 256 + tid;
            int r = idx >> 3, q = idx & 7;
            int gk = k0 + q * 4;
            int gr = row0 + r;
            short4v v;
            if (gr < M && gk + 3 < K) {
                v = *reinterpret_cast<const short4v*>(&A[(size_t)gr * K + gk]);
            } else {
                #pragma unroll
                for (int j = 0; j < 4; ++j)
                    v[j] = (gr < M && gk + j < K) ? A[(size_t)gr * K + gk + j] : (short)0;
            }
            *reinterpret_cast<short4v*>(&As[r][q * 4]) = v;
            int gc = col0 + r;
            short4v u;
            if (gc < N && gk + 3 < K) {
                u = *reinterpret_cast<const short4v*>(&BT[(size_t)gc * K + gk]);
            } else {
                #pragma unroll
                for (int j = 0; j < 4; ++j)
                    u[j] = (gc < N && gk + j < K) ? BT[(size_t)gc * K + gk + j] : (short)0;
            }
            *reinterpret_cast<short4v*>(&Bs[r][q * 4]) = u;
        }
        __syncthreads();
        bf16x8 af[4], bfr[4];
        #pragma unroll
        for (int mi = 0; mi < 4; ++mi)
            af[mi] = *reinterpret_cast<const bf16x8*>(&As[wr * 64 + mi * 16 + lr][lg * 8]);
        #pragma unroll
        for (int ni = 0; ni < 4; ++ni)
            bfr[ni] = *reinterpret_cast<const bf16x8*>(&Bs[wc * 64 + ni * 16 + lr][lg * 8]);
        #pragma unroll
        for (int mi = 0; mi < 4; ++mi)
            #pragma unroll
            for (int ni = 0; ni < 4; ++ni)
                acc[mi][ni] = __builtin_amdgcn_mfma_f32_16x16x32_bf16(af[mi], bfr[ni], acc[mi][ni], 0, 0, 0);
        __syncthreads();
    }

    #pragma unroll
    for (int mi = 0; mi < 4; ++mi) {
        #pragma unroll
        for (int ni = 0; ni < 4; ++ni) {
            int col = col0 + wc * 64 + ni * 16 + lr;
            float bv = bias ? bias[col] : 0.f;
            #pragma unroll
            for (int r = 0; r < 4; ++r) {
                int row = row0 + wr * 64 + mi * 16 + lg * 4 + r;
                if (row >= M) continue;
                float v = acc[mi][ni][r] + bv;
                if (ACT) v = fmaxf(v, 0.f);
                if (OUTBF) ((short*)Cout)[(size_t)row * N + col] = f2bf(v);
                else       ((float*)Cout)[(size_t)row * N + col] = v;
            }
        }
    }
}

// ========== fused xp + Y kernel v7: transposed-operand phase 2, u32 fp8 packing ==========
__global__ __launch_bounds__(256) void fused_xpy(const float* __restrict__ h,
                                                 const short* __restrict__ wnTh,
                                                 const short* __restrict__ wnTl,
                                                 const short* __restrict__ wbBT,
                                                 const float* __restrict__ wl1,
                                                 const float* __restrict__ wl2,
                                                 const float* __restrict__ wlb,
                                                 int* __restrict__ xphl,
                                                 float* __restrict__ ubuf,
                                                 unsigned char* __restrict__ Y, int M) {
    __shared__ short sbuf[15360];
    __shared__ unsigned char yb[64 * 136];   // 8704 B fp8 full-ct bounce
    short* Ah = sbuf;                        // 64 x 40
    short* Al = sbuf + 2560;
    short* Bh = sbuf + 5120;                 // 128 x 40
    short* Bl = sbuf + 10240;
    short* xpH = sbuf;                       // 64 x 136 (aliases staging after phase-1 final barrier)

    const int tid = threadIdx.x;
    const int row0 = blockIdx.x * 64;
    const int lane = tid & 63, w = tid >> 6;
    const int lr = lane & 15, lg = lane >> 4;

    // ---- phase 1 ----
    f32x4 acc1[4][2] = {};
    for (int k0 = 0; k0 < 128; k0 += 32) {
        #pragma unroll
        for (int i = 0; i < 2; ++i) {
            int idx = i * 256 + tid;
            int r = idx >> 3, q = idx & 7;
            int gr = row0 + r, gk = k0 + q * 4;
            f32x4 v;
            if (gr < M) {
                v = *reinterpret_cast<const f32x4*>(&h[(size_t)gr * 128 + gk]);
            } else {
                #pragma unroll
                for (int j = 0; j < 4; ++j) v[j] = 0.f;
            }
            short4v hh, ll;
            #pragma unroll
            for (int j = 0; j < 4; ++j) {
                hh[j] = f2bf(v[j]);
                ll[j] = f2bf(v[j] - bf2f(hh[j]));
            }
            *reinterpret_cast<short4v*>(&Ah[r * 40 + q * 4]) = hh;
            *reinterpret_cast<short4v*>(&Al[r * 40 + q * 4]) = ll;
        }
        #pragma unroll
        for (int i = 0; i < 4; ++i) {
            int idx = i * 256 + tid;
            int r = idx >> 3, q = idx & 7;
            int gk = k0 + q * 4;
            short4v bh = *reinterpret_cast<const short4v*>(&wnTh[(size_t)r * 128 + gk]);
            short4v bl = *reinterpret_cast<const short4v*>(&wnTl[(size_t)r * 128 + gk]);
            *reinterpret_cast<short4v*>(&Bh[r * 40 + q * 4]) = bh;
            *reinterpret_cast<short4v*>(&Bl[r * 40 + q * 4]) = bl;
        }
        __syncthreads();
        bf16x8 afh[4], afl[4], bfh[2], bfl[2];
        #pragma unroll
        for (int mi = 0; mi < 4; ++mi) {
            afh[mi] = *reinterpret_cast<const bf16x8*>(&Ah[(mi * 16 + lr) * 40 + lg * 8]);
            afl[mi] = *reinterpret_cast<const bf16x8*>(&Al[(mi * 16 + lr) * 40 + lg * 8]);
        }
        #pragma unroll
        for (int ni = 0; ni < 2; ++ni) {
            bfh[ni] = *reinterpret_cast<const bf16x8*>(&Bh[(w * 32 + ni * 16 + lr) * 40 + lg * 8]);
            bfl[ni] = *reinterpret_cast<const bf16x8*>(&Bl[(w * 32 + ni * 16 + lr) * 40 + lg * 8]);
        }
        #pragma unroll
        for (int mi = 0; mi < 4; ++mi)
            #pragma unroll
            for (int ni = 0; ni < 2; ++ni) {
                acc1[mi][ni] = __builtin_amdgcn_mfma_f32_16x16x32_bf16(afh[mi], bfh[ni], acc1[mi][ni], 0, 0, 0);
                acc1[mi][ni] = __builtin_amdgcn_mfma_f32_16x16x32_bf16(afl[mi], bfh[ni], acc1[mi][ni], 0, 0, 0);
                acc1[mi][ni] = __builtin_amdgcn_mfma_f32_16x16x32_bf16(afh[mi], bfl[ni], acc1[mi][ni], 0, 0, 0);
            }
        __syncthreads();
    }

    // ---- write xp: LDS hi + global packed {hi,lo} ----
    #pragma unroll
    for (int mi = 0; mi < 4; ++mi) {
        #pragma unroll
        for (int ni = 0; ni < 2; ++ni) {
            int col = w * 32 + ni * 16 + lr;
            #pragma unroll
            for (int r = 0; r < 4; ++r) {
                int rl = mi * 16 + lg * 4 + r;
                float v = acc1[mi][ni][r];
                short hi = f2bf(v);
                short lo = f2bf(v - bf2f(hi));
                xpH[rl * 136 + col] = hi;
                int row = row0 + rl;
                if (row < M)
                    xphl[(size_t)row * 128 + col] =
                        ((int)(unsigned short)lo << 16) | (unsigned short)hi;
            }
        }
    }
    __syncthreads();

    // ---- u = xp_hi . wl2 + wlb (vectorized LDS reads) ----
    #pragma unroll
    for (int o = tid; o < 512; o += 256) {
        int rl = o >> 3, s = o & 7;
        int row = row0 + rl;
        if (row < M) {
            float p = wlb[s];
            #pragma unroll
            for (int j = 0; j < 16; ++j) {
                bf16x8 xv = *reinterpret_cast<const bf16x8*>(&xpH[rl * 136 + j * 8]);
                #pragma unroll
                for (int k = 0; k < 8; ++k)
                    p += bf2f(xv[k]) * wl2[(j * 8 + k) * 8 + s];
            }
            ubuf[(size_t)row * 8 + s] = p;
        }
    }

    // ---- phase 2 (transposed operands): accT[ni][mi] rows=Y cols, cols=Y rows ----
    for (int ct = 0; ct < 8; ++ct) {
        f32x4 accT[2][4] = {};
        #pragma unroll
        for (int k = 0; k < 4; ++k) {
            bf16x8 bfr[2];
            #pragma unroll
            for (int ni = 0; ni < 2; ++ni) {
                int col = ct * 128 + w * 32 + ni * 16 + lr;
                bfr[ni] = *reinterpret_cast<const bf16x8*>(&wbBT[(size_t)col * 128 + k * 32 + lg * 8]);
            }
            bf16x8 ah[4];
            #pragma unroll
            for (int mi = 0; mi < 4; ++mi)
                ah[mi] = *reinterpret_cast<const bf16x8*>(&xpH[(mi * 16 + lr) * 136 + k * 32 + lg * 8]);
            #pragma unroll
            for (int ni = 0; ni < 2; ++ni)
                #pragma unroll
                for (int mi = 0; mi < 4; ++mi)
                    accT[ni][mi] = __builtin_amdgcn_mfma_f32_16x16x32_bf16(bfr[ni], ah[mi], accT[ni][mi], 0, 0, 0);
        }
        // pack 4 consecutive Y-cols (lg*4+r) of one Y-row (mi*16+lr) into one u32
        #pragma unroll
        for (int ni = 0; ni < 2; ++ni) {
            int colg = w * 32 + ni * 16 + lg * 4;
            #pragma unroll
            for (int mi = 0; mi < 4; ++mi) {
                unsigned pk = 0;
                #pragma unroll
                for (int r = 0; r < 4; ++r) {
                    float v = accT[ni][mi][r] + wl1[(colg + r) * 8 + ct];
                    pk |= (unsigned)f2fp8(v) << (8 * r);
                }
                *reinterpret_cast<unsigned*>(&yb[(mi * 16 + lr) * 136 + colg]) = pk;
            }
        }
        __syncthreads();
        // coalesced store: 8KB tile, 2 passes x 256 threads x 16B
        #pragma unroll
        for (int pass = 0; pass < 2; ++pass) {
            int flat = pass * 4096 + tid * 16;
            int rl = flat >> 7, cs = flat & 127;
            int row = row0 + rl;
            if (row < M) {
                uchar16v vv = *reinterpret_cast<const uchar16v*>(&yb[rl * 136 + cs]);
                *reinterpret_cast<uchar16v*>(&Y[(size_t)row * 1024 + ct * 128 + cs]) = vv;
            }
        }
        __syncthreads();
    }
}

// ========== rowdot8 (v only) ==========
template<int SPLITIN>
__global__ __launch_bounds__(256) void rowdot8(const short* __restrict__ Ah,
                                               const short* __restrict__ Al,
                                               const float* __restrict__ Wg,
                                               const float* __restrict__ bias8,
                                               float* __restrict__ out, int M) {
    __shared__ float sw[128][9];
    __shared__ float sb[8];
    for (int i = threadIdx.x; i < 1024; i += 256) sw[i >> 3][i & 7] = Wg[i];
    if (threadIdx.x < 8) sb[threadIdx.x] = bias8 ? bias8[threadIdx.x] : 0.f;
    __syncthreads();
    int r = blockIdx.x * 4 + (threadIdx.x >> 6);
    if (r >= M) return;
    int l = threadIdx.x & 63;
    int s = l & 7, c0 = (l >> 3) * 16;
    const short* ah = Ah + (size_t)r * 128 + c0;
    bf16x8 h0 = *reinterpret_cast<const bf16x8*>(ah);
    bf16x8 h1 = *reinterpret_cast<const bf16x8*>(ah + 8);
    float p = 0.f;
    #pragma unroll
    for (int j = 0; j < 8; ++j) {
        p += bf2f(h0[j]) * sw[c0 + j][s];
        p += bf2f(h1[j]) * sw[c0 + 8 + j][s];
    }
    p += __shfl_xor(p, 8); p += __shfl_xor(p, 16); p += __shfl_xor(p, 32);
    if (l < 8) out[(size_t)r * 8 + l] = p + sb[l];
}

// ========== fused edge kernel v4 (packed xp, fp8 Y) ==========
__global__ __launch_bounds__(256) void edge_fused2(const int* __restrict__ xphl,
                                                   const short* __restrict__ ep,
                                                   const unsigned char* __restrict__ Y,
                                                   const int* __restrict__ ei,
                                                   const float* __restrict__ u,
                                                   const float* __restrict__ v,
                                                   float* __restrict__ agg, int E) {
    int e = blockIdx.x * 4 + (threadIdx.x >> 6);
    if (e >= E) return;
    int l = threadIdx.x & 63;
    int s = l & 7, c0 = (l >> 3) * 16;
    int src = ei[e], dst = ei[E + e];
    const unsigned char* y = Y + (size_t)src * 1024 + s * 128 + c0;
    uchar16v yv = *reinterpret_cast<const uchar16v*>(y);
    const short* xi = (const short*)(xphl + (size_t)dst * 128 + c0);
    short16v xv0 = *reinterpret_cast<const short16v*>(xi);
    short16v xv1 = *reinterpret_cast<const short16v*>(xi + 16);
    float p = 0.f;
    #pragma unroll
    for (int j = 0; j < 8; ++j) {
        p += (bf2f(xv0[2 * j]) + bf2f(xv0[2 * j + 1])) * fp82f(yv[j]);
        p += (bf2f(xv1[2 * j]) + bf2f(xv1[2 * j + 1])) * fp82f(yv[8 + j]);
    }
    p += __shfl_xor(p, 8); p += __shfl_xor(p, 16); p += __shfl_xor(p, 32);
    float alpha = tanhf(p + u[(size_t)src * 8 + s] + v[(size_t)e * 8 + s]);
    float aa0 = __shfl(alpha, l >> 4);
    float aa1 = __shfl(alpha, 4 + (l >> 4));
    int pj0 = xphl[(size_t)src * 128 + l];
    int pj1 = xphl[(size_t)src * 128 + l + 64];
    float xj0 = bf2f((short)(pj0 & 0xffff)) + bf2f((short)(pj0 >> 16));
    float xj1 = bf2f((short)(pj1 & 0xffff)) + bf2f((short)(pj1 >> 16));
    float e0 = bf2f(ep[(size_t)e * 128 + l]);
    float e1 = bf2f(ep[(size_t)e * 128 + l + 64]);
    atomicAdd(&agg[(size_t)dst * 128 + l],      fmaxf(xj0, e0) * aa0);
    atomicAdd(&agg[(size_t)dst * 128 + l + 64], fmaxf(xj1, e1) * aa1);
}

// ========== gate GEMM v2: 64-row tiles, split-3, K=256 combined, in place ==========
__global__ __launch_bounds__(256) void gate_gemm_split(float* __restrict__ h,
                                                       const float* __restrict__ aggv,
                                                       const short* __restrict__ BTh,
                                                       const short* __restrict__ BTl,
                                                       const float* __restrict__ gb,
                                                       int M) {
    __shared__ short Ah[64][40];
    __shared__ short Al[64][40];
    __shared__ short Bh[128][40];
    __shared__ short Bl[128][40];
    const int tid = threadIdx.x;
    const int row0 = blockIdx.x * 64;
    const int lane = tid & 63, w = tid >> 6;
    const int lr = lane & 15, lg = lane >> 4;
    f32x4 acc[4][2] = {};

    for (int k0 = 0; k0 < 256; k0 += 32) {
        int sec = k0 >> 7;
        #pragma unroll
        for (int i = 0; i < 2; ++i) {
            int idx = i * 256 + tid;
            int r = idx >> 3, q = idx & 7;
            int gr = row0 + r;
            int ks = (k0 & 127) + q * 4;
            f32x4 v;
            if (gr < M) {
                if (sec == 0) {
                    v = *reinterpret_cast<const f32x4*>(&h[(size_t)gr * 128 + ks]);
                } else {
                    f32x4 a = *reinterpret_cast<const f32x4*>(&aggv[(size_t)gr * 128 + ks]);
                    #pragma unroll
                    for (int j = 0; j < 4; ++j) v[j] = fmaxf(a[j], 0.f);
                }
            } else {
                #pragma unroll
                for (int j = 0; j < 4; ++j) v[j] = 0.f;
            }
            short4v hh, ll;
            #pragma unroll
            for (int j = 0; j < 4; ++j) {
                hh[j] = f2bf(v[j]);
                ll[j] = f2bf(v[j] - bf2f(hh[j]));
            }
            *reinterpret_cast<short4v*>(&Ah[r][q * 4]) = hh;
            *reinterpret_cast<short4v*>(&Al[r][q * 4]) = ll;
        }
        #pragma unroll
        for (int i = 0; i < 4; ++i) {
            int idx = i * 256 + tid;
            int r = idx >> 3, q = idx & 7;
            short4v uu = *reinterpret_cast<const short4v*>(&BTh[(size_t)r * 256 + k0 + q * 4]);
            short4v ul = *reinterpret_cast<const short4v*>(&BTl[(size_t)r * 256 + k0 + q * 4]);
            *reinterpret_cast<short4v*>(&Bh[r][q * 4]) = uu;
            *reinterpret_cast<short4v*>(&Bl[r][q * 4]) = ul;
        }
        __syncthreads();
        bf16x8 afh[4], afl[4], bfh[2], bfl[2];
        #pragma unroll
        for (int mi = 0; mi < 4; ++mi) {
            afh[mi] = *reinterpret_cast<const bf16x8*>(&Ah[mi * 16 + lr][lg * 8]);
            afl[mi] = *reinterpret_cast<const bf16x8*>(&Al[mi * 16 + lr][lg * 8]);
        }
        #pragma unroll
        for (int ni = 0; ni < 2; ++ni) {
            bfh[ni] = *reinterpret_cast<const bf16x8*>(&Bh[w * 32 + ni * 16 + lr][lg * 8]);
            bfl[ni] = *reinterpret_cast<const bf16x8*>(&Bl[w * 32 + ni * 16 + lr][lg * 8]);
        }
        #pragma unroll
        for (int mi = 0; mi < 4; ++mi)
            #pragma unroll
            for (int ni = 0; ni < 2; ++ni) {
                acc[mi][ni] = __builtin_amdgcn_mfma_f32_16x16x32_bf16(afh[mi], bfh[ni], acc[mi][ni], 0, 0, 0);
                acc[mi][ni] = __builtin_amdgcn_mfma_f32_16x16x32_bf16(afl[mi], bfh[ni], acc[mi][ni], 0, 0, 0);
                acc[mi][ni] = __builtin_amdgcn_mfma_f32_16x16x32_bf16(afh[mi], bfl[ni], acc[mi][ni], 0, 0, 0);
            }
        __syncthreads();
    }

    #pragma unroll
    for (int mi = 0; mi < 4; ++mi) {
        #pragma unroll
        for (int ni = 0; ni < 2; ++ni) {
            int col = w * 32 + ni * 16 + lr;
            float gbv = gb[col];
            #pragma unroll
            for (int r = 0; r < 4; ++r) {
                int row = row0 + mi * 16 + lg * 4 + r;
                if (row >= M) continue;
                float beta = fmaxf(acc[mi][ni][r] + gbv, 0.f);
                float hv = h[(size_t)row * 128 + col];
                float hh = fmaxf(aggv[(size_t)row * 128 + col], 0.f);
                h[(size_t)row * 128 + col] = beta * hv + (1.f - beta) * hh;
            }
        }
    }
}

// ========== batch norm ==========
__global__ void bn_stats(const float* __restrict__ z, float* __restrict__ gsum,
                         float* __restrict__ gsq, int M) {
    int c = threadIdx.x & 127;
    int rr = threadIdx.x >> 7;
    float s = 0.f, q = 0.f;
    for (int r = blockIdx.x * 2 + rr; r < M; r += gridDim.x * 2) {
        float v = z[(size_t)r * 128 + c];
        s += v; q += v * v;
    }
    __shared__ float ls[256], lq[256];
    ls[threadIdx.x] = s; lq[threadIdx.x] = q;
    __syncthreads();
    if (threadIdx.x < 128) {
        atomicAdd(&gsum[c], ls[threadIdx.x] + ls[threadIdx.x + 128]);
        atomicAdd(&gsq[c],  lq[threadIdx.x] + lq[threadIdx.x + 128]);
    }
}

__global__ void bn_apply(float* __restrict__ z, const float* __restrict__ gsum,
                         const float* __restrict__ gsq, const float* __restrict__ g,
                         const float* __restrict__ b, int M) {
    size_t total = (size_t)M * 128;
    for (size_t idx = (size_t)blockIdx.x * 256 + threadIdx.x; idx < total;
         idx += (size_t)gridDim.x * 256) {
        int c = idx & 127;
        float mu = gsum[c] / (float)M;
        float var = gsq[c] / (float)M - mu * mu;
        float rs = rsqrtf(var + EPS);
        float v = (z[idx] - mu) * rs * g[c] + b[c];
        z[idx] = fmaxf(v, 0.f);
    }
}

__global__ void bn_stats_bf(const short* __restrict__ z, float* __restrict__ gsum,
                            float* __restrict__ gsq, int M) {
    int c = threadIdx.x & 127;
    int rr = threadIdx.x >> 7;
    float s = 0.f, q = 0.f;
    for (int r = blockIdx.x * 2 + rr; r < M; r += gridDim.x * 2) {
        float v = bf2f(z[(size_t)r * 128 + c]);
        s += v; q += v * v;
    }
    __shared__ float ls[256], lq[256];
    ls[threadIdx.x] = s; lq[threadIdx.x] = q;
    __syncthreads();
    if (threadIdx.x < 128) {
        atomicAdd(&gsum[c], ls[threadIdx.x] + ls[threadIdx.x + 128]);
        atomicAdd(&gsq[c],  lq[threadIdx.x] + lq[threadIdx.x + 128]);
    }
}

__global__ void bn_apply_bf(short* __restrict__ z, const float* __restrict__ gsum,
                            const float* __restrict__ gsq, const float* __restrict__ g,
                            const float* __restrict__ b, int M) {
    size_t total = (size_t)M * 128;
    for (size_t idx = (size_t)blockIdx.x * 256 + threadIdx.x; idx < total;
         idx += (size_t)gridDim.x * 256) {
        int c = idx & 127;
        float mu = gsum[c] / (float)M;
        float var = gsq[c] / (float)M - mu * mu;
        float rs = rsqrtf(var + EPS);
        float v = (bf2f(z[idx]) - mu) * rs * g[c] + b[c];
        z[idx] = f2bf(fmaxf(v, 0.f));
    }
}

// ========== prep ==========
__global__ void transpose_split(const float* __restrict__ in, short* __restrict__ outh,
                                short* __restrict__ outl, int K, int N) {
    int idx = blockIdx.x * 256 + threadIdx.x;
    if (idx >= K * N) return;
    int nI = idx / K, k = idx - nI * K;
    float v = in[(size_t)k * N + nI];
    short h = f2bf(v);
    outh[idx] = h;
    outl[idx] = f2bf(v - bf2f(h));
}

__global__ void cvt_f2b(const float* __restrict__ in, short* __restrict__ out, int n) {
    int i = blockIdx.x * 256 + threadIdx.x;
    if (i < n) out[i] = f2bf(in[i]);
}

__global__ void gate_combine_split(const float* __restrict__ gw, short* __restrict__ BTh,
                                   short* __restrict__ BTl) {
    int idx = blockIdx.x * 256 + threadIdx.x;
    if (idx >= 128 * 256) return;
    int n = idx >> 8, k = idx & 255;
    float v;
    if (k < 128) v = gw[(size_t)k * 128 + n] + gw[(size_t)(256 + k) * 128 + n];
    else {
        int kk = k - 128;
        v = gw[(size_t)(128 + kk) * 128 + n] - gw[(size_t)(256 + kk) * 128 + n];
    }
    short h = f2bf(v);
    BTh[idx] = h;
    BTl[idx] = f2bf(v - bf2f(h));
}

__global__ void build_wm(const float* __restrict__ wsrc, float* __restrict__ wm) {
    int idx = blockIdx.x * 256 + threadIdx.x;
    if (idx >= 128 * 128) return;
    int d = idx >> 7, c = idx & 127;
    float s = 0.f;
    #pragma unroll
    for (int h = 0; h < 8; ++h) s += wsrc[(size_t)d * 1024 + h * 128 + c];
    wm[idx] = s * 0.125f;
}

__global__ void perm_build(const int* __restrict__ ci, int* __restrict__ perm, int NF) {
    int i = blockIdx.x * 256 + threadIdx.x;
    if (i >= NF) return;
    int c = ci[i];
    if (i == 0 || ci[i - 1] != c) perm[c] = i;
}

__global__ void seg_pool(const float* __restrict__ fx, const int* __restrict__ perm,
                         float* __restrict__ pool, int F, int NF) {
    int idx = blockIdx.x * 256 + threadIdx.x;
    if (idx >= F * 128) return;
    int f = idx >> 7, c = idx & 127;
    int s = perm[f];
    int e = (f + 1 < F) ? perm[f + 1] : NF;
    float acc = 0.f;
    for (int i = s; i < e; ++i) acc += fx[(size_t)i * 128 + c];
    pool[idx] = fmaxf(acc, 0.f);
}

// ========== output ==========
__global__ __launch_bounds__(256) void out_phase1(const float* __restrict__ h,
                                                  const float* __restrict__ out_w,
                                                  const float* __restrict__ out_b,
                                                  const float* __restrict__ gat_bias,
                                                  float* __restrict__ out, int M) {
    int n = blockIdx.x * 4 + (threadIdx.x >> 6);
    if (n >= M) return;
    int l = threadIdx.x & 63;
    float p = fmaxf(h[(size_t)n * 128 + l], 0.f) * out_w[l]
            + fmaxf(h[(size_t)n * 128 + l + 64], 0.f) * out_w[l + 64];
    p += fmaxf(gat_bias[l], 0.f) * out_w[128 + l]
       + fmaxf(gat_bias[l + 64], 0.f) * out_w[128 + l + 64];
    #pragma unroll
    for (int off = 32; off; off >>= 1) p += __shfl_xor(p, off);
    if (l == 0) out[n] = p + out_b[0];
}

__global__ __launch_bounds__(256) void out_phase2(const float* __restrict__ fmv,
                                                  const int* __restrict__ perm,
                                                  const float* __restrict__ out_w,
                                                  const float* __restrict__ gat_bias,
                                                  float* __restrict__ out, int F) {
    int f = blockIdx.x * 4 + (threadIdx.x >> 6);
    if (f >= F) return;
    int l = threadIdx.x & 63;
    float p = fmv[(size_t)f * 128 + l] * out_w[128 + l]
            + fmv[(size_t)f * 128 + l + 64] * out_w[128 + l + 64];
    float b = fmaxf(gat_bias[l], 0.f) * out_w[128 + l]
            + fmaxf(gat_bias[l + 64], 0.f) * out_w[128 + l + 64];
    float d = p - b;
    #pragma unroll
    for (int off = 32; off; off >>= 1) d += __shfl_xor(d, off);
    if (l == 0) out[perm[f]] += d;
}

// ========== host ==========
extern "C" void kernel_launch(void* const* d_in, const int* in_sizes, int n_in,
                              void* d_out, int out_size, void* d_ws, size_t ws_size,
                              hipStream_t stream) {
    const int N = 50000, E = 100000, NF = 20000, EF = 40000, F = 10000;

    const float* x          = (const float*)d_in[0];
    const float* edge_attr  = (const float*)d_in[1];
    const float* frag_x     = (const float*)d_in[2];
    const float* frag_ea    = (const float*)d_in[3];
    const float* la_w = (const float*)d_in[4];
    const float* la_b = (const float*)d_in[5];
    const float* lb_w = (const float*)d_in[6];
    const float* lb_b = (const float*)d_in[7];
    const float* bn1_g = (const float*)d_in[8];
    const float* bn1_b = (const float*)d_in[9];
    const float* bn2_g = (const float*)d_in[10];
    const float* bn2_b = (const float*)d_in[11];
    const float* wn = (const float*)d_in[12];
    const float* wb = (const float*)d_in[13];
    const float* wl = (const float*)d_in[14];
    const float* wlb = (const float*)d_in[15];
    const float* gate_w = (const float*)d_in[16];
    const float* gate_b = (const float*)d_in[17];
    const float* gat_wsrc = (const float*)d_in[18];
    const float* gat_bias = (const float*)d_in[22];
    const float* out_w = (const float*)d_in[23];
    const float* out_b = (const float*)d_in[24];
    const int* edge_index = (const int*)d_in[25];
    const int* frag_edge_index = (const int*)d_in[26];
    const int* cluster_index = (const int*)d_in[27];

    char* p = (char*)d_ws;
    auto alloc = [&](size_t bytes) { char* r = p; p += (bytes + 255) & ~(size_t)255; return (void*)r; };
    float* hA    = (float*)alloc((size_t)N * 128 * 4);
    short* ea1   = (short*)alloc((size_t)E * 128 * 2);
    int*   xphl  = (int*)alloc((size_t)N * 128 * 4);
    short* ep    = (short*)alloc((size_t)E * 128 * 2);
    unsigned char* Y = (unsigned char*)alloc((size_t)N * 1024);
    float* agg   = (float*)alloc((size_t)N * 128 * 4);
    float* ubuf  = (float*)alloc((size_t)N * 8 * 4);
    float* vbuf  = (float*)alloc((size_t)E * 8 * 4);
    short* la_wTh = (short*)alloc(128 * 128 * 2);
    short* la_wTl = (short*)alloc(128 * 128 * 2);
    short* lb_wTh = (short*)alloc(128 * 16 * 2);
    short* lb_wTl = (short*)alloc(128 * 16 * 2);
    short* wnTh   = (short*)alloc(3 * 128 * 128 * 2);
    short* wnTl   = (short*)alloc(3 * 128 * 128 * 2);
    short* wbH    = (short*)alloc(3 * 1024 * 128 * 2);
    short* gate2Th = (short*)alloc(128 * 256 * 2);
    short* gate2Tl = (short*)alloc(128 * 256 * 2);
    float* wmF    = (float*)alloc(128 * 128 * 4);
    short* wmTh   = (short*)alloc(128 * 128 * 2);
    short* wmTl   = (short*)alloc(128 * 128 * 2);
    float* stats  = (float*)alloc(256 * 4);
    char* yq = (char*)Y;
    float* fpool = (float*)yq;              yq += (size_t)F * 128 * 4;
    float* fmv   = (float*)yq;              yq += (size_t)F * 128 * 4;
    int*   perm  = (int*)yq;

    auto cdiv = [](int a, int b) { return (a + b - 1) / b; };

    // ---- weight prep ----
    transpose_split<<<cdiv(128 * 128, 256), 256, 0, stream>>>(la_w, la_wTh, la_wTl, 128, 128);
    transpose_split<<<cdiv(16 * 128, 256), 256, 0, stream>>>(lb_w, lb_wTh, lb_wTl, 16, 128);
    for (int l = 0; l < 3; ++l)
        transpose_split<<<cdiv(128 * 128, 256), 256, 0, stream>>>(
            wn + (size_t)l * 16384, wnTh + (size_t)l * 16384, wnTl + (size_t)l * 16384, 128, 128);
    cvt_f2b<<<cdiv(3 * 1024 * 128, 256), 256, 0, stream>>>(wb, wbH, 3 * 1024 * 128);
    gate_combine_split<<<cdiv(128 * 256, 256), 256, 0, stream>>>(gate_w, gate2Th, gate2Tl);
    build_wm<<<cdiv(128 * 128, 256), 256, 0, stream>>>(gat_wsrc, wmF);
    transpose_split<<<cdiv(128 * 128, 256), 256, 0, stream>>>(wmF, wmTh, wmTl, 128, 128);

    auto run_layer = [&](float* h, const short* ea_buf, const int* ei, int Mn, int Me, int layer) {
        const short* wnTh_l = wnTh + (size_t)layer * 16384;
        const short* wnTl_l = wnTl + (size_t)layer * 16384;
        const short* wb_l   = wbH + (size_t)layer * 131072;
        const float* wl_l   = wl + (size_t)layer * 384 * 8;
        const float* wlb_l  = wlb + (size_t)layer * 8;
        fused_xpy<<<cdiv(Mn, 64), 256, 0, stream>>>(h, wnTh_l, wnTl_l, wb_l, wl_l,
                                                    wl_l + 256 * 8, wlb_l, xphl, ubuf, Y, Mn);
        gemm_bf16<0, 1><<<dim3(1, cdiv(Me, 128)), 256, 0, stream>>>(ea_buf, wnTh_l, nullptr, ep, Me, 128, 128);
        rowdot8<0><<<cdiv(Me, 4), 256, 0, stream>>>(ep, nullptr, wl_l + 128 * 8, nullptr, vbuf, Me);
        hipMemsetAsync(agg, 0, (size_t)Mn * 128 * 4, stream);
        edge_fused2<<<cdiv(Me, 4), 256, 0, stream>>>(xphl, ep, Y, ei, ubuf, vbuf, agg, Me);
        gate_gemm_split<<<cdiv(Mn, 64), 256, 0, stream>>>(h, agg, gate2Th, gate2Tl, gate_b, Mn);
    };

    // ---- atom path ----
    gemm_split<3, 0, 0><<<dim3(1, cdiv(N, 128)), 256, 0, stream>>>(x, la_wTh, la_wTl, la_b, hA, nullptr, N, 128, 128);
    hipMemsetAsync(stats, 0, 1024, stream);
    bn_stats<<<256, 256, 0, stream>>>(hA, stats, stats + 128, N);
    bn_apply<<<2048, 256, 0, stream>>>(hA, stats, stats + 128, bn1_g, bn1_b, N);

    gemm_split<3, 0, 1><<<dim3(1, cdiv(E, 128)), 256, 0, stream>>>(edge_attr, lb_wTh, lb_wTl, lb_b, ea1, nullptr, E, 128, 16);
    hipMemsetAsync(stats, 0, 1024, stream);
    bn_stats_bf<<<256, 256, 0, stream>>>(ea1, stats, stats + 128, E);
    bn_apply_bf<<<2048, 256, 0, stream>>>(ea1, stats, stats + 128, bn2_g, bn2_b, E);

    for (int l = 0; l < 3; ++l) run_layer(hA, ea1, edge_index, N, E, l);
    out_phase1<<<cdiv(N, 4), 256, 0, stream>>>(hA, out_w, out_b, gat_bias, (float*)d_out, N);

    // ---- fragment path ----
    gemm_split<3, 1, 0><<<dim3(1, cdiv(NF, 128)), 256, 0, stream>>>(frag_x, la_wTh, la_wTl, la_b, hA, nullptr, NF, 128, 128);

    gemm_split<3, 0, 1><<<dim3(1, cdiv(EF, 128)), 256, 0, stream>>>(frag_ea, lb_wTh, lb_wTl, lb_b, ea1, nullptr, EF, 128, 16);
    hipMemsetAsync(stats, 0, 1024, stream);
    bn_stats_bf<<<256, 256, 0, stream>>>(ea1, stats, stats + 128, EF);
    bn_apply_bf<<<2048, 256, 0, stream>>>(ea1, stats, stats + 128, bn2_g, bn2_b, EF);

    for (int l = 0; l < 3; ++l) run_layer(hA, ea1, frag_edge_index, NF, EF, l);

    perm_build<<<cdiv(NF, 256), 256, 0, stream>>>(cluster_index, perm, NF);
    seg_pool<<<cdiv(F * 128, 256), 256, 0, stream>>>(hA, perm, fpool, F, NF);
    gemm_split<3, 1, 0><<<dim3(1, cdiv(F, 128)), 256, 0, stream>>>(fpool, wmTh, wmTl, gat_bias, fmv, nullptr, F, 128, 128);
    out_phase2<<<cdiv(F, 4), 256, 0, stream>>>(fmv, perm, out_w, gat_bias, (float*)d_out, F);
}

// Round 15
// 1212.217 us; speedup vs baseline: 1.4080x; 1.0256x over previous
//
#include <hip/hip_runtime.h>
#include <hip/hip_bf16.h>
#include <hip/hip_fp8.h>

#define EPS 1e-5f

typedef short bf16x8 __attribute__((ext_vector_type(8)));
typedef short short4v __attribute__((ext_vector_type(4)));
typedef short short16v __attribute__((ext_vector_type(16)));
typedef float f32x4 __attribute__((ext_vector_type(4)));
typedef float f32x2 __attribute__((ext_vector_type(2)));
typedef unsigned char uchar16v __attribute__((ext_vector_type(16)));

static __device__ __forceinline__ short f2bf(float x) {
    __hip_bfloat16 h = __float2bfloat16(x);
    return *reinterpret_cast<short*>(&h);
}
static __device__ __forceinline__ float bf2f(short x) {
    __hip_bfloat16 h;
    *reinterpret_cast<short*>(&h) = x;
    return __bfloat162float(h);
}
static __device__ __forceinline__ unsigned char f2fp8(float x) {
    __hip_fp8_e4m3 q(x);
    return (unsigned char)q.__x;
}
static __device__ __forceinline__ float fp82f(unsigned char b) {
    __hip_fp8_e4m3 q;
    q.__x = (__hip_fp8_storage_t)b;
    return (float)q;
}
static __device__ __forceinline__ unsigned pack4_fp8(float v0, float v1, float v2, float v3) {
#if __has_builtin(__builtin_amdgcn_cvt_pk_fp8_f32)
    int pk = __builtin_amdgcn_cvt_pk_fp8_f32(v0, v1, 0, false);
    pk = __builtin_amdgcn_cvt_pk_fp8_f32(v2, v3, pk, true);
    return (unsigned)pk;
#else
    return (unsigned)f2fp8(v0) | ((unsigned)f2fp8(v1) << 8) |
           ((unsigned)f2fp8(v2) << 16) | ((unsigned)f2fp8(v3) << 24);
#endif
}
template<bool HI>
static __device__ __forceinline__ f32x2 unpack2_fp8(int w) {
#if __has_builtin(__builtin_amdgcn_cvt_pk_f32_fp8)
    return __builtin_amdgcn_cvt_pk_f32_fp8(w, HI);
#else
    f32x2 r;
    const int sh = HI ? 16 : 0;
    r[0] = fp82f((unsigned char)((w >> sh) & 0xff));
    r[1] = fp82f((unsigned char)((w >> (sh + 8)) & 0xff));
    return r;
#endif
}

// ========== split-bf16 MFMA GEMM: C = act(A[M,K](f32) @ BT[N,K]^T + bias) ==========
template<int SPLIT, int ACT, int OUTM>
__global__ __launch_bounds__(256) void gemm_split(const float* __restrict__ A,
                                                  const short* __restrict__ BTh,
                                                  const short* __restrict__ BTl,
                                                  const float* __restrict__ bias,
                                                  void* __restrict__ Cout,
                                                  void* __restrict__ Cout2,
                                                  int M, int N, int K) {
    __shared__ short Ah[128][40];
    __shared__ short Al[128][40];
    __shared__ short Bh[128][40];
    __shared__ short Bl[128][40];
    const int tid = threadIdx.x;
    const int row0 = blockIdx.y * 128, col0 = blockIdx.x * 128;
    const int lane = tid & 63, w = tid >> 6;
    const int wr = w >> 1, wc = w & 1;
    const int lr = lane & 15, lg = lane >> 4;
    f32x4 acc[4][4] = {};

    for (int k0 = 0; k0 < K; k0 += 32) {
        #pragma unroll
        for (int i = 0; i < 4; ++i) {
            int idx = i * 256 + tid;
            int r = idx >> 3, q = idx & 7;
            int gr = row0 + r, gk = k0 + q * 4;
            f32x4 v;
            if (gr < M && gk + 3 < K) {
                v = *reinterpret_cast<const f32x4*>(&A[(size_t)gr * K + gk]);
            } else {
                #pragma unroll
                for (int j = 0; j < 4; ++j)
                    v[j] = (gr < M && gk + j < K) ? A[(size_t)gr * K + gk + j] : 0.f;
            }
            short4v h, l;
            #pragma unroll
            for (int j = 0; j < 4; ++j) {
                h[j] = f2bf(v[j]);
                l[j] = f2bf(v[j] - bf2f(h[j]));
            }
            *reinterpret_cast<short4v*>(&Ah[r][q * 4]) = h;
            *reinterpret_cast<short4v*>(&Al[r][q * 4]) = l;
        }
        #pragma unroll
        for (int i = 0; i < 4; ++i) {
            int idx = i * 256 + tid;
            int r = idx >> 3, q = idx & 7;
            int gc = col0 + r, gk = k0 + q * 4;
            short4v u, ul;
            if (gk + 3 < K) {
                u = *reinterpret_cast<const short4v*>(&BTh[(size_t)gc * K + gk]);
                if (SPLIT == 3) ul = *reinterpret_cast<const short4v*>(&BTl[(size_t)gc * K + gk]);
            } else {
                #pragma unroll
                for (int j = 0; j < 4; ++j) {
                    u[j] = (gk + j < K) ? BTh[(size_t)gc * K + gk + j] : (short)0;
                    if (SPLIT == 3) ul[j] = (gk + j < K) ? BTl[(size_t)gc * K + gk + j] : (short)0;
                }
            }
            *reinterpret_cast<short4v*>(&Bh[r][q * 4]) = u;
            if (SPLIT == 3) *reinterpret_cast<short4v*>(&Bl[r][q * 4]) = ul;
        }
        __syncthreads();
        bf16x8 afh[4], afl[4], bfh[4];
        #pragma unroll
        for (int mi = 0; mi < 4; ++mi) {
            afh[mi] = *reinterpret_cast<const bf16x8*>(&Ah[wr * 64 + mi * 16 + lr][lg * 8]);
            afl[mi] = *reinterpret_cast<const bf16x8*>(&Al[wr * 64 + mi * 16 + lr][lg * 8]);
        }
        #pragma unroll
        for (int ni = 0; ni < 4; ++ni)
            bfh[ni] = *reinterpret_cast<const bf16x8*>(&Bh[wc * 64 + ni * 16 + lr][lg * 8]);
        #pragma unroll
        for (int mi = 0; mi < 4; ++mi)
            #pragma unroll
            for (int ni = 0; ni < 4; ++ni) {
                acc[mi][ni] = __builtin_amdgcn_mfma_f32_16x16x32_bf16(afh[mi], bfh[ni], acc[mi][ni], 0, 0, 0);
                acc[mi][ni] = __builtin_amdgcn_mfma_f32_16x16x32_bf16(afl[mi], bfh[ni], acc[mi][ni], 0, 0, 0);
            }
        if (SPLIT == 3) {
            bf16x8 bfl[4];
            #pragma unroll
            for (int ni = 0; ni < 4; ++ni)
                bfl[ni] = *reinterpret_cast<const bf16x8*>(&Bl[wc * 64 + ni * 16 + lr][lg * 8]);
            #pragma unroll
            for (int mi = 0; mi < 4; ++mi)
                #pragma unroll
                for (int ni = 0; ni < 4; ++ni)
                    acc[mi][ni] = __builtin_amdgcn_mfma_f32_16x16x32_bf16(afh[mi], bfl[ni], acc[mi][ni], 0, 0, 0);
        }
        __syncthreads();
    }

    #pragma unroll
    for (int mi = 0; mi < 4; ++mi) {
        #pragma unroll
        for (int ni = 0; ni < 4; ++ni) {
            int col = col0 + wc * 64 + ni * 16 + lr;
            float bv = bias ? bias[col] : 0.f;
            #pragma unroll
            for (int r = 0; r < 4; ++r) {
                int row = row0 + wr * 64 + mi * 16 + lg * 4 + r;
                if (row >= M) continue;
                float v = acc[mi][ni][r] + bv;
                if (ACT) v = fmaxf(v, 0.f);
                if (OUTM == 0) ((float*)Cout)[(size_t)row * N + col] = v;
                else ((short*)Cout)[(size_t)row * N + col] = f2bf(v);
            }
        }
    }
}

// ========== plain bf16 GEMM (tolerant path: ep projection) ==========
template<int ACT, int OUTBF>
__global__ __launch_bounds__(256) void gemm_bf16(const short* __restrict__ A,
                                                 const short* __restrict__ BT,
                                                 const float* __restrict__ bias,
                                                 void* __restrict__ Cout,
                                                 int M, int N, int K) {
    __shared__ short As[128][40];
    __shared__ short Bs[128][40];
    const int tid = threadIdx.x;
    const int row0 = blockIdx.y * 128, col0 = blockIdx.x * 128;
    const int lane = tid & 63, w = tid >> 6;
    const int wr = w >> 1, wc = w & 1;
    const int lr = lane & 15, lg = lane >> 4;
    f32x4 acc[4][4] = {};

    for (int k0 = 0; k0 < K; k0 += 32) {
        #pragma unroll
        for (int i = 0; i < 4; ++i) {
            int idx = i * 256 + tid;
            int r = idx >> 3, q = idx & 7;
            int gk = k0 + q * 4;
            int gr = row0 + r;
            short4v v;
            if (gr < M && gk + 3 < K) {
                v = *reinterpret_cast<const short4v*>(&A[(size_t)gr * K + gk]);
            } else {
                #pragma unroll
                for (int j = 0; j < 4; ++j)
                    v[j] = (gr < M && gk + j < K) ? A[(size_t)gr * K + gk + j] : (short)0;
            }
            *reinterpret_cast<short4v*>(&As[r][q * 4]) = v;
            int gc = col0 + r;
            short4v u;
            if (gc < N && gk + 3 < K) {
                u = *reinterpret_cast<const short4v*>(&BT[(size_t)gc * K + gk]);
            } else {
                #pragma unroll
                for (int j = 0; j < 4; ++j)
                    u[j] = (gc < N && gk + j < K) ? BT[(size_t)gc * K + gk + j] : (short)0;
            }
            *reinterpret_cast<short4v*>(&Bs[r][q * 4]) = u;
        }
        __syncthreads();
        bf16x8 af[4], bfr[4];
        #pragma unroll
        for (int mi = 0; mi < 4; ++mi)
            af[mi] = *reinterpret_cast<const bf16x8*>(&As[wr * 64 + mi * 16 + lr][lg * 8]);
        #pragma unroll
        for (int ni = 0; ni < 4; ++ni)
            bfr[ni] = *reinterpret_cast<const bf16x8*>(&Bs[wc * 64 + ni * 16 + lr][lg * 8]);
        #pragma unroll
        for (int mi = 0; mi < 4; ++mi)
            #pragma unroll
            for (int ni = 0; ni < 4; ++ni)
                acc[mi][ni] = __builtin_amdgcn_mfma_f32_16x16x32_bf16(af[mi], bfr[ni], acc[mi][ni], 0, 0, 0);
        __syncthreads();
    }

    #pragma unroll
    for (int mi = 0; mi < 4; ++mi) {
        #pragma unroll
        for (int ni = 0; ni < 4; ++ni) {
            int col = col0 + wc * 64 + ni * 16 + lr;
            float bv = bias ? bias[col] : 0.f;
            #pragma unroll
            for (int r = 0; r < 4; ++r) {
                int row = row0 + wr * 64 + mi * 16 + lg * 4 + r;
                if (row >= M) continue;
                float v = acc[mi][ni][r] + bv;
                if (ACT) v = fmaxf(v, 0.f);
                if (OUTBF) ((short*)Cout)[(size_t)row * N + col] = f2bf(v);
                else       ((float*)Cout)[(size_t)row * N + col] = v;
            }
        }
    }
}

// ========== fused xp + Y kernel v8: transposed phase 2, packed HW fp8 ==========
__global__ __launch_bounds__(256) void fused_xpy(const float* __restrict__ h,
                                                 const short* __restrict__ wnTh,
                                                 const short* __restrict__ wnTl,
                                                 const short* __restrict__ wbBT,
                                                 const float* __restrict__ wl1,
                                                 const float* __restrict__ wl2,
                                                 const float* __restrict__ wlb,
                                                 int* __restrict__ xphl,
                                                 float* __restrict__ ubuf,
                                                 unsigned char* __restrict__ Y, int M) {
    __shared__ short sbuf[15360];
    __shared__ unsigned char yb[64 * 136];
    short* Ah = sbuf;
    short* Al = sbuf + 2560;
    short* Bh = sbuf + 5120;
    short* Bl = sbuf + 10240;
    short* xpH = sbuf;

    const int tid = threadIdx.x;
    const int row0 = blockIdx.x * 64;
    const int lane = tid & 63, w = tid >> 6;
    const int lr = lane & 15, lg = lane >> 4;

    // ---- phase 1 ----
    f32x4 acc1[4][2] = {};
    for (int k0 = 0; k0 < 128; k0 += 32) {
        #pragma unroll
        for (int i = 0; i < 2; ++i) {
            int idx = i * 256 + tid;
            int r = idx >> 3, q = idx & 7;
            int gr = row0 + r, gk = k0 + q * 4;
            f32x4 v;
            if (gr < M) {
                v = *reinterpret_cast<const f32x4*>(&h[(size_t)gr * 128 + gk]);
            } else {
                #pragma unroll
                for (int j = 0; j < 4; ++j) v[j] = 0.f;
            }
            short4v hh, ll;
            #pragma unroll
            for (int j = 0; j < 4; ++j) {
                hh[j] = f2bf(v[j]);
                ll[j] = f2bf(v[j] - bf2f(hh[j]));
            }
            *reinterpret_cast<short4v*>(&Ah[r * 40 + q * 4]) = hh;
            *reinterpret_cast<short4v*>(&Al[r * 40 + q * 4]) = ll;
        }
        #pragma unroll
        for (int i = 0; i < 4; ++i) {
            int idx = i * 256 + tid;
            int r = idx >> 3, q = idx & 7;
            int gk = k0 + q * 4;
            short4v bh = *reinterpret_cast<const short4v*>(&wnTh[(size_t)r * 128 + gk]);
            short4v bl = *reinterpret_cast<const short4v*>(&wnTl[(size_t)r * 128 + gk]);
            *reinterpret_cast<short4v*>(&Bh[r * 40 + q * 4]) = bh;
            *reinterpret_cast<short4v*>(&Bl[r * 40 + q * 4]) = bl;
        }
        __syncthreads();
        bf16x8 afh[4], afl[4], bfh[2], bfl[2];
        #pragma unroll
        for (int mi = 0; mi < 4; ++mi) {
            afh[mi] = *reinterpret_cast<const bf16x8*>(&Ah[(mi * 16 + lr) * 40 + lg * 8]);
            afl[mi] = *reinterpret_cast<const bf16x8*>(&Al[(mi * 16 + lr) * 40 + lg * 8]);
        }
        #pragma unroll
        for (int ni = 0; ni < 2; ++ni) {
            bfh[ni] = *reinterpret_cast<const bf16x8*>(&Bh[(w * 32 + ni * 16 + lr) * 40 + lg * 8]);
            bfl[ni] = *reinterpret_cast<const bf16x8*>(&Bl[(w * 32 + ni * 16 + lr) * 40 + lg * 8]);
        }
        #pragma unroll
        for (int mi = 0; mi < 4; ++mi)
            #pragma unroll
            for (int ni = 0; ni < 2; ++ni) {
                acc1[mi][ni] = __builtin_amdgcn_mfma_f32_16x16x32_bf16(afh[mi], bfh[ni], acc1[mi][ni], 0, 0, 0);
                acc1[mi][ni] = __builtin_amdgcn_mfma_f32_16x16x32_bf16(afl[mi], bfh[ni], acc1[mi][ni], 0, 0, 0);
                acc1[mi][ni] = __builtin_amdgcn_mfma_f32_16x16x32_bf16(afh[mi], bfl[ni], acc1[mi][ni], 0, 0, 0);
            }
        __syncthreads();
    }

    // ---- write xp: LDS hi + global packed {hi,lo} ----
    #pragma unroll
    for (int mi = 0; mi < 4; ++mi) {
        #pragma unroll
        for (int ni = 0; ni < 2; ++ni) {
            int col = w * 32 + ni * 16 + lr;
            #pragma unroll
            for (int r = 0; r < 4; ++r) {
                int rl = mi * 16 + lg * 4 + r;
                float v = acc1[mi][ni][r];
                short hi = f2bf(v);
                short lo = f2bf(v - bf2f(hi));
                xpH[rl * 136 + col] = hi;
                int row = row0 + rl;
                if (row < M)
                    xphl[(size_t)row * 128 + col] =
                        ((int)(unsigned short)lo << 16) | (unsigned short)hi;
            }
        }
    }
    __syncthreads();

    // ---- u = xp_hi . wl2 + wlb ----
    #pragma unroll
    for (int o = tid; o < 512; o += 256) {
        int rl = o >> 3, s = o & 7;
        int row = row0 + rl;
        if (row < M) {
            float p = wlb[s];
            #pragma unroll
            for (int j = 0; j < 16; ++j) {
                bf16x8 xv = *reinterpret_cast<const bf16x8*>(&xpH[rl * 136 + j * 8]);
                #pragma unroll
                for (int k = 0; k < 8; ++k)
                    p += bf2f(xv[k]) * wl2[(j * 8 + k) * 8 + s];
            }
            ubuf[(size_t)row * 8 + s] = p;
        }
    }

    // ---- phase 2 (transposed operands) ----
    for (int ct = 0; ct < 8; ++ct) {
        f32x4 accT[2][4] = {};
        #pragma unroll
        for (int k = 0; k < 4; ++k) {
            bf16x8 bfr[2];
            #pragma unroll
            for (int ni = 0; ni < 2; ++ni) {
                int col = ct * 128 + w * 32 + ni * 16 + lr;
                bfr[ni] = *reinterpret_cast<const bf16x8*>(&wbBT[(size_t)col * 128 + k * 32 + lg * 8]);
            }
            bf16x8 ah[4];
            #pragma unroll
            for (int mi = 0; mi < 4; ++mi)
                ah[mi] = *reinterpret_cast<const bf16x8*>(&xpH[(mi * 16 + lr) * 136 + k * 32 + lg * 8]);
            #pragma unroll
            for (int ni = 0; ni < 2; ++ni)
                #pragma unroll
                for (int mi = 0; mi < 4; ++mi)
                    accT[ni][mi] = __builtin_amdgcn_mfma_f32_16x16x32_bf16(bfr[ni], ah[mi], accT[ni][mi], 0, 0, 0);
        }
        #pragma unroll
        for (int ni = 0; ni < 2; ++ni) {
            int colg = w * 32 + ni * 16 + lg * 4;
            #pragma unroll
            for (int mi = 0; mi < 4; ++mi) {
                unsigned pk = pack4_fp8(accT[ni][mi][0] + wl1[(colg + 0) * 8 + ct],
                                        accT[ni][mi][1] + wl1[(colg + 1) * 8 + ct],
                                        accT[ni][mi][2] + wl1[(colg + 2) * 8 + ct],
                                        accT[ni][mi][3] + wl1[(colg + 3) * 8 + ct]);
                *reinterpret_cast<unsigned*>(&yb[(mi * 16 + lr) * 136 + colg]) = pk;
            }
        }
        __syncthreads();
        #pragma unroll
        for (int pass = 0; pass < 2; ++pass) {
            int flat = pass * 4096 + tid * 16;
            int rl = flat >> 7, cs = flat & 127;
            int row = row0 + rl;
            if (row < M) {
                uchar16v vv = *reinterpret_cast<const uchar16v*>(&yb[rl * 136 + cs]);
                *reinterpret_cast<uchar16v*>(&Y[(size_t)row * 1024 + ct * 128 + cs]) = vv;
            }
        }
        __syncthreads();
    }
}

// ========== fused edge kernel v5: inline block-v, packed fp8 decode ==========
__global__ __launch_bounds__(256) void edge_fused2(const int* __restrict__ xphl,
                                                   const short* __restrict__ ep,
                                                   const unsigned char* __restrict__ Y,
                                                   const int* __restrict__ ei,
                                                   const float* __restrict__ u,
                                                   const float* __restrict__ wl2g,
                                                   float* __restrict__ agg, int E) {
    __shared__ float swl[128][9];
    for (int i = threadIdx.x; i < 1024; i += 256) swl[i >> 3][i & 7] = wl2g[i];
    __syncthreads();
    int e = blockIdx.x * 4 + (threadIdx.x >> 6);
    if (e >= E) return;
    int l = threadIdx.x & 63;
    int s = l & 7, c0 = (l >> 3) * 16;
    int src = ei[e], dst = ei[E + e];
    const unsigned char* y = Y + (size_t)src * 1024 + s * 128 + c0;
    uchar16v yv = *reinterpret_cast<const uchar16v*>(y);
    const int* yw = reinterpret_cast<const int*>(&yv);
    float yf[16];
    #pragma unroll
    for (int q = 0; q < 4; ++q) {
        f32x2 a = unpack2_fp8<false>(yw[q]);
        f32x2 b = unpack2_fp8<true>(yw[q]);
        yf[q * 4 + 0] = a[0]; yf[q * 4 + 1] = a[1];
        yf[q * 4 + 2] = b[0]; yf[q * 4 + 3] = b[1];
    }
    const short* xi = (const short*)(xphl + (size_t)dst * 128 + c0);
    short16v xv0 = *reinterpret_cast<const short16v*>(xi);
    short16v xv1 = *reinterpret_cast<const short16v*>(xi + 16);
    short16v ev = *reinterpret_cast<const short16v*>(ep + (size_t)e * 128 + c0);
    float p = 0.f;
    #pragma unroll
    for (int j = 0; j < 8; ++j) {
        p += (bf2f(xv0[2 * j]) + bf2f(xv0[2 * j + 1])) * yf[j];
        p += (bf2f(xv1[2 * j]) + bf2f(xv1[2 * j + 1])) * yf[8 + j];
        p += bf2f(ev[j]) * swl[c0 + j][s];
        p += bf2f(ev[8 + j]) * swl[c0 + 8 + j][s];
    }
    p += __shfl_xor(p, 8); p += __shfl_xor(p, 16); p += __shfl_xor(p, 32);
    float alpha = tanhf(p + u[(size_t)src * 8 + s]);
    float aa0 = __shfl(alpha, l >> 4);
    float aa1 = __shfl(alpha, 4 + (l >> 4));
    int pj0 = xphl[(size_t)src * 128 + l];
    int pj1 = xphl[(size_t)src * 128 + l + 64];
    float xj0 = bf2f((short)(pj0 & 0xffff)) + bf2f((short)(pj0 >> 16));
    float xj1 = bf2f((short)(pj1 & 0xffff)) + bf2f((short)(pj1 >> 16));
    float e0 = bf2f(ep[(size_t)e * 128 + l]);
    float e1 = bf2f(ep[(size_t)e * 128 + l + 64]);
    atomicAdd(&agg[(size_t)dst * 128 + l],      fmaxf(xj0, e0) * aa0);
    atomicAdd(&agg[(size_t)dst * 128 + l + 64], fmaxf(xj1, e1) * aa1);
}

// ========== gate GEMM v2: 64-row tiles, split-3, K=256 combined, in place ==========
__global__ __launch_bounds__(256) void gate_gemm_split(float* __restrict__ h,
                                                       const float* __restrict__ aggv,
                                                       const short* __restrict__ BTh,
                                                       const short* __restrict__ BTl,
                                                       const float* __restrict__ gb,
                                                       int M) {
    __shared__ short Ah[64][40];
    __shared__ short Al[64][40];
    __shared__ short Bh[128][40];
    __shared__ short Bl[128][40];
    const int tid = threadIdx.x;
    const int row0 = blockIdx.x * 64;
    const int lane = tid & 63, w = tid >> 6;
    const int lr = lane & 15, lg = lane >> 4;
    f32x4 acc[4][2] = {};

    for (int k0 = 0; k0 < 256; k0 += 32) {
        int sec = k0 >> 7;
        #pragma unroll
        for (int i = 0; i < 2; ++i) {
            int idx = i * 256 + tid;
            int r = idx >> 3, q = idx & 7;
            int gr = row0 + r;
            int ks = (k0 & 127) + q * 4;
            f32x4 v;
            if (gr < M) {
                if (sec == 0) {
                    v = *reinterpret_cast<const f32x4*>(&h[(size_t)gr * 128 + ks]);
                } else {
                    f32x4 a = *reinterpret_cast<const f32x4*>(&aggv[(size_t)gr * 128 + ks]);
                    #pragma unroll
                    for (int j = 0; j < 4; ++j) v[j] = fmaxf(a[j], 0.f);
                }
            } else {
                #pragma unroll
                for (int j = 0; j < 4; ++j) v[j] = 0.f;
            }
            short4v hh, ll;
            #pragma unroll
            for (int j = 0; j < 4; ++j) {
                hh[j] = f2bf(v[j]);
                ll[j] = f2bf(v[j] - bf2f(hh[j]));
            }
            *reinterpret_cast<short4v*>(&Ah[r][q * 4]) = hh;
            *reinterpret_cast<short4v*>(&Al[r][q * 4]) = ll;
        }
        #pragma unroll
        for (int i = 0; i < 4; ++i) {
            int idx = i * 256 + tid;
            int r = idx >> 3, q = idx & 7;
            short4v uu = *reinterpret_cast<const short4v*>(&BTh[(size_t)r * 256 + k0 + q * 4]);
            short4v ul = *reinterpret_cast<const short4v*>(&BTl[(size_t)r * 256 + k0 + q * 4]);
            *reinterpret_cast<short4v*>(&Bh[r][q * 4]) = uu;
            *reinterpret_cast<short4v*>(&Bl[r][q * 4]) = ul;
        }
        __syncthreads();
        bf16x8 afh[4], afl[4], bfh[2], bfl[2];
        #pragma unroll
        for (int mi = 0; mi < 4; ++mi) {
            afh[mi] = *reinterpret_cast<const bf16x8*>(&Ah[mi * 16 + lr][lg * 8]);
            afl[mi] = *reinterpret_cast<const bf16x8*>(&Al[mi * 16 + lr][lg * 8]);
        }
        #pragma unroll
        for (int ni = 0; ni < 2; ++ni) {
            bfh[ni] = *reinterpret_cast<const bf16x8*>(&Bh[w * 32 + ni * 16 + lr][lg * 8]);
            bfl[ni] = *reinterpret_cast<const bf16x8*>(&Bl[w * 32 + ni * 16 + lr][lg * 8]);
        }
        #pragma unroll
        for (int mi = 0; mi < 4; ++mi)
            #pragma unroll
            for (int ni = 0; ni < 2; ++ni) {
                acc[mi][ni] = __builtin_amdgcn_mfma_f32_16x16x32_bf16(afh[mi], bfh[ni], acc[mi][ni], 0, 0, 0);
                acc[mi][ni] = __builtin_amdgcn_mfma_f32_16x16x32_bf16(afl[mi], bfh[ni], acc[mi][ni], 0, 0, 0);
                acc[mi][ni] = __builtin_amdgcn_mfma_f32_16x16x32_bf16(afh[mi], bfl[ni], acc[mi][ni], 0, 0, 0);
            }
        __syncthreads();
    }

    #pragma unroll
    for (int mi = 0; mi < 4; ++mi) {
        #pragma unroll
        for (int ni = 0; ni < 2; ++ni) {
            int col = w * 32 + ni * 16 + lr;
            float gbv = gb[col];
            #pragma unroll
            for (int r = 0; r < 4; ++r) {
                int row = row0 + mi * 16 + lg * 4 + r;
                if (row >= M) continue;
                float beta = fmaxf(acc[mi][ni][r] + gbv, 0.f);
                float hv = h[(size_t)row * 128 + col];
                float hh = fmaxf(aggv[(size_t)row * 128 + col], 0.f);
                h[(size_t)row * 128 + col] = beta * hv + (1.f - beta) * hh;
            }
        }
    }
}

// ========== batch norm ==========
__global__ void bn_stats(const float* __restrict__ z, float* __restrict__ gsum,
                         float* __restrict__ gsq, int M) {
    int c = threadIdx.x & 127;
    int rr = threadIdx.x >> 7;
    float s = 0.f, q = 0.f;
    for (int r = blockIdx.x * 2 + rr; r < M; r += gridDim.x * 2) {
        float v = z[(size_t)r * 128 + c];
        s += v; q += v * v;
    }
    __shared__ float ls[256], lq[256];
    ls[threadIdx.x] = s; lq[threadIdx.x] = q;
    __syncthreads();
    if (threadIdx.x < 128) {
        atomicAdd(&gsum[c], ls[threadIdx.x] + ls[threadIdx.x + 128]);
        atomicAdd(&gsq[c],  lq[threadIdx.x] + lq[threadIdx.x + 128]);
    }
}

__global__ void bn_apply(float* __restrict__ z, const float* __restrict__ gsum,
                         const float* __restrict__ gsq, const float* __restrict__ g,
                         const float* __restrict__ b, int M) {
    size_t total = (size_t)M * 128;
    for (size_t idx = (size_t)blockIdx.x * 256 + threadIdx.x; idx < total;
         idx += (size_t)gridDim.x * 256) {
        int c = idx & 127;
        float mu = gsum[c] / (float)M;
        float var = gsq[c] / (float)M - mu * mu;
        float rs = rsqrtf(var + EPS);
        float v = (z[idx] - mu) * rs * g[c] + b[c];
        z[idx] = fmaxf(v, 0.f);
    }
}

__global__ void bn_stats_bf(const short* __restrict__ z, float* __restrict__ gsum,
                            float* __restrict__ gsq, int M) {
    int c = threadIdx.x & 127;
    int rr = threadIdx.x >> 7;
    float s = 0.f, q = 0.f;
    for (int r = blockIdx.x * 2 + rr; r < M; r += gridDim.x * 2) {
        float v = bf2f(z[(size_t)r * 128 + c]);
        s += v; q += v * v;
    }
    __shared__ float ls[256], lq[256];
    ls[threadIdx.x] = s; lq[threadIdx.x] = q;
    __syncthreads();
    if (threadIdx.x < 128) {
        atomicAdd(&gsum[c], ls[threadIdx.x] + ls[threadIdx.x + 128]);
        atomicAdd(&gsq[c],  lq[threadIdx.x] + lq[threadIdx.x + 128]);
    }
}

__global__ void bn_apply_bf(short* __restrict__ z, const float* __restrict__ gsum,
                            const float* __restrict__ gsq, const float* __restrict__ g,
                            const float* __restrict__ b, int M) {
    size_t total = (size_t)M * 128;
    for (size_t idx = (size_t)blockIdx.x * 256 + threadIdx.x; idx < total;
         idx += (size_t)gridDim.x * 256) {
        int c = idx & 127;
        float mu = gsum[c] / (float)M;
        float var = gsq[c] / (float)M - mu * mu;
        float rs = rsqrtf(var + EPS);
        float v = (bf2f(z[idx]) - mu) * rs * g[c] + b[c];
        z[idx] = f2bf(fmaxf(v, 0.f));
    }
}

// ========== prep ==========
__global__ void transpose_split(const float* __restrict__ in, short* __restrict__ outh,
                                short* __restrict__ outl, int K, int N) {
    int idx = blockIdx.x * 256 + threadIdx.x;
    if (idx >= K * N) return;
    int nI = idx / K, k = idx - nI * K;
    float v = in[(size_t)k * N + nI];
    short h = f2bf(v);
    outh[idx] = h;
    outl[idx] = f2bf(v - bf2f(h));
}

__global__ void cvt_f2b(const float* __restrict__ in, short* __restrict__ out, int n) {
    int i = blockIdx.x * 256 + threadIdx.x;
    if (i < n) out[i] = f2bf(in[i]);
}

__global__ void gate_combine_split(const float* __restrict__ gw, short* __restrict__ BTh,
                                   short* __restrict__ BTl) {
    int idx = blockIdx.x * 256 + threadIdx.x;
    if (idx >= 128 * 256) return;
    int n = idx >> 8, k = idx & 255;
    float v;
    if (k < 128) v = gw[(size_t)k * 128 + n] + gw[(size_t)(256 + k) * 128 + n];
    else {
        int kk = k - 128;
        v = gw[(size_t)(128 + kk) * 128 + n] - gw[(size_t)(256 + kk) * 128 + n];
    }
    short h = f2bf(v);
    BTh[idx] = h;
    BTl[idx] = f2bf(v - bf2f(h));
}

__global__ void build_wm(const float* __restrict__ wsrc, float* __restrict__ wm) {
    int idx = blockIdx.x * 256 + threadIdx.x;
    if (idx >= 128 * 128) return;
    int d = idx >> 7, c = idx & 127;
    float s = 0.f;
    #pragma unroll
    for (int h = 0; h < 8; ++h) s += wsrc[(size_t)d * 1024 + h * 128 + c];
    wm[idx] = s * 0.125f;
}

__global__ void perm_build(const int* __restrict__ ci, int* __restrict__ perm, int NF) {
    int i = blockIdx.x * 256 + threadIdx.x;
    if (i >= NF) return;
    int c = ci[i];
    if (i == 0 || ci[i - 1] != c) perm[c] = i;
}

__global__ void seg_pool(const float* __restrict__ fx, const int* __restrict__ perm,
                         float* __restrict__ pool, int F, int NF) {
    int idx = blockIdx.x * 256 + threadIdx.x;
    if (idx >= F * 128) return;
    int f = idx >> 7, c = idx & 127;
    int s = perm[f];
    int e = (f + 1 < F) ? perm[f + 1] : NF;
    float acc = 0.f;
    for (int i = s; i < e; ++i) acc += fx[(size_t)i * 128 + c];
    pool[idx] = fmaxf(acc, 0.f);
}

// ========== output ==========
__global__ __launch_bounds__(256) void out_phase1(const float* __restrict__ h,
                                                  const float* __restrict__ out_w,
                                                  const float* __restrict__ out_b,
                                                  const float* __restrict__ gat_bias,
                                                  float* __restrict__ out, int M) {
    int n = blockIdx.x * 4 + (threadIdx.x >> 6);
    if (n >= M) return;
    int l = threadIdx.x & 63;
    float p = fmaxf(h[(size_t)n * 128 + l], 0.f) * out_w[l]
            + fmaxf(h[(size_t)n * 128 + l + 64], 0.f) * out_w[l + 64];
    p += fmaxf(gat_bias[l], 0.f) * out_w[128 + l]
       + fmaxf(gat_bias[l + 64], 0.f) * out_w[128 + l + 64];
    #pragma unroll
    for (int off = 32; off; off >>= 1) p += __shfl_xor(p, off);
    if (l == 0) out[n] = p + out_b[0];
}

__global__ __launch_bounds__(256) void out_phase2(const float* __restrict__ fmv,
                                                  const int* __restrict__ perm,
                                                  const float* __restrict__ out_w,
                                                  const float* __restrict__ gat_bias,
                                                  float* __restrict__ out, int F) {
    int f = blockIdx.x * 4 + (threadIdx.x >> 6);
    if (f >= F) return;
    int l = threadIdx.x & 63;
    float p = fmv[(size_t)f * 128 + l] * out_w[128 + l]
            + fmv[(size_t)f * 128 + l + 64] * out_w[128 + l + 64];
    float b = fmaxf(gat_bias[l], 0.f) * out_w[128 + l]
            + fmaxf(gat_bias[l + 64], 0.f) * out_w[128 + l + 64];
    float d = p - b;
    #pragma unroll
    for (int off = 32; off; off >>= 1) d += __shfl_xor(d, off);
    if (l == 0) out[perm[f]] += d;
}

// ========== host ==========
extern "C" void kernel_launch(void* const* d_in, const int* in_sizes, int n_in,
                              void* d_out, int out_size, void* d_ws, size_t ws_size,
                              hipStream_t stream) {
    const int N = 50000, E = 100000, NF = 20000, EF = 40000, F = 10000;

    const float* x          = (const float*)d_in[0];
    const float* edge_attr  = (const float*)d_in[1];
    const float* frag_x     = (const float*)d_in[2];
    const float* frag_ea    = (const float*)d_in[3];
    const float* la_w = (const float*)d_in[4];
    const float* la_b = (const float*)d_in[5];
    const float* lb_w = (const float*)d_in[6];
    const float* lb_b = (const float*)d_in[7];
    const float* bn1_g = (const float*)d_in[8];
    const float* bn1_b = (const float*)d_in[9];
    const float* bn2_g = (const float*)d_in[10];
    const float* bn2_b = (const float*)d_in[11];
    const float* wn = (const float*)d_in[12];
    const float* wb = (const float*)d_in[13];
    const float* wl = (const float*)d_in[14];
    const float* wlb = (const float*)d_in[15];
    const float* gate_w = (const float*)d_in[16];
    const float* gate_b = (const float*)d_in[17];
    const float* gat_wsrc = (const float*)d_in[18];
    const float* gat_bias = (const float*)d_in[22];
    const float* out_w = (const float*)d_in[23];
    const float* out_b = (const float*)d_in[24];
    const int* edge_index = (const int*)d_in[25];
    const int* frag_edge_index = (const int*)d_in[26];
    const int* cluster_index = (const int*)d_in[27];

    char* p = (char*)d_ws;
    auto alloc = [&](size_t bytes) { char* r = p; p += (bytes + 255) & ~(size_t)255; return (void*)r; };
    float* hA    = (float*)alloc((size_t)N * 128 * 4);
    short* ea1   = (short*)alloc((size_t)E * 128 * 2);
    int*   xphl  = (int*)alloc((size_t)N * 128 * 4);
    short* ep    = (short*)alloc((size_t)E * 128 * 2);
    unsigned char* Y = (unsigned char*)alloc((size_t)N * 1024);
    float* agg   = (float*)alloc((size_t)N * 128 * 4);
    float* ubuf  = (float*)alloc((size_t)N * 8 * 4);
    short* la_wTh = (short*)alloc(128 * 128 * 2);
    short* la_wTl = (short*)alloc(128 * 128 * 2);
    short* lb_wTh = (short*)alloc(128 * 16 * 2);
    short* lb_wTl = (short*)alloc(128 * 16 * 2);
    short* wnTh   = (short*)alloc(3 * 128 * 128 * 2);
    short* wnTl   = (short*)alloc(3 * 128 * 128 * 2);
    short* wbH    = (short*)alloc(3 * 1024 * 128 * 2);
    short* gate2Th = (short*)alloc(128 * 256 * 2);
    short* gate2Tl = (short*)alloc(128 * 256 * 2);
    float* wmF    = (float*)alloc(128 * 128 * 4);
    short* wmTh   = (short*)alloc(128 * 128 * 2);
    short* wmTl   = (short*)alloc(128 * 128 * 2);
    float* stats  = (float*)alloc(256 * 4);
    char* yq = (char*)Y;
    float* fpool = (float*)yq;              yq += (size_t)F * 128 * 4;
    float* fmv   = (float*)yq;              yq += (size_t)F * 128 * 4;
    int*   perm  = (int*)yq;

    auto cdiv = [](int a, int b) { return (a + b - 1) / b; };

    // ---- weight prep ----
    transpose_split<<<cdiv(128 * 128, 256), 256, 0, stream>>>(la_w, la_wTh, la_wTl, 128, 128);
    transpose_split<<<cdiv(16 * 128, 256), 256, 0, stream>>>(lb_w, lb_wTh, lb_wTl, 16, 128);
    for (int l = 0; l < 3; ++l)
        transpose_split<<<cdiv(128 * 128, 256), 256, 0, stream>>>(
            wn + (size_t)l * 16384, wnTh + (size_t)l * 16384, wnTl + (size_t)l * 16384, 128, 128);
    cvt_f2b<<<cdiv(3 * 1024 * 128, 256), 256, 0, stream>>>(wb, wbH, 3 * 1024 * 128);
    gate_combine_split<<<cdiv(128 * 256, 256), 256, 0, stream>>>(gate_w, gate2Th, gate2Tl);
    build_wm<<<cdiv(128 * 128, 256), 256, 0, stream>>>(gat_wsrc, wmF);
    transpose_split<<<cdiv(128 * 128, 256), 256, 0, stream>>>(wmF, wmTh, wmTl, 128, 128);

    auto run_layer = [&](float* h, const short* ea_buf, const int* ei, int Mn, int Me, int layer) {
        const short* wnTh_l = wnTh + (size_t)layer * 16384;
        const short* wnTl_l = wnTl + (size_t)layer * 16384;
        const short* wb_l   = wbH + (size_t)layer * 131072;
        const float* wl_l   = wl + (size_t)layer * 384 * 8;
        const float* wlb_l  = wlb + (size_t)layer * 8;
        fused_xpy<<<cdiv(Mn, 64), 256, 0, stream>>>(h, wnTh_l, wnTl_l, wb_l, wl_l,
                                                    wl_l + 256 * 8, wlb_l, xphl, ubuf, Y, Mn);
        gemm_bf16<0, 1><<<dim3(1, cdiv(Me, 128)), 256, 0, stream>>>(ea_buf, wnTh_l, nullptr, ep, Me, 128, 128);
        hipMemsetAsync(agg, 0, (size_t)Mn * 128 * 4, stream);
        edge_fused2<<<cdiv(Me, 4), 256, 0, stream>>>(xphl, ep, Y, ei, ubuf, wl_l + 128 * 8, agg, Me);
        gate_gemm_split<<<cdiv(Mn, 64), 256, 0, stream>>>(h, agg, gate2Th, gate2Tl, gate_b, Mn);
    };

    // ---- atom path ----
    gemm_split<3, 0, 0><<<dim3(1, cdiv(N, 128)), 256, 0, stream>>>(x, la_wTh, la_wTl, la_b, hA, nullptr, N, 128, 128);
    hipMemsetAsync(stats, 0, 1024, stream);
    bn_stats<<<256, 256, 0, stream>>>(hA, stats, stats + 128, N);
    bn_apply<<<2048, 256, 0, stream>>>(hA, stats, stats + 128, bn1_g, bn1_b, N);

    gemm_split<3, 0, 1><<<dim3(1, cdiv(E, 128)), 256, 0, stream>>>(edge_attr, lb_wTh, lb_wTl, lb_b, ea1, nullptr, E, 128, 16);
    hipMemsetAsync(stats, 0, 1024, stream);
    bn_stats_bf<<<256, 256, 0, stream>>>(ea1, stats, stats + 128, E);
    bn_apply_bf<<<2048, 256, 0, stream>>>(ea1, stats, stats + 128, bn2_g, bn2_b, E);

    for (int l = 0; l < 3; ++l) run_layer(hA, ea1, edge_index, N, E, l);
    out_phase1<<<cdiv(N, 4), 256, 0, stream>>>(hA, out_w, out_b, gat_bias, (float*)d_out, N);

    // ---- fragment path ----
    gemm_split<3, 1, 0><<<dim3(1, cdiv(NF, 128)), 256, 0, stream>>>(frag_x, la_wTh, la_wTl, la_b, hA, nullptr, NF, 128, 128);

    gemm_split<3, 0, 1><<<dim3(1, cdiv(EF, 128)), 256, 0, stream>>>(frag_ea, lb_wTh, lb_wTl, lb_b, ea1, nullptr, EF, 128, 16);
    hipMemsetAsync(stats, 0, 1024, stream);
    bn_stats_bf<<<256, 256, 0, stream>>>(ea1, stats, stats + 128, EF);
    bn_apply_bf<<<2048, 256, 0, stream>>>(ea1, stats, stats + 128, bn2_g, bn2_b, EF);

    for (int l = 0; l < 3; ++l) run_layer(hA, ea1, frag_edge_index, NF, EF, l);

    perm_build<<<cdiv(NF, 256), 256, 0, stream>>>(cluster_index, perm, NF);
    seg_pool<<<cdiv(F * 128, 256), 256, 0, stream>>>(hA, perm, fpool, F, NF);
    gemm_split<3, 1, 0><<<dim3(1, cdiv(F, 128)), 256, 0, stream>>>(fpool, wmTh, wmTl, gat_bias, fmv, nullptr, F, 128, 128);
    out_phase2<<<cdiv(F, 4), 256, 0, stream>>>(fmv, perm, out_w, gat_bias, (float*)d_out, F);
}

// Round 16
// 1170.256 us; speedup vs baseline: 1.4585x; 1.0359x over previous
//
#include <hip/hip_runtime.h>
#include <hip/hip_bf16.h>
#include <hip/hip_fp8.h>

#define EPS 1e-5f

typedef short bf16x8 __attribute__((ext_vector_type(8)));
typedef short short4v __attribute__((ext_vector_type(4)));
typedef short short16v __attribute__((ext_vector_type(16)));
typedef float f32x4 __attribute__((ext_vector_type(4)));
typedef float f32x2 __attribute__((ext_vector_type(2)));
typedef unsigned char uchar16v __attribute__((ext_vector_type(16)));

static __device__ __forceinline__ short f2bf(float x) {
    __hip_bfloat16 h = __float2bfloat16(x);
    return *reinterpret_cast<short*>(&h);
}
static __device__ __forceinline__ float bf2f(short x) {
    __hip_bfloat16 h;
    *reinterpret_cast<short*>(&h) = x;
    return __bfloat162float(h);
}
static __device__ __forceinline__ unsigned char f2fp8(float x) {
    __hip_fp8_e4m3 q(x);
    return (unsigned char)q.__x;
}
static __device__ __forceinline__ float fp82f(unsigned char b) {
    __hip_fp8_e4m3 q;
    q.__x = (__hip_fp8_storage_t)b;
    return (float)q;
}
static __device__ __forceinline__ unsigned pack4_fp8(float v0, float v1, float v2, float v3) {
#if __has_builtin(__builtin_amdgcn_cvt_pk_fp8_f32)
    int pk = __builtin_amdgcn_cvt_pk_fp8_f32(v0, v1, 0, false);
    pk = __builtin_amdgcn_cvt_pk_fp8_f32(v2, v3, pk, true);
    return (unsigned)pk;
#else
    return (unsigned)f2fp8(v0) | ((unsigned)f2fp8(v1) << 8) |
           ((unsigned)f2fp8(v2) << 16) | ((unsigned)f2fp8(v3) << 24);
#endif
}
template<bool HI>
static __device__ __forceinline__ f32x2 unpack2_fp8(int w) {
#if __has_builtin(__builtin_amdgcn_cvt_pk_f32_fp8)
    return __builtin_amdgcn_cvt_pk_f32_fp8(w, HI);
#else
    f32x2 r;
    const int sh = HI ? 16 : 0;
    r[0] = fp82f((unsigned char)((w >> sh) & 0xff));
    r[1] = fp82f((unsigned char)((w >> (sh + 8)) & 0xff));
    return r;
#endif
}

// ========== split-bf16 MFMA GEMM: C = act(A[M,K](f32) @ BT[N,K]^T + bias) ==========
template<int SPLIT, int ACT, int OUTM>
__global__ __launch_bounds__(256) void gemm_split(const float* __restrict__ A,
                                                  const short* __restrict__ BTh,
                                                  const short* __restrict__ BTl,
                                                  const float* __restrict__ bias,
                                                  void* __restrict__ Cout,
                                                  void* __restrict__ Cout2,
                                                  int M, int N, int K) {
    __shared__ short Ah[128][40];
    __shared__ short Al[128][40];
    __shared__ short Bh[128][40];
    __shared__ short Bl[128][40];
    const int tid = threadIdx.x;
    const int row0 = blockIdx.y * 128, col0 = blockIdx.x * 128;
    const int lane = tid & 63, w = tid >> 6;
    const int wr = w >> 1, wc = w & 1;
    const int lr = lane & 15, lg = lane >> 4;
    f32x4 acc[4][4] = {};

    for (int k0 = 0; k0 < K; k0 += 32) {
        #pragma unroll
        for (int i = 0; i < 4; ++i) {
            int idx = i * 256 + tid;
            int r = idx >> 3, q = idx & 7;
            int gr = row0 + r, gk = k0 + q * 4;
            f32x4 v;
            if (gr < M && gk + 3 < K) {
                v = *reinterpret_cast<const f32x4*>(&A[(size_t)gr * K + gk]);
            } else {
                #pragma unroll
                for (int j = 0; j < 4; ++j)
                    v[j] = (gr < M && gk + j < K) ? A[(size_t)gr * K + gk + j] : 0.f;
            }
            short4v h, l;
            #pragma unroll
            for (int j = 0; j < 4; ++j) {
                h[j] = f2bf(v[j]);
                l[j] = f2bf(v[j] - bf2f(h[j]));
            }
            *reinterpret_cast<short4v*>(&Ah[r][q * 4]) = h;
            *reinterpret_cast<short4v*>(&Al[r][q * 4]) = l;
        }
        #pragma unroll
        for (int i = 0; i < 4; ++i) {
            int idx = i * 256 + tid;
            int r = idx >> 3, q = idx & 7;
            int gc = col0 + r, gk = k0 + q * 4;
            short4v u, ul;
            if (gk + 3 < K) {
                u = *reinterpret_cast<const short4v*>(&BTh[(size_t)gc * K + gk]);
                if (SPLIT == 3) ul = *reinterpret_cast<const short4v*>(&BTl[(size_t)gc * K + gk]);
            } else {
                #pragma unroll
                for (int j = 0; j < 4; ++j) {
                    u[j] = (gk + j < K) ? BTh[(size_t)gc * K + gk + j] : (short)0;
                    if (SPLIT == 3) ul[j] = (gk + j < K) ? BTl[(size_t)gc * K + gk + j] : (short)0;
                }
            }
            *reinterpret_cast<short4v*>(&Bh[r][q * 4]) = u;
            if (SPLIT == 3) *reinterpret_cast<short4v*>(&Bl[r][q * 4]) = ul;
        }
        __syncthreads();
        bf16x8 afh[4], afl[4], bfh[4];
        #pragma unroll
        for (int mi = 0; mi < 4; ++mi) {
            afh[mi] = *reinterpret_cast<const bf16x8*>(&Ah[wr * 64 + mi * 16 + lr][lg * 8]);
            afl[mi] = *reinterpret_cast<const bf16x8*>(&Al[wr * 64 + mi * 16 + lr][lg * 8]);
        }
        #pragma unroll
        for (int ni = 0; ni < 4; ++ni)
            bfh[ni] = *reinterpret_cast<const bf16x8*>(&Bh[wc * 64 + ni * 16 + lr][lg * 8]);
        #pragma unroll
        for (int mi = 0; mi < 4; ++mi)
            #pragma unroll
            for (int ni = 0; ni < 4; ++ni) {
                acc[mi][ni] = __builtin_amdgcn_mfma_f32_16x16x32_bf16(afh[mi], bfh[ni], acc[mi][ni], 0, 0, 0);
                acc[mi][ni] = __builtin_amdgcn_mfma_f32_16x16x32_bf16(afl[mi], bfh[ni], acc[mi][ni], 0, 0, 0);
            }
        if (SPLIT == 3) {
            bf16x8 bfl[4];
            #pragma unroll
            for (int ni = 0; ni < 4; ++ni)
                bfl[ni] = *reinterpret_cast<const bf16x8*>(&Bl[wc * 64 + ni * 16 + lr][lg * 8]);
            #pragma unroll
            for (int mi = 0; mi < 4; ++mi)
                #pragma unroll
                for (int ni = 0; ni < 4; ++ni)
                    acc[mi][ni] = __builtin_amdgcn_mfma_f32_16x16x32_bf16(afh[mi], bfl[ni], acc[mi][ni], 0, 0, 0);
        }
        __syncthreads();
    }

    #pragma unroll
    for (int mi = 0; mi < 4; ++mi) {
        #pragma unroll
        for (int ni = 0; ni < 4; ++ni) {
            int col = col0 + wc * 64 + ni * 16 + lr;
            float bv = bias ? bias[col] : 0.f;
            #pragma unroll
            for (int r = 0; r < 4; ++r) {
                int row = row0 + wr * 64 + mi * 16 + lg * 4 + r;
                if (row >= M) continue;
                float v = acc[mi][ni][r] + bv;
                if (ACT) v = fmaxf(v, 0.f);
                if (OUTM == 0) ((float*)Cout)[(size_t)row * N + col] = v;
                else ((short*)Cout)[(size_t)row * N + col] = f2bf(v);
            }
        }
    }
}

// ========== plain bf16 GEMM (tolerant path: ep projection) ==========
template<int ACT, int OUTBF>
__global__ __launch_bounds__(256) void gemm_bf16(const short* __restrict__ A,
                                                 const short* __restrict__ BT,
                                                 const float* __restrict__ bias,
                                                 void* __restrict__ Cout,
                                                 int M, int N, int K) {
    __shared__ short As[128][40];
    __shared__ short Bs[128][40];
    const int tid = threadIdx.x;
    const int row0 = blockIdx.y * 128, col0 = blockIdx.x * 128;
    const int lane = tid & 63, w = tid >> 6;
    const int wr = w >> 1, wc = w & 1;
    const int lr = lane & 15, lg = lane >> 4;
    f32x4 acc[4][4] = {};

    for (int k0 = 0; k0 < K; k0 += 32) {
        #pragma unroll
        for (int i = 0; i < 4; ++i) {
            int idx = i * 256 + tid;
            int r = idx >> 3, q = idx & 7;
            int gk = k0 + q * 4;
            int gr = row0 + r;
            short4v v;
            if (gr < M && gk + 3 < K) {
                v = *reinterpret_cast<const short4v*>(&A[(size_t)gr * K + gk]);
            } else {
                #pragma unroll
                for (int j = 0; j < 4; ++j)
                    v[j] = (gr < M && gk + j < K) ? A[(size_t)gr * K + gk + j] : (short)0;
            }
            *reinterpret_cast<short4v*>(&As[r][q * 4]) = v;
            int gc = col0 + r;
            short4v u;
            if (gc < N && gk + 3 < K) {
                u = *reinterpret_cast<const short4v*>(&BT[(size_t)gc * K + gk]);
            } else {
                #pragma unroll
                for (int j = 0; j < 4; ++j)
                    u[j] = (gc < N && gk + j < K) ? BT[(size_t)gc * K + gk + j] : (short)0;
            }
            *reinterpret_cast<short4v*>(&Bs[r][q * 4]) = u;
        }
        __syncthreads();
        bf16x8 af[4], bfr[4];
        #pragma unroll
        for (int mi = 0; mi < 4; ++mi)
            af[mi] = *reinterpret_cast<const bf16x8*>(&As[wr * 64 + mi * 16 + lr][lg * 8]);
        #pragma unroll
        for (int ni = 0; ni < 4; ++ni)
            bfr[ni] = *reinterpret_cast<const bf16x8*>(&Bs[wc * 64 + ni * 16 + lr][lg * 8]);
        #pragma unroll
        for (int mi = 0; mi < 4; ++mi)
            #pragma unroll
            for (int ni = 0; ni < 4; ++ni)
                acc[mi][ni] = __builtin_amdgcn_mfma_f32_16x16x32_bf16(af[mi], bfr[ni], acc[mi][ni], 0, 0, 0);
        __syncthreads();
    }

    #pragma unroll
    for (int mi = 0; mi < 4; ++mi) {
        #pragma unroll
        for (int ni = 0; ni < 4; ++ni) {
            int col = col0 + wc * 64 + ni * 16 + lr;
            float bv = bias ? bias[col] : 0.f;
            #pragma unroll
            for (int r = 0; r < 4; ++r) {
                int row = row0 + wr * 64 + mi * 16 + lg * 4 + r;
                if (row >= M) continue;
                float v = acc[mi][ni][r] + bv;
                if (ACT) v = fmaxf(v, 0.f);
                if (OUTBF) ((short*)Cout)[(size_t)row * N + col] = f2bf(v);
                else       ((float*)Cout)[(size_t)row * N + col] = v;
            }
        }
    }
}

// ========== fused xp + Y kernel v9: fp32 xp output for edge path ==========
__global__ __launch_bounds__(256) void fused_xpy(const float* __restrict__ h,
                                                 const short* __restrict__ wnTh,
                                                 const short* __restrict__ wnTl,
                                                 const short* __restrict__ wbBT,
                                                 const float* __restrict__ wl1,
                                                 const float* __restrict__ wl2,
                                                 const float* __restrict__ wlb,
                                                 float* __restrict__ xpf,
                                                 float* __restrict__ ubuf,
                                                 unsigned char* __restrict__ Y, int M) {
    __shared__ short sbuf[15360];
    __shared__ unsigned char yb[64 * 136];
    short* Ah = sbuf;
    short* Al = sbuf + 2560;
    short* Bh = sbuf + 5120;
    short* Bl = sbuf + 10240;
    short* xpH = sbuf;

    const int tid = threadIdx.x;
    const int row0 = blockIdx.x * 64;
    const int lane = tid & 63, w = tid >> 6;
    const int lr = lane & 15, lg = lane >> 4;

    // ---- phase 1 ----
    f32x4 acc1[4][2] = {};
    for (int k0 = 0; k0 < 128; k0 += 32) {
        #pragma unroll
        for (int i = 0; i < 2; ++i) {
            int idx = i * 256 + tid;
            int r = idx >> 3, q = idx & 7;
            int gr = row0 + r, gk = k0 + q * 4;
            f32x4 v;
            if (gr < M) {
                v = *reinterpret_cast<const f32x4*>(&h[(size_t)gr * 128 + gk]);
            } else {
                #pragma unroll
                for (int j = 0; j < 4; ++j) v[j] = 0.f;
            }
            short4v hh, ll;
            #pragma unroll
            for (int j = 0; j < 4; ++j) {
                hh[j] = f2bf(v[j]);
                ll[j] = f2bf(v[j] - bf2f(hh[j]));
            }
            *reinterpret_cast<short4v*>(&Ah[r * 40 + q * 4]) = hh;
            *reinterpret_cast<short4v*>(&Al[r * 40 + q * 4]) = ll;
        }
        #pragma unroll
        for (int i = 0; i < 4; ++i) {
            int idx = i * 256 + tid;
            int r = idx >> 3, q = idx & 7;
            int gk = k0 + q * 4;
            short4v bh = *reinterpret_cast<const short4v*>(&wnTh[(size_t)r * 128 + gk]);
            short4v bl = *reinterpret_cast<const short4v*>(&wnTl[(size_t)r * 128 + gk]);
            *reinterpret_cast<short4v*>(&Bh[r * 40 + q * 4]) = bh;
            *reinterpret_cast<short4v*>(&Bl[r * 40 + q * 4]) = bl;
        }
        __syncthreads();
        bf16x8 afh[4], afl[4], bfh[2], bfl[2];
        #pragma unroll
        for (int mi = 0; mi < 4; ++mi) {
            afh[mi] = *reinterpret_cast<const bf16x8*>(&Ah[(mi * 16 + lr) * 40 + lg * 8]);
            afl[mi] = *reinterpret_cast<const bf16x8*>(&Al[(mi * 16 + lr) * 40 + lg * 8]);
        }
        #pragma unroll
        for (int ni = 0; ni < 2; ++ni) {
            bfh[ni] = *reinterpret_cast<const bf16x8*>(&Bh[(w * 32 + ni * 16 + lr) * 40 + lg * 8]);
            bfl[ni] = *reinterpret_cast<const bf16x8*>(&Bl[(w * 32 + ni * 16 + lr) * 40 + lg * 8]);
        }
        #pragma unroll
        for (int mi = 0; mi < 4; ++mi)
            #pragma unroll
            for (int ni = 0; ni < 2; ++ni) {
                acc1[mi][ni] = __builtin_amdgcn_mfma_f32_16x16x32_bf16(afh[mi], bfh[ni], acc1[mi][ni], 0, 0, 0);
                acc1[mi][ni] = __builtin_amdgcn_mfma_f32_16x16x32_bf16(afl[mi], bfh[ni], acc1[mi][ni], 0, 0, 0);
                acc1[mi][ni] = __builtin_amdgcn_mfma_f32_16x16x32_bf16(afh[mi], bfl[ni], acc1[mi][ni], 0, 0, 0);
            }
        __syncthreads();
    }

    // ---- write xp: LDS hi (bf16) + global fp32 ----
    #pragma unroll
    for (int mi = 0; mi < 4; ++mi) {
        #pragma unroll
        for (int ni = 0; ni < 2; ++ni) {
            int col = w * 32 + ni * 16 + lr;
            #pragma unroll
            for (int r = 0; r < 4; ++r) {
                int rl = mi * 16 + lg * 4 + r;
                float v = acc1[mi][ni][r];
                xpH[rl * 136 + col] = f2bf(v);
                int row = row0 + rl;
                if (row < M) xpf[(size_t)row * 128 + col] = v;
            }
        }
    }
    __syncthreads();

    // ---- u = xp_hi . wl2 + wlb ----
    #pragma unroll
    for (int o = tid; o < 512; o += 256) {
        int rl = o >> 3, s = o & 7;
        int row = row0 + rl;
        if (row < M) {
            float p = wlb[s];
            #pragma unroll
            for (int j = 0; j < 16; ++j) {
                bf16x8 xv = *reinterpret_cast<const bf16x8*>(&xpH[rl * 136 + j * 8]);
                #pragma unroll
                for (int k = 0; k < 8; ++k)
                    p += bf2f(xv[k]) * wl2[(j * 8 + k) * 8 + s];
            }
            ubuf[(size_t)row * 8 + s] = p;
        }
    }

    // ---- phase 2 (transposed operands) ----
    for (int ct = 0; ct < 8; ++ct) {
        f32x4 accT[2][4] = {};
        #pragma unroll
        for (int k = 0; k < 4; ++k) {
            bf16x8 bfr[2];
            #pragma unroll
            for (int ni = 0; ni < 2; ++ni) {
                int col = ct * 128 + w * 32 + ni * 16 + lr;
                bfr[ni] = *reinterpret_cast<const bf16x8*>(&wbBT[(size_t)col * 128 + k * 32 + lg * 8]);
            }
            bf16x8 ah[4];
            #pragma unroll
            for (int mi = 0; mi < 4; ++mi)
                ah[mi] = *reinterpret_cast<const bf16x8*>(&xpH[(mi * 16 + lr) * 136 + k * 32 + lg * 8]);
            #pragma unroll
            for (int ni = 0; ni < 2; ++ni)
                #pragma unroll
                for (int mi = 0; mi < 4; ++mi)
                    accT[ni][mi] = __builtin_amdgcn_mfma_f32_16x16x32_bf16(bfr[ni], ah[mi], accT[ni][mi], 0, 0, 0);
        }
        #pragma unroll
        for (int ni = 0; ni < 2; ++ni) {
            int colg = w * 32 + ni * 16 + lg * 4;
            #pragma unroll
            for (int mi = 0; mi < 4; ++mi) {
                unsigned pk = pack4_fp8(accT[ni][mi][0] + wl1[(colg + 0) * 8 + ct],
                                        accT[ni][mi][1] + wl1[(colg + 1) * 8 + ct],
                                        accT[ni][mi][2] + wl1[(colg + 2) * 8 + ct],
                                        accT[ni][mi][3] + wl1[(colg + 3) * 8 + ct]);
                *reinterpret_cast<unsigned*>(&yb[(mi * 16 + lr) * 136 + colg]) = pk;
            }
        }
        __syncthreads();
        #pragma unroll
        for (int pass = 0; pass < 2; ++pass) {
            int flat = pass * 4096 + tid * 16;
            int rl = flat >> 7, cs = flat & 127;
            int row = row0 + rl;
            if (row < M) {
                uchar16v vv = *reinterpret_cast<const uchar16v*>(&yb[rl * 136 + cs]);
                *reinterpret_cast<uchar16v*>(&Y[(size_t)row * 1024 + ct * 128 + cs]) = vv;
            }
        }
        __syncthreads();
    }
}

// ========== fused edge kernel v6: fp32 xp, inline block-v, packed fp8 decode ==========
__global__ __launch_bounds__(256) void edge_fused2(const float* __restrict__ xpf,
                                                   const short* __restrict__ ep,
                                                   const unsigned char* __restrict__ Y,
                                                   const int* __restrict__ ei,
                                                   const float* __restrict__ u,
                                                   const float* __restrict__ wl2g,
                                                   float* __restrict__ agg, int E) {
    __shared__ float swl[128][9];
    for (int i = threadIdx.x; i < 1024; i += 256) swl[i >> 3][i & 7] = wl2g[i];
    __syncthreads();
    int e = blockIdx.x * 4 + (threadIdx.x >> 6);
    if (e >= E) return;
    int l = threadIdx.x & 63;
    int s = l & 7, c0 = (l >> 3) * 16;
    int src = ei[e], dst = ei[E + e];
    const unsigned char* y = Y + (size_t)src * 1024 + s * 128 + c0;
    uchar16v yv = *reinterpret_cast<const uchar16v*>(y);
    const int* yw = reinterpret_cast<const int*>(&yv);
    float yf[16];
    #pragma unroll
    for (int q = 0; q < 4; ++q) {
        f32x2 a = unpack2_fp8<false>(yw[q]);
        f32x2 b = unpack2_fp8<true>(yw[q]);
        yf[q * 4 + 0] = a[0]; yf[q * 4 + 1] = a[1];
        yf[q * 4 + 2] = b[0]; yf[q * 4 + 3] = b[1];
    }
    const float* xi = xpf + (size_t)dst * 128 + c0;
    f32x4 xa = *reinterpret_cast<const f32x4*>(xi);
    f32x4 xb = *reinterpret_cast<const f32x4*>(xi + 4);
    f32x4 xc = *reinterpret_cast<const f32x4*>(xi + 8);
    f32x4 xd = *reinterpret_cast<const f32x4*>(xi + 12);
    short16v ev = *reinterpret_cast<const short16v*>(ep + (size_t)e * 128 + c0);
    float p = 0.f;
    #pragma unroll
    for (int j = 0; j < 4; ++j) {
        p += xa[j] * yf[j];
        p += xb[j] * yf[4 + j];
        p += xc[j] * yf[8 + j];
        p += xd[j] * yf[12 + j];
    }
    #pragma unroll
    for (int j = 0; j < 8; ++j) {
        p += bf2f(ev[j]) * swl[c0 + j][s];
        p += bf2f(ev[8 + j]) * swl[c0 + 8 + j][s];
    }
    p += __shfl_xor(p, 8); p += __shfl_xor(p, 16); p += __shfl_xor(p, 32);
    float alpha = tanhf(p + u[(size_t)src * 8 + s]);
    float aa0 = __shfl(alpha, l >> 4);
    float aa1 = __shfl(alpha, 4 + (l >> 4));
    float xj0 = xpf[(size_t)src * 128 + l];
    float xj1 = xpf[(size_t)src * 128 + l + 64];
    float e0 = bf2f(ep[(size_t)e * 128 + l]);
    float e1 = bf2f(ep[(size_t)e * 128 + l + 64]);
    atomicAdd(&agg[(size_t)dst * 128 + l],      fmaxf(xj0, e0) * aa0);
    atomicAdd(&agg[(size_t)dst * 128 + l + 64], fmaxf(xj1, e1) * aa1);
}

// ========== gate GEMM v2: 64-row tiles, split-3, K=256 combined, in place ==========
__global__ __launch_bounds__(256) void gate_gemm_split(float* __restrict__ h,
                                                       const float* __restrict__ aggv,
                                                       const short* __restrict__ BTh,
                                                       const short* __restrict__ BTl,
                                                       const float* __restrict__ gb,
                                                       int M) {
    __shared__ short Ah[64][40];
    __shared__ short Al[64][40];
    __shared__ short Bh[128][40];
    __shared__ short Bl[128][40];
    const int tid = threadIdx.x;
    const int row0 = blockIdx.x * 64;
    const int lane = tid & 63, w = tid >> 6;
    const int lr = lane & 15, lg = lane >> 4;
    f32x4 acc[4][2] = {};

    for (int k0 = 0; k0 < 256; k0 += 32) {
        int sec = k0 >> 7;
        #pragma unroll
        for (int i = 0; i < 2; ++i) {
            int idx = i * 256 + tid;
            int r = idx >> 3, q = idx & 7;
            int gr = row0 + r;
            int ks = (k0 & 127) + q * 4;
            f32x4 v;
            if (gr < M) {
                if (sec == 0) {
                    v = *reinterpret_cast<const f32x4*>(&h[(size_t)gr * 128 + ks]);
                } else {
                    f32x4 a = *reinterpret_cast<const f32x4*>(&aggv[(size_t)gr * 128 + ks]);
                    #pragma unroll
                    for (int j = 0; j < 4; ++j) v[j] = fmaxf(a[j], 0.f);
                }
            } else {
                #pragma unroll
                for (int j = 0; j < 4; ++j) v[j] = 0.f;
            }
            short4v hh, ll;
            #pragma unroll
            for (int j = 0; j < 4; ++j) {
                hh[j] = f2bf(v[j]);
                ll[j] = f2bf(v[j] - bf2f(hh[j]));
            }
            *reinterpret_cast<short4v*>(&Ah[r][q * 4]) = hh;
            *reinterpret_cast<short4v*>(&Al[r][q * 4]) = ll;
        }
        #pragma unroll
        for (int i = 0; i < 4; ++i) {
            int idx = i * 256 + tid;
            int r = idx >> 3, q = idx & 7;
            short4v uu = *reinterpret_cast<const short4v*>(&BTh[(size_t)r * 256 + k0 + q * 4]);
            short4v ul = *reinterpret_cast<const short4v*>(&BTl[(size_t)r * 256 + k0 + q * 4]);
            *reinterpret_cast<short4v*>(&Bh[r][q * 4]) = uu;
            *reinterpret_cast<short4v*>(&Bl[r][q * 4]) = ul;
        }
        __syncthreads();
        bf16x8 afh[4], afl[4], bfh[2], bfl[2];
        #pragma unroll
        for (int mi = 0; mi < 4; ++mi) {
            afh[mi] = *reinterpret_cast<const bf16x8*>(&Ah[mi * 16 + lr][lg * 8]);
            afl[mi] = *reinterpret_cast<const bf16x8*>(&Al[mi * 16 + lr][lg * 8]);
        }
        #pragma unroll
        for (int ni = 0; ni < 2; ++ni) {
            bfh[ni] = *reinterpret_cast<const bf16x8*>(&Bh[w * 32 + ni * 16 + lr][lg * 8]);
            bfl[ni] = *reinterpret_cast<const bf16x8*>(&Bl[w * 32 + ni * 16 + lr][lg * 8]);
        }
        #pragma unroll
        for (int mi = 0; mi < 4; ++mi)
            #pragma unroll
            for (int ni = 0; ni < 2; ++ni) {
                acc[mi][ni] = __builtin_amdgcn_mfma_f32_16x16x32_bf16(afh[mi], bfh[ni], acc[mi][ni], 0, 0, 0);
                acc[mi][ni] = __builtin_amdgcn_mfma_f32_16x16x32_bf16(afl[mi], bfh[ni], acc[mi][ni], 0, 0, 0);
                acc[mi][ni] = __builtin_amdgcn_mfma_f32_16x16x32_bf16(afh[mi], bfl[ni], acc[mi][ni], 0, 0, 0);
            }
        __syncthreads();
    }

    #pragma unroll
    for (int mi = 0; mi < 4; ++mi) {
        #pragma unroll
        for (int ni = 0; ni < 2; ++ni) {
            int col = w * 32 + ni * 16 + lr;
            float gbv = gb[col];
            #pragma unroll
            for (int r = 0; r < 4; ++r) {
                int row = row0 + mi * 16 + lg * 4 + r;
                if (row >= M) continue;
                float beta = fmaxf(acc[mi][ni][r] + gbv, 0.f);
                float hv = h[(size_t)row * 128 + col];
                float hh = fmaxf(aggv[(size_t)row * 128 + col], 0.f);
                h[(size_t)row * 128 + col] = beta * hv + (1.f - beta) * hh;
            }
        }
    }
}

// ========== batch norm ==========
__global__ void bn_stats(const float* __restrict__ z, float* __restrict__ gsum,
                         float* __restrict__ gsq, int M) {
    int c = threadIdx.x & 127;
    int rr = threadIdx.x >> 7;
    float s = 0.f, q = 0.f;
    for (int r = blockIdx.x * 2 + rr; r < M; r += gridDim.x * 2) {
        float v = z[(size_t)r * 128 + c];
        s += v; q += v * v;
    }
    __shared__ float ls[256], lq[256];
    ls[threadIdx.x] = s; lq[threadIdx.x] = q;
    __syncthreads();
    if (threadIdx.x < 128) {
        atomicAdd(&gsum[c], ls[threadIdx.x] + ls[threadIdx.x + 128]);
        atomicAdd(&gsq[c],  lq[threadIdx.x] + lq[threadIdx.x + 128]);
    }
}

__global__ void bn_apply(float* __restrict__ z, const float* __restrict__ gsum,
                         const float* __restrict__ gsq, const float* __restrict__ g,
                         const float* __restrict__ b, int M) {
    size_t total = (size_t)M * 128;
    for (size_t idx = (size_t)blockIdx.x * 256 + threadIdx.x; idx < total;
         idx += (size_t)gridDim.x * 256) {
        int c = idx & 127;
        float mu = gsum[c] / (float)M;
        float var = gsq[c] / (float)M - mu * mu;
        float rs = rsqrtf(var + EPS);
        float v = (z[idx] - mu) * rs * g[c] + b[c];
        z[idx] = fmaxf(v, 0.f);
    }
}

__global__ void bn_stats_bf(const short* __restrict__ z, float* __restrict__ gsum,
                            float* __restrict__ gsq, int M) {
    int c = threadIdx.x & 127;
    int rr = threadIdx.x >> 7;
    float s = 0.f, q = 0.f;
    for (int r = blockIdx.x * 2 + rr; r < M; r += gridDim.x * 2) {
        float v = bf2f(z[(size_t)r * 128 + c]);
        s += v; q += v * v;
    }
    __shared__ float ls[256], lq[256];
    ls[threadIdx.x] = s; lq[threadIdx.x] = q;
    __syncthreads();
    if (threadIdx.x < 128) {
        atomicAdd(&gsum[c], ls[threadIdx.x] + ls[threadIdx.x + 128]);
        atomicAdd(&gsq[c],  lq[threadIdx.x] + lq[threadIdx.x + 128]);
    }
}

__global__ void bn_apply_bf(short* __restrict__ z, const float* __restrict__ gsum,
                            const float* __restrict__ gsq, const float* __restrict__ g,
                            const float* __restrict__ b, int M) {
    size_t total = (size_t)M * 128;
    for (size_t idx = (size_t)blockIdx.x * 256 + threadIdx.x; idx < total;
         idx += (size_t)gridDim.x * 256) {
        int c = idx & 127;
        float mu = gsum[c] / (float)M;
        float var = gsq[c] / (float)M - mu * mu;
        float rs = rsqrtf(var + EPS);
        float v = (bf2f(z[idx]) - mu) * rs * g[c] + b[c];
        z[idx] = f2bf(fmaxf(v, 0.f));
    }
}

// ========== prep ==========
__global__ void transpose_split(const float* __restrict__ in, short* __restrict__ outh,
                                short* __restrict__ outl, int K, int N) {
    int idx = blockIdx.x * 256 + threadIdx.x;
    if (idx >= K * N) return;
    int nI = idx / K, k = idx - nI * K;
    float v = in[(size_t)k * N + nI];
    short h = f2bf(v);
    outh[idx] = h;
    outl[idx] = f2bf(v - bf2f(h));
}

__global__ void cvt_f2b(const float* __restrict__ in, short* __restrict__ out, int n) {
    int i = blockIdx.x * 256 + threadIdx.x;
    if (i < n) out[i] = f2bf(in[i]);
}

__global__ void gate_combine_split(const float* __restrict__ gw, short* __restrict__ BTh,
                                   short* __restrict__ BTl) {
    int idx = blockIdx.x * 256 + threadIdx.x;
    if (idx >= 128 * 256) return;
    int n = idx >> 8, k = idx & 255;
    float v;
    if (k < 128) v = gw[(size_t)k * 128 + n] + gw[(size_t)(256 + k) * 128 + n];
    else {
        int kk = k - 128;
        v = gw[(size_t)(128 + kk) * 128 + n] - gw[(size_t)(256 + kk) * 128 + n];
    }
    short h = f2bf(v);
    BTh[idx] = h;
    BTl[idx] = f2bf(v - bf2f(h));
}

__global__ void build_wm(const float* __restrict__ wsrc, float* __restrict__ wm) {
    int idx = blockIdx.x * 256 + threadIdx.x;
    if (idx >= 128 * 128) return;
    int d = idx >> 7, c = idx & 127;
    float s = 0.f;
    #pragma unroll
    for (int h = 0; h < 8; ++h) s += wsrc[(size_t)d * 1024 + h * 128 + c];
    wm[idx] = s * 0.125f;
}

__global__ void perm_build(const int* __restrict__ ci, int* __restrict__ perm, int NF) {
    int i = blockIdx.x * 256 + threadIdx.x;
    if (i >= NF) return;
    int c = ci[i];
    if (i == 0 || ci[i - 1] != c) perm[c] = i;
}

__global__ void seg_pool(const float* __restrict__ fx, const int* __restrict__ perm,
                         float* __restrict__ pool, int F, int NF) {
    int idx = blockIdx.x * 256 + threadIdx.x;
    if (idx >= F * 128) return;
    int f = idx >> 7, c = idx & 127;
    int s = perm[f];
    int e = (f + 1 < F) ? perm[f + 1] : NF;
    float acc = 0.f;
    for (int i = s; i < e; ++i) acc += fx[(size_t)i * 128 + c];
    pool[idx] = fmaxf(acc, 0.f);
}

// ========== output ==========
__global__ __launch_bounds__(256) void out_phase1(const float* __restrict__ h,
                                                  const float* __restrict__ out_w,
                                                  const float* __restrict__ out_b,
                                                  const float* __restrict__ gat_bias,
                                                  float* __restrict__ out, int M) {
    int n = blockIdx.x * 4 + (threadIdx.x >> 6);
    if (n >= M) return;
    int l = threadIdx.x & 63;
    float p = fmaxf(h[(size_t)n * 128 + l], 0.f) * out_w[l]
            + fmaxf(h[(size_t)n * 128 + l + 64], 0.f) * out_w[l + 64];
    p += fmaxf(gat_bias[l], 0.f) * out_w[128 + l]
       + fmaxf(gat_bias[l + 64], 0.f) * out_w[128 + l + 64];
    #pragma unroll
    for (int off = 32; off; off >>= 1) p += __shfl_xor(p, off);
    if (l == 0) out[n] = p + out_b[0];
}

__global__ __launch_bounds__(256) void out_phase2(const float* __restrict__ fmv,
                                                  const int* __restrict__ perm,
                                                  const float* __restrict__ out_w,
                                                  const float* __restrict__ gat_bias,
                                                  float* __restrict__ out, int F) {
    int f = blockIdx.x * 4 + (threadIdx.x >> 6);
    if (f >= F) return;
    int l = threadIdx.x & 63;
    float p = fmv[(size_t)f * 128 + l] * out_w[128 + l]
            + fmv[(size_t)f * 128 + l + 64] * out_w[128 + l + 64];
    float b = fmaxf(gat_bias[l], 0.f) * out_w[128 + l]
            + fmaxf(gat_bias[l + 64], 0.f) * out_w[128 + l + 64];
    float d = p - b;
    #pragma unroll
    for (int off = 32; off; off >>= 1) d += __shfl_xor(d, off);
    if (l == 0) out[perm[f]] += d;
}

// ========== host ==========
extern "C" void kernel_launch(void* const* d_in, const int* in_sizes, int n_in,
                              void* d_out, int out_size, void* d_ws, size_t ws_size,
                              hipStream_t stream) {
    const int N = 50000, E = 100000, NF = 20000, EF = 40000, F = 10000;

    const float* x          = (const float*)d_in[0];
    const float* edge_attr  = (const float*)d_in[1];
    const float* frag_x     = (const float*)d_in[2];
    const float* frag_ea    = (const float*)d_in[3];
    const float* la_w = (const float*)d_in[4];
    const float* la_b = (const float*)d_in[5];
    const float* lb_w = (const float*)d_in[6];
    const float* lb_b = (const float*)d_in[7];
    const float* bn1_g = (const float*)d_in[8];
    const float* bn1_b = (const float*)d_in[9];
    const float* bn2_g = (const float*)d_in[10];
    const float* bn2_b = (const float*)d_in[11];
    const float* wn = (const float*)d_in[12];
    const float* wb = (const float*)d_in[13];
    const float* wl = (const float*)d_in[14];
    const float* wlb = (const float*)d_in[15];
    const float* gate_w = (const float*)d_in[16];
    const float* gate_b = (const float*)d_in[17];
    const float* gat_wsrc = (const float*)d_in[18];
    const float* gat_bias = (const float*)d_in[22];
    const float* out_w = (const float*)d_in[23];
    const float* out_b = (const float*)d_in[24];
    const int* edge_index = (const int*)d_in[25];
    const int* frag_edge_index = (const int*)d_in[26];
    const int* cluster_index = (const int*)d_in[27];

    char* p = (char*)d_ws;
    auto alloc = [&](size_t bytes) { char* r = p; p += (bytes + 255) & ~(size_t)255; return (void*)r; };
    float* hA    = (float*)alloc((size_t)N * 128 * 4);
    short* ea1   = (short*)alloc((size_t)E * 128 * 2);
    float* xpf   = (float*)alloc((size_t)N * 128 * 4);
    short* ep    = (short*)alloc((size_t)E * 128 * 2);
    unsigned char* Y = (unsigned char*)alloc((size_t)N * 1024);
    float* agg   = (float*)alloc((size_t)N * 128 * 4);
    float* ubuf  = (float*)alloc((size_t)N * 8 * 4);
    short* la_wTh = (short*)alloc(128 * 128 * 2);
    short* la_wTl = (short*)alloc(128 * 128 * 2);
    short* lb_wTh = (short*)alloc(128 * 16 * 2);
    short* lb_wTl = (short*)alloc(128 * 16 * 2);
    short* wnTh   = (short*)alloc(3 * 128 * 128 * 2);
    short* wnTl   = (short*)alloc(3 * 128 * 128 * 2);
    short* wbH    = (short*)alloc(3 * 1024 * 128 * 2);
    short* gate2Th = (short*)alloc(128 * 256 * 2);
    short* gate2Tl = (short*)alloc(128 * 256 * 2);
    float* wmF    = (float*)alloc(128 * 128 * 4);
    short* wmTh   = (short*)alloc(128 * 128 * 2);
    short* wmTl   = (short*)alloc(128 * 128 * 2);
    float* stats  = (float*)alloc(256 * 4);
    char* yq = (char*)Y;
    float* fpool = (float*)yq;              yq += (size_t)F * 128 * 4;
    float* fmv   = (float*)yq;              yq += (size_t)F * 128 * 4;
    int*   perm  = (int*)yq;

    auto cdiv = [](int a, int b) { return (a + b - 1) / b; };

    // ---- weight prep ----
    transpose_split<<<cdiv(128 * 128, 256), 256, 0, stream>>>(la_w, la_wTh, la_wTl, 128, 128);
    transpose_split<<<cdiv(16 * 128, 256), 256, 0, stream>>>(lb_w, lb_wTh, lb_wTl, 16, 128);
    for (int l = 0; l < 3; ++l)
        transpose_split<<<cdiv(128 * 128, 256), 256, 0, stream>>>(
            wn + (size_t)l * 16384, wnTh + (size_t)l * 16384, wnTl + (size_t)l * 16384, 128, 128);
    cvt_f2b<<<cdiv(3 * 1024 * 128, 256), 256, 0, stream>>>(wb, wbH, 3 * 1024 * 128);
    gate_combine_split<<<cdiv(128 * 256, 256), 256, 0, stream>>>(gate_w, gate2Th, gate2Tl);
    build_wm<<<cdiv(128 * 128, 256), 256, 0, stream>>>(gat_wsrc, wmF);
    transpose_split<<<cdiv(128 * 128, 256), 256, 0, stream>>>(wmF, wmTh, wmTl, 128, 128);

    auto run_layer = [&](float* h, const short* ea_buf, const int* ei, int Mn, int Me, int layer) {
        const short* wnTh_l = wnTh + (size_t)layer * 16384;
        const short* wnTl_l = wnTl + (size_t)layer * 16384;
        const short* wb_l   = wbH + (size_t)layer * 131072;
        const float* wl_l   = wl + (size_t)layer * 384 * 8;
        const float* wlb_l  = wlb + (size_t)layer * 8;
        fused_xpy<<<cdiv(Mn, 64), 256, 0, stream>>>(h, wnTh_l, wnTl_l, wb_l, wl_l,
                                                    wl_l + 256 * 8, wlb_l, xpf, ubuf, Y, Mn);
        gemm_bf16<0, 1><<<dim3(1, cdiv(Me, 128)), 256, 0, stream>>>(ea_buf, wnTh_l, nullptr, ep, Me, 128, 128);
        hipMemsetAsync(agg, 0, (size_t)Mn * 128 * 4, stream);
        edge_fused2<<<cdiv(Me, 4), 256, 0, stream>>>(xpf, ep, Y, ei, ubuf, wl_l + 128 * 8, agg, Me);
        gate_gemm_split<<<cdiv(Mn, 64), 256, 0, stream>>>(h, agg, gate2Th, gate2Tl, gate_b, Mn);
    };

    // ---- atom path ----
    gemm_split<3, 0, 0><<<dim3(1, cdiv(N, 128)), 256, 0, stream>>>(x, la_wTh, la_wTl, la_b, hA, nullptr, N, 128, 128);
    hipMemsetAsync(stats, 0, 1024, stream);
    bn_stats<<<256, 256, 0, stream>>>(hA, stats, stats + 128, N);
    bn_apply<<<2048, 256, 0, stream>>>(hA, stats, stats + 128, bn1_g, bn1_b, N);

    gemm_split<3, 0, 1><<<dim3(1, cdiv(E, 128)), 256, 0, stream>>>(edge_attr, lb_wTh, lb_wTl, lb_b, ea1, nullptr, E, 128, 16);
    hipMemsetAsync(stats, 0, 1024, stream);
    bn_stats_bf<<<256, 256, 0, stream>>>(ea1, stats, stats + 128, E);
    bn_apply_bf<<<2048, 256, 0, stream>>>(ea1, stats, stats + 128, bn2_g, bn2_b, E);

    for (int l = 0; l < 3; ++l) run_layer(hA, ea1, edge_index, N, E, l);
    out_phase1<<<cdiv(N, 4), 256, 0, stream>>>(hA, out_w, out_b, gat_bias, (float*)d_out, N);

    // ---- fragment path ----
    gemm_split<3, 1, 0><<<dim3(1, cdiv(NF, 128)), 256, 0, stream>>>(frag_x, la_wTh, la_wTl, la_b, hA, nullptr, NF, 128, 128);

    gemm_split<3, 0, 1><<<dim3(1, cdiv(EF, 128)), 256, 0, stream>>>(frag_ea, lb_wTh, lb_wTl, lb_b, ea1, nullptr, EF, 128, 16);
    hipMemsetAsync(stats, 0, 1024, stream);
    bn_stats_bf<<<256, 256, 0, stream>>>(ea1, stats, stats + 128, EF);
    bn_apply_bf<<<2048, 256, 0, stream>>>(ea1, stats, stats + 128, bn2_g, bn2_b, EF);

    for (int l = 0; l < 3; ++l) run_layer(hA, ea1, frag_edge_index, NF, EF, l);

    perm_build<<<cdiv(NF, 256), 256, 0, stream>>>(cluster_index, perm, NF);
    seg_pool<<<cdiv(F * 128, 256), 256, 0, stream>>>(hA, perm, fpool, F, NF);
    gemm_split<3, 1, 0><<<dim3(1, cdiv(F, 128)), 256, 0, stream>>>(fpool, wmTh, wmTl, gat_bias, fmv, nullptr, F, 128, 128);
    out_phase2<<<cdiv(F, 4), 256, 0, stream>>>(fmv, perm, out_w, gat_bias, (float*)d_out, F);
}

// Round 17
// 1081.644 us; speedup vs baseline: 1.5780x; 1.0819x over previous
//
#include <hip/hip_runtime.h>
#include <hip/hip_bf16.h>
#include <hip/hip_fp8.h>

#define EPS 1e-5f

typedef short bf16x8 __attribute__((ext_vector_type(8)));
typedef short short4v __attribute__((ext_vector_type(4)));
typedef short short16v __attribute__((ext_vector_type(16)));
typedef float f32x4 __attribute__((ext_vector_type(4)));
typedef float f32x2 __attribute__((ext_vector_type(2)));
typedef unsigned char uchar16v __attribute__((ext_vector_type(16)));

static __device__ __forceinline__ short f2bf(float x) {
    __hip_bfloat16 h = __float2bfloat16(x);
    return *reinterpret_cast<short*>(&h);
}
static __device__ __forceinline__ float bf2f(short x) {
    __hip_bfloat16 h;
    *reinterpret_cast<short*>(&h) = x;
    return __bfloat162float(h);
}
static __device__ __forceinline__ unsigned char f2fp8(float x) {
    __hip_fp8_e4m3 q(x);
    return (unsigned char)q.__x;
}
static __device__ __forceinline__ float fp82f(unsigned char b) {
    __hip_fp8_e4m3 q;
    q.__x = (__hip_fp8_storage_t)b;
    return (float)q;
}
static __device__ __forceinline__ unsigned pack4_fp8(float v0, float v1, float v2, float v3) {
#if __has_builtin(__builtin_amdgcn_cvt_pk_fp8_f32)
    int pk = __builtin_amdgcn_cvt_pk_fp8_f32(v0, v1, 0, false);
    pk = __builtin_amdgcn_cvt_pk_fp8_f32(v2, v3, pk, true);
    return (unsigned)pk;
#else
    return (unsigned)f2fp8(v0) | ((unsigned)f2fp8(v1) << 8) |
           ((unsigned)f2fp8(v2) << 16) | ((unsigned)f2fp8(v3) << 24);
#endif
}
template<bool HI>
static __device__ __forceinline__ f32x2 unpack2_fp8(int w) {
#if __has_builtin(__builtin_amdgcn_cvt_pk_f32_fp8)
    return __builtin_amdgcn_cvt_pk_f32_fp8(w, HI);
#else
    f32x2 r;
    const int sh = HI ? 16 : 0;
    r[0] = fp82f((unsigned char)((w >> sh) & 0xff));
    r[1] = fp82f((unsigned char)((w >> (sh + 8)) & 0xff));
    return r;
#endif
}

// ========== split-bf16 MFMA GEMM: C = act(A[M,K](f32) @ BT[N,K]^T + bias) ==========
template<int SPLIT, int ACT, int OUTM>
__global__ __launch_bounds__(256) void gemm_split(const float* __restrict__ A,
                                                  const short* __restrict__ BTh,
                                                  const short* __restrict__ BTl,
                                                  const float* __restrict__ bias,
                                                  void* __restrict__ Cout,
                                                  void* __restrict__ Cout2,
                                                  int M, int N, int K) {
    __shared__ short Ah[128][40];
    __shared__ short Al[128][40];
    __shared__ short Bh[128][40];
    __shared__ short Bl[128][40];
    const int tid = threadIdx.x;
    const int row0 = blockIdx.y * 128, col0 = blockIdx.x * 128;
    const int lane = tid & 63, w = tid >> 6;
    const int wr = w >> 1, wc = w & 1;
    const int lr = lane & 15, lg = lane >> 4;
    f32x4 acc[4][4] = {};

    for (int k0 = 0; k0 < K; k0 += 32) {
        #pragma unroll
        for (int i = 0; i < 4; ++i) {
            int idx = i * 256 + tid;
            int r = idx >> 3, q = idx & 7;
            int gr = row0 + r, gk = k0 + q * 4;
            f32x4 v;
            if (gr < M && gk + 3 < K) {
                v = *reinterpret_cast<const f32x4*>(&A[(size_t)gr * K + gk]);
            } else {
                #pragma unroll
                for (int j = 0; j < 4; ++j)
                    v[j] = (gr < M && gk + j < K) ? A[(size_t)gr * K + gk + j] : 0.f;
            }
            short4v h, l;
            #pragma unroll
            for (int j = 0; j < 4; ++j) {
                h[j] = f2bf(v[j]);
                l[j] = f2bf(v[j] - bf2f(h[j]));
            }
            *reinterpret_cast<short4v*>(&Ah[r][q * 4]) = h;
            *reinterpret_cast<short4v*>(&Al[r][q * 4]) = l;
        }
        #pragma unroll
        for (int i = 0; i < 4; ++i) {
            int idx = i * 256 + tid;
            int r = idx >> 3, q = idx & 7;
            int gc = col0 + r, gk = k0 + q * 4;
            short4v u, ul;
            if (gk + 3 < K) {
                u = *reinterpret_cast<const short4v*>(&BTh[(size_t)gc * K + gk]);
                if (SPLIT == 3) ul = *reinterpret_cast<const short4v*>(&BTl[(size_t)gc * K + gk]);
            } else {
                #pragma unroll
                for (int j = 0; j < 4; ++j) {
                    u[j] = (gk + j < K) ? BTh[(size_t)gc * K + gk + j] : (short)0;
                    if (SPLIT == 3) ul[j] = (gk + j < K) ? BTl[(size_t)gc * K + gk + j] : (short)0;
                }
            }
            *reinterpret_cast<short4v*>(&Bh[r][q * 4]) = u;
            if (SPLIT == 3) *reinterpret_cast<short4v*>(&Bl[r][q * 4]) = ul;
        }
        __syncthreads();
        bf16x8 afh[4], afl[4], bfh[4];
        #pragma unroll
        for (int mi = 0; mi < 4; ++mi) {
            afh[mi] = *reinterpret_cast<const bf16x8*>(&Ah[wr * 64 + mi * 16 + lr][lg * 8]);
            afl[mi] = *reinterpret_cast<const bf16x8*>(&Al[wr * 64 + mi * 16 + lr][lg * 8]);
        }
        #pragma unroll
        for (int ni = 0; ni < 4; ++ni)
            bfh[ni] = *reinterpret_cast<const bf16x8*>(&Bh[wc * 64 + ni * 16 + lr][lg * 8]);
        #pragma unroll
        for (int mi = 0; mi < 4; ++mi)
            #pragma unroll
            for (int ni = 0; ni < 4; ++ni) {
                acc[mi][ni] = __builtin_amdgcn_mfma_f32_16x16x32_bf16(afh[mi], bfh[ni], acc[mi][ni], 0, 0, 0);
                acc[mi][ni] = __builtin_amdgcn_mfma_f32_16x16x32_bf16(afl[mi], bfh[ni], acc[mi][ni], 0, 0, 0);
            }
        if (SPLIT == 3) {
            bf16x8 bfl[4];
            #pragma unroll
            for (int ni = 0; ni < 4; ++ni)
                bfl[ni] = *reinterpret_cast<const bf16x8*>(&Bl[wc * 64 + ni * 16 + lr][lg * 8]);
            #pragma unroll
            for (int mi = 0; mi < 4; ++mi)
                #pragma unroll
                for (int ni = 0; ni < 4; ++ni)
                    acc[mi][ni] = __builtin_amdgcn_mfma_f32_16x16x32_bf16(afh[mi], bfl[ni], acc[mi][ni], 0, 0, 0);
        }
        __syncthreads();
    }

    #pragma unroll
    for (int mi = 0; mi < 4; ++mi) {
        #pragma unroll
        for (int ni = 0; ni < 4; ++ni) {
            int col = col0 + wc * 64 + ni * 16 + lr;
            float bv = bias ? bias[col] : 0.f;
            #pragma unroll
            for (int r = 0; r < 4; ++r) {
                int row = row0 + wr * 64 + mi * 16 + lg * 4 + r;
                if (row >= M) continue;
                float v = acc[mi][ni][r] + bv;
                if (ACT) v = fmaxf(v, 0.f);
                if (OUTM == 0) ((float*)Cout)[(size_t)row * N + col] = v;
                else ((short*)Cout)[(size_t)row * N + col] = f2bf(v);
            }
        }
    }
}

// ========== ep GEMM: ep[M,128] = ea1[M,128] @ wnT^T, 64-row tiles, B staged once ==========
__global__ __launch_bounds__(256) void ep_gemm64(const short* __restrict__ A,
                                                 const short* __restrict__ BT,
                                                 short* __restrict__ Cout, int M) {
    __shared__ short Bf[128 * 136];   // full B, 34816 B
    __shared__ short As[64 * 40];     // 5120 B
    const int tid = threadIdx.x;
    const int row0 = blockIdx.x * 64;
    const int lane = tid & 63, w = tid >> 6;
    const int lr = lane & 15, lg = lane >> 4;

    // stage full B (128x128): 2048 chunks of 8 shorts
    #pragma unroll
    for (int i = 0; i < 8; ++i) {
        int idx = i * 256 + tid;
        int r = idx >> 4, q = idx & 15;
        *reinterpret_cast<bf16x8*>(&Bf[r * 136 + q * 8]) =
            *reinterpret_cast<const bf16x8*>(&BT[(size_t)r * 128 + q * 8]);
    }
    __syncthreads();

    f32x4 acc[4][2] = {};
    for (int k0 = 0; k0 < 128; k0 += 32) {
        #pragma unroll
        for (int i = 0; i < 2; ++i) {     // A: 64 rows x 8 chunks of 4
            int idx = i * 256 + tid;
            int r = idx >> 3, q = idx & 7;
            int gr = row0 + r;
            short4v v;
            if (gr < M) {
                v = *reinterpret_cast<const short4v*>(&A[(size_t)gr * 128 + k0 + q * 4]);
            } else {
                #pragma unroll
                for (int j = 0; j < 4; ++j) v[j] = 0;
            }
            *reinterpret_cast<short4v*>(&As[r * 40 + q * 4]) = v;
        }
        __syncthreads();
        bf16x8 af[4], bfr[2];
        #pragma unroll
        for (int mi = 0; mi < 4; ++mi)
            af[mi] = *reinterpret_cast<const bf16x8*>(&As[(mi * 16 + lr) * 40 + lg * 8]);
        #pragma unroll
        for (int ni = 0; ni < 2; ++ni)
            bfr[ni] = *reinterpret_cast<const bf16x8*>(&Bf[(w * 32 + ni * 16 + lr) * 136 + k0 + lg * 8]);
        #pragma unroll
        for (int mi = 0; mi < 4; ++mi)
            #pragma unroll
            for (int ni = 0; ni < 2; ++ni)
                acc[mi][ni] = __builtin_amdgcn_mfma_f32_16x16x32_bf16(af[mi], bfr[ni], acc[mi][ni], 0, 0, 0);
        __syncthreads();
    }

    #pragma unroll
    for (int mi = 0; mi < 4; ++mi) {
        #pragma unroll
        for (int ni = 0; ni < 2; ++ni) {
            int col = w * 32 + ni * 16 + lr;
            #pragma unroll
            for (int r = 0; r < 4; ++r) {
                int row = row0 + mi * 16 + lg * 4 + r;
                if (row >= M) continue;
                Cout[(size_t)row * 128 + col] = f2bf(acc[mi][ni][r]);
            }
        }
    }
}

// ========== fused xp + Y kernel v9: fp32 xp output for edge path ==========
__global__ __launch_bounds__(256) void fused_xpy(const float* __restrict__ h,
                                                 const short* __restrict__ wnTh,
                                                 const short* __restrict__ wnTl,
                                                 const short* __restrict__ wbBT,
                                                 const float* __restrict__ wl1,
                                                 const float* __restrict__ wl2,
                                                 const float* __restrict__ wlb,
                                                 float* __restrict__ xpf,
                                                 float* __restrict__ ubuf,
                                                 unsigned char* __restrict__ Y, int M) {
    __shared__ short sbuf[15360];
    __shared__ unsigned char yb[64 * 136];
    short* Ah = sbuf;
    short* Al = sbuf + 2560;
    short* Bh = sbuf + 5120;
    short* Bl = sbuf + 10240;
    short* xpH = sbuf;

    const int tid = threadIdx.x;
    const int row0 = blockIdx.x * 64;
    const int lane = tid & 63, w = tid >> 6;
    const int lr = lane & 15, lg = lane >> 4;

    // ---- phase 1 ----
    f32x4 acc1[4][2] = {};
    for (int k0 = 0; k0 < 128; k0 += 32) {
        #pragma unroll
        for (int i = 0; i < 2; ++i) {
            int idx = i * 256 + tid;
            int r = idx >> 3, q = idx & 7;
            int gr = row0 + r, gk = k0 + q * 4;
            f32x4 v;
            if (gr < M) {
                v = *reinterpret_cast<const f32x4*>(&h[(size_t)gr * 128 + gk]);
            } else {
                #pragma unroll
                for (int j = 0; j < 4; ++j) v[j] = 0.f;
            }
            short4v hh, ll;
            #pragma unroll
            for (int j = 0; j < 4; ++j) {
                hh[j] = f2bf(v[j]);
                ll[j] = f2bf(v[j] - bf2f(hh[j]));
            }
            *reinterpret_cast<short4v*>(&Ah[r * 40 + q * 4]) = hh;
            *reinterpret_cast<short4v*>(&Al[r * 40 + q * 4]) = ll;
        }
        #pragma unroll
        for (int i = 0; i < 4; ++i) {
            int idx = i * 256 + tid;
            int r = idx >> 3, q = idx & 7;
            int gk = k0 + q * 4;
            short4v bh = *reinterpret_cast<const short4v*>(&wnTh[(size_t)r * 128 + gk]);
            short4v bl = *reinterpret_cast<const short4v*>(&wnTl[(size_t)r * 128 + gk]);
            *reinterpret_cast<short4v*>(&Bh[r * 40 + q * 4]) = bh;
            *reinterpret_cast<short4v*>(&Bl[r * 40 + q * 4]) = bl;
        }
        __syncthreads();
        bf16x8 afh[4], afl[4], bfh[2], bfl[2];
        #pragma unroll
        for (int mi = 0; mi < 4; ++mi) {
            afh[mi] = *reinterpret_cast<const bf16x8*>(&Ah[(mi * 16 + lr) * 40 + lg * 8]);
            afl[mi] = *reinterpret_cast<const bf16x8*>(&Al[(mi * 16 + lr) * 40 + lg * 8]);
        }
        #pragma unroll
        for (int ni = 0; ni < 2; ++ni) {
            bfh[ni] = *reinterpret_cast<const bf16x8*>(&Bh[(w * 32 + ni * 16 + lr) * 40 + lg * 8]);
            bfl[ni] = *reinterpret_cast<const bf16x8*>(&Bl[(w * 32 + ni * 16 + lr) * 40 + lg * 8]);
        }
        #pragma unroll
        for (int mi = 0; mi < 4; ++mi)
            #pragma unroll
            for (int ni = 0; ni < 2; ++ni) {
                acc1[mi][ni] = __builtin_amdgcn_mfma_f32_16x16x32_bf16(afh[mi], bfh[ni], acc1[mi][ni], 0, 0, 0);
                acc1[mi][ni] = __builtin_amdgcn_mfma_f32_16x16x32_bf16(afl[mi], bfh[ni], acc1[mi][ni], 0, 0, 0);
                acc1[mi][ni] = __builtin_amdgcn_mfma_f32_16x16x32_bf16(afh[mi], bfl[ni], acc1[mi][ni], 0, 0, 0);
            }
        __syncthreads();
    }

    // ---- write xp: LDS hi (bf16) + global fp32 ----
    #pragma unroll
    for (int mi = 0; mi < 4; ++mi) {
        #pragma unroll
        for (int ni = 0; ni < 2; ++ni) {
            int col = w * 32 + ni * 16 + lr;
            #pragma unroll
            for (int r = 0; r < 4; ++r) {
                int rl = mi * 16 + lg * 4 + r;
                float v = acc1[mi][ni][r];
                xpH[rl * 136 + col] = f2bf(v);
                int row = row0 + rl;
                if (row < M) xpf[(size_t)row * 128 + col] = v;
            }
        }
    }
    __syncthreads();

    // ---- u = xp_hi . wl2 + wlb ----
    #pragma unroll
    for (int o = tid; o < 512; o += 256) {
        int rl = o >> 3, s = o & 7;
        int row = row0 + rl;
        if (row < M) {
            float p = wlb[s];
            #pragma unroll
            for (int j = 0; j < 16; ++j) {
                bf16x8 xv = *reinterpret_cast<const bf16x8*>(&xpH[rl * 136 + j * 8]);
                #pragma unroll
                for (int k = 0; k < 8; ++k)
                    p += bf2f(xv[k]) * wl2[(j * 8 + k) * 8 + s];
            }
            ubuf[(size_t)row * 8 + s] = p;
        }
    }

    // ---- phase 2 (transposed operands) ----
    for (int ct = 0; ct < 8; ++ct) {
        f32x4 accT[2][4] = {};
        #pragma unroll
        for (int k = 0; k < 4; ++k) {
            bf16x8 bfr[2];
            #pragma unroll
            for (int ni = 0; ni < 2; ++ni) {
                int col = ct * 128 + w * 32 + ni * 16 + lr;
                bfr[ni] = *reinterpret_cast<const bf16x8*>(&wbBT[(size_t)col * 128 + k * 32 + lg * 8]);
            }
            bf16x8 ah[4];
            #pragma unroll
            for (int mi = 0; mi < 4; ++mi)
                ah[mi] = *reinterpret_cast<const bf16x8*>(&xpH[(mi * 16 + lr) * 136 + k * 32 + lg * 8]);
            #pragma unroll
            for (int ni = 0; ni < 2; ++ni)
                #pragma unroll
                for (int mi = 0; mi < 4; ++mi)
                    accT[ni][mi] = __builtin_amdgcn_mfma_f32_16x16x32_bf16(bfr[ni], ah[mi], accT[ni][mi], 0, 0, 0);
        }
        #pragma unroll
        for (int ni = 0; ni < 2; ++ni) {
            int colg = w * 32 + ni * 16 + lg * 4;
            #pragma unroll
            for (int mi = 0; mi < 4; ++mi) {
                unsigned pk = pack4_fp8(accT[ni][mi][0] + wl1[(colg + 0) * 8 + ct],
                                        accT[ni][mi][1] + wl1[(colg + 1) * 8 + ct],
                                        accT[ni][mi][2] + wl1[(colg + 2) * 8 + ct],
                                        accT[ni][mi][3] + wl1[(colg + 3) * 8 + ct]);
                *reinterpret_cast<unsigned*>(&yb[(mi * 16 + lr) * 136 + colg]) = pk;
            }
        }
        __syncthreads();
        #pragma unroll
        for (int pass = 0; pass < 2; ++pass) {
            int flat = pass * 4096 + tid * 16;
            int rl = flat >> 7, cs = flat & 127;
            int row = row0 + rl;
            if (row < M) {
                uchar16v vv = *reinterpret_cast<const uchar16v*>(&yb[rl * 136 + cs]);
                *reinterpret_cast<uchar16v*>(&Y[(size_t)row * 1024 + ct * 128 + cs]) = vv;
            }
        }
        __syncthreads();
    }
}

// ========== fused edge kernel v6: fp32 xp, inline block-v, packed fp8 decode ==========
__global__ __launch_bounds__(256) void edge_fused2(const float* __restrict__ xpf,
                                                   const short* __restrict__ ep,
                                                   const unsigned char* __restrict__ Y,
                                                   const int* __restrict__ ei,
                                                   const float* __restrict__ u,
                                                   const float* __restrict__ wl2g,
                                                   float* __restrict__ agg, int E) {
    __shared__ float swl[128][9];
    for (int i = threadIdx.x; i < 1024; i += 256) swl[i >> 3][i & 7] = wl2g[i];
    __syncthreads();
    int e = blockIdx.x * 4 + (threadIdx.x >> 6);
    if (e >= E) return;
    int l = threadIdx.x & 63;
    int s = l & 7, c0 = (l >> 3) * 16;
    int src = ei[e], dst = ei[E + e];
    const unsigned char* y = Y + (size_t)src * 1024 + s * 128 + c0;
    uchar16v yv = *reinterpret_cast<const uchar16v*>(y);
    const int* yw = reinterpret_cast<const int*>(&yv);
    float yf[16];
    #pragma unroll
    for (int q = 0; q < 4; ++q) {
        f32x2 a = unpack2_fp8<false>(yw[q]);
        f32x2 b = unpack2_fp8<true>(yw[q]);
        yf[q * 4 + 0] = a[0]; yf[q * 4 + 1] = a[1];
        yf[q * 4 + 2] = b[0]; yf[q * 4 + 3] = b[1];
    }
    const float* xi = xpf + (size_t)dst * 128 + c0;
    f32x4 xa = *reinterpret_cast<const f32x4*>(xi);
    f32x4 xb = *reinterpret_cast<const f32x4*>(xi + 4);
    f32x4 xc = *reinterpret_cast<const f32x4*>(xi + 8);
    f32x4 xd = *reinterpret_cast<const f32x4*>(xi + 12);
    short16v ev = *reinterpret_cast<const short16v*>(ep + (size_t)e * 128 + c0);
    float p = 0.f;
    #pragma unroll
    for (int j = 0; j < 4; ++j) {
        p += xa[j] * yf[j];
        p += xb[j] * yf[4 + j];
        p += xc[j] * yf[8 + j];
        p += xd[j] * yf[12 + j];
    }
    #pragma unroll
    for (int j = 0; j < 8; ++j) {
        p += bf2f(ev[j]) * swl[c0 + j][s];
        p += bf2f(ev[8 + j]) * swl[c0 + 8 + j][s];
    }
    p += __shfl_xor(p, 8); p += __shfl_xor(p, 16); p += __shfl_xor(p, 32);
    float alpha = tanhf(p + u[(size_t)src * 8 + s]);
    float aa0 = __shfl(alpha, l >> 4);
    float aa1 = __shfl(alpha, 4 + (l >> 4));
    float xj0 = xpf[(size_t)src * 128 + l];
    float xj1 = xpf[(size_t)src * 128 + l + 64];
    float e0 = bf2f(ep[(size_t)e * 128 + l]);
    float e1 = bf2f(ep[(size_t)e * 128 + l + 64]);
    atomicAdd(&agg[(size_t)dst * 128 + l],      fmaxf(xj0, e0) * aa0);
    atomicAdd(&agg[(size_t)dst * 128 + l + 64], fmaxf(xj1, e1) * aa1);
}

// ========== gate GEMM v2: 64-row tiles, split-3, K=256 combined, in place ==========
__global__ __launch_bounds__(256) void gate_gemm_split(float* __restrict__ h,
                                                       const float* __restrict__ aggv,
                                                       const short* __restrict__ BTh,
                                                       const short* __restrict__ BTl,
                                                       const float* __restrict__ gb,
                                                       int M) {
    __shared__ short Ah[64][40];
    __shared__ short Al[64][40];
    __shared__ short Bh[128][40];
    __shared__ short Bl[128][40];
    const int tid = threadIdx.x;
    const int row0 = blockIdx.x * 64;
    const int lane = tid & 63, w = tid >> 6;
    const int lr = lane & 15, lg = lane >> 4;
    f32x4 acc[4][2] = {};

    for (int k0 = 0; k0 < 256; k0 += 32) {
        int sec = k0 >> 7;
        #pragma unroll
        for (int i = 0; i < 2; ++i) {
            int idx = i * 256 + tid;
            int r = idx >> 3, q = idx & 7;
            int gr = row0 + r;
            int ks = (k0 & 127) + q * 4;
            f32x4 v;
            if (gr < M) {
                if (sec == 0) {
                    v = *reinterpret_cast<const f32x4*>(&h[(size_t)gr * 128 + ks]);
                } else {
                    f32x4 a = *reinterpret_cast<const f32x4*>(&aggv[(size_t)gr * 128 + ks]);
                    #pragma unroll
                    for (int j = 0; j < 4; ++j) v[j] = fmaxf(a[j], 0.f);
                }
            } else {
                #pragma unroll
                for (int j = 0; j < 4; ++j) v[j] = 0.f;
            }
            short4v hh, ll;
            #pragma unroll
            for (int j = 0; j < 4; ++j) {
                hh[j] = f2bf(v[j]);
                ll[j] = f2bf(v[j] - bf2f(hh[j]));
            }
            *reinterpret_cast<short4v*>(&Ah[r][q * 4]) = hh;
            *reinterpret_cast<short4v*>(&Al[r][q * 4]) = ll;
        }
        #pragma unroll
        for (int i = 0; i < 4; ++i) {
            int idx = i * 256 + tid;
            int r = idx >> 3, q = idx & 7;
            short4v uu = *reinterpret_cast<const short4v*>(&BTh[(size_t)r * 256 + k0 + q * 4]);
            short4v ul = *reinterpret_cast<const short4v*>(&BTl[(size_t)r * 256 + k0 + q * 4]);
            *reinterpret_cast<short4v*>(&Bh[r][q * 4]) = uu;
            *reinterpret_cast<short4v*>(&Bl[r][q * 4]) = ul;
        }
        __syncthreads();
        bf16x8 afh[4], afl[4], bfh[2], bfl[2];
        #pragma unroll
        for (int mi = 0; mi < 4; ++mi) {
            afh[mi] = *reinterpret_cast<const bf16x8*>(&Ah[mi * 16 + lr][lg * 8]);
            afl[mi] = *reinterpret_cast<const bf16x8*>(&Al[mi * 16 + lr][lg * 8]);
        }
        #pragma unroll
        for (int ni = 0; ni < 2; ++ni) {
            bfh[ni] = *reinterpret_cast<const bf16x8*>(&Bh[w * 32 + ni * 16 + lr][lg * 8]);
            bfl[ni] = *reinterpret_cast<const bf16x8*>(&Bl[w * 32 + ni * 16 + lr][lg * 8]);
        }
        #pragma unroll
        for (int mi = 0; mi < 4; ++mi)
            #pragma unroll
            for (int ni = 0; ni < 2; ++ni) {
                acc[mi][ni] = __builtin_amdgcn_mfma_f32_16x16x32_bf16(afh[mi], bfh[ni], acc[mi][ni], 0, 0, 0);
                acc[mi][ni] = __builtin_amdgcn_mfma_f32_16x16x32_bf16(afl[mi], bfh[ni], acc[mi][ni], 0, 0, 0);
                acc[mi][ni] = __builtin_amdgcn_mfma_f32_16x16x32_bf16(afh[mi], bfl[ni], acc[mi][ni], 0, 0, 0);
            }
        __syncthreads();
    }

    #pragma unroll
    for (int mi = 0; mi < 4; ++mi) {
        #pragma unroll
        for (int ni = 0; ni < 2; ++ni) {
            int col = w * 32 + ni * 16 + lr;
            float gbv = gb[col];
            #pragma unroll
            for (int r = 0; r < 4; ++r) {
                int row = row0 + mi * 16 + lg * 4 + r;
                if (row >= M) continue;
                float beta = fmaxf(acc[mi][ni][r] + gbv, 0.f);
                float hv = h[(size_t)row * 128 + col];
                float hh = fmaxf(aggv[(size_t)row * 128 + col], 0.f);
                h[(size_t)row * 128 + col] = beta * hv + (1.f - beta) * hh;
            }
        }
    }
}

// ========== batch norm ==========
__global__ void bn_stats(const float* __restrict__ z, float* __restrict__ gsum,
                         float* __restrict__ gsq, int M) {
    int c = threadIdx.x & 127;
    int rr = threadIdx.x >> 7;
    float s = 0.f, q = 0.f;
    for (int r = blockIdx.x * 2 + rr; r < M; r += gridDim.x * 2) {
        float v = z[(size_t)r * 128 + c];
        s += v; q += v * v;
    }
    __shared__ float ls[256], lq[256];
    ls[threadIdx.x] = s; lq[threadIdx.x] = q;
    __syncthreads();
    if (threadIdx.x < 128) {
        atomicAdd(&gsum[c], ls[threadIdx.x] + ls[threadIdx.x + 128]);
        atomicAdd(&gsq[c],  lq[threadIdx.x] + lq[threadIdx.x + 128]);
    }
}

__global__ void bn_apply(float* __restrict__ z, const float* __restrict__ gsum,
                         const float* __restrict__ gsq, const float* __restrict__ g,
                         const float* __restrict__ b, int M) {
    size_t total = (size_t)M * 128;
    for (size_t idx = (size_t)blockIdx.x * 256 + threadIdx.x; idx < total;
         idx += (size_t)gridDim.x * 256) {
        int c = idx & 127;
        float mu = gsum[c] / (float)M;
        float var = gsq[c] / (float)M - mu * mu;
        float rs = rsqrtf(var + EPS);
        float v = (z[idx] - mu) * rs * g[c] + b[c];
        z[idx] = fmaxf(v, 0.f);
    }
}

__global__ void bn_stats_bf(const short* __restrict__ z, float* __restrict__ gsum,
                            float* __restrict__ gsq, int M) {
    int c = threadIdx.x & 127;
    int rr = threadIdx.x >> 7;
    float s = 0.f, q = 0.f;
    for (int r = blockIdx.x * 2 + rr; r < M; r += gridDim.x * 2) {
        float v = bf2f(z[(size_t)r * 128 + c]);
        s += v; q += v * v;
    }
    __shared__ float ls[256], lq[256];
    ls[threadIdx.x] = s; lq[threadIdx.x] = q;
    __syncthreads();
    if (threadIdx.x < 128) {
        atomicAdd(&gsum[c], ls[threadIdx.x] + ls[threadIdx.x + 128]);
        atomicAdd(&gsq[c],  lq[threadIdx.x] + lq[threadIdx.x + 128]);
    }
}

__global__ void bn_apply_bf(short* __restrict__ z, const float* __restrict__ gsum,
                            const float* __restrict__ gsq, const float* __restrict__ g,
                            const float* __restrict__ b, int M) {
    size_t total = (size_t)M * 128;
    for (size_t idx = (size_t)blockIdx.x * 256 + threadIdx.x; idx < total;
         idx += (size_t)gridDim.x * 256) {
        int c = idx & 127;
        float mu = gsum[c] / (float)M;
        float var = gsq[c] / (float)M - mu * mu;
        float rs = rsqrtf(var + EPS);
        float v = (bf2f(z[idx]) - mu) * rs * g[c] + b[c];
        z[idx] = f2bf(fmaxf(v, 0.f));
    }
}

// ========== prep ==========
__global__ void transpose_split(const float* __restrict__ in, short* __restrict__ outh,
                                short* __restrict__ outl, int K, int N) {
    int idx = blockIdx.x * 256 + threadIdx.x;
    if (idx >= K * N) return;
    int nI = idx / K, k = idx - nI * K;
    float v = in[(size_t)k * N + nI];
    short h = f2bf(v);
    outh[idx] = h;
    outl[idx] = f2bf(v - bf2f(h));
}

__global__ void cvt_f2b(const float* __restrict__ in, short* __restrict__ out, int n) {
    int i = blockIdx.x * 256 + threadIdx.x;
    if (i < n) out[i] = f2bf(in[i]);
}

__global__ void gate_combine_split(const float* __restrict__ gw, short* __restrict__ BTh,
                                   short* __restrict__ BTl) {
    int idx = blockIdx.x * 256 + threadIdx.x;
    if (idx >= 128 * 256) return;
    int n = idx >> 8, k = idx & 255;
    float v;
    if (k < 128) v = gw[(size_t)k * 128 + n] + gw[(size_t)(256 + k) * 128 + n];
    else {
        int kk = k - 128;
        v = gw[(size_t)(128 + kk) * 128 + n] - gw[(size_t)(256 + kk) * 128 + n];
    }
    short h = f2bf(v);
    BTh[idx] = h;
    BTl[idx] = f2bf(v - bf2f(h));
}

__global__ void build_wm(const float* __restrict__ wsrc, float* __restrict__ wm) {
    int idx = blockIdx.x * 256 + threadIdx.x;
    if (idx >= 128 * 128) return;
    int d = idx >> 7, c = idx & 127;
    float s = 0.f;
    #pragma unroll
    for (int h = 0; h < 8; ++h) s += wsrc[(size_t)d * 1024 + h * 128 + c];
    wm[idx] = s * 0.125f;
}

__global__ void perm_build(const int* __restrict__ ci, int* __restrict__ perm, int NF) {
    int i = blockIdx.x * 256 + threadIdx.x;
    if (i >= NF) return;
    int c = ci[i];
    if (i == 0 || ci[i - 1] != c) perm[c] = i;
}

__global__ void seg_pool(const float* __restrict__ fx, const int* __restrict__ perm,
                         float* __restrict__ pool, int F, int NF) {
    int idx = blockIdx.x * 256 + threadIdx.x;
    if (idx >= F * 128) return;
    int f = idx >> 7, c = idx & 127;
    int s = perm[f];
    int e = (f + 1 < F) ? perm[f + 1] : NF;
    float acc = 0.f;
    for (int i = s; i < e; ++i) acc += fx[(size_t)i * 128 + c];
    pool[idx] = fmaxf(acc, 0.f);
}

// ========== output ==========
__global__ __launch_bounds__(256) void out_phase1(const float* __restrict__ h,
                                                  const float* __restrict__ out_w,
                                                  const float* __restrict__ out_b,
                                                  const float* __restrict__ gat_bias,
                                                  float* __restrict__ out, int M) {
    int n = blockIdx.x * 4 + (threadIdx.x >> 6);
    if (n >= M) return;
    int l = threadIdx.x & 63;
    float p = fmaxf(h[(size_t)n * 128 + l], 0.f) * out_w[l]
            + fmaxf(h[(size_t)n * 128 + l + 64], 0.f) * out_w[l + 64];
    p += fmaxf(gat_bias[l], 0.f) * out_w[128 + l]
       + fmaxf(gat_bias[l + 64], 0.f) * out_w[128 + l + 64];
    #pragma unroll
    for (int off = 32; off; off >>= 1) p += __shfl_xor(p, off);
    if (l == 0) out[n] = p + out_b[0];
}

__global__ __launch_bounds__(256) void out_phase2(const float* __restrict__ fmv,
                                                  const int* __restrict__ perm,
                                                  const float* __restrict__ out_w,
                                                  const float* __restrict__ gat_bias,
                                                  float* __restrict__ out, int F) {
    int f = blockIdx.x * 4 + (threadIdx.x >> 6);
    if (f >= F) return;
    int l = threadIdx.x & 63;
    float p = fmv[(size_t)f * 128 + l] * out_w[128 + l]
            + fmv[(size_t)f * 128 + l + 64] * out_w[128 + l + 64];
    float b = fmaxf(gat_bias[l], 0.f) * out_w[128 + l]
            + fmaxf(gat_bias[l + 64], 0.f) * out_w[128 + l + 64];
    float d = p - b;
    #pragma unroll
    for (int off = 32; off; off >>= 1) d += __shfl_xor(d, off);
    if (l == 0) out[perm[f]] += d;
}

// ========== host ==========
extern "C" void kernel_launch(void* const* d_in, const int* in_sizes, int n_in,
                              void* d_out, int out_size, void* d_ws, size_t ws_size,
                              hipStream_t stream) {
    const int N = 50000, E = 100000, NF = 20000, EF = 40000, F = 10000;

    const float* x          = (const float*)d_in[0];
    const float* edge_attr  = (const float*)d_in[1];
    const float* frag_x     = (const float*)d_in[2];
    const float* frag_ea    = (const float*)d_in[3];
    const float* la_w = (const float*)d_in[4];
    const float* la_b = (const float*)d_in[5];
    const float* lb_w = (const float*)d_in[6];
    const float* lb_b = (const float*)d_in[7];
    const float* bn1_g = (const float*)d_in[8];
    const float* bn1_b = (const float*)d_in[9];
    const float* bn2_g = (const float*)d_in[10];
    const float* bn2_b = (const float*)d_in[11];
    const float* wn = (const float*)d_in[12];
    const float* wb = (const float*)d_in[13];
    const float* wl = (const float*)d_in[14];
    const float* wlb = (const float*)d_in[15];
    const float* gate_w = (const float*)d_in[16];
    const float* gate_b = (const float*)d_in[17];
    const float* gat_wsrc = (const float*)d_in[18];
    const float* gat_bias = (const float*)d_in[22];
    const float* out_w = (const float*)d_in[23];
    const float* out_b = (const float*)d_in[24];
    const int* edge_index = (const int*)d_in[25];
    const int* frag_edge_index = (const int*)d_in[26];
    const int* cluster_index = (const int*)d_in[27];

    char* p = (char*)d_ws;
    auto alloc = [&](size_t bytes) { char* r = p; p += (bytes + 255) & ~(size_t)255; return (void*)r; };
    float* hA    = (float*)alloc((size_t)N * 128 * 4);
    short* ea1   = (short*)alloc((size_t)E * 128 * 2);
    float* xpf   = (float*)alloc((size_t)N * 128 * 4);
    short* ep    = (short*)alloc((size_t)E * 128 * 2);
    unsigned char* Y = (unsigned char*)alloc((size_t)N * 1024);
    float* agg   = (float*)alloc((size_t)N * 128 * 4);
    float* ubuf  = (float*)alloc((size_t)N * 8 * 4);
    short* la_wTh = (short*)alloc(128 * 128 * 2);
    short* la_wTl = (short*)alloc(128 * 128 * 2);
    short* lb_wTh = (short*)alloc(128 * 16 * 2);
    short* lb_wTl = (short*)alloc(128 * 16 * 2);
    short* wnTh   = (short*)alloc(3 * 128 * 128 * 2);
    short* wnTl   = (short*)alloc(3 * 128 * 128 * 2);
    short* wbH    = (short*)alloc(3 * 1024 * 128 * 2);
    short* gate2Th = (short*)alloc(128 * 256 * 2);
    short* gate2Tl = (short*)alloc(128 * 256 * 2);
    float* wmF    = (float*)alloc(128 * 128 * 4);
    short* wmTh   = (short*)alloc(128 * 128 * 2);
    short* wmTl   = (short*)alloc(128 * 128 * 2);
    float* stats  = (float*)alloc(256 * 4);
    char* yq = (char*)Y;
    float* fpool = (float*)yq;              yq += (size_t)F * 128 * 4;
    float* fmv   = (float*)yq;              yq += (size_t)F * 128 * 4;
    int*   perm  = (int*)yq;

    auto cdiv = [](int a, int b) { return (a + b - 1) / b; };

    // ---- weight prep ----
    transpose_split<<<cdiv(128 * 128, 256), 256, 0, stream>>>(la_w, la_wTh, la_wTl, 128, 128);
    transpose_split<<<cdiv(16 * 128, 256), 256, 0, stream>>>(lb_w, lb_wTh, lb_wTl, 16, 128);
    for (int l = 0; l < 3; ++l)
        transpose_split<<<cdiv(128 * 128, 256), 256, 0, stream>>>(
            wn + (size_t)l * 16384, wnTh + (size_t)l * 16384, wnTl + (size_t)l * 16384, 128, 128);
    cvt_f2b<<<cdiv(3 * 1024 * 128, 256), 256, 0, stream>>>(wb, wbH, 3 * 1024 * 128);
    gate_combine_split<<<cdiv(128 * 256, 256), 256, 0, stream>>>(gate_w, gate2Th, gate2Tl);
    build_wm<<<cdiv(128 * 128, 256), 256, 0, stream>>>(gat_wsrc, wmF);
    transpose_split<<<cdiv(128 * 128, 256), 256, 0, stream>>>(wmF, wmTh, wmTl, 128, 128);

    auto run_layer = [&](float* h, const short* ea_buf, const int* ei, int Mn, int Me, int layer) {
        const short* wnTh_l = wnTh + (size_t)layer * 16384;
        const short* wnTl_l = wnTl + (size_t)layer * 16384;
        const short* wb_l   = wbH + (size_t)layer * 131072;
        const float* wl_l   = wl + (size_t)layer * 384 * 8;
        const float* wlb_l  = wlb + (size_t)layer * 8;
        fused_xpy<<<cdiv(Mn, 64), 256, 0, stream>>>(h, wnTh_l, wnTl_l, wb_l, wl_l,
                                                    wl_l + 256 * 8, wlb_l, xpf, ubuf, Y, Mn);
        ep_gemm64<<<cdiv(Me, 64), 256, 0, stream>>>(ea_buf, wnTh_l, ep, Me);
        hipMemsetAsync(agg, 0, (size_t)Mn * 128 * 4, stream);
        edge_fused2<<<cdiv(Me, 4), 256, 0, stream>>>(xpf, ep, Y, ei, ubuf, wl_l + 128 * 8, agg, Me);
        gate_gemm_split<<<cdiv(Mn, 64), 256, 0, stream>>>(h, agg, gate2Th, gate2Tl, gate_b, Mn);
    };

    // ---- atom path ----
    gemm_split<3, 0, 0><<<dim3(1, cdiv(N, 128)), 256, 0, stream>>>(x, la_wTh, la_wTl, la_b, hA, nullptr, N, 128, 128);
    hipMemsetAsync(stats, 0, 1024, stream);
    bn_stats<<<256, 256, 0, stream>>>(hA, stats, stats + 128, N);
    bn_apply<<<2048, 256, 0, stream>>>(hA, stats, stats + 128, bn1_g, bn1_b, N);

    gemm_split<3, 0, 1><<<dim3(1, cdiv(E, 128)), 256, 0, stream>>>(edge_attr, lb_wTh, lb_wTl, lb_b, ea1, nullptr, E, 128, 16);
    hipMemsetAsync(stats, 0, 1024, stream);
    bn_stats_bf<<<256, 256, 0, stream>>>(ea1, stats, stats + 128, E);
    bn_apply_bf<<<2048, 256, 0, stream>>>(ea1, stats, stats + 128, bn2_g, bn2_b, E);

    for (int l = 0; l < 3; ++l) run_layer(hA, ea1, edge_index, N, E, l);
    out_phase1<<<cdiv(N, 4), 256, 0, stream>>>(hA, out_w, out_b, gat_bias, (float*)d_out, N);

    // ---- fragment path ----
    gemm_split<3, 1, 0><<<dim3(1, cdiv(NF, 128)), 256, 0, stream>>>(frag_x, la_wTh, la_wTl, la_b, hA, nullptr, NF, 128, 128);

    gemm_split<3, 0, 1><<<dim3(1, cdiv(EF, 128)), 256, 0, stream>>>(frag_ea, lb_wTh, lb_wTl, lb_b, ea1, nullptr, EF, 128, 16);
    hipMemsetAsync(stats, 0, 1024, stream);
    bn_stats_bf<<<256, 256, 0, stream>>>(ea1, stats, stats + 128, EF);
    bn_apply_bf<<<2048, 256, 0, stream>>>(ea1, stats, stats + 128, bn2_g, bn2_b, EF);

    for (int l = 0; l < 3; ++l) run_layer(hA, ea1, frag_edge_index, NF, EF, l);

    perm_build<<<cdiv(NF, 256), 256, 0, stream>>>(cluster_index, perm, NF);
    seg_pool<<<cdiv(F * 128, 256), 256, 0, stream>>>(hA, perm, fpool, F, NF);
    gemm_split<3, 1, 0><<<dim3(1, cdiv(F, 128)), 256, 0, stream>>>(fpool, wmTh, wmTl, gat_bias, fmv, nullptr, F, 128, 128);
    out_phase2<<<cdiv(F, 4), 256, 0, stream>>>(fmv, perm, out_w, gat_bias, (float*)d_out, F);
}

// Round 18
// 1041.273 us; speedup vs baseline: 1.6391x; 1.0388x over previous
//
#include <hip/hip_runtime.h>
#include <hip/hip_bf16.h>
#include <hip/hip_fp8.h>

#define EPS 1e-5f

typedef short bf16x8 __attribute__((ext_vector_type(8)));
typedef short short4v __attribute__((ext_vector_type(4)));
typedef short short16v __attribute__((ext_vector_type(16)));
typedef float f32x4 __attribute__((ext_vector_type(4)));
typedef float f32x2 __attribute__((ext_vector_type(2)));
typedef unsigned char uchar16v __attribute__((ext_vector_type(16)));

static __device__ __forceinline__ short f2bf(float x) {
    __hip_bfloat16 h = __float2bfloat16(x);
    return *reinterpret_cast<short*>(&h);
}
static __device__ __forceinline__ float bf2f(short x) {
    __hip_bfloat16 h;
    *reinterpret_cast<short*>(&h) = x;
    return __bfloat162float(h);
}
static __device__ __forceinline__ unsigned char f2fp8(float x) {
    __hip_fp8_e4m3 q(x);
    return (unsigned char)q.__x;
}
static __device__ __forceinline__ float fp82f(unsigned char b) {
    __hip_fp8_e4m3 q;
    q.__x = (__hip_fp8_storage_t)b;
    return (float)q;
}
static __device__ __forceinline__ unsigned pack4_fp8(float v0, float v1, float v2, float v3) {
#if __has_builtin(__builtin_amdgcn_cvt_pk_fp8_f32)
    int pk = __builtin_amdgcn_cvt_pk_fp8_f32(v0, v1, 0, false);
    pk = __builtin_amdgcn_cvt_pk_fp8_f32(v2, v3, pk, true);
    return (unsigned)pk;
#else
    return (unsigned)f2fp8(v0) | ((unsigned)f2fp8(v1) << 8) |
           ((unsigned)f2fp8(v2) << 16) | ((unsigned)f2fp8(v3) << 24);
#endif
}
template<bool HI>
static __device__ __forceinline__ f32x2 unpack2_fp8(int w) {
#if __has_builtin(__builtin_amdgcn_cvt_pk_f32_fp8)
    return __builtin_amdgcn_cvt_pk_f32_fp8(w, HI);
#else
    f32x2 r;
    const int sh = HI ? 16 : 0;
    r[0] = fp82f((unsigned char)((w >> sh) & 0xff));
    r[1] = fp82f((unsigned char)((w >> (sh + 8)) & 0xff));
    return r;
#endif
}

// ========== split-bf16 MFMA GEMM: C = act(A[M,K](f32) @ BT[N,K]^T + bias) ==========
template<int SPLIT, int ACT, int OUTM>
__global__ __launch_bounds__(256) void gemm_split(const float* __restrict__ A,
                                                  const short* __restrict__ BTh,
                                                  const short* __restrict__ BTl,
                                                  const float* __restrict__ bias,
                                                  void* __restrict__ Cout,
                                                  void* __restrict__ Cout2,
                                                  int M, int N, int K) {
    __shared__ short Ah[128][40];
    __shared__ short Al[128][40];
    __shared__ short Bh[128][40];
    __shared__ short Bl[128][40];
    const int tid = threadIdx.x;
    const int row0 = blockIdx.y * 128, col0 = blockIdx.x * 128;
    const int lane = tid & 63, w = tid >> 6;
    const int wr = w >> 1, wc = w & 1;
    const int lr = lane & 15, lg = lane >> 4;
    f32x4 acc[4][4] = {};

    for (int k0 = 0; k0 < K; k0 += 32) {
        #pragma unroll
        for (int i = 0; i < 4; ++i) {
            int idx = i * 256 + tid;
            int r = idx >> 3, q = idx & 7;
            int gr = row0 + r, gk = k0 + q * 4;
            f32x4 v;
            if (gr < M && gk + 3 < K) {
                v = *reinterpret_cast<const f32x4*>(&A[(size_t)gr * K + gk]);
            } else {
                #pragma unroll
                for (int j = 0; j < 4; ++j)
                    v[j] = (gr < M && gk + j < K) ? A[(size_t)gr * K + gk + j] : 0.f;
            }
            short4v h, l;
            #pragma unroll
            for (int j = 0; j < 4; ++j) {
                h[j] = f2bf(v[j]);
                l[j] = f2bf(v[j] - bf2f(h[j]));
            }
            *reinterpret_cast<short4v*>(&Ah[r][q * 4]) = h;
            *reinterpret_cast<short4v*>(&Al[r][q * 4]) = l;
        }
        #pragma unroll
        for (int i = 0; i < 4; ++i) {
            int idx = i * 256 + tid;
            int r = idx >> 3, q = idx & 7;
            int gc = col0 + r, gk = k0 + q * 4;
            short4v u, ul;
            if (gk + 3 < K) {
                u = *reinterpret_cast<const short4v*>(&BTh[(size_t)gc * K + gk]);
                if (SPLIT == 3) ul = *reinterpret_cast<const short4v*>(&BTl[(size_t)gc * K + gk]);
            } else {
                #pragma unroll
                for (int j = 0; j < 4; ++j) {
                    u[j] = (gk + j < K) ? BTh[(size_t)gc * K + gk + j] : (short)0;
                    if (SPLIT == 3) ul[j] = (gk + j < K) ? BTl[(size_t)gc * K + gk + j] : (short)0;
                }
            }
            *reinterpret_cast<short4v*>(&Bh[r][q * 4]) = u;
            if (SPLIT == 3) *reinterpret_cast<short4v*>(&Bl[r][q * 4]) = ul;
        }
        __syncthreads();
        bf16x8 afh[4], afl[4], bfh[4];
        #pragma unroll
        for (int mi = 0; mi < 4; ++mi) {
            afh[mi] = *reinterpret_cast<const bf16x8*>(&Ah[wr * 64 + mi * 16 + lr][lg * 8]);
            afl[mi] = *reinterpret_cast<const bf16x8*>(&Al[wr * 64 + mi * 16 + lr][lg * 8]);
        }
        #pragma unroll
        for (int ni = 0; ni < 4; ++ni)
            bfh[ni] = *reinterpret_cast<const bf16x8*>(&Bh[wc * 64 + ni * 16 + lr][lg * 8]);
        #pragma unroll
        for (int mi = 0; mi < 4; ++mi)
            #pragma unroll
            for (int ni = 0; ni < 4; ++ni) {
                acc[mi][ni] = __builtin_amdgcn_mfma_f32_16x16x32_bf16(afh[mi], bfh[ni], acc[mi][ni], 0, 0, 0);
                acc[mi][ni] = __builtin_amdgcn_mfma_f32_16x16x32_bf16(afl[mi], bfh[ni], acc[mi][ni], 0, 0, 0);
            }
        if (SPLIT == 3) {
            bf16x8 bfl[4];
            #pragma unroll
            for (int ni = 0; ni < 4; ++ni)
                bfl[ni] = *reinterpret_cast<const bf16x8*>(&Bl[wc * 64 + ni * 16 + lr][lg * 8]);
            #pragma unroll
            for (int mi = 0; mi < 4; ++mi)
                #pragma unroll
                for (int ni = 0; ni < 4; ++ni)
                    acc[mi][ni] = __builtin_amdgcn_mfma_f32_16x16x32_bf16(afh[mi], bfl[ni], acc[mi][ni], 0, 0, 0);
        }
        __syncthreads();
    }

    #pragma unroll
    for (int mi = 0; mi < 4; ++mi) {
        #pragma unroll
        for (int ni = 0; ni < 4; ++ni) {
            int col = col0 + wc * 64 + ni * 16 + lr;
            float bv = bias ? bias[col] : 0.f;
            #pragma unroll
            for (int r = 0; r < 4; ++r) {
                int row = row0 + wr * 64 + mi * 16 + lg * 4 + r;
                if (row >= M) continue;
                float v = acc[mi][ni][r] + bv;
                if (ACT) v = fmaxf(v, 0.f);
                if (OUTM == 0) ((float*)Cout)[(size_t)row * N + col] = v;
                else ((short*)Cout)[(size_t)row * N + col] = f2bf(v);
            }
        }
    }
}

// ========== ep GEMM: ep[M,128] = ea1[M,128] @ wnT^T, 64-row tiles, B staged once ==========
__global__ __launch_bounds__(256) void ep_gemm64(const short* __restrict__ A,
                                                 const short* __restrict__ BT,
                                                 short* __restrict__ Cout, int M) {
    __shared__ short Bf[128 * 136];
    __shared__ short As[64 * 40];
    const int tid = threadIdx.x;
    const int row0 = blockIdx.x * 64;
    const int lane = tid & 63, w = tid >> 6;
    const int lr = lane & 15, lg = lane >> 4;

    #pragma unroll
    for (int i = 0; i < 8; ++i) {
        int idx = i * 256 + tid;
        int r = idx >> 4, q = idx & 15;
        *reinterpret_cast<bf16x8*>(&Bf[r * 136 + q * 8]) =
            *reinterpret_cast<const bf16x8*>(&BT[(size_t)r * 128 + q * 8]);
    }
    __syncthreads();

    f32x4 acc[4][2] = {};
    for (int k0 = 0; k0 < 128; k0 += 32) {
        #pragma unroll
        for (int i = 0; i < 2; ++i) {
            int idx = i * 256 + tid;
            int r = idx >> 3, q = idx & 7;
            int gr = row0 + r;
            short4v v;
            if (gr < M) {
                v = *reinterpret_cast<const short4v*>(&A[(size_t)gr * 128 + k0 + q * 4]);
            } else {
                #pragma unroll
                for (int j = 0; j < 4; ++j) v[j] = 0;
            }
            *reinterpret_cast<short4v*>(&As[r * 40 + q * 4]) = v;
        }
        __syncthreads();
        bf16x8 af[4], bfr[2];
        #pragma unroll
        for (int mi = 0; mi < 4; ++mi)
            af[mi] = *reinterpret_cast<const bf16x8*>(&As[(mi * 16 + lr) * 40 + lg * 8]);
        #pragma unroll
        for (int ni = 0; ni < 2; ++ni)
            bfr[ni] = *reinterpret_cast<const bf16x8*>(&Bf[(w * 32 + ni * 16 + lr) * 136 + k0 + lg * 8]);
        #pragma unroll
        for (int mi = 0; mi < 4; ++mi)
            #pragma unroll
            for (int ni = 0; ni < 2; ++ni)
                acc[mi][ni] = __builtin_amdgcn_mfma_f32_16x16x32_bf16(af[mi], bfr[ni], acc[mi][ni], 0, 0, 0);
        __syncthreads();
    }

    #pragma unroll
    for (int mi = 0; mi < 4; ++mi) {
        #pragma unroll
        for (int ni = 0; ni < 2; ++ni) {
            int col = w * 32 + ni * 16 + lr;
            #pragma unroll
            for (int r = 0; r < 4; ++r) {
                int row = row0 + mi * 16 + lg * 4 + r;
                if (row >= M) continue;
                Cout[(size_t)row * 128 + col] = f2bf(acc[mi][ni][r]);
            }
        }
    }
}

// ========== fused xp + Y kernel v10: fp32 xp, agg zeroing folded in ==========
__global__ __launch_bounds__(256) void fused_xpy(const float* __restrict__ h,
                                                 const short* __restrict__ wnTh,
                                                 const short* __restrict__ wnTl,
                                                 const short* __restrict__ wbBT,
                                                 const float* __restrict__ wl1,
                                                 const float* __restrict__ wl2,
                                                 const float* __restrict__ wlb,
                                                 float* __restrict__ xpf,
                                                 float* __restrict__ ubuf,
                                                 unsigned char* __restrict__ Y,
                                                 float* __restrict__ agg, int M) {
    __shared__ short sbuf[15360];
    __shared__ unsigned char yb[64 * 136];
    short* Ah = sbuf;
    short* Al = sbuf + 2560;
    short* Bh = sbuf + 5120;
    short* Bl = sbuf + 10240;
    short* xpH = sbuf;

    const int tid = threadIdx.x;
    const int row0 = blockIdx.x * 64;
    const int lane = tid & 63, w = tid >> 6;
    const int lr = lane & 15, lg = lane >> 4;

    // ---- zero agg for this block's rows (32KB, coalesced 16B stores) ----
    {
        f32x4 z = {0.f, 0.f, 0.f, 0.f};
        #pragma unroll
        for (int i = 0; i < 8; ++i) {
            int flat = i * 1024 + tid * 4;       // f32 index in 64x128 tile
            int rl = flat >> 7, cs = flat & 127;
            int row = row0 + rl;
            if (row < M)
                *reinterpret_cast<f32x4*>(&agg[(size_t)row * 128 + cs]) = z;
        }
    }

    // ---- phase 1 ----
    f32x4 acc1[4][2] = {};
    for (int k0 = 0; k0 < 128; k0 += 32) {
        #pragma unroll
        for (int i = 0; i < 2; ++i) {
            int idx = i * 256 + tid;
            int r = idx >> 3, q = idx & 7;
            int gr = row0 + r, gk = k0 + q * 4;
            f32x4 v;
            if (gr < M) {
                v = *reinterpret_cast<const f32x4*>(&h[(size_t)gr * 128 + gk]);
            } else {
                #pragma unroll
                for (int j = 0; j < 4; ++j) v[j] = 0.f;
            }
            short4v hh, ll;
            #pragma unroll
            for (int j = 0; j < 4; ++j) {
                hh[j] = f2bf(v[j]);
                ll[j] = f2bf(v[j] - bf2f(hh[j]));
            }
            *reinterpret_cast<short4v*>(&Ah[r * 40 + q * 4]) = hh;
            *reinterpret_cast<short4v*>(&Al[r * 40 + q * 4]) = ll;
        }
        #pragma unroll
        for (int i = 0; i < 4; ++i) {
            int idx = i * 256 + tid;
            int r = idx >> 3, q = idx & 7;
            int gk = k0 + q * 4;
            short4v bh = *reinterpret_cast<const short4v*>(&wnTh[(size_t)r * 128 + gk]);
            short4v bl = *reinterpret_cast<const short4v*>(&wnTl[(size_t)r * 128 + gk]);
            *reinterpret_cast<short4v*>(&Bh[r * 40 + q * 4]) = bh;
            *reinterpret_cast<short4v*>(&Bl[r * 40 + q * 4]) = bl;
        }
        __syncthreads();
        bf16x8 afh[4], afl[4], bfh[2], bfl[2];
        #pragma unroll
        for (int mi = 0; mi < 4; ++mi) {
            afh[mi] = *reinterpret_cast<const bf16x8*>(&Ah[(mi * 16 + lr) * 40 + lg * 8]);
            afl[mi] = *reinterpret_cast<const bf16x8*>(&Al[(mi * 16 + lr) * 40 + lg * 8]);
        }
        #pragma unroll
        for (int ni = 0; ni < 2; ++ni) {
            bfh[ni] = *reinterpret_cast<const bf16x8*>(&Bh[(w * 32 + ni * 16 + lr) * 40 + lg * 8]);
            bfl[ni] = *reinterpret_cast<const bf16x8*>(&Bl[(w * 32 + ni * 16 + lr) * 40 + lg * 8]);
        }
        #pragma unroll
        for (int mi = 0; mi < 4; ++mi)
            #pragma unroll
            for (int ni = 0; ni < 2; ++ni) {
                acc1[mi][ni] = __builtin_amdgcn_mfma_f32_16x16x32_bf16(afh[mi], bfh[ni], acc1[mi][ni], 0, 0, 0);
                acc1[mi][ni] = __builtin_amdgcn_mfma_f32_16x16x32_bf16(afl[mi], bfh[ni], acc1[mi][ni], 0, 0, 0);
                acc1[mi][ni] = __builtin_amdgcn_mfma_f32_16x16x32_bf16(afh[mi], bfl[ni], acc1[mi][ni], 0, 0, 0);
            }
        __syncthreads();
    }

    // ---- write xp: LDS hi (bf16) + global fp32 ----
    #pragma unroll
    for (int mi = 0; mi < 4; ++mi) {
        #pragma unroll
        for (int ni = 0; ni < 2; ++ni) {
            int col = w * 32 + ni * 16 + lr;
            #pragma unroll
            for (int r = 0; r < 4; ++r) {
                int rl = mi * 16 + lg * 4 + r;
                float v = acc1[mi][ni][r];
                xpH[rl * 136 + col] = f2bf(v);
                int row = row0 + rl;
                if (row < M) xpf[(size_t)row * 128 + col] = v;
            }
        }
    }
    __syncthreads();

    // ---- u = xp_hi . wl2 + wlb ----
    #pragma unroll
    for (int o = tid; o < 512; o += 256) {
        int rl = o >> 3, s = o & 7;
        int row = row0 + rl;
        if (row < M) {
            float p = wlb[s];
            #pragma unroll
            for (int j = 0; j < 16; ++j) {
                bf16x8 xv = *reinterpret_cast<const bf16x8*>(&xpH[rl * 136 + j * 8]);
                #pragma unroll
                for (int k = 0; k < 8; ++k)
                    p += bf2f(xv[k]) * wl2[(j * 8 + k) * 8 + s];
            }
            ubuf[(size_t)row * 8 + s] = p;
        }
    }

    // ---- phase 2 (transposed operands) ----
    for (int ct = 0; ct < 8; ++ct) {
        f32x4 accT[2][4] = {};
        #pragma unroll
        for (int k = 0; k < 4; ++k) {
            bf16x8 bfr[2];
            #pragma unroll
            for (int ni = 0; ni < 2; ++ni) {
                int col = ct * 128 + w * 32 + ni * 16 + lr;
                bfr[ni] = *reinterpret_cast<const bf16x8*>(&wbBT[(size_t)col * 128 + k * 32 + lg * 8]);
            }
            bf16x8 ah[4];
            #pragma unroll
            for (int mi = 0; mi < 4; ++mi)
                ah[mi] = *reinterpret_cast<const bf16x8*>(&xpH[(mi * 16 + lr) * 136 + k * 32 + lg * 8]);
            #pragma unroll
            for (int ni = 0; ni < 2; ++ni)
                #pragma unroll
                for (int mi = 0; mi < 4; ++mi)
                    accT[ni][mi] = __builtin_amdgcn_mfma_f32_16x16x32_bf16(bfr[ni], ah[mi], accT[ni][mi], 0, 0, 0);
        }
        #pragma unroll
        for (int ni = 0; ni < 2; ++ni) {
            int colg = w * 32 + ni * 16 + lg * 4;
            #pragma unroll
            for (int mi = 0; mi < 4; ++mi) {
                unsigned pk = pack4_fp8(accT[ni][mi][0] + wl1[(colg + 0) * 8 + ct],
                                        accT[ni][mi][1] + wl1[(colg + 1) * 8 + ct],
                                        accT[ni][mi][2] + wl1[(colg + 2) * 8 + ct],
                                        accT[ni][mi][3] + wl1[(colg + 3) * 8 + ct]);
                *reinterpret_cast<unsigned*>(&yb[(mi * 16 + lr) * 136 + colg]) = pk;
            }
        }
        __syncthreads();
        #pragma unroll
        for (int pass = 0; pass < 2; ++pass) {
            int flat = pass * 4096 + tid * 16;
            int rl = flat >> 7, cs = flat & 127;
            int row = row0 + rl;
            if (row < M) {
                uchar16v vv = *reinterpret_cast<const uchar16v*>(&yb[rl * 136 + cs]);
                *reinterpret_cast<uchar16v*>(&Y[(size_t)row * 1024 + ct * 128 + cs]) = vv;
            }
        }
        __syncthreads();
    }
}

// ========== fused edge kernel v7: 2 edges/wave for load ILP ==========
__global__ __launch_bounds__(256) void edge_fused3(const float* __restrict__ xpf,
                                                   const short* __restrict__ ep,
                                                   const unsigned char* __restrict__ Y,
                                                   const int* __restrict__ ei,
                                                   const float* __restrict__ u,
                                                   const float* __restrict__ wl2g,
                                                   float* __restrict__ agg, int E) {
    __shared__ float swl[128][9];
    for (int i = threadIdx.x; i < 1024; i += 256) swl[i >> 3][i & 7] = wl2g[i];
    __syncthreads();
    int w = threadIdx.x >> 6;
    int l = threadIdx.x & 63;
    int s = l & 7, c0 = (l >> 3) * 16;
    int e0 = blockIdx.x * 8 + w;
    int e1 = e0 + 4;
    bool ok0 = e0 < E, ok1 = e1 < E;
    int src0 = ok0 ? ei[e0] : 0, dst0 = ok0 ? ei[E + e0] : 0;
    int src1 = ok1 ? ei[e1] : 0, dst1 = ok1 ? ei[E + e1] : 0;

    uchar16v yv0 = *reinterpret_cast<const uchar16v*>(Y + (size_t)src0 * 1024 + s * 128 + c0);
    uchar16v yv1 = *reinterpret_cast<const uchar16v*>(Y + (size_t)src1 * 1024 + s * 128 + c0);
    const float* xi0 = xpf + (size_t)dst0 * 128 + c0;
    const float* xi1 = xpf + (size_t)dst1 * 128 + c0;
    f32x4 xa0 = *reinterpret_cast<const f32x4*>(xi0);
    f32x4 xb0 = *reinterpret_cast<const f32x4*>(xi0 + 4);
    f32x4 xc0 = *reinterpret_cast<const f32x4*>(xi0 + 8);
    f32x4 xd0 = *reinterpret_cast<const f32x4*>(xi0 + 12);
    f32x4 xa1 = *reinterpret_cast<const f32x4*>(xi1);
    f32x4 xb1 = *reinterpret_cast<const f32x4*>(xi1 + 4);
    f32x4 xc1 = *reinterpret_cast<const f32x4*>(xi1 + 8);
    f32x4 xd1 = *reinterpret_cast<const f32x4*>(xi1 + 12);
    short16v ev0 = *reinterpret_cast<const short16v*>(ep + (size_t)e0 * 128 + c0);
    short16v ev1 = *reinterpret_cast<const short16v*>(ep + (size_t)(ok1 ? e1 : e0) * 128 + c0);
    float xj00 = xpf[(size_t)src0 * 128 + l];
    float xj01 = xpf[(size_t)src0 * 128 + l + 64];
    float xj10 = xpf[(size_t)src1 * 128 + l];
    float xj11 = xpf[(size_t)src1 * 128 + l + 64];
    float u0 = u[(size_t)src0 * 8 + s];
    float u1 = u[(size_t)src1 * 8 + s];
    float em00 = bf2f(ep[(size_t)e0 * 128 + l]);
    float em01 = bf2f(ep[(size_t)e0 * 128 + l + 64]);
    float em10 = bf2f(ep[(size_t)(ok1 ? e1 : e0) * 128 + l]);
    float em11 = bf2f(ep[(size_t)(ok1 ? e1 : e0) * 128 + l + 64]);

    const int* yw0 = reinterpret_cast<const int*>(&yv0);
    const int* yw1 = reinterpret_cast<const int*>(&yv1);
    float p0 = 0.f, p1 = 0.f;
    #pragma unroll
    for (int q = 0; q < 4; ++q) {
        f32x2 a0 = unpack2_fp8<false>(yw0[q]);
        f32x2 b0 = unpack2_fp8<true>(yw0[q]);
        f32x2 a1 = unpack2_fp8<false>(yw1[q]);
        f32x2 b1 = unpack2_fp8<true>(yw1[q]);
        const f32x4* xq0 = (q == 0) ? &xa0 : (q == 1) ? &xb0 : (q == 2) ? &xc0 : &xd0;
        const f32x4* xq1 = (q == 0) ? &xa1 : (q == 1) ? &xb1 : (q == 2) ? &xc1 : &xd1;
        p0 += (*xq0)[0] * a0[0] + (*xq0)[1] * a0[1] + (*xq0)[2] * b0[0] + (*xq0)[3] * b0[1];
        p1 += (*xq1)[0] * a1[0] + (*xq1)[1] * a1[1] + (*xq1)[2] * b1[0] + (*xq1)[3] * b1[1];
    }
    #pragma unroll
    for (int j = 0; j < 8; ++j) {
        float w0 = swl[c0 + j][s], w1 = swl[c0 + 8 + j][s];
        p0 += bf2f(ev0[j]) * w0 + bf2f(ev0[8 + j]) * w1;
        p1 += bf2f(ev1[j]) * w0 + bf2f(ev1[8 + j]) * w1;
    }
    p0 += __shfl_xor(p0, 8); p0 += __shfl_xor(p0, 16); p0 += __shfl_xor(p0, 32);
    p1 += __shfl_xor(p1, 8); p1 += __shfl_xor(p1, 16); p1 += __shfl_xor(p1, 32);
    float alpha0 = tanhf(p0 + u0);
    float alpha1 = tanhf(p1 + u1);
    float a00 = __shfl(alpha0, l >> 4);
    float a01 = __shfl(alpha0, 4 + (l >> 4));
    float a10 = __shfl(alpha1, l >> 4);
    float a11 = __shfl(alpha1, 4 + (l >> 4));
    if (ok0) {
        atomicAdd(&agg[(size_t)dst0 * 128 + l],      fmaxf(xj00, em00) * a00);
        atomicAdd(&agg[(size_t)dst0 * 128 + l + 64], fmaxf(xj01, em01) * a01);
    }
    if (ok1) {
        atomicAdd(&agg[(size_t)dst1 * 128 + l],      fmaxf(xj10, em10) * a10);
        atomicAdd(&agg[(size_t)dst1 * 128 + l + 64], fmaxf(xj11, em11) * a11);
    }
}

// ========== gate GEMM v2: 64-row tiles, split-3, K=256 combined, in place ==========
__global__ __launch_bounds__(256) void gate_gemm_split(float* __restrict__ h,
                                                       const float* __restrict__ aggv,
                                                       const short* __restrict__ BTh,
                                                       const short* __restrict__ BTl,
                                                       const float* __restrict__ gb,
                                                       int M) {
    __shared__ short Ah[64][40];
    __shared__ short Al[64][40];
    __shared__ short Bh[128][40];
    __shared__ short Bl[128][40];
    const int tid = threadIdx.x;
    const int row0 = blockIdx.x * 64;
    const int lane = tid & 63, w = tid >> 6;
    const int lr = lane & 15, lg = lane >> 4;
    f32x4 acc[4][2] = {};

    for (int k0 = 0; k0 < 256; k0 += 32) {
        int sec = k0 >> 7;
        #pragma unroll
        for (int i = 0; i < 2; ++i) {
            int idx = i * 256 + tid;
            int r = idx >> 3, q = idx & 7;
            int gr = row0 + r;
            int ks = (k0 & 127) + q * 4;
            f32x4 v;
            if (gr < M) {
                if (sec == 0) {
                    v = *reinterpret_cast<const f32x4*>(&h[(size_t)gr * 128 + ks]);
                } else {
                    f32x4 a = *reinterpret_cast<const f32x4*>(&aggv[(size_t)gr * 128 + ks]);
                    #pragma unroll
                    for (int j = 0; j < 4; ++j) v[j] = fmaxf(a[j], 0.f);
                }
            } else {
                #pragma unroll
                for (int j = 0; j < 4; ++j) v[j] = 0.f;
            }
            short4v hh, ll;
            #pragma unroll
            for (int j = 0; j < 4; ++j) {
                hh[j] = f2bf(v[j]);
                ll[j] = f2bf(v[j] - bf2f(hh[j]));
            }
            *reinterpret_cast<short4v*>(&Ah[r][q * 4]) = hh;
            *reinterpret_cast<short4v*>(&Al[r][q * 4]) = ll;
        }
        #pragma unroll
        for (int i = 0; i < 4; ++i) {
            int idx = i * 256 + tid;
            int r = idx >> 3, q = idx & 7;
            short4v uu = *reinterpret_cast<const short4v*>(&BTh[(size_t)r * 256 + k0 + q * 4]);
            short4v ul = *reinterpret_cast<const short4v*>(&BTl[(size_t)r * 256 + k0 + q * 4]);
            *reinterpret_cast<short4v*>(&Bh[r][q * 4]) = uu;
            *reinterpret_cast<short4v*>(&Bl[r][q * 4]) = ul;
        }
        __syncthreads();
        bf16x8 afh[4], afl[4], bfh[2], bfl[2];
        #pragma unroll
        for (int mi = 0; mi < 4; ++mi) {
            afh[mi] = *reinterpret_cast<const bf16x8*>(&Ah[mi * 16 + lr][lg * 8]);
            afl[mi] = *reinterpret_cast<const bf16x8*>(&Al[mi * 16 + lr][lg * 8]);
        }
        #pragma unroll
        for (int ni = 0; ni < 2; ++ni) {
            bfh[ni] = *reinterpret_cast<const bf16x8*>(&Bh[w * 32 + ni * 16 + lr][lg * 8]);
            bfl[ni] = *reinterpret_cast<const bf16x8*>(&Bl[w * 32 + ni * 16 + lr][lg * 8]);
        }
        #pragma unroll
        for (int mi = 0; mi < 4; ++mi)
            #pragma unroll
            for (int ni = 0; ni < 2; ++ni) {
                acc[mi][ni] = __builtin_amdgcn_mfma_f32_16x16x32_bf16(afh[mi], bfh[ni], acc[mi][ni], 0, 0, 0);
                acc[mi][ni] = __builtin_amdgcn_mfma_f32_16x16x32_bf16(afl[mi], bfh[ni], acc[mi][ni], 0, 0, 0);
                acc[mi][ni] = __builtin_amdgcn_mfma_f32_16x16x32_bf16(afh[mi], bfl[ni], acc[mi][ni], 0, 0, 0);
            }
        __syncthreads();
    }

    #pragma unroll
    for (int mi = 0; mi < 4; ++mi) {
        #pragma unroll
        for (int ni = 0; ni < 2; ++ni) {
            int col = w * 32 + ni * 16 + lr;
            float gbv = gb[col];
            #pragma unroll
            for (int r = 0; r < 4; ++r) {
                int row = row0 + mi * 16 + lg * 4 + r;
                if (row >= M) continue;
                float beta = fmaxf(acc[mi][ni][r] + gbv, 0.f);
                float hv = h[(size_t)row * 128 + col];
                float hh = fmaxf(aggv[(size_t)row * 128 + col], 0.f);
                h[(size_t)row * 128 + col] = beta * hv + (1.f - beta) * hh;
            }
        }
    }
}

// ========== batch norm ==========
__global__ void bn_stats(const float* __restrict__ z, float* __restrict__ gsum,
                         float* __restrict__ gsq, int M) {
    int c = threadIdx.x & 127;
    int rr = threadIdx.x >> 7;
    float s = 0.f, q = 0.f;
    for (int r = blockIdx.x * 2 + rr; r < M; r += gridDim.x * 2) {
        float v = z[(size_t)r * 128 + c];
        s += v; q += v * v;
    }
    __shared__ float ls[256], lq[256];
    ls[threadIdx.x] = s; lq[threadIdx.x] = q;
    __syncthreads();
    if (threadIdx.x < 128) {
        atomicAdd(&gsum[c], ls[threadIdx.x] + ls[threadIdx.x + 128]);
        atomicAdd(&gsq[c],  lq[threadIdx.x] + lq[threadIdx.x + 128]);
    }
}

__global__ void bn_apply(float* __restrict__ z, const float* __restrict__ gsum,
                         const float* __restrict__ gsq, const float* __restrict__ g,
                         const float* __restrict__ b, int M) {
    size_t total = (size_t)M * 128;
    for (size_t idx = (size_t)blockIdx.x * 256 + threadIdx.x; idx < total;
         idx += (size_t)gridDim.x * 256) {
        int c = idx & 127;
        float mu = gsum[c] / (float)M;
        float var = gsq[c] / (float)M - mu * mu;
        float rs = rsqrtf(var + EPS);
        float v = (z[idx] - mu) * rs * g[c] + b[c];
        z[idx] = fmaxf(v, 0.f);
    }
}

__global__ void bn_stats_bf(const short* __restrict__ z, float* __restrict__ gsum,
                            float* __restrict__ gsq, int M) {
    int c = threadIdx.x & 127;
    int rr = threadIdx.x >> 7;
    float s = 0.f, q = 0.f;
    for (int r = blockIdx.x * 2 + rr; r < M; r += gridDim.x * 2) {
        float v = bf2f(z[(size_t)r * 128 + c]);
        s += v; q += v * v;
    }
    __shared__ float ls[256], lq[256];
    ls[threadIdx.x] = s; lq[threadIdx.x] = q;
    __syncthreads();
    if (threadIdx.x < 128) {
        atomicAdd(&gsum[c], ls[threadIdx.x] + ls[threadIdx.x + 128]);
        atomicAdd(&gsq[c],  lq[threadIdx.x] + lq[threadIdx.x + 128]);
    }
}

__global__ void bn_apply_bf(short* __restrict__ z, const float* __restrict__ gsum,
                            const float* __restrict__ gsq, const float* __restrict__ g,
                            const float* __restrict__ b, int M) {
    size_t total = (size_t)M * 128;
    for (size_t idx = (size_t)blockIdx.x * 256 + threadIdx.x; idx < total;
         idx += (size_t)gridDim.x * 256) {
        int c = idx & 127;
        float mu = gsum[c] / (float)M;
        float var = gsq[c] / (float)M - mu * mu;
        float rs = rsqrtf(var + EPS);
        float v = (bf2f(z[idx]) - mu) * rs * g[c] + b[c];
        z[idx] = f2bf(fmaxf(v, 0.f));
    }
}

// ========== prep ==========
__global__ void transpose_split(const float* __restrict__ in, short* __restrict__ outh,
                                short* __restrict__ outl, int K, int N) {
    int idx = blockIdx.x * 256 + threadIdx.x;
    if (idx >= K * N) return;
    int nI = idx / K, k = idx - nI * K;
    float v = in[(size_t)k * N + nI];
    short h = f2bf(v);
    outh[idx] = h;
    outl[idx] = f2bf(v - bf2f(h));
}

__global__ void cvt_f2b(const float* __restrict__ in, short* __restrict__ out, int n) {
    int i = blockIdx.x * 256 + threadIdx.x;
    if (i < n) out[i] = f2bf(in[i]);
}

__global__ void gate_combine_split(const float* __restrict__ gw, short* __restrict__ BTh,
                                   short* __restrict__ BTl) {
    int idx = blockIdx.x * 256 + threadIdx.x;
    if (idx >= 128 * 256) return;
    int n = idx >> 8, k = idx & 255;
    float v;
    if (k < 128) v = gw[(size_t)k * 128 + n] + gw[(size_t)(256 + k) * 128 + n];
    else {
        int kk = k - 128;
        v = gw[(size_t)(128 + kk) * 128 + n] - gw[(size_t)(256 + kk) * 128 + n];
    }
    short h = f2bf(v);
    BTh[idx] = h;
    BTl[idx] = f2bf(v - bf2f(h));
}

__global__ void build_wm(const float* __restrict__ wsrc, float* __restrict__ wm) {
    int idx = blockIdx.x * 256 + threadIdx.x;
    if (idx >= 128 * 128) return;
    int d = idx >> 7, c = idx & 127;
    float s = 0.f;
    #pragma unroll
    for (int h = 0; h < 8; ++h) s += wsrc[(size_t)d * 1024 + h * 128 + c];
    wm[idx] = s * 0.125f;
}

__global__ void perm_build(const int* __restrict__ ci, int* __restrict__ perm, int NF) {
    int i = blockIdx.x * 256 + threadIdx.x;
    if (i >= NF) return;
    int c = ci[i];
    if (i == 0 || ci[i - 1] != c) perm[c] = i;
}

__global__ void seg_pool(const float* __restrict__ fx, const int* __restrict__ perm,
                         float* __restrict__ pool, int F, int NF) {
    int idx = blockIdx.x * 256 + threadIdx.x;
    if (idx >= F * 128) return;
    int f = idx >> 7, c = idx & 127;
    int s = perm[f];
    int e = (f + 1 < F) ? perm[f + 1] : NF;
    float acc = 0.f;
    for (int i = s; i < e; ++i) acc += fx[(size_t)i * 128 + c];
    pool[idx] = fmaxf(acc, 0.f);
}

// ========== output ==========
__global__ __launch_bounds__(256) void out_phase1(const float* __restrict__ h,
                                                  const float* __restrict__ out_w,
                                                  const float* __restrict__ out_b,
                                                  const float* __restrict__ gat_bias,
                                                  float* __restrict__ out, int M) {
    int n = blockIdx.x * 4 + (threadIdx.x >> 6);
    if (n >= M) return;
    int l = threadIdx.x & 63;
    float p = fmaxf(h[(size_t)n * 128 + l], 0.f) * out_w[l]
            + fmaxf(h[(size_t)n * 128 + l + 64], 0.f) * out_w[l + 64];
    p += fmaxf(gat_bias[l], 0.f) * out_w[128 + l]
       + fmaxf(gat_bias[l + 64], 0.f) * out_w[128 + l + 64];
    #pragma unroll
    for (int off = 32; off; off >>= 1) p += __shfl_xor(p, off);
    if (l == 0) out[n] = p + out_b[0];
}

__global__ __launch_bounds__(256) void out_phase2(const float* __restrict__ fmv,
                                                  const int* __restrict__ perm,
                                                  const float* __restrict__ out_w,
                                                  const float* __restrict__ gat_bias,
                                                  float* __restrict__ out, int F) {
    int f = blockIdx.x * 4 + (threadIdx.x >> 6);
    if (f >= F) return;
    int l = threadIdx.x & 63;
    float p = fmv[(size_t)f * 128 + l] * out_w[128 + l]
            + fmv[(size_t)f * 128 + l + 64] * out_w[128 + l + 64];
    float b = fmaxf(gat_bias[l], 0.f) * out_w[128 + l]
            + fmaxf(gat_bias[l + 64], 0.f) * out_w[128 + l + 64];
    float d = p - b;
    #pragma unroll
    for (int off = 32; off; off >>= 1) d += __shfl_xor(d, off);
    if (l == 0) out[perm[f]] += d;
}

// ========== host ==========
extern "C" void kernel_launch(void* const* d_in, const int* in_sizes, int n_in,
                              void* d_out, int out_size, void* d_ws, size_t ws_size,
                              hipStream_t stream) {
    const int N = 50000, E = 100000, NF = 20000, EF = 40000, F = 10000;

    const float* x          = (const float*)d_in[0];
    const float* edge_attr  = (const float*)d_in[1];
    const float* frag_x     = (const float*)d_in[2];
    const float* frag_ea    = (const float*)d_in[3];
    const float* la_w = (const float*)d_in[4];
    const float* la_b = (const float*)d_in[5];
    const float* lb_w = (const float*)d_in[6];
    const float* lb_b = (const float*)d_in[7];
    const float* bn1_g = (const float*)d_in[8];
    const float* bn1_b = (const float*)d_in[9];
    const float* bn2_g = (const float*)d_in[10];
    const float* bn2_b = (const float*)d_in[11];
    const float* wn = (const float*)d_in[12];
    const float* wb = (const float*)d_in[13];
    const float* wl = (const float*)d_in[14];
    const float* wlb = (const float*)d_in[15];
    const float* gate_w = (const float*)d_in[16];
    const float* gate_b = (const float*)d_in[17];
    const float* gat_wsrc = (const float*)d_in[18];
    const float* gat_bias = (const float*)d_in[22];
    const float* out_w = (const float*)d_in[23];
    const float* out_b = (const float*)d_in[24];
    const int* edge_index = (const int*)d_in[25];
    const int* frag_edge_index = (const int*)d_in[26];
    const int* cluster_index = (const int*)d_in[27];

    char* p = (char*)d_ws;
    auto alloc = [&](size_t bytes) { char* r = p; p += (bytes + 255) & ~(size_t)255; return (void*)r; };
    float* hA    = (float*)alloc((size_t)N * 128 * 4);
    short* ea1   = (short*)alloc((size_t)E * 128 * 2);
    float* xpf   = (float*)alloc((size_t)N * 128 * 4);
    short* ep    = (short*)alloc((size_t)E * 128 * 2);
    unsigned char* Y = (unsigned char*)alloc((size_t)N * 1024);
    float* agg   = (float*)alloc((size_t)N * 128 * 4);
    float* ubuf  = (float*)alloc((size_t)N * 8 * 4);
    short* la_wTh = (short*)alloc(128 * 128 * 2);
    short* la_wTl = (short*)alloc(128 * 128 * 2);
    short* lb_wTh = (short*)alloc(128 * 16 * 2);
    short* lb_wTl = (short*)alloc(128 * 16 * 2);
    short* wnTh   = (short*)alloc(3 * 128 * 128 * 2);
    short* wnTl   = (short*)alloc(3 * 128 * 128 * 2);
    short* wbH    = (short*)alloc(3 * 1024 * 128 * 2);
    short* gate2Th = (short*)alloc(128 * 256 * 2);
    short* gate2Tl = (short*)alloc(128 * 256 * 2);
    float* wmF    = (float*)alloc(128 * 128 * 4);
    short* wmTh   = (short*)alloc(128 * 128 * 2);
    short* wmTl   = (short*)alloc(128 * 128 * 2);
    float* stats  = (float*)alloc(256 * 4);
    char* yq = (char*)Y;
    float* fpool = (float*)yq;              yq += (size_t)F * 128 * 4;
    float* fmv   = (float*)yq;              yq += (size_t)F * 128 * 4;
    int*   perm  = (int*)yq;

    auto cdiv = [](int a, int b) { return (a + b - 1) / b; };

    // ---- weight prep ----
    transpose_split<<<cdiv(128 * 128, 256), 256, 0, stream>>>(la_w, la_wTh, la_wTl, 128, 128);
    transpose_split<<<cdiv(16 * 128, 256), 256, 0, stream>>>(lb_w, lb_wTh, lb_wTl, 16, 128);
    for (int l = 0; l < 3; ++l)
        transpose_split<<<cdiv(128 * 128, 256), 256, 0, stream>>>(
            wn + (size_t)l * 16384, wnTh + (size_t)l * 16384, wnTl + (size_t)l * 16384, 128, 128);
    cvt_f2b<<<cdiv(3 * 1024 * 128, 256), 256, 0, stream>>>(wb, wbH, 3 * 1024 * 128);
    gate_combine_split<<<cdiv(128 * 256, 256), 256, 0, stream>>>(gate_w, gate2Th, gate2Tl);
    build_wm<<<cdiv(128 * 128, 256), 256, 0, stream>>>(gat_wsrc, wmF);
    transpose_split<<<cdiv(128 * 128, 256), 256, 0, stream>>>(wmF, wmTh, wmTl, 128, 128);

    auto run_layer = [&](float* h, const short* ea_buf, const int* ei, int Mn, int Me, int layer) {
        const short* wnTh_l = wnTh + (size_t)layer * 16384;
        const short* wnTl_l = wnTl + (size_t)layer * 16384;
        const short* wb_l   = wbH + (size_t)layer * 131072;
        const float* wl_l   = wl + (size_t)layer * 384 * 8;
        const float* wlb_l  = wlb + (size_t)layer * 8;
        fused_xpy<<<cdiv(Mn, 64), 256, 0, stream>>>(h, wnTh_l, wnTl_l, wb_l, wl_l,
                                                    wl_l + 256 * 8, wlb_l, xpf, ubuf, Y, agg, Mn);
        ep_gemm64<<<cdiv(Me, 64), 256, 0, stream>>>(ea_buf, wnTh_l, ep, Me);
        edge_fused3<<<cdiv(Me, 8), 256, 0, stream>>>(xpf, ep, Y, ei, ubuf, wl_l + 128 * 8, agg, Me);
        gate_gemm_split<<<cdiv(Mn, 64), 256, 0, stream>>>(h, agg, gate2Th, gate2Tl, gate_b, Mn);
    };

    // ---- atom path ----
    gemm_split<3, 0, 0><<<dim3(1, cdiv(N, 128)), 256, 0, stream>>>(x, la_wTh, la_wTl, la_b, hA, nullptr, N, 128, 128);
    hipMemsetAsync(stats, 0, 1024, stream);
    bn_stats<<<256, 256, 0, stream>>>(hA, stats, stats + 128, N);
    bn_apply<<<2048, 256, 0, stream>>>(hA, stats, stats + 128, bn1_g, bn1_b, N);

    gemm_split<3, 0, 1><<<dim3(1, cdiv(E, 128)), 256, 0, stream>>>(edge_attr, lb_wTh, lb_wTl, lb_b, ea1, nullptr, E, 128, 16);
    hipMemsetAsync(stats, 0, 1024, stream);
    bn_stats_bf<<<256, 256, 0, stream>>>(ea1, stats, stats + 128, E);
    bn_apply_bf<<<2048, 256, 0, stream>>>(ea1, stats, stats + 128, bn2_g, bn2_b, E);

    for (int l = 0; l < 3; ++l) run_layer(hA, ea1, edge_index, N, E, l);
    out_phase1<<<cdiv(N, 4), 256, 0, stream>>>(hA, out_w, out_b, gat_bias, (float*)d_out, N);

    // ---- fragment path ----
    gemm_split<3, 1, 0><<<dim3(1, cdiv(NF, 128)), 256, 0, stream>>>(frag_x, la_wTh, la_wTl, la_b, hA, nullptr, NF, 128, 128);

    gemm_split<3, 0, 1><<<dim3(1, cdiv(EF, 128)), 256, 0, stream>>>(frag_ea, lb_wTh, lb_wTl, lb_b, ea1, nullptr, EF, 128, 16);
    hipMemsetAsync(stats, 0, 1024, stream);
    bn_stats_bf<<<256, 256, 0, stream>>>(ea1, stats, stats + 128, EF);
    bn_apply_bf<<<2048, 256, 0, stream>>>(ea1, stats, stats + 128, bn2_g, bn2_b, EF);

    for (int l = 0; l < 3; ++l) run_layer(hA, ea1, frag_edge_index, NF, EF, l);

    perm_build<<<cdiv(NF, 256), 256, 0, stream>>>(cluster_index, perm, NF);
    seg_pool<<<cdiv(F * 128, 256), 256, 0, stream>>>(hA, perm, fpool, F, NF);
    gemm_split<3, 1, 0><<<dim3(1, cdiv(F, 128)), 256, 0, stream>>>(fpool, wmTh, wmTl, gat_bias, fmv, nullptr, F, 128, 128);
    out_phase2<<<cdiv(F, 4), 256, 0, stream>>>(fmv, perm, out_w, gat_bias, (float*)d_out, F);
}